// Round 1
// baseline (15152.339 us; speedup 1.0000x reference)
//
#include <hip/hip_runtime.h>
#include <math.h>

#define TN 32768
#define C_ 256
#define E_ 524288
#define B_ 64
#define N_ 512
#define H_ 4
#define DH_ 64
#define M_ 266
#define MP_ 320
#define L_ 5
#define LN_EPS_ 1e-5f
#define EPSK_ 1e-3f

__device__ __forceinline__ float gelu_exact(float v) {
    return 0.5f * v * (1.0f + erff(v * 0.70710678118654752f));
}

// ---------------- embed: atoms = log(x+1) @ node_w + node_b ----------------
__global__ __launch_bounds__(256) void embed_kernel(
    const float* __restrict__ x, const float* __restrict__ nw,
    const float* __restrict__ nb, float* __restrict__ atoms) {
    int node = blockIdx.x;
    int c = threadIdx.x;
    __shared__ float lx[11];
    if (c < 11) lx[c] = logf(x[node * 11 + c] + 1.0f);
    __syncthreads();
    float acc = nb[c];
#pragma unroll
    for (int j = 0; j < 11; ++j) acc = fmaf(lx[j], nw[j * C_ + c], acc);
    atoms[(size_t)node * C_ + c] = acc;
}

// ------------- GINE message + scatter (ea fused, atomics) ------------------
__global__ __launch_bounds__(256) void scatter_kernel(
    const float* __restrict__ atoms, const float* __restrict__ eattr,
    const int* __restrict__ eidx, const float* __restrict__ ew,
    const float* __restrict__ eb, float* __restrict__ aggr) {
    int gid = blockIdx.x * 256 + threadIdx.x;   // E*64 items, 4 chans each
    int e = gid >> 6;
    int q = (gid & 63) << 2;
    int src = eidx[e];
    int dst = eidx[E_ + e];
    float4 ea = *(const float4*)(eattr + (size_t)e * 4);
    float4 w0 = *(const float4*)(ew + 0 * C_ + q);
    float4 w1 = *(const float4*)(ew + 1 * C_ + q);
    float4 w2 = *(const float4*)(ew + 2 * C_ + q);
    float4 w3 = *(const float4*)(ew + 3 * C_ + q);
    float4 bb = *(const float4*)(eb + q);
    float4 av = *(const float4*)(atoms + (size_t)src * C_ + q);
    float m0 = av.x + bb.x + ea.x * w0.x + ea.y * w1.x + ea.z * w2.x + ea.w * w3.x;
    float m1 = av.y + bb.y + ea.x * w0.y + ea.y * w1.y + ea.z * w2.y + ea.w * w3.y;
    float m2 = av.z + bb.z + ea.x * w0.z + ea.y * w1.z + ea.z * w2.z + ea.w * w3.z;
    float m3 = av.w + bb.w + ea.x * w0.w + ea.y * w1.w + ea.z * w2.w + ea.w * w3.w;
    float* base = aggr + (size_t)dst * C_ + q;
    atomicAdd(base + 0, fmaxf(m0, 0.f));
    atomicAdd(base + 1, fmaxf(m1, 0.f));
    atomicAdd(base + 2, fmaxf(m2, 0.f));
    atomicAdd(base + 3, fmaxf(m3, 0.f));
}

// ------------- generic tiled fp32 matmul, 64x64 tile, fused epilogues ------
// EPI: 0=none, 1=gelu, 2=+R1, 3=+R1+R2.  IN_ADD: X := X + X2 on load.
template <bool IN_ADD, int EPI>
__global__ __launch_bounds__(256) void mm_kernel(
    const float* __restrict__ X, const float* __restrict__ X2,
    const float* __restrict__ W, const float* __restrict__ bias,
    const float* __restrict__ R1, const float* __restrict__ R2,
    float* __restrict__ Y, int K, int NC) {
    __shared__ float Xs[16][65];   // [k][row]
    __shared__ float Ws[16][68];   // [k][col], float4-storable
    int tid = threadIdx.x;
    int tx = tid & 15, ty = tid >> 4;
    int rowBase = blockIdx.y * 64;
    int colBase = blockIdx.x * 64;
    int lr = tid >> 2;            // 0..63 row
    int lk = (tid & 3) << 2;      // 0,4,8,12
    int wk = tid >> 4;            // 0..15 k-row
    int wc = (tid & 15) << 2;     // col quad
    const float* Xp = X + (size_t)(rowBase + lr) * K + lk;
    const float* X2p = IN_ADD ? (X2 + (size_t)(rowBase + lr) * K + lk) : X;
    const float* Wp = W + (size_t)wk * NC + colBase + wc;
    float acc[4][4] = {};
    for (int k0 = 0; k0 < K; k0 += 16) {
        float4 xv = *(const float4*)(Xp + k0);
        if (IN_ADD) {
            float4 x2 = *(const float4*)(X2p + k0);
            xv.x += x2.x; xv.y += x2.y; xv.z += x2.z; xv.w += x2.w;
        }
        float4 wv = *(const float4*)(Wp + (size_t)k0 * NC);
        __syncthreads();
        Xs[lk + 0][lr] = xv.x;
        Xs[lk + 1][lr] = xv.y;
        Xs[lk + 2][lr] = xv.z;
        Xs[lk + 3][lr] = xv.w;
        *(float4*)&Ws[wk][wc] = wv;
        __syncthreads();
#pragma unroll
        for (int kk = 0; kk < 16; ++kk) {
            float a[4], b[4];
#pragma unroll
            for (int i = 0; i < 4; ++i) a[i] = Xs[kk][ty * 4 + i];
#pragma unroll
            for (int j = 0; j < 4; ++j) b[j] = Ws[kk][tx * 4 + j];
#pragma unroll
            for (int i = 0; i < 4; ++i)
#pragma unroll
                for (int j = 0; j < 4; ++j) acc[i][j] = fmaf(a[i], b[j], acc[i][j]);
        }
    }
    int c0 = colBase + tx * 4;
    float4 bv = make_float4(0.f, 0.f, 0.f, 0.f);
    if (bias) bv = *(const float4*)(bias + c0);
#pragma unroll
    for (int i = 0; i < 4; ++i) {
        int r = rowBase + ty * 4 + i;
        float4 y;
        y.x = acc[i][0] + bv.x; y.y = acc[i][1] + bv.y;
        y.z = acc[i][2] + bv.z; y.w = acc[i][3] + bv.w;
        if (EPI == 1) {
            y.x = gelu_exact(y.x); y.y = gelu_exact(y.y);
            y.z = gelu_exact(y.z); y.w = gelu_exact(y.w);
        }
        if (EPI >= 2) {
            float4 r1 = *(const float4*)(R1 + (size_t)r * NC + c0);
            y.x += r1.x; y.y += r1.y; y.z += r1.z; y.w += r1.w;
        }
        if (EPI == 3) {
            float4 r2 = *(const float4*)(R2 + (size_t)r * NC + c0);
            y.x += r2.x; y.y += r2.y; y.z += r2.z; y.w += r2.w;
        }
        *(float4*)(Y + (size_t)r * NC + c0) = y;
    }
}

// ------------------------------ LayerNorm ----------------------------------
__global__ __launch_bounds__(256) void ln_kernel(
    const float* __restrict__ X, const float* __restrict__ g,
    const float* __restrict__ bta, float* __restrict__ Y) {
    __shared__ float rs[4], rs2[4];
    __shared__ float mu_s, inv_s;
    int row = blockIdx.x, t = threadIdx.x;
    size_t off = (size_t)row * C_ + t;
    float v = X[off];
    float s = v, s2 = v * v;
#pragma unroll
    for (int o = 32; o > 0; o >>= 1) {
        s += __shfl_down(s, o);
        s2 += __shfl_down(s2, o);
    }
    int w = t >> 6, lane = t & 63;
    if (lane == 0) { rs[w] = s; rs2[w] = s2; }
    __syncthreads();
    if (t == 0) {
        float tot = rs[0] + rs[1] + rs[2] + rs[3];
        float tot2 = rs2[0] + rs2[1] + rs2[2] + rs2[3];
        float mu = tot * (1.f / C_);
        float var = tot2 * (1.f / C_) - mu * mu;
        mu_s = mu;
        inv_s = rsqrtf(var + LN_EPS_);
    }
    __syncthreads();
    Y[off] = (v - mu_s) * inv_s * g[t] + bta[t];
}

// -------- Performer pass 1: ctx[bh,m,d] = kp^T @ v, ksum[bh,m] -------------
__global__ __launch_bounds__(256) void p1_kernel(
    const float* __restrict__ kbuf, const float* __restrict__ vbuf,
    const float* __restrict__ proj, float* __restrict__ ctx,
    float* __restrict__ ksum) {
    int mt = blockIdx.x;          // 0..4
    int bh = blockIdx.y;          // 0..255
    int b = bh >> 2, h = bh & 3;
    __shared__ float Pt[64][65];  // proj m-tile [m][d]
    __shared__ float KV[64][65];  // K tile, then reused as V tile
    __shared__ float S[64][65];   // kp tile [n][m]
    int tid = threadIdx.x;
    int tx = tid & 15, ty = tid >> 4;
    for (int idx = tid; idx < 4096; idx += 256) {
        int r = idx >> 6, c = idx & 63;
        int mg = mt * 64 + r;
        Pt[r][c] = (mg < M_) ? proj[mg * DH_ + c] : 0.f;
    }
    float cacc[4][4] = {};
    float ksacc = 0.f;
    size_t base = ((size_t)b * N_) * C_ + h * DH_;
    for (int nt = 0; nt < 8; ++nt) {
        __syncthreads();
        for (int idx = tid; idx < 4096; idx += 256) {
            int r = idx >> 6, c = idx & 63;
            KV[r][c] = kbuf[base + (size_t)(nt * 64 + r) * C_ + c];
        }
        __syncthreads();
        float s[4][4] = {};
        for (int dd = 0; dd < 64; ++dd) {
            float a[4], bq[4];
#pragma unroll
            for (int i = 0; i < 4; ++i) a[i] = KV[ty * 4 + i][dd];
#pragma unroll
            for (int j = 0; j < 4; ++j) bq[j] = Pt[tx * 4 + j][dd];
#pragma unroll
            for (int i = 0; i < 4; ++i)
#pragma unroll
                for (int j = 0; j < 4; ++j) s[i][j] = fmaf(a[i], bq[j], s[i][j]);
        }
        __syncthreads();  // all reads of KV done
#pragma unroll
        for (int i = 0; i < 4; ++i)
#pragma unroll
            for (int j = 0; j < 4; ++j) {
                int mg = mt * 64 + tx * 4 + j;
                S[ty * 4 + i][tx * 4 + j] =
                    (mg < M_) ? (fmaxf(s[i][j], 0.f) + EPSK_) : 0.f;
            }
        for (int idx = tid; idx < 4096; idx += 256) {
            int r = idx >> 6, c = idx & 63;
            KV[r][c] = vbuf[base + (size_t)(nt * 64 + r) * C_ + c];
        }
        __syncthreads();
        // ctx[m][d] += sum_n S[n][m] * V[n][d]
        for (int nn = 0; nn < 64; ++nn) {
            float sm[4], vd[4];
#pragma unroll
            for (int i = 0; i < 4; ++i) sm[i] = S[nn][ty * 4 + i];
#pragma unroll
            for (int j = 0; j < 4; ++j) vd[j] = KV[nn][tx * 4 + j];
#pragma unroll
            for (int i = 0; i < 4; ++i)
#pragma unroll
                for (int j = 0; j < 4; ++j) cacc[i][j] = fmaf(sm[i], vd[j], cacc[i][j]);
        }
        if (tid < 64) {
            for (int nn = 0; nn < 64; ++nn) ksacc += S[nn][tid];
        }
    }
    float* cp = ctx + ((size_t)bh * MP_ + mt * 64) * DH_;
#pragma unroll
    for (int i = 0; i < 4; ++i)
#pragma unroll
        for (int j = 0; j < 4; ++j)
            cp[(ty * 4 + i) * DH_ + tx * 4 + j] = cacc[i][j];
    if (tid < 64) ksum[bh * MP_ + mt * 64 + tid] = ksacc;
}

// -------- Performer pass 2: att = (qp @ ctx) * (1/(qp @ ksum)) -------------
__global__ __launch_bounds__(256) void p2_kernel(
    const float* __restrict__ qbuf, const float* __restrict__ proj,
    const float* __restrict__ ctx, const float* __restrict__ ksum,
    float* __restrict__ attout) {
    int nt = blockIdx.x;          // 0..7
    int bh = blockIdx.y;          // 0..255
    int b = bh >> 2, h = bh & 3;
    __shared__ float Qt[64][65];
    __shared__ float PC[64][65];  // proj tile, then ctx tile
    __shared__ float S[64][65];
    __shared__ float ks[64], dinv[64];
    int tid = threadIdx.x;
    int tx = tid & 15, ty = tid >> 4;
    size_t base = ((size_t)b * N_) * C_ + h * DH_;
    for (int idx = tid; idx < 4096; idx += 256) {
        int r = idx >> 6, c = idx & 63;
        Qt[r][c] = qbuf[base + (size_t)(nt * 64 + r) * C_ + c];
    }
    float aacc[4][4] = {};
    float dacc = 0.f;
    for (int mt = 0; mt < 5; ++mt) {
        __syncthreads();
        for (int idx = tid; idx < 4096; idx += 256) {
            int r = idx >> 6, c = idx & 63;
            int mg = mt * 64 + r;
            PC[r][c] = (mg < M_) ? proj[mg * DH_ + c] : 0.f;
        }
        if (tid < 64) ks[tid] = ksum[bh * MP_ + mt * 64 + tid];
        __syncthreads();
        float s[4][4] = {};
        for (int dd = 0; dd < 64; ++dd) {
            float a[4], bq[4];
#pragma unroll
            for (int i = 0; i < 4; ++i) a[i] = Qt[ty * 4 + i][dd];
#pragma unroll
            for (int j = 0; j < 4; ++j) bq[j] = PC[tx * 4 + j][dd];
#pragma unroll
            for (int i = 0; i < 4; ++i)
#pragma unroll
                for (int j = 0; j < 4; ++j) s[i][j] = fmaf(a[i], bq[j], s[i][j]);
        }
        __syncthreads();  // reads of PC (proj) done
#pragma unroll
        for (int i = 0; i < 4; ++i)
#pragma unroll
            for (int j = 0; j < 4; ++j) {
                int mg = mt * 64 + tx * 4 + j;
                S[ty * 4 + i][tx * 4 + j] =
                    (mg < M_) ? (fmaxf(s[i][j], 0.f) + EPSK_) : 0.f;
            }
        for (int idx = tid; idx < 4096; idx += 256) {
            int r = idx >> 6, c = idx & 63;
            PC[r][c] = ctx[((size_t)bh * MP_ + mt * 64 + r) * DH_ + c];
        }
        __syncthreads();
        for (int mm = 0; mm < 64; ++mm) {
            float sm[4], cd[4];
#pragma unroll
            for (int i = 0; i < 4; ++i) sm[i] = S[ty * 4 + i][mm];
#pragma unroll
            for (int j = 0; j < 4; ++j) cd[j] = PC[mm][tx * 4 + j];
#pragma unroll
            for (int i = 0; i < 4; ++i)
#pragma unroll
                for (int j = 0; j < 4; ++j) aacc[i][j] = fmaf(sm[i], cd[j], aacc[i][j]);
        }
        if (tid < 64) {
            for (int mm = 0; mm < 64; ++mm) dacc = fmaf(S[tid][mm], ks[mm], dacc);
        }
    }
    __syncthreads();
    if (tid < 64) dinv[tid] = 1.f / dacc;
    __syncthreads();
#pragma unroll
    for (int i = 0; i < 4; ++i) {
        int n = ty * 4 + i;
        float di = dinv[n];
        float4 y = make_float4(aacc[i][0] * di, aacc[i][1] * di,
                               aacc[i][2] * di, aacc[i][3] * di);
        *(float4*)(attout + base + (size_t)(nt * 64 + n) * C_ + tx * 4) = y;
    }
}

// ------------------------------ mean pool ----------------------------------
__global__ __launch_bounds__(256) void pool_kernel(const float* __restrict__ atoms,
                                                   float* __restrict__ out) {
    int b = blockIdx.x >> 3;
    int chunk = blockIdx.x & 7;
    int c = threadIdx.x;
    const float* p = atoms + ((size_t)(b * N_ + chunk * 64)) * C_ + c;
    float s = 0.f;
    for (int n = 0; n < 64; ++n) s += p[(size_t)n * C_];
    atomicAdd(out + b * C_ + c, s * (1.f / 512.f));
}

extern "C" void kernel_launch(void* const* d_in, const int* in_sizes, int n_in,
                              void* d_out, int out_size, void* d_ws, size_t ws_size,
                              hipStream_t stream) {
    (void)in_sizes; (void)n_in; (void)ws_size;
    const float* x = (const float*)d_in[0];
    const float* edge_attr = (const float*)d_in[1];
    const int* edge_index = (const int*)d_in[2];
    const float* node_w = (const float*)d_in[4];
    const float* node_b = (const float*)d_in[5];
    const float* edge_w = (const float*)d_in[6];
    const float* edge_b = (const float*)d_in[7];
    const float* gine_w1 = (const float*)d_in[8];
    const float* gine_b1 = (const float*)d_in[9];
    const float* gine_w2 = (const float*)d_in[10];
    const float* gine_b2 = (const float*)d_in[11];
    const float* q_w = (const float*)d_in[12];
    const float* k_w = (const float*)d_in[13];
    const float* v_w = (const float*)d_in[14];
    const float* o_w = (const float*)d_in[15];
    const float* o_b = (const float*)d_in[16];
    const float* proj = (const float*)d_in[17];
    const float* n1g = (const float*)d_in[18];
    const float* n1b = (const float*)d_in[19];
    const float* n2g = (const float*)d_in[20];
    const float* n2b = (const float*)d_in[21];
    const float* n3g = (const float*)d_in[22];
    const float* n3b = (const float*)d_in[23];
    const float* mw1 = (const float*)d_in[24];
    const float* mb1 = (const float*)d_in[25];
    const float* mw2 = (const float*)d_in[26];
    const float* mb2 = (const float*)d_in[27];

    const size_t SZ = (size_t)TN * C_;  // 8,388,608 floats
    float* ws = (float*)d_ws;
    float* A  = ws;            // atoms (persistent per layer)
    float* AG = A + SZ;        // aggr; later aliased as Q / h_att
    float* T  = AG + SZ;       // 2*SZ: GINE hidden / FFN hidden; also k/att+ctx+ksum
    float* HL = T + 2 * SZ;    // h_loc
    float* Vb = HL + SZ;       // v; later r3
    float* Q  = AG;            // alias: q lives after aggr is dead
    float* Kb = T;             // alias: k (then att) lives after t1 is dead
    float* CTX = T + SZ;       // 256*320*64 = 5,242,880 floats (fits in T[SZ..2SZ))
    float* KS  = CTX + (size_t)256 * MP_ * DH_;
    // total workspace use: 6*SZ floats = 201.3 MB

    dim3 g256(4, 512);   // NC=256 tiles
    dim3 g512(8, 512);   // NC=512 tiles

    embed_kernel<<<TN, 256, 0, stream>>>(x, node_w, node_b, A);
    for (int l = 0; l < L_; ++l) {
        hipMemsetAsync(AG, 0, SZ * sizeof(float), stream);
        scatter_kernel<<<E_ * 64 / 256, 256, 0, stream>>>(A, edge_attr, edge_index,
                                                          edge_w, edge_b, AG);
        // t1 = gelu((atoms+aggr) @ w1 + b1)
        mm_kernel<true, 1><<<g256, 256, 0, stream>>>(A, AG, gine_w1 + l * 65536,
                                                     gine_b1 + l * 256, nullptr, nullptr,
                                                     T, 256, 256);
        // h_loc_raw = t1 @ w2 + b2 + atoms
        mm_kernel<false, 2><<<g256, 256, 0, stream>>>(T, nullptr, gine_w2 + l * 65536,
                                                      gine_b2 + l * 256, A, nullptr,
                                                      HL, 256, 256);
        ln_kernel<<<TN, 256, 0, stream>>>(HL, n1g + l * 256, n1b + l * 256, HL);
        // q,k,v (no bias)
        mm_kernel<false, 0><<<g256, 256, 0, stream>>>(A, nullptr, q_w + l * 65536, nullptr,
                                                      nullptr, nullptr, Q, 256, 256);
        mm_kernel<false, 0><<<g256, 256, 0, stream>>>(A, nullptr, k_w + l * 65536, nullptr,
                                                      nullptr, nullptr, Kb, 256, 256);
        mm_kernel<false, 0><<<g256, 256, 0, stream>>>(A, nullptr, v_w + l * 65536, nullptr,
                                                      nullptr, nullptr, Vb, 256, 256);
        p1_kernel<<<dim3(5, 256), 256, 0, stream>>>(Kb, Vb, proj + l * (M_ * DH_), CTX, KS);
        p2_kernel<<<dim3(8, 256), 256, 0, stream>>>(Q, proj + l * (M_ * DH_), CTX, KS, Kb);
        // h_att_raw = att @ o_w + o_b + atoms   (att is in Kb, output into Q)
        mm_kernel<false, 2><<<g256, 256, 0, stream>>>(Kb, nullptr, o_w + l * 65536,
                                                      o_b + l * 256, A, nullptr,
                                                      Q, 256, 256);
        ln_kernel<<<TN, 256, 0, stream>>>(Q, n2g + l * 256, n2b + l * 256, Q);
        // t2 = gelu((h_loc + h_att) @ mw1 + mb1)   [NC=512]
        mm_kernel<true, 1><<<g512, 256, 0, stream>>>(HL, Q, mw1 + l * 131072,
                                                     mb1 + l * 512, nullptr, nullptr,
                                                     T, 256, 512);
        // r3 = t2 @ mw2 + mb2 + h_loc + h_att     [K=512]
        mm_kernel<false, 3><<<g256, 256, 0, stream>>>(T, nullptr, mw2 + l * 131072,
                                                      mb2 + l * 256, HL, Q,
                                                      Vb, 512, 256);
        ln_kernel<<<TN, 256, 0, stream>>>(Vb, n3g + l * 256, n3b + l * 256, A);
    }
    hipMemsetAsync(d_out, 0, (size_t)out_size * sizeof(float), stream);
    pool_kernel<<<512, 256, 0, stream>>>(A, (float*)d_out);
}

// Round 2
// 6649.205 us; speedup vs baseline: 2.2788x; 2.2788x over previous
//
#include <hip/hip_runtime.h>
#include <math.h>

#define TN 32768
#define C_ 256
#define E_ 524288
#define B_ 64
#define N_ 512
#define H_ 4
#define DH_ 64
#define M_ 266
#define MP_ 320
#define L_ 5
#define LN_EPS_ 1e-5f
#define EPSK_ 1e-3f

__device__ __forceinline__ float gelu_exact(float v) {
    return 0.5f * v * (1.0f + erff(v * 0.70710678118654752f));
}

// ---------------- embed: atoms = log(x+1) @ node_w + node_b ----------------
__global__ __launch_bounds__(256) void embed_kernel(
    const float* __restrict__ x, const float* __restrict__ nw,
    const float* __restrict__ nb, float* __restrict__ atoms) {
    int node = blockIdx.x;
    int c = threadIdx.x;
    __shared__ float lx[11];
    if (c < 11) lx[c] = logf(x[node * 11 + c] + 1.0f);
    __syncthreads();
    float acc = nb[c];
#pragma unroll
    for (int j = 0; j < 11; ++j) acc = fmaf(lx[j], nw[j * C_ + c], acc);
    atoms[(size_t)node * C_ + c] = acc;
}

// ----------------------- CSR build: count / scan / fill --------------------
__global__ __launch_bounds__(256) void count_kernel(const int* __restrict__ eidx,
                                                    int* __restrict__ deg) {
    int e = blockIdx.x * 256 + threadIdx.x;
    atomicAdd(&deg[eidx[E_ + e]], 1);
}

__global__ __launch_bounds__(1024) void scan_kernel(const int* __restrict__ deg,
                                                    int* __restrict__ offs,
                                                    int* __restrict__ cursor) {
    __shared__ int tsum[1024];
    int t = threadIdx.x;
    int base = t * 32;
    int local[32];
    int s = 0;
#pragma unroll
    for (int i = 0; i < 32; ++i) { local[i] = deg[base + i]; s += local[i]; }
    tsum[t] = s;
    __syncthreads();
    for (int off = 1; off < 1024; off <<= 1) {
        int v = tsum[t];
        int add = (t >= off) ? tsum[t - off] : 0;
        __syncthreads();
        tsum[t] = v + add;
        __syncthreads();
    }
    int run = tsum[t] - s;  // exclusive prefix of this thread's chunk
#pragma unroll
    for (int i = 0; i < 32; ++i) {
        offs[base + i] = run;
        cursor[base + i] = run;
        run += local[i];
    }
    if (t == 1023) offs[TN] = run;
}

__global__ __launch_bounds__(256) void fill_kernel(const int* __restrict__ eidx,
                                                   int* __restrict__ cursor,
                                                   int* __restrict__ esrc,
                                                   int* __restrict__ eidl) {
    int e = blockIdx.x * 256 + threadIdx.x;
    int d = eidx[E_ + e];
    int pos = atomicAdd(&cursor[d], 1);
    esrc[pos] = eidx[e];
    eidl[pos] = e;
}

// ------------- GINE message + gather (atomic-free, ea fused) ---------------
__global__ __launch_bounds__(256) void gather_kernel(
    const float* __restrict__ atoms, const float* __restrict__ eattr,
    const int* __restrict__ offs, const int* __restrict__ esrc,
    const int* __restrict__ eidl, const float* __restrict__ ew,
    const float* __restrict__ eb, float* __restrict__ aggr) {
    int node = blockIdx.x;
    int c = threadIdx.x;
    __shared__ int s_src[64];
    __shared__ float4 s_ea[64];
    int start = offs[node];
    int cnt = offs[node + 1] - start;
    float w0 = ew[c], w1 = ew[C_ + c], w2 = ew[2 * C_ + c], w3 = ew[3 * C_ + c];
    float bb = eb[c];
    float acc = 0.f;
    for (int baseI = 0; baseI < cnt; baseI += 64) {
        int nb = min(64, cnt - baseI);
        if (c < nb) {
            s_src[c] = esrc[start + baseI + c];
            int e = eidl[start + baseI + c];
            s_ea[c] = *(const float4*)(eattr + (size_t)e * 4);
        }
        __syncthreads();
        for (int i = 0; i < nb; ++i) {
            float4 ea = s_ea[i];
            float m = atoms[(size_t)s_src[i] * C_ + c] + bb +
                      ea.x * w0 + ea.y * w1 + ea.z * w2 + ea.w * w3;
            acc += fmaxf(m, 0.f);
        }
        __syncthreads();
    }
    aggr[(size_t)node * C_ + c] = acc;
}

// ------------- fallback: atomic scatter (if ws too small) ------------------
__global__ __launch_bounds__(256) void scatter_kernel(
    const float* __restrict__ atoms, const float* __restrict__ eattr,
    const int* __restrict__ eidx, const float* __restrict__ ew,
    const float* __restrict__ eb, float* __restrict__ aggr) {
    int gid = blockIdx.x * 256 + threadIdx.x;
    int e = gid >> 6;
    int q = (gid & 63) << 2;
    int src = eidx[e];
    int dst = eidx[E_ + e];
    float4 ea = *(const float4*)(eattr + (size_t)e * 4);
    float4 w0 = *(const float4*)(ew + 0 * C_ + q);
    float4 w1 = *(const float4*)(ew + 1 * C_ + q);
    float4 w2 = *(const float4*)(ew + 2 * C_ + q);
    float4 w3 = *(const float4*)(ew + 3 * C_ + q);
    float4 bb = *(const float4*)(eb + q);
    float4 av = *(const float4*)(atoms + (size_t)src * C_ + q);
    float m0 = av.x + bb.x + ea.x * w0.x + ea.y * w1.x + ea.z * w2.x + ea.w * w3.x;
    float m1 = av.y + bb.y + ea.x * w0.y + ea.y * w1.y + ea.z * w2.y + ea.w * w3.y;
    float m2 = av.z + bb.z + ea.x * w0.z + ea.y * w1.z + ea.z * w2.z + ea.w * w3.z;
    float m3 = av.w + bb.w + ea.x * w0.w + ea.y * w1.w + ea.z * w2.w + ea.w * w3.w;
    float* base = aggr + (size_t)dst * C_ + q;
    atomicAdd(base + 0, fmaxf(m0, 0.f));
    atomicAdd(base + 1, fmaxf(m1, 0.f));
    atomicAdd(base + 2, fmaxf(m2, 0.f));
    atomicAdd(base + 3, fmaxf(m3, 0.f));
}

// ------------- generic tiled fp32 matmul, 64x64 tile, fused epilogues ------
// EPI: 0=none, 1=gelu, 2=+R1, 3=+R1+R2.  IN_ADD: X := X + X2 on load.
template <bool IN_ADD, int EPI>
__global__ __launch_bounds__(256) void mm_kernel(
    const float* __restrict__ X, const float* __restrict__ X2,
    const float* __restrict__ W, const float* __restrict__ bias,
    const float* __restrict__ R1, const float* __restrict__ R2,
    float* __restrict__ Y, int K, int NC) {
    __shared__ float Xs[16][65];   // [k][row]
    __shared__ float Ws[16][68];   // [k][col], float4-storable
    int tid = threadIdx.x;
    int tx = tid & 15, ty = tid >> 4;
    int rowBase = blockIdx.y * 64;
    int colBase = blockIdx.x * 64;
    int lr = tid >> 2;            // 0..63 row
    int lk = (tid & 3) << 2;      // 0,4,8,12
    int wk = tid >> 4;            // 0..15 k-row
    int wc = (tid & 15) << 2;     // col quad
    const float* Xp = X + (size_t)(rowBase + lr) * K + lk;
    const float* X2p = IN_ADD ? (X2 + (size_t)(rowBase + lr) * K + lk) : X;
    const float* Wp = W + (size_t)wk * NC + colBase + wc;
    float acc[4][4] = {};
    for (int k0 = 0; k0 < K; k0 += 16) {
        float4 xv = *(const float4*)(Xp + k0);
        if (IN_ADD) {
            float4 x2 = *(const float4*)(X2p + k0);
            xv.x += x2.x; xv.y += x2.y; xv.z += x2.z; xv.w += x2.w;
        }
        float4 wv = *(const float4*)(Wp + (size_t)k0 * NC);
        __syncthreads();
        Xs[lk + 0][lr] = xv.x;
        Xs[lk + 1][lr] = xv.y;
        Xs[lk + 2][lr] = xv.z;
        Xs[lk + 3][lr] = xv.w;
        *(float4*)&Ws[wk][wc] = wv;
        __syncthreads();
#pragma unroll
        for (int kk = 0; kk < 16; ++kk) {
            float a[4], b[4];
#pragma unroll
            for (int i = 0; i < 4; ++i) a[i] = Xs[kk][ty * 4 + i];
#pragma unroll
            for (int j = 0; j < 4; ++j) b[j] = Ws[kk][tx * 4 + j];
#pragma unroll
            for (int i = 0; i < 4; ++i)
#pragma unroll
                for (int j = 0; j < 4; ++j) acc[i][j] = fmaf(a[i], b[j], acc[i][j]);
        }
    }
    int c0 = colBase + tx * 4;
    float4 bv = make_float4(0.f, 0.f, 0.f, 0.f);
    if (bias) bv = *(const float4*)(bias + c0);
#pragma unroll
    for (int i = 0; i < 4; ++i) {
        int r = rowBase + ty * 4 + i;
        float4 y;
        y.x = acc[i][0] + bv.x; y.y = acc[i][1] + bv.y;
        y.z = acc[i][2] + bv.z; y.w = acc[i][3] + bv.w;
        if (EPI == 1) {
            y.x = gelu_exact(y.x); y.y = gelu_exact(y.y);
            y.z = gelu_exact(y.z); y.w = gelu_exact(y.w);
        }
        if (EPI >= 2) {
            float4 r1 = *(const float4*)(R1 + (size_t)r * NC + c0);
            y.x += r1.x; y.y += r1.y; y.z += r1.z; y.w += r1.w;
        }
        if (EPI == 3) {
            float4 r2 = *(const float4*)(R2 + (size_t)r * NC + c0);
            y.x += r2.x; y.y += r2.y; y.z += r2.z; y.w += r2.w;
        }
        *(float4*)(Y + (size_t)r * NC + c0) = y;
    }
}

// ------------------------------ LayerNorm ----------------------------------
__global__ __launch_bounds__(256) void ln_kernel(
    const float* __restrict__ X, const float* __restrict__ g,
    const float* __restrict__ bta, float* __restrict__ Y) {
    __shared__ float rs[4], rs2[4];
    __shared__ float mu_s, inv_s;
    int row = blockIdx.x, t = threadIdx.x;
    size_t off = (size_t)row * C_ + t;
    float v = X[off];
    float s = v, s2 = v * v;
#pragma unroll
    for (int o = 32; o > 0; o >>= 1) {
        s += __shfl_down(s, o);
        s2 += __shfl_down(s2, o);
    }
    int w = t >> 6, lane = t & 63;
    if (lane == 0) { rs[w] = s; rs2[w] = s2; }
    __syncthreads();
    if (t == 0) {
        float tot = rs[0] + rs[1] + rs[2] + rs[3];
        float tot2 = rs2[0] + rs2[1] + rs2[2] + rs2[3];
        float mu = tot * (1.f / C_);
        float var = tot2 * (1.f / C_) - mu * mu;
        mu_s = mu;
        inv_s = rsqrtf(var + LN_EPS_);
    }
    __syncthreads();
    Y[off] = (v - mu_s) * inv_s * g[t] + bta[t];
}

// -------- Performer pass 1: ctx[bh,m,d] = kp^T @ v, ksum[bh,m] -------------
__global__ __launch_bounds__(256) void p1_kernel(
    const float* __restrict__ kbuf, const float* __restrict__ vbuf,
    const float* __restrict__ proj, float* __restrict__ ctx,
    float* __restrict__ ksum) {
    int mt = blockIdx.x;          // 0..4
    int bh = blockIdx.y;          // 0..255
    int b = bh >> 2, h = bh & 3;
    __shared__ float Pt[64][65];  // proj m-tile [m][d]
    __shared__ float KV[64][65];  // K tile, then reused as V tile
    __shared__ float S[64][65];   // kp tile [n][m]
    int tid = threadIdx.x;
    int tx = tid & 15, ty = tid >> 4;
    for (int idx = tid; idx < 4096; idx += 256) {
        int r = idx >> 6, c = idx & 63;
        int mg = mt * 64 + r;
        Pt[r][c] = (mg < M_) ? proj[mg * DH_ + c] : 0.f;
    }
    float cacc[4][4] = {};
    float ksacc = 0.f;
    size_t base = ((size_t)b * N_) * C_ + h * DH_;
    for (int nt = 0; nt < 8; ++nt) {
        __syncthreads();
        for (int idx = tid; idx < 4096; idx += 256) {
            int r = idx >> 6, c = idx & 63;
            KV[r][c] = kbuf[base + (size_t)(nt * 64 + r) * C_ + c];
        }
        __syncthreads();
        float s[4][4] = {};
        for (int dd = 0; dd < 64; ++dd) {
            float a[4], bq[4];
#pragma unroll
            for (int i = 0; i < 4; ++i) a[i] = KV[ty * 4 + i][dd];
#pragma unroll
            for (int j = 0; j < 4; ++j) bq[j] = Pt[tx * 4 + j][dd];
#pragma unroll
            for (int i = 0; i < 4; ++i)
#pragma unroll
                for (int j = 0; j < 4; ++j) s[i][j] = fmaf(a[i], bq[j], s[i][j]);
        }
        __syncthreads();  // all reads of KV done
#pragma unroll
        for (int i = 0; i < 4; ++i)
#pragma unroll
            for (int j = 0; j < 4; ++j) {
                int mg = mt * 64 + tx * 4 + j;
                S[ty * 4 + i][tx * 4 + j] =
                    (mg < M_) ? (fmaxf(s[i][j], 0.f) + EPSK_) : 0.f;
            }
        for (int idx = tid; idx < 4096; idx += 256) {
            int r = idx >> 6, c = idx & 63;
            KV[r][c] = vbuf[base + (size_t)(nt * 64 + r) * C_ + c];
        }
        __syncthreads();
        // ctx[m][d] += sum_n S[n][m] * V[n][d]
        for (int nn = 0; nn < 64; ++nn) {
            float sm[4], vd[4];
#pragma unroll
            for (int i = 0; i < 4; ++i) sm[i] = S[nn][ty * 4 + i];
#pragma unroll
            for (int j = 0; j < 4; ++j) vd[j] = KV[nn][tx * 4 + j];
#pragma unroll
            for (int i = 0; i < 4; ++i)
#pragma unroll
                for (int j = 0; j < 4; ++j) cacc[i][j] = fmaf(sm[i], vd[j], cacc[i][j]);
        }
        if (tid < 64) {
            for (int nn = 0; nn < 64; ++nn) ksacc += S[nn][tid];
        }
    }
    float* cp = ctx + ((size_t)bh * MP_ + mt * 64) * DH_;
#pragma unroll
    for (int i = 0; i < 4; ++i)
#pragma unroll
        for (int j = 0; j < 4; ++j)
            cp[(ty * 4 + i) * DH_ + tx * 4 + j] = cacc[i][j];
    if (tid < 64) ksum[bh * MP_ + mt * 64 + tid] = ksacc;
}

// -------- Performer pass 2: att = (qp @ ctx) * (1/(qp @ ksum)) -------------
__global__ __launch_bounds__(256) void p2_kernel(
    const float* __restrict__ qbuf, const float* __restrict__ proj,
    const float* __restrict__ ctx, const float* __restrict__ ksum,
    float* __restrict__ attout) {
    int nt = blockIdx.x;          // 0..7
    int bh = blockIdx.y;          // 0..255
    int b = bh >> 2, h = bh & 3;
    __shared__ float Qt[64][65];
    __shared__ float PC[64][65];  // proj tile, then ctx tile
    __shared__ float S[64][65];
    __shared__ float ks[64], dinv[64];
    int tid = threadIdx.x;
    int tx = tid & 15, ty = tid >> 4;
    size_t base = ((size_t)b * N_) * C_ + h * DH_;
    for (int idx = tid; idx < 4096; idx += 256) {
        int r = idx >> 6, c = idx & 63;
        Qt[r][c] = qbuf[base + (size_t)(nt * 64 + r) * C_ + c];
    }
    float aacc[4][4] = {};
    float dacc = 0.f;
    for (int mt = 0; mt < 5; ++mt) {
        __syncthreads();
        for (int idx = tid; idx < 4096; idx += 256) {
            int r = idx >> 6, c = idx & 63;
            int mg = mt * 64 + r;
            PC[r][c] = (mg < M_) ? proj[mg * DH_ + c] : 0.f;
        }
        if (tid < 64) ks[tid] = ksum[bh * MP_ + mt * 64 + tid];
        __syncthreads();
        float s[4][4] = {};
        for (int dd = 0; dd < 64; ++dd) {
            float a[4], bq[4];
#pragma unroll
            for (int i = 0; i < 4; ++i) a[i] = Qt[ty * 4 + i][dd];
#pragma unroll
            for (int j = 0; j < 4; ++j) bq[j] = PC[tx * 4 + j][dd];
#pragma unroll
            for (int i = 0; i < 4; ++i)
#pragma unroll
                for (int j = 0; j < 4; ++j) s[i][j] = fmaf(a[i], bq[j], s[i][j]);
        }
        __syncthreads();  // reads of PC (proj) done
#pragma unroll
        for (int i = 0; i < 4; ++i)
#pragma unroll
            for (int j = 0; j < 4; ++j) {
                int mg = mt * 64 + tx * 4 + j;
                S[ty * 4 + i][tx * 4 + j] =
                    (mg < M_) ? (fmaxf(s[i][j], 0.f) + EPSK_) : 0.f;
            }
        for (int idx = tid; idx < 4096; idx += 256) {
            int r = idx >> 6, c = idx & 63;
            PC[r][c] = ctx[((size_t)bh * MP_ + mt * 64 + r) * DH_ + c];
        }
        __syncthreads();
        for (int mm = 0; mm < 64; ++mm) {
            float sm[4], cd[4];
#pragma unroll
            for (int i = 0; i < 4; ++i) sm[i] = S[ty * 4 + i][mm];
#pragma unroll
            for (int j = 0; j < 4; ++j) cd[j] = PC[mm][tx * 4 + j];
#pragma unroll
            for (int i = 0; i < 4; ++i)
#pragma unroll
                for (int j = 0; j < 4; ++j) aacc[i][j] = fmaf(sm[i], cd[j], aacc[i][j]);
        }
        if (tid < 64) {
            for (int mm = 0; mm < 64; ++mm) dacc = fmaf(S[tid][mm], ks[mm], dacc);
        }
    }
    __syncthreads();
    if (tid < 64) dinv[tid] = 1.f / dacc;
    __syncthreads();
#pragma unroll
    for (int i = 0; i < 4; ++i) {
        int n = ty * 4 + i;
        float di = dinv[n];
        float4 y = make_float4(aacc[i][0] * di, aacc[i][1] * di,
                               aacc[i][2] * di, aacc[i][3] * di);
        *(float4*)(attout + base + (size_t)(nt * 64 + n) * C_ + tx * 4) = y;
    }
}

// ------------------------------ mean pool ----------------------------------
__global__ __launch_bounds__(256) void pool_kernel(const float* __restrict__ atoms,
                                                   float* __restrict__ out) {
    int b = blockIdx.x >> 3;
    int chunk = blockIdx.x & 7;
    int c = threadIdx.x;
    const float* p = atoms + ((size_t)(b * N_ + chunk * 64)) * C_ + c;
    float s = 0.f;
    for (int n = 0; n < 64; ++n) s += p[(size_t)n * C_];
    atomicAdd(out + b * C_ + c, s * (1.f / 512.f));
}

extern "C" void kernel_launch(void* const* d_in, const int* in_sizes, int n_in,
                              void* d_out, int out_size, void* d_ws, size_t ws_size,
                              hipStream_t stream) {
    (void)in_sizes; (void)n_in;
    const float* x = (const float*)d_in[0];
    const float* edge_attr = (const float*)d_in[1];
    const int* edge_index = (const int*)d_in[2];
    const float* node_w = (const float*)d_in[4];
    const float* node_b = (const float*)d_in[5];
    const float* edge_w = (const float*)d_in[6];
    const float* edge_b = (const float*)d_in[7];
    const float* gine_w1 = (const float*)d_in[8];
    const float* gine_b1 = (const float*)d_in[9];
    const float* gine_w2 = (const float*)d_in[10];
    const float* gine_b2 = (const float*)d_in[11];
    const float* q_w = (const float*)d_in[12];
    const float* k_w = (const float*)d_in[13];
    const float* v_w = (const float*)d_in[14];
    const float* o_w = (const float*)d_in[15];
    const float* o_b = (const float*)d_in[16];
    const float* proj = (const float*)d_in[17];
    const float* n1g = (const float*)d_in[18];
    const float* n1b = (const float*)d_in[19];
    const float* n2g = (const float*)d_in[20];
    const float* n2b = (const float*)d_in[21];
    const float* n3g = (const float*)d_in[22];
    const float* n3b = (const float*)d_in[23];
    const float* mw1 = (const float*)d_in[24];
    const float* mb1 = (const float*)d_in[25];
    const float* mw2 = (const float*)d_in[26];
    const float* mb2 = (const float*)d_in[27];

    const size_t SZ = (size_t)TN * C_;  // 8,388,608 floats
    float* ws = (float*)d_ws;
    float* A  = ws;            // atoms (persistent per layer)
    float* AG = A + SZ;        // aggr; later aliased as Q / h_att
    float* T  = AG + SZ;       // 2*SZ: GINE hidden / FFN hidden; also k/att+ctx+ksum
    float* HL = T + 2 * SZ;    // h_loc
    float* Vb = HL + SZ;       // v; later r3
    float* Q  = AG;            // alias: q lives after aggr is dead
    float* Kb = T;             // alias: k (then att) lives after t1 is dead
    float* CTX = T + SZ;       // 256*320*64 floats (fits in T[SZ..2SZ))
    float* KS  = CTX + (size_t)256 * MP_ * DH_;

    // CSR arrays appended after the 6*SZ float region
    int* deg    = (int*)(ws + 6 * SZ);
    int* offs   = deg + TN;          // TN+1
    int* cursor = offs + TN + 1;
    int* esrc   = cursor + TN;       // E_
    int* eidl   = esrc + E_;         // E_
    size_t need = 6 * SZ * sizeof(float) +
                  (size_t)(TN + TN + 1 + TN + 2 * E_) * sizeof(int);
    bool use_csr = ws_size >= need;

    dim3 g256(4, 512);   // NC=256 tiles
    dim3 g512(8, 512);   // NC=512 tiles

    embed_kernel<<<TN, 256, 0, stream>>>(x, node_w, node_b, A);
    if (use_csr) {
        hipMemsetAsync(deg, 0, TN * sizeof(int), stream);
        count_kernel<<<E_ / 256, 256, 0, stream>>>(edge_index, deg);
        scan_kernel<<<1, 1024, 0, stream>>>(deg, offs, cursor);
        fill_kernel<<<E_ / 256, 256, 0, stream>>>(edge_index, cursor, esrc, eidl);
    }
    for (int l = 0; l < L_; ++l) {
        if (use_csr) {
            gather_kernel<<<TN, 256, 0, stream>>>(A, edge_attr, offs, esrc, eidl,
                                                  edge_w, edge_b, AG);
        } else {
            hipMemsetAsync(AG, 0, SZ * sizeof(float), stream);
            scatter_kernel<<<E_ * 64 / 256, 256, 0, stream>>>(A, edge_attr, edge_index,
                                                              edge_w, edge_b, AG);
        }
        // t1 = gelu((atoms+aggr) @ w1 + b1)
        mm_kernel<true, 1><<<g256, 256, 0, stream>>>(A, AG, gine_w1 + l * 65536,
                                                     gine_b1 + l * 256, nullptr, nullptr,
                                                     T, 256, 256);
        // h_loc_raw = t1 @ w2 + b2 + atoms
        mm_kernel<false, 2><<<g256, 256, 0, stream>>>(T, nullptr, gine_w2 + l * 65536,
                                                      gine_b2 + l * 256, A, nullptr,
                                                      HL, 256, 256);
        ln_kernel<<<TN, 256, 0, stream>>>(HL, n1g + l * 256, n1b + l * 256, HL);
        // q,k,v (no bias)
        mm_kernel<false, 0><<<g256, 256, 0, stream>>>(A, nullptr, q_w + l * 65536, nullptr,
                                                      nullptr, nullptr, Q, 256, 256);
        mm_kernel<false, 0><<<g256, 256, 0, stream>>>(A, nullptr, k_w + l * 65536, nullptr,
                                                      nullptr, nullptr, Kb, 256, 256);
        mm_kernel<false, 0><<<g256, 256, 0, stream>>>(A, nullptr, v_w + l * 65536, nullptr,
                                                      nullptr, nullptr, Vb, 256, 256);
        p1_kernel<<<dim3(5, 256), 256, 0, stream>>>(Kb, Vb, proj + l * (M_ * DH_), CTX, KS);
        p2_kernel<<<dim3(8, 256), 256, 0, stream>>>(Q, proj + l * (M_ * DH_), CTX, KS, Kb);
        // h_att_raw = att @ o_w + o_b + atoms   (att is in Kb, output into Q)
        mm_kernel<false, 2><<<g256, 256, 0, stream>>>(Kb, nullptr, o_w + l * 65536,
                                                      o_b + l * 256, A, nullptr,
                                                      Q, 256, 256);
        ln_kernel<<<TN, 256, 0, stream>>>(Q, n2g + l * 256, n2b + l * 256, Q);
        // t2 = gelu((h_loc + h_att) @ mw1 + mb1)   [NC=512]
        mm_kernel<true, 1><<<g512, 256, 0, stream>>>(HL, Q, mw1 + l * 131072,
                                                     mb1 + l * 512, nullptr, nullptr,
                                                     T, 256, 512);
        // r3 = t2 @ mw2 + mb2 + h_loc + h_att     [K=512]
        mm_kernel<false, 3><<<g256, 256, 0, stream>>>(T, nullptr, mw2 + l * 131072,
                                                      mb2 + l * 256, HL, Q,
                                                      Vb, 512, 256);
        ln_kernel<<<TN, 256, 0, stream>>>(Vb, n3g + l * 256, n3b + l * 256, A);
    }
    hipMemsetAsync(d_out, 0, (size_t)out_size * sizeof(float), stream);
    pool_kernel<<<512, 256, 0, stream>>>(A, (float*)d_out);
}

// Round 3
// 4537.102 us; speedup vs baseline: 3.3397x; 1.4655x over previous
//
#include <hip/hip_runtime.h>
#include <math.h>

#define TN 32768
#define C_ 256
#define E_ 524288
#define B_ 64
#define N_ 512
#define H_ 4
#define DH_ 64
#define M_ 266
#define MP_ 320
#define L_ 5
#define LN_EPS_ 1e-5f
#define EPSK_ 1e-3f

typedef short short8 __attribute__((ext_vector_type(8)));
typedef short short4v __attribute__((ext_vector_type(4)));
typedef float floatx4 __attribute__((ext_vector_type(4)));

__device__ __forceinline__ float gelu_exact(float v) {
    return 0.5f * v * (1.0f + erff(v * 0.70710678118654752f));
}

__device__ __forceinline__ short f2bf(float f) {
    union { float f; unsigned u; } v; v.f = f;
    unsigned r = v.u + 0x7FFF + ((v.u >> 16) & 1);
    return (short)(r >> 16);
}

// ---------------- embed: atoms = log(x+1) @ node_w + node_b ----------------
__global__ __launch_bounds__(256) void embed_kernel(
    const float* __restrict__ x, const float* __restrict__ nw,
    const float* __restrict__ nb, float* __restrict__ atoms) {
    int node = blockIdx.x;
    int c = threadIdx.x;
    __shared__ float lx[11];
    if (c < 11) lx[c] = logf(x[node * 11 + c] + 1.0f);
    __syncthreads();
    float acc = nb[c];
#pragma unroll
    for (int j = 0; j < 11; ++j) acc = fmaf(lx[j], nw[j * C_ + c], acc);
    atoms[(size_t)node * C_ + c] = acc;
}

// ----------------------- CSR build: count / scan / fill --------------------
__global__ __launch_bounds__(256) void count_kernel(const int* __restrict__ eidx,
                                                    int* __restrict__ deg) {
    int e = blockIdx.x * 256 + threadIdx.x;
    atomicAdd(&deg[eidx[E_ + e]], 1);
}

__global__ __launch_bounds__(1024) void scan_kernel(const int* __restrict__ deg,
                                                    int* __restrict__ offs,
                                                    int* __restrict__ cursor) {
    __shared__ int tsum[1024];
    int t = threadIdx.x;
    int base = t * 32;
    int local[32];
    int s = 0;
#pragma unroll
    for (int i = 0; i < 32; ++i) { local[i] = deg[base + i]; s += local[i]; }
    tsum[t] = s;
    __syncthreads();
    for (int off = 1; off < 1024; off <<= 1) {
        int v = tsum[t];
        int add = (t >= off) ? tsum[t - off] : 0;
        __syncthreads();
        tsum[t] = v + add;
        __syncthreads();
    }
    int run = tsum[t] - s;
#pragma unroll
    for (int i = 0; i < 32; ++i) {
        offs[base + i] = run;
        cursor[base + i] = run;
        run += local[i];
    }
    if (t == 1023) offs[TN] = run;
}

__global__ __launch_bounds__(256) void fill_kernel(const int* __restrict__ eidx,
                                                   int* __restrict__ cursor,
                                                   int* __restrict__ esrc,
                                                   int* __restrict__ eidl) {
    int e = blockIdx.x * 256 + threadIdx.x;
    int d = eidx[E_ + e];
    int pos = atomicAdd(&cursor[d], 1);
    esrc[pos] = eidx[e];
    eidl[pos] = e;
}

// ------------- GINE message + gather (atomic-free, ea fused) ---------------
__global__ __launch_bounds__(256) void gather_kernel(
    const float* __restrict__ atoms, const float* __restrict__ eattr,
    const int* __restrict__ offs, const int* __restrict__ esrc,
    const int* __restrict__ eidl, const float* __restrict__ ew,
    const float* __restrict__ eb, float* __restrict__ aggr) {
    int node = blockIdx.x;
    int c = threadIdx.x;
    __shared__ int s_src[64];
    __shared__ float4 s_ea[64];
    int start = offs[node];
    int cnt = offs[node + 1] - start;
    float w0 = ew[c], w1 = ew[C_ + c], w2 = ew[2 * C_ + c], w3 = ew[3 * C_ + c];
    float bb = eb[c];
    float acc = 0.f;
    for (int baseI = 0; baseI < cnt; baseI += 64) {
        int nb = min(64, cnt - baseI);
        if (c < nb) {
            s_src[c] = esrc[start + baseI + c];
            int e = eidl[start + baseI + c];
            s_ea[c] = *(const float4*)(eattr + (size_t)e * 4);
        }
        __syncthreads();
        for (int i = 0; i < nb; ++i) {
            float4 ea = s_ea[i];
            float m = atoms[(size_t)s_src[i] * C_ + c] + bb +
                      ea.x * w0 + ea.y * w1 + ea.z * w2 + ea.w * w3;
            acc += fmaxf(m, 0.f);
        }
        __syncthreads();
    }
    aggr[(size_t)node * C_ + c] = acc;
}

// ------------- fallback: atomic scatter (if ws too small) ------------------
__global__ __launch_bounds__(256) void scatter_kernel(
    const float* __restrict__ atoms, const float* __restrict__ eattr,
    const int* __restrict__ eidx, const float* __restrict__ ew,
    const float* __restrict__ eb, float* __restrict__ aggr) {
    int gid = blockIdx.x * 256 + threadIdx.x;
    int e = gid >> 6;
    int q = (gid & 63) << 2;
    int src = eidx[e];
    int dst = eidx[E_ + e];
    float4 ea = *(const float4*)(eattr + (size_t)e * 4);
    float4 w0 = *(const float4*)(ew + 0 * C_ + q);
    float4 w1 = *(const float4*)(ew + 1 * C_ + q);
    float4 w2 = *(const float4*)(ew + 2 * C_ + q);
    float4 w3 = *(const float4*)(ew + 3 * C_ + q);
    float4 bb = *(const float4*)(eb + q);
    float4 av = *(const float4*)(atoms + (size_t)src * C_ + q);
    float m0 = av.x + bb.x + ea.x * w0.x + ea.y * w1.x + ea.z * w2.x + ea.w * w3.x;
    float m1 = av.y + bb.y + ea.x * w0.y + ea.y * w1.y + ea.z * w2.y + ea.w * w3.y;
    float m2 = av.z + bb.z + ea.x * w0.z + ea.y * w1.z + ea.z * w2.z + ea.w * w3.z;
    float m3 = av.w + bb.w + ea.x * w0.w + ea.y * w1.w + ea.z * w2.w + ea.w * w3.w;
    float* base = aggr + (size_t)dst * C_ + q;
    atomicAdd(base + 0, fmaxf(m0, 0.f));
    atomicAdd(base + 1, fmaxf(m1, 0.f));
    atomicAdd(base + 2, fmaxf(m2, 0.f));
    atomicAdd(base + 3, fmaxf(m3, 0.f));
}

// ------------ weight transpose+cast: Wt[n][k] bf16 from W[k][n] fp32 -------
__global__ __launch_bounds__(256) void wt_kernel(const float* __restrict__ W,
                                                 short* __restrict__ Wt,
                                                 int K, int NC) {
    __shared__ short tile[64][65];
    int l = blockIdx.z;
    int k0 = blockIdx.y * 64, n0 = blockIdx.x * 64;
    const float* Wl = W + (size_t)l * K * NC;
    short* Wtl = Wt + (size_t)l * K * NC;
    int t = threadIdx.x;
    int rr = t >> 4;
    int cc = (t & 15) * 4;
#pragma unroll
    for (int rep = 0; rep < 4; ++rep) {
        int r = rr + rep * 16;
        float4 v = *(const float4*)(Wl + (size_t)(k0 + r) * NC + n0 + cc);
        tile[cc + 0][r] = f2bf(v.x);
        tile[cc + 1][r] = f2bf(v.y);
        tile[cc + 2][r] = f2bf(v.z);
        tile[cc + 3][r] = f2bf(v.w);
    }
    __syncthreads();
#pragma unroll
    for (int rep = 0; rep < 4; ++rep) {
        int r = rr + rep * 16;   // n-local
        short4v s;
        s.x = tile[r][cc + 0];
        s.y = tile[r][cc + 1];
        s.z = tile[r][cc + 2];
        s.w = tile[r][cc + 3];
        *(short4v*)(Wtl + (size_t)(n0 + r) * K + k0 + cc) = s;
    }
}

// ---------------- MFMA bf16 matmul: Y = X @ W (+epilogue) ------------------
// Wt is pre-transposed bf16 [NC][K]. 128x128 tile, 4 waves, 4x4 frag each.
// EPI: 0=none, 1=gelu, 2=+R1, 3=+R1+R2.  IN_ADD: X := X + X2 on load.
template <bool IN_ADD, int EPI>
__global__ __launch_bounds__(256) void mfmm_kernel(
    const float* __restrict__ X, const float* __restrict__ X2,
    const short* __restrict__ Wt, const float* __restrict__ bias,
    const float* __restrict__ R1, const float* __restrict__ R2,
    float* __restrict__ Y, int K, int NC) {
    __shared__ short As[128][56];   // [m][k] bf16, pitch 112B (16B-mult)
    __shared__ short Bs[128][56];   // [n][k] bf16
    int tid = threadIdx.x;
    int rowBase = blockIdx.y * 128, colBase = blockIdx.x * 128;
    int w = tid >> 6, lane = tid & 63;
    int wm = w & 1, wn = w >> 1;
    int quad = lane >> 4, l16 = lane & 15;
    int sr = tid >> 1;            // staging row 0..127
    int sk = (tid & 1) * 16;      // staging k offset (elements)
    const float* Xp = X + (size_t)(rowBase + sr) * K + sk;
    const float* X2p = IN_ADD ? (X2 + (size_t)(rowBase + sr) * K + sk) : X;
    const short* Wp = Wt + (size_t)(colBase + sr) * K + sk;
    floatx4 acc[4][4];
#pragma unroll
    for (int i = 0; i < 4; ++i)
#pragma unroll
        for (int j = 0; j < 4; ++j)
            acc[i][j] = (floatx4){0.f, 0.f, 0.f, 0.f};
    for (int k0 = 0; k0 < K; k0 += 32) {
        float4 x0 = *(const float4*)(Xp + k0);
        float4 x1 = *(const float4*)(Xp + k0 + 4);
        float4 x2 = *(const float4*)(Xp + k0 + 8);
        float4 x3 = *(const float4*)(Xp + k0 + 12);
        if (IN_ADD) {
            float4 y0 = *(const float4*)(X2p + k0);
            float4 y1 = *(const float4*)(X2p + k0 + 4);
            float4 y2 = *(const float4*)(X2p + k0 + 8);
            float4 y3 = *(const float4*)(X2p + k0 + 12);
            x0.x += y0.x; x0.y += y0.y; x0.z += y0.z; x0.w += y0.w;
            x1.x += y1.x; x1.y += y1.y; x1.z += y1.z; x1.w += y1.w;
            x2.x += y2.x; x2.y += y2.y; x2.z += y2.z; x2.w += y2.w;
            x3.x += y3.x; x3.y += y3.y; x3.z += y3.z; x3.w += y3.w;
        }
        uint4 wv0 = *(const uint4*)(Wp + k0);
        uint4 wv1 = *(const uint4*)(Wp + k0 + 8);
        short8 s0, s1;
        s0[0] = f2bf(x0.x); s0[1] = f2bf(x0.y); s0[2] = f2bf(x0.z); s0[3] = f2bf(x0.w);
        s0[4] = f2bf(x1.x); s0[5] = f2bf(x1.y); s0[6] = f2bf(x1.z); s0[7] = f2bf(x1.w);
        s1[0] = f2bf(x2.x); s1[1] = f2bf(x2.y); s1[2] = f2bf(x2.z); s1[3] = f2bf(x2.w);
        s1[4] = f2bf(x3.x); s1[5] = f2bf(x3.y); s1[6] = f2bf(x3.z); s1[7] = f2bf(x3.w);
        __syncthreads();
        *(short8*)&As[sr][sk] = s0;
        *(short8*)&As[sr][sk + 8] = s1;
        *(uint4*)&Bs[sr][sk] = wv0;
        *(uint4*)&Bs[sr][sk + 8] = wv1;
        __syncthreads();
        short8 a[4], b[4];
#pragma unroll
        for (int mi = 0; mi < 4; ++mi)
            a[mi] = *(const short8*)&As[wm * 64 + mi * 16 + l16][quad * 8];
#pragma unroll
        for (int ni = 0; ni < 4; ++ni)
            b[ni] = *(const short8*)&Bs[wn * 64 + ni * 16 + l16][quad * 8];
#pragma unroll
        for (int mi = 0; mi < 4; ++mi)
#pragma unroll
            for (int ni = 0; ni < 4; ++ni)
                acc[mi][ni] = __builtin_amdgcn_mfma_f32_16x16x32_bf16(
                    a[mi], b[ni], acc[mi][ni], 0, 0, 0);
    }
    // epilogue: D[row=quad*4+r][col=l16] per 16x16 tile
#pragma unroll
    for (int ni = 0; ni < 4; ++ni) {
        int colg = colBase + wn * 64 + ni * 16 + l16;
        float bv = bias ? bias[colg] : 0.f;
#pragma unroll
        for (int mi = 0; mi < 4; ++mi) {
#pragma unroll
            for (int r = 0; r < 4; ++r) {
                int rowg = rowBase + wm * 64 + mi * 16 + quad * 4 + r;
                float y = acc[mi][ni][r] + bv;
                if (EPI == 1) y = gelu_exact(y);
                if (EPI >= 2) y += R1[(size_t)rowg * NC + colg];
                if (EPI == 3) y += R2[(size_t)rowg * NC + colg];
                Y[(size_t)rowg * NC + colg] = y;
            }
        }
    }
}

// ------------- fallback fp32 tiled matmul (old path) -----------------------
template <bool IN_ADD, int EPI>
__global__ __launch_bounds__(256) void mm_kernel(
    const float* __restrict__ X, const float* __restrict__ X2,
    const float* __restrict__ W, const float* __restrict__ bias,
    const float* __restrict__ R1, const float* __restrict__ R2,
    float* __restrict__ Y, int K, int NC) {
    __shared__ float Xs[16][65];
    __shared__ float Ws[16][68];
    int tid = threadIdx.x;
    int tx = tid & 15, ty = tid >> 4;
    int rowBase = blockIdx.y * 64;
    int colBase = blockIdx.x * 64;
    int lr = tid >> 2;
    int lk = (tid & 3) << 2;
    int wk = tid >> 4;
    int wc = (tid & 15) << 2;
    const float* Xp = X + (size_t)(rowBase + lr) * K + lk;
    const float* X2p = IN_ADD ? (X2 + (size_t)(rowBase + lr) * K + lk) : X;
    const float* Wp = W + (size_t)wk * NC + colBase + wc;
    float acc[4][4] = {};
    for (int k0 = 0; k0 < K; k0 += 16) {
        float4 xv = *(const float4*)(Xp + k0);
        if (IN_ADD) {
            float4 x2 = *(const float4*)(X2p + k0);
            xv.x += x2.x; xv.y += x2.y; xv.z += x2.z; xv.w += x2.w;
        }
        float4 wv = *(const float4*)(Wp + (size_t)k0 * NC);
        __syncthreads();
        Xs[lk + 0][lr] = xv.x;
        Xs[lk + 1][lr] = xv.y;
        Xs[lk + 2][lr] = xv.z;
        Xs[lk + 3][lr] = xv.w;
        *(float4*)&Ws[wk][wc] = wv;
        __syncthreads();
#pragma unroll
        for (int kk = 0; kk < 16; ++kk) {
            float a[4], b[4];
#pragma unroll
            for (int i = 0; i < 4; ++i) a[i] = Xs[kk][ty * 4 + i];
#pragma unroll
            for (int j = 0; j < 4; ++j) b[j] = Ws[kk][tx * 4 + j];
#pragma unroll
            for (int i = 0; i < 4; ++i)
#pragma unroll
                for (int j = 0; j < 4; ++j) acc[i][j] = fmaf(a[i], b[j], acc[i][j]);
        }
    }
    int c0 = colBase + tx * 4;
    float4 bv = make_float4(0.f, 0.f, 0.f, 0.f);
    if (bias) bv = *(const float4*)(bias + c0);
#pragma unroll
    for (int i = 0; i < 4; ++i) {
        int r = rowBase + ty * 4 + i;
        float4 y;
        y.x = acc[i][0] + bv.x; y.y = acc[i][1] + bv.y;
        y.z = acc[i][2] + bv.z; y.w = acc[i][3] + bv.w;
        if (EPI == 1) {
            y.x = gelu_exact(y.x); y.y = gelu_exact(y.y);
            y.z = gelu_exact(y.z); y.w = gelu_exact(y.w);
        }
        if (EPI >= 2) {
            float4 r1 = *(const float4*)(R1 + (size_t)r * NC + c0);
            y.x += r1.x; y.y += r1.y; y.z += r1.z; y.w += r1.w;
        }
        if (EPI == 3) {
            float4 r2 = *(const float4*)(R2 + (size_t)r * NC + c0);
            y.x += r2.x; y.y += r2.y; y.z += r2.z; y.w += r2.w;
        }
        *(float4*)(Y + (size_t)r * NC + c0) = y;
    }
}

// ------------------------------ LayerNorm ----------------------------------
__global__ __launch_bounds__(256) void ln_kernel(
    const float* __restrict__ X, const float* __restrict__ g,
    const float* __restrict__ bta, float* __restrict__ Y) {
    __shared__ float rs[4], rs2[4];
    __shared__ float mu_s, inv_s;
    int row = blockIdx.x, t = threadIdx.x;
    size_t off = (size_t)row * C_ + t;
    float v = X[off];
    float s = v, s2 = v * v;
#pragma unroll
    for (int o = 32; o > 0; o >>= 1) {
        s += __shfl_down(s, o);
        s2 += __shfl_down(s2, o);
    }
    int w = t >> 6, lane = t & 63;
    if (lane == 0) { rs[w] = s; rs2[w] = s2; }
    __syncthreads();
    if (t == 0) {
        float tot = rs[0] + rs[1] + rs[2] + rs[3];
        float tot2 = rs2[0] + rs2[1] + rs2[2] + rs2[3];
        float mu = tot * (1.f / C_);
        float var = tot2 * (1.f / C_) - mu * mu;
        mu_s = mu;
        inv_s = rsqrtf(var + LN_EPS_);
    }
    __syncthreads();
    Y[off] = (v - mu_s) * inv_s * g[t] + bta[t];
}

// -------- Performer pass 1: ctx[bh,m,d] = kp^T @ v, ksum[bh,m] -------------
__global__ __launch_bounds__(256) void p1_kernel(
    const float* __restrict__ kbuf, const float* __restrict__ vbuf,
    const float* __restrict__ proj, float* __restrict__ ctx,
    float* __restrict__ ksum) {
    int mt = blockIdx.x;
    int bh = blockIdx.y;
    int b = bh >> 2, h = bh & 3;
    __shared__ float Pt[64][65];
    __shared__ float KV[64][65];
    __shared__ float S[64][65];
    int tid = threadIdx.x;
    int tx = tid & 15, ty = tid >> 4;
    for (int idx = tid; idx < 4096; idx += 256) {
        int r = idx >> 6, c = idx & 63;
        int mg = mt * 64 + r;
        Pt[r][c] = (mg < M_) ? proj[mg * DH_ + c] : 0.f;
    }
    float cacc[4][4] = {};
    float ksacc = 0.f;
    size_t base = ((size_t)b * N_) * C_ + h * DH_;
    for (int nt = 0; nt < 8; ++nt) {
        __syncthreads();
        for (int idx = tid; idx < 4096; idx += 256) {
            int r = idx >> 6, c = idx & 63;
            KV[r][c] = kbuf[base + (size_t)(nt * 64 + r) * C_ + c];
        }
        __syncthreads();
        float s[4][4] = {};
        for (int dd = 0; dd < 64; ++dd) {
            float a[4], bq[4];
#pragma unroll
            for (int i = 0; i < 4; ++i) a[i] = KV[ty * 4 + i][dd];
#pragma unroll
            for (int j = 0; j < 4; ++j) bq[j] = Pt[16 * j + tx][dd];
#pragma unroll
            for (int i = 0; i < 4; ++i)
#pragma unroll
                for (int j = 0; j < 4; ++j) s[i][j] = fmaf(a[i], bq[j], s[i][j]);
        }
        __syncthreads();
#pragma unroll
        for (int i = 0; i < 4; ++i)
#pragma unroll
            for (int j = 0; j < 4; ++j) {
                int mg = mt * 64 + 16 * j + tx;
                S[ty * 4 + i][16 * j + tx] =
                    (mg < M_) ? (fmaxf(s[i][j], 0.f) + EPSK_) : 0.f;
            }
        for (int idx = tid; idx < 4096; idx += 256) {
            int r = idx >> 6, c = idx & 63;
            KV[r][c] = vbuf[base + (size_t)(nt * 64 + r) * C_ + c];
        }
        __syncthreads();
        for (int nn = 0; nn < 64; ++nn) {
            float sm[4], vd[4];
#pragma unroll
            for (int i = 0; i < 4; ++i) sm[i] = S[nn][ty * 4 + i];
#pragma unroll
            for (int j = 0; j < 4; ++j) vd[j] = KV[nn][tx * 4 + j];
#pragma unroll
            for (int i = 0; i < 4; ++i)
#pragma unroll
                for (int j = 0; j < 4; ++j) cacc[i][j] = fmaf(sm[i], vd[j], cacc[i][j]);
        }
        if (tid < 64) {
            for (int nn = 0; nn < 64; ++nn) ksacc += S[nn][tid];
        }
    }
    float* cp = ctx + ((size_t)bh * MP_ + mt * 64) * DH_;
#pragma unroll
    for (int i = 0; i < 4; ++i)
#pragma unroll
        for (int j = 0; j < 4; ++j)
            cp[(ty * 4 + i) * DH_ + tx * 4 + j] = cacc[i][j];
    if (tid < 64) ksum[bh * MP_ + mt * 64 + tid] = ksacc;
}

// -------- Performer pass 2: att = (qp @ ctx) * (1/(qp @ ksum)) -------------
__global__ __launch_bounds__(256) void p2_kernel(
    const float* __restrict__ qbuf, const float* __restrict__ proj,
    const float* __restrict__ ctx, const float* __restrict__ ksum,
    float* __restrict__ attout) {
    int nt = blockIdx.x;
    int bh = blockIdx.y;
    int b = bh >> 2, h = bh & 3;
    __shared__ float Qt[64][65];
    __shared__ float PC[64][65];
    __shared__ float S[64][65];
    __shared__ float ks[64], dinv[64];
    int tid = threadIdx.x;
    int tx = tid & 15, ty = tid >> 4;
    size_t base = ((size_t)b * N_) * C_ + h * DH_;
    for (int idx = tid; idx < 4096; idx += 256) {
        int r = idx >> 6, c = idx & 63;
        Qt[r][c] = qbuf[base + (size_t)(nt * 64 + r) * C_ + c];
    }
    float aacc[4][4] = {};
    float dacc = 0.f;
    for (int mt = 0; mt < 5; ++mt) {
        __syncthreads();
        for (int idx = tid; idx < 4096; idx += 256) {
            int r = idx >> 6, c = idx & 63;
            int mg = mt * 64 + r;
            PC[r][c] = (mg < M_) ? proj[mg * DH_ + c] : 0.f;
        }
        if (tid < 64) ks[tid] = ksum[bh * MP_ + mt * 64 + tid];
        __syncthreads();
        float s[4][4] = {};
        for (int dd = 0; dd < 64; ++dd) {
            float a[4], bq[4];
#pragma unroll
            for (int i = 0; i < 4; ++i) a[i] = Qt[ty * 4 + i][dd];
#pragma unroll
            for (int j = 0; j < 4; ++j) bq[j] = PC[16 * j + tx][dd];
#pragma unroll
            for (int i = 0; i < 4; ++i)
#pragma unroll
                for (int j = 0; j < 4; ++j) s[i][j] = fmaf(a[i], bq[j], s[i][j]);
        }
        __syncthreads();
#pragma unroll
        for (int i = 0; i < 4; ++i)
#pragma unroll
            for (int j = 0; j < 4; ++j) {
                int mg = mt * 64 + 16 * j + tx;
                S[ty * 4 + i][16 * j + tx] =
                    (mg < M_) ? (fmaxf(s[i][j], 0.f) + EPSK_) : 0.f;
            }
        for (int idx = tid; idx < 4096; idx += 256) {
            int r = idx >> 6, c = idx & 63;
            PC[r][c] = ctx[((size_t)bh * MP_ + mt * 64 + r) * DH_ + c];
        }
        __syncthreads();
        for (int mm = 0; mm < 64; ++mm) {
            float sm[4], cd[4];
#pragma unroll
            for (int i = 0; i < 4; ++i) sm[i] = S[ty * 4 + i][mm];
#pragma unroll
            for (int j = 0; j < 4; ++j) cd[j] = PC[mm][tx * 4 + j];
#pragma unroll
            for (int i = 0; i < 4; ++i)
#pragma unroll
                for (int j = 0; j < 4; ++j) aacc[i][j] = fmaf(sm[i], cd[j], aacc[i][j]);
        }
        if (tid < 64) {
            for (int mm = 0; mm < 64; ++mm) dacc = fmaf(S[tid][mm], ks[mm], dacc);
        }
    }
    __syncthreads();
    if (tid < 64) dinv[tid] = 1.f / dacc;
    __syncthreads();
#pragma unroll
    for (int i = 0; i < 4; ++i) {
        int n = ty * 4 + i;
        float di = dinv[n];
        float4 y = make_float4(aacc[i][0] * di, aacc[i][1] * di,
                               aacc[i][2] * di, aacc[i][3] * di);
        *(float4*)(attout + base + (size_t)(nt * 64 + n) * C_ + tx * 4) = y;
    }
}

// ------------------------------ mean pool ----------------------------------
__global__ __launch_bounds__(256) void pool_kernel(const float* __restrict__ atoms,
                                                   float* __restrict__ out) {
    int b = blockIdx.x >> 3;
    int chunk = blockIdx.x & 7;
    int c = threadIdx.x;
    const float* p = atoms + ((size_t)(b * N_ + chunk * 64)) * C_ + c;
    float s = 0.f;
    for (int n = 0; n < 64; ++n) s += p[(size_t)n * C_];
    atomicAdd(out + b * C_ + c, s * (1.f / 512.f));
}

extern "C" void kernel_launch(void* const* d_in, const int* in_sizes, int n_in,
                              void* d_out, int out_size, void* d_ws, size_t ws_size,
                              hipStream_t stream) {
    (void)in_sizes; (void)n_in;
    const float* x = (const float*)d_in[0];
    const float* edge_attr = (const float*)d_in[1];
    const int* edge_index = (const int*)d_in[2];
    const float* node_w = (const float*)d_in[4];
    const float* node_b = (const float*)d_in[5];
    const float* edge_w = (const float*)d_in[6];
    const float* edge_b = (const float*)d_in[7];
    const float* gine_w1 = (const float*)d_in[8];
    const float* gine_b1 = (const float*)d_in[9];
    const float* gine_w2 = (const float*)d_in[10];
    const float* gine_b2 = (const float*)d_in[11];
    const float* q_w = (const float*)d_in[12];
    const float* k_w = (const float*)d_in[13];
    const float* v_w = (const float*)d_in[14];
    const float* o_w = (const float*)d_in[15];
    const float* o_b = (const float*)d_in[16];
    const float* proj = (const float*)d_in[17];
    const float* n1g = (const float*)d_in[18];
    const float* n1b = (const float*)d_in[19];
    const float* n2g = (const float*)d_in[20];
    const float* n2b = (const float*)d_in[21];
    const float* n3g = (const float*)d_in[22];
    const float* n3b = (const float*)d_in[23];
    const float* mw1 = (const float*)d_in[24];
    const float* mb1 = (const float*)d_in[25];
    const float* mw2 = (const float*)d_in[26];
    const float* mb2 = (const float*)d_in[27];

    const size_t SZ = (size_t)TN * C_;
    float* ws = (float*)d_ws;
    float* A  = ws;
    float* AG = A + SZ;
    float* T  = AG + SZ;
    float* HL = T + 2 * SZ;
    float* Vb = HL + SZ;
    float* Q  = AG;
    float* Kb = T;
    float* CTX = T + SZ;
    float* KS  = CTX + (size_t)256 * MP_ * DH_;

    int* deg    = (int*)(ws + 6 * SZ);
    int* offs   = deg + TN;
    int* cursor = offs + TN + 1;
    int* esrc   = cursor + TN;
    int* eidl   = esrc + E_;
    short* WT   = (short*)(eidl + E_);
    const size_t W65 = (size_t)5 * 65536;   // per small weight tensor (bf16 elems)
    short* WTg1 = WT;
    short* WTg2 = WTg1 + W65;
    short* WTq  = WTg2 + W65;
    short* WTk  = WTq + W65;
    short* WTv  = WTk + W65;
    short* WTo  = WTv + W65;
    short* WTm1 = WTo + W65;                // 5*131072
    short* WTm2 = WTm1 + (size_t)5 * 131072;
    size_t need = 6 * SZ * sizeof(float) +
                  (size_t)(3 * TN + 1 + 2 * E_) * sizeof(int) +
                  ((size_t)6 * 5 * 65536 + (size_t)2 * 5 * 131072) * sizeof(short);
    bool full = ws_size >= need;

    dim3 gm256(2, 256), gm512(4, 256);   // MFMA 128-tiles
    dim3 g256(4, 512), g512(8, 512);     // fallback fp32 64-tiles

    embed_kernel<<<TN, 256, 0, stream>>>(x, node_w, node_b, A);
    if (full) {
        hipMemsetAsync(deg, 0, TN * sizeof(int), stream);
        count_kernel<<<E_ / 256, 256, 0, stream>>>(edge_index, deg);
        scan_kernel<<<1, 1024, 0, stream>>>(deg, offs, cursor);
        fill_kernel<<<E_ / 256, 256, 0, stream>>>(edge_index, cursor, esrc, eidl);
        wt_kernel<<<dim3(4, 4, L_), 256, 0, stream>>>(gine_w1, WTg1, 256, 256);
        wt_kernel<<<dim3(4, 4, L_), 256, 0, stream>>>(gine_w2, WTg2, 256, 256);
        wt_kernel<<<dim3(4, 4, L_), 256, 0, stream>>>(q_w, WTq, 256, 256);
        wt_kernel<<<dim3(4, 4, L_), 256, 0, stream>>>(k_w, WTk, 256, 256);
        wt_kernel<<<dim3(4, 4, L_), 256, 0, stream>>>(v_w, WTv, 256, 256);
        wt_kernel<<<dim3(4, 4, L_), 256, 0, stream>>>(o_w, WTo, 256, 256);
        wt_kernel<<<dim3(8, 4, L_), 256, 0, stream>>>(mw1, WTm1, 256, 512);
        wt_kernel<<<dim3(4, 8, L_), 256, 0, stream>>>(mw2, WTm2, 512, 256);
    }
    for (int l = 0; l < L_; ++l) {
        if (full) {
            gather_kernel<<<TN, 256, 0, stream>>>(A, edge_attr, offs, esrc, eidl,
                                                  edge_w, edge_b, AG);
            mfmm_kernel<true, 1><<<gm256, 256, 0, stream>>>(
                A, AG, WTg1 + (size_t)l * 65536, gine_b1 + l * 256,
                nullptr, nullptr, T, 256, 256);
            mfmm_kernel<false, 2><<<gm256, 256, 0, stream>>>(
                T, nullptr, WTg2 + (size_t)l * 65536, gine_b2 + l * 256,
                A, nullptr, HL, 256, 256);
            ln_kernel<<<TN, 256, 0, stream>>>(HL, n1g + l * 256, n1b + l * 256, HL);
            mfmm_kernel<false, 0><<<gm256, 256, 0, stream>>>(
                A, nullptr, WTq + (size_t)l * 65536, nullptr, nullptr, nullptr,
                Q, 256, 256);
            mfmm_kernel<false, 0><<<gm256, 256, 0, stream>>>(
                A, nullptr, WTk + (size_t)l * 65536, nullptr, nullptr, nullptr,
                Kb, 256, 256);
            mfmm_kernel<false, 0><<<gm256, 256, 0, stream>>>(
                A, nullptr, WTv + (size_t)l * 65536, nullptr, nullptr, nullptr,
                Vb, 256, 256);
            p1_kernel<<<dim3(5, 256), 256, 0, stream>>>(Kb, Vb, proj + l * (M_ * DH_),
                                                        CTX, KS);
            p2_kernel<<<dim3(8, 256), 256, 0, stream>>>(Q, proj + l * (M_ * DH_),
                                                        CTX, KS, Kb);
            mfmm_kernel<false, 2><<<gm256, 256, 0, stream>>>(
                Kb, nullptr, WTo + (size_t)l * 65536, o_b + l * 256,
                A, nullptr, Q, 256, 256);
            ln_kernel<<<TN, 256, 0, stream>>>(Q, n2g + l * 256, n2b + l * 256, Q);
            mfmm_kernel<true, 1><<<gm512, 256, 0, stream>>>(
                HL, Q, WTm1 + (size_t)l * 131072, mb1 + l * 512,
                nullptr, nullptr, T, 256, 512);
            mfmm_kernel<false, 3><<<gm256, 256, 0, stream>>>(
                T, nullptr, WTm2 + (size_t)l * 131072, mb2 + l * 256,
                HL, Q, Vb, 512, 256);
            ln_kernel<<<TN, 256, 0, stream>>>(Vb, n3g + l * 256, n3b + l * 256, A);
        } else {
            hipMemsetAsync(AG, 0, SZ * sizeof(float), stream);
            scatter_kernel<<<E_ * 64 / 256, 256, 0, stream>>>(A, edge_attr, edge_index,
                                                              edge_w, edge_b, AG);
            mm_kernel<true, 1><<<g256, 256, 0, stream>>>(A, AG, gine_w1 + l * 65536,
                                                         gine_b1 + l * 256, nullptr,
                                                         nullptr, T, 256, 256);
            mm_kernel<false, 2><<<g256, 256, 0, stream>>>(T, nullptr, gine_w2 + l * 65536,
                                                          gine_b2 + l * 256, A, nullptr,
                                                          HL, 256, 256);
            ln_kernel<<<TN, 256, 0, stream>>>(HL, n1g + l * 256, n1b + l * 256, HL);
            mm_kernel<false, 0><<<g256, 256, 0, stream>>>(A, nullptr, q_w + l * 65536,
                                                          nullptr, nullptr, nullptr,
                                                          Q, 256, 256);
            mm_kernel<false, 0><<<g256, 256, 0, stream>>>(A, nullptr, k_w + l * 65536,
                                                          nullptr, nullptr, nullptr,
                                                          Kb, 256, 256);
            mm_kernel<false, 0><<<g256, 256, 0, stream>>>(A, nullptr, v_w + l * 65536,
                                                          nullptr, nullptr, nullptr,
                                                          Vb, 256, 256);
            p1_kernel<<<dim3(5, 256), 256, 0, stream>>>(Kb, Vb, proj + l * (M_ * DH_),
                                                        CTX, KS);
            p2_kernel<<<dim3(8, 256), 256, 0, stream>>>(Q, proj + l * (M_ * DH_),
                                                        CTX, KS, Kb);
            mm_kernel<false, 2><<<g256, 256, 0, stream>>>(Kb, nullptr, o_w + l * 65536,
                                                          o_b + l * 256, A, nullptr,
                                                          Q, 256, 256);
            ln_kernel<<<TN, 256, 0, stream>>>(Q, n2g + l * 256, n2b + l * 256, Q);
            mm_kernel<true, 1><<<g512, 256, 0, stream>>>(HL, Q, mw1 + l * 131072,
                                                         mb1 + l * 512, nullptr, nullptr,
                                                         T, 256, 512);
            mm_kernel<false, 3><<<g256, 256, 0, stream>>>(T, nullptr, mw2 + l * 131072,
                                                          mb2 + l * 256, HL, Q,
                                                          Vb, 512, 256);
            ln_kernel<<<TN, 256, 0, stream>>>(Vb, n3g + l * 256, n3b + l * 256, A);
        }
    }
    hipMemsetAsync(d_out, 0, (size_t)out_size * sizeof(float), stream);
    pool_kernel<<<512, 256, 0, stream>>>(A, (float*)d_out);
}

// Round 4
// 2587.371 us; speedup vs baseline: 5.8563x; 1.7536x over previous
//
#include <hip/hip_runtime.h>
#include <math.h>

#define TN 32768
#define C_ 256
#define E_ 524288
#define B_ 64
#define N_ 512
#define H_ 4
#define DH_ 64
#define M_ 266
#define MP_ 320
#define L_ 5
#define LN_EPS_ 1e-5f
#define EPSK_ 1e-3f

typedef short short8 __attribute__((ext_vector_type(8)));
typedef short short4v __attribute__((ext_vector_type(4)));
typedef float floatx4 __attribute__((ext_vector_type(4)));

__device__ __forceinline__ float gelu_exact(float v) {
    return 0.5f * v * (1.0f + erff(v * 0.70710678118654752f));
}

__device__ __forceinline__ short f2bf(float f) {
    union { float f; unsigned u; } v; v.f = f;
    unsigned r = v.u + 0x7FFF + ((v.u >> 16) & 1);
    return (short)(r >> 16);
}

__device__ __forceinline__ float bf2f(short s) {
    union { unsigned u; float f; } v;
    v.u = ((unsigned)(unsigned short)s) << 16;
    return v.f;
}

// ---------------- embed: atoms = log(x+1) @ node_w + node_b ----------------
__global__ __launch_bounds__(256) void embed_kernel(
    const float* __restrict__ x, const float* __restrict__ nw,
    const float* __restrict__ nb, float* __restrict__ atoms) {
    int node = blockIdx.x;
    int c = threadIdx.x;
    __shared__ float lx[11];
    if (c < 11) lx[c] = logf(x[node * 11 + c] + 1.0f);
    __syncthreads();
    float acc = nb[c];
#pragma unroll
    for (int j = 0; j < 11; ++j) acc = fmaf(lx[j], nw[j * C_ + c], acc);
    atoms[(size_t)node * C_ + c] = acc;
}

// ----------------------- CSR build: count / scan / fill --------------------
__global__ __launch_bounds__(256) void count_kernel(const int* __restrict__ eidx,
                                                    int* __restrict__ deg) {
    int e = blockIdx.x * 256 + threadIdx.x;
    atomicAdd(&deg[eidx[E_ + e]], 1);
}

__global__ __launch_bounds__(1024) void scan_kernel(const int* __restrict__ deg,
                                                    int* __restrict__ offs,
                                                    int* __restrict__ cursor) {
    __shared__ int tsum[1024];
    int t = threadIdx.x;
    int base = t * 32;
    int local[32];
    int s = 0;
#pragma unroll
    for (int i = 0; i < 32; ++i) { local[i] = deg[base + i]; s += local[i]; }
    tsum[t] = s;
    __syncthreads();
    for (int off = 1; off < 1024; off <<= 1) {
        int v = tsum[t];
        int add = (t >= off) ? tsum[t - off] : 0;
        __syncthreads();
        tsum[t] = v + add;
        __syncthreads();
    }
    int run = tsum[t] - s;
#pragma unroll
    for (int i = 0; i < 32; ++i) {
        offs[base + i] = run;
        cursor[base + i] = run;
        run += local[i];
    }
    if (t == 1023) offs[TN] = run;
}

__global__ __launch_bounds__(256) void fill_kernel(const int* __restrict__ eidx,
                                                   int* __restrict__ cursor,
                                                   int* __restrict__ esrc,
                                                   int* __restrict__ eidl) {
    int e = blockIdx.x * 256 + threadIdx.x;
    int d = eidx[E_ + e];
    int pos = atomicAdd(&cursor[d], 1);
    esrc[pos] = eidx[e];
    eidl[pos] = e;
}

// ------------- GINE message + gather (atomic-free, ea fused) ---------------
__global__ __launch_bounds__(256) void gather_kernel(
    const float* __restrict__ atoms, const float* __restrict__ eattr,
    const int* __restrict__ offs, const int* __restrict__ esrc,
    const int* __restrict__ eidl, const float* __restrict__ ew,
    const float* __restrict__ eb, float* __restrict__ aggr) {
    int node = blockIdx.x;
    int c = threadIdx.x;
    __shared__ int s_src[64];
    __shared__ float4 s_ea[64];
    int start = offs[node];
    int cnt = offs[node + 1] - start;
    float w0 = ew[c], w1 = ew[C_ + c], w2 = ew[2 * C_ + c], w3 = ew[3 * C_ + c];
    float bb = eb[c];
    float acc = 0.f;
    for (int baseI = 0; baseI < cnt; baseI += 64) {
        int nb = min(64, cnt - baseI);
        if (c < nb) {
            s_src[c] = esrc[start + baseI + c];
            int e = eidl[start + baseI + c];
            s_ea[c] = *(const float4*)(eattr + (size_t)e * 4);
        }
        __syncthreads();
        for (int i = 0; i < nb; ++i) {
            float4 ea = s_ea[i];
            float m = atoms[(size_t)s_src[i] * C_ + c] + bb +
                      ea.x * w0 + ea.y * w1 + ea.z * w2 + ea.w * w3;
            acc += fmaxf(m, 0.f);
        }
        __syncthreads();
    }
    aggr[(size_t)node * C_ + c] = acc;
}

// ------------- fallback: atomic scatter (if ws too small) ------------------
__global__ __launch_bounds__(256) void scatter_kernel(
    const float* __restrict__ atoms, const float* __restrict__ eattr,
    const int* __restrict__ eidx, const float* __restrict__ ew,
    const float* __restrict__ eb, float* __restrict__ aggr) {
    int gid = blockIdx.x * 256 + threadIdx.x;
    int e = gid >> 6;
    int q = (gid & 63) << 2;
    int src = eidx[e];
    int dst = eidx[E_ + e];
    float4 ea = *(const float4*)(eattr + (size_t)e * 4);
    float4 w0 = *(const float4*)(ew + 0 * C_ + q);
    float4 w1 = *(const float4*)(ew + 1 * C_ + q);
    float4 w2 = *(const float4*)(ew + 2 * C_ + q);
    float4 w3 = *(const float4*)(ew + 3 * C_ + q);
    float4 bb = *(const float4*)(eb + q);
    float4 av = *(const float4*)(atoms + (size_t)src * C_ + q);
    float m0 = av.x + bb.x + ea.x * w0.x + ea.y * w1.x + ea.z * w2.x + ea.w * w3.x;
    float m1 = av.y + bb.y + ea.x * w0.y + ea.y * w1.y + ea.z * w2.y + ea.w * w3.y;
    float m2 = av.z + bb.z + ea.x * w0.z + ea.y * w1.z + ea.z * w2.z + ea.w * w3.z;
    float m3 = av.w + bb.w + ea.x * w0.w + ea.y * w1.w + ea.z * w2.w + ea.w * w3.w;
    float* base = aggr + (size_t)dst * C_ + q;
    atomicAdd(base + 0, fmaxf(m0, 0.f));
    atomicAdd(base + 1, fmaxf(m1, 0.f));
    atomicAdd(base + 2, fmaxf(m2, 0.f));
    atomicAdd(base + 3, fmaxf(m3, 0.f));
}

// ------------ weight transpose+cast: Wt[n][k] bf16 from W[k][n] fp32 -------
__global__ __launch_bounds__(256) void wt_kernel(const float* __restrict__ W,
                                                 short* __restrict__ Wt,
                                                 int K, int NC) {
    __shared__ short tile[64][65];
    int l = blockIdx.z;
    int k0 = blockIdx.y * 64, n0 = blockIdx.x * 64;
    const float* Wl = W + (size_t)l * K * NC;
    short* Wtl = Wt + (size_t)l * K * NC;
    int t = threadIdx.x;
    int rr = t >> 4;
    int cc = (t & 15) * 4;
#pragma unroll
    for (int rep = 0; rep < 4; ++rep) {
        int r = rr + rep * 16;
        float4 v = *(const float4*)(Wl + (size_t)(k0 + r) * NC + n0 + cc);
        tile[cc + 0][r] = f2bf(v.x);
        tile[cc + 1][r] = f2bf(v.y);
        tile[cc + 2][r] = f2bf(v.z);
        tile[cc + 3][r] = f2bf(v.w);
    }
    __syncthreads();
#pragma unroll
    for (int rep = 0; rep < 4; ++rep) {
        int r = rr + rep * 16;
        short4v s;
        s.x = tile[r][cc + 0];
        s.y = tile[r][cc + 1];
        s.z = tile[r][cc + 2];
        s.w = tile[r][cc + 3];
        *(short4v*)(Wtl + (size_t)(n0 + r) * K + k0 + cc) = s;
    }
}

// ---------- proj cast: Pbf[l][m][d] bf16, padded to MP_ with zeros ---------
__global__ __launch_bounds__(256) void pcast_kernel(const float* __restrict__ proj,
                                                    short* __restrict__ Pbf) {
    int l = blockIdx.x;
    for (int idx = threadIdx.x; idx < MP_ * 64; idx += 256) {
        int m = idx >> 6, d = idx & 63;
        float v = (m < M_) ? proj[(size_t)l * M_ * 64 + m * 64 + d] : 0.f;
        Pbf[(size_t)l * MP_ * 64 + idx] = f2bf(v);
    }
}

// ---------------- MFMA bf16 matmul: Y = X @ W (+epilogue) ------------------
// Wt pre-transposed bf16 [NC][K]. 128x128 tile, 4 waves, 4x4 frags each.
// EPI: 0=none, 1=gelu, 2=+R1, 3=+R1+R2.  IN_ADD: X := X + X2 on load.
// OUT: 0=fp32 row-major, 1=bf16 row-major, 2=bf16 per-head transposed [bh][d][n]
template <bool IN_ADD, int EPI, int OUT>
__global__ __launch_bounds__(256) void mfmm_kernel(
    const float* __restrict__ X, const float* __restrict__ X2,
    const short* __restrict__ Wt, const float* __restrict__ bias,
    const float* __restrict__ R1, const float* __restrict__ R2,
    void* __restrict__ Yout, int K, int NC) {
    __shared__ short As[128][56];
    __shared__ short Bs[128][56];
    int tid = threadIdx.x;
    int rowBase = blockIdx.y * 128, colBase = blockIdx.x * 128;
    int w = tid >> 6, lane = tid & 63;
    int wm = w & 1, wn = w >> 1;
    int quad = lane >> 4, l16 = lane & 15;
    int sr = tid >> 1;
    int sk = (tid & 1) * 16;
    const float* Xp = X + (size_t)(rowBase + sr) * K + sk;
    const float* X2p = IN_ADD ? (X2 + (size_t)(rowBase + sr) * K + sk) : X;
    const short* Wp = Wt + (size_t)(colBase + sr) * K + sk;
    floatx4 acc[4][4];
#pragma unroll
    for (int i = 0; i < 4; ++i)
#pragma unroll
        for (int j = 0; j < 4; ++j)
            acc[i][j] = (floatx4){0.f, 0.f, 0.f, 0.f};
    for (int k0 = 0; k0 < K; k0 += 32) {
        float4 x0 = *(const float4*)(Xp + k0);
        float4 x1 = *(const float4*)(Xp + k0 + 4);
        float4 x2 = *(const float4*)(Xp + k0 + 8);
        float4 x3 = *(const float4*)(Xp + k0 + 12);
        if (IN_ADD) {
            float4 y0 = *(const float4*)(X2p + k0);
            float4 y1 = *(const float4*)(X2p + k0 + 4);
            float4 y2 = *(const float4*)(X2p + k0 + 8);
            float4 y3 = *(const float4*)(X2p + k0 + 12);
            x0.x += y0.x; x0.y += y0.y; x0.z += y0.z; x0.w += y0.w;
            x1.x += y1.x; x1.y += y1.y; x1.z += y1.z; x1.w += y1.w;
            x2.x += y2.x; x2.y += y2.y; x2.z += y2.z; x2.w += y2.w;
            x3.x += y3.x; x3.y += y3.y; x3.z += y3.z; x3.w += y3.w;
        }
        uint4 wv0 = *(const uint4*)(Wp + k0);
        uint4 wv1 = *(const uint4*)(Wp + k0 + 8);
        short8 s0, s1;
        s0[0] = f2bf(x0.x); s0[1] = f2bf(x0.y); s0[2] = f2bf(x0.z); s0[3] = f2bf(x0.w);
        s0[4] = f2bf(x1.x); s0[5] = f2bf(x1.y); s0[6] = f2bf(x1.z); s0[7] = f2bf(x1.w);
        s1[0] = f2bf(x2.x); s1[1] = f2bf(x2.y); s1[2] = f2bf(x2.z); s1[3] = f2bf(x2.w);
        s1[4] = f2bf(x3.x); s1[5] = f2bf(x3.y); s1[6] = f2bf(x3.z); s1[7] = f2bf(x3.w);
        __syncthreads();
        *(short8*)&As[sr][sk] = s0;
        *(short8*)&As[sr][sk + 8] = s1;
        *(uint4*)&Bs[sr][sk] = wv0;
        *(uint4*)&Bs[sr][sk + 8] = wv1;
        __syncthreads();
        short8 a[4], b[4];
#pragma unroll
        for (int mi = 0; mi < 4; ++mi)
            a[mi] = *(const short8*)&As[wm * 64 + mi * 16 + l16][quad * 8];
#pragma unroll
        for (int ni = 0; ni < 4; ++ni)
            b[ni] = *(const short8*)&Bs[wn * 64 + ni * 16 + l16][quad * 8];
#pragma unroll
        for (int mi = 0; mi < 4; ++mi)
#pragma unroll
            for (int ni = 0; ni < 4; ++ni)
                acc[mi][ni] = __builtin_amdgcn_mfma_f32_16x16x32_bf16(
                    a[mi], b[ni], acc[mi][ni], 0, 0, 0);
    }
    if (OUT == 0) {
        float* Y = (float*)Yout;
#pragma unroll
        for (int ni = 0; ni < 4; ++ni) {
            int colg = colBase + wn * 64 + ni * 16 + l16;
            float bv = bias ? bias[colg] : 0.f;
#pragma unroll
            for (int mi = 0; mi < 4; ++mi) {
#pragma unroll
                for (int r = 0; r < 4; ++r) {
                    int rowg = rowBase + wm * 64 + mi * 16 + quad * 4 + r;
                    float y = acc[mi][ni][r] + bv;
                    if (EPI == 1) y = gelu_exact(y);
                    if (EPI >= 2) y += R1[(size_t)rowg * NC + colg];
                    if (EPI == 3) y += R2[(size_t)rowg * NC + colg];
                    Y[(size_t)rowg * NC + colg] = y;
                }
            }
        }
    } else if (OUT == 1) {
        short* Yb = (short*)Yout;
#pragma unroll
        for (int ni = 0; ni < 4; ++ni) {
            int colg = colBase + wn * 64 + ni * 16 + l16;
#pragma unroll
            for (int mi = 0; mi < 4; ++mi) {
#pragma unroll
                for (int r = 0; r < 4; ++r) {
                    int rowg = rowBase + wm * 64 + mi * 16 + quad * 4 + r;
                    Yb[(size_t)rowg * NC + colg] = f2bf(acc[mi][ni][r]);
                }
            }
        }
    } else {  // OUT == 2: V transposed per-head  VbfT[((b*4+h)*64+d)*512 + n]
        short* Yb = (short*)Yout;
#pragma unroll
        for (int ni = 0; ni < 4; ++ni) {
            int colg = colBase + wn * 64 + ni * 16 + l16;
            int hh = colg >> 6, dd = colg & 63;
#pragma unroll
            for (int mi = 0; mi < 4; ++mi) {
                int rowg0 = rowBase + wm * 64 + mi * 16 + quad * 4;
                int bb = rowg0 >> 9, ng = rowg0 & 511;
                short4v pv;
#pragma unroll
                for (int r = 0; r < 4; ++r) pv[r] = f2bf(acc[mi][ni][r]);
                *(short4v*)(Yb + (((size_t)bb * 4 + hh) * 64 + dd) * 512 + ng) = pv;
            }
        }
    }
}

// ------------- fallback fp32 tiled matmul (old path) -----------------------
template <bool IN_ADD, int EPI>
__global__ __launch_bounds__(256) void mm_kernel(
    const float* __restrict__ X, const float* __restrict__ X2,
    const float* __restrict__ W, const float* __restrict__ bias,
    const float* __restrict__ R1, const float* __restrict__ R2,
    float* __restrict__ Y, int K, int NC) {
    __shared__ float Xs[16][65];
    __shared__ float Ws[16][68];
    int tid = threadIdx.x;
    int tx = tid & 15, ty = tid >> 4;
    int rowBase = blockIdx.y * 64;
    int colBase = blockIdx.x * 64;
    int lr = tid >> 2;
    int lk = (tid & 3) << 2;
    int wk = tid >> 4;
    int wc = (tid & 15) << 2;
    const float* Xp = X + (size_t)(rowBase + lr) * K + lk;
    const float* X2p = IN_ADD ? (X2 + (size_t)(rowBase + lr) * K + lk) : X;
    const float* Wp = W + (size_t)wk * NC + colBase + wc;
    float acc[4][4] = {};
    for (int k0 = 0; k0 < K; k0 += 16) {
        float4 xv = *(const float4*)(Xp + k0);
        if (IN_ADD) {
            float4 x2 = *(const float4*)(X2p + k0);
            xv.x += x2.x; xv.y += x2.y; xv.z += x2.z; xv.w += x2.w;
        }
        float4 wv = *(const float4*)(Wp + (size_t)k0 * NC);
        __syncthreads();
        Xs[lk + 0][lr] = xv.x;
        Xs[lk + 1][lr] = xv.y;
        Xs[lk + 2][lr] = xv.z;
        Xs[lk + 3][lr] = xv.w;
        *(float4*)&Ws[wk][wc] = wv;
        __syncthreads();
#pragma unroll
        for (int kk = 0; kk < 16; ++kk) {
            float a[4], b[4];
#pragma unroll
            for (int i = 0; i < 4; ++i) a[i] = Xs[kk][ty * 4 + i];
#pragma unroll
            for (int j = 0; j < 4; ++j) b[j] = Ws[kk][tx * 4 + j];
#pragma unroll
            for (int i = 0; i < 4; ++i)
#pragma unroll
                for (int j = 0; j < 4; ++j) acc[i][j] = fmaf(a[i], b[j], acc[i][j]);
        }
    }
    int c0 = colBase + tx * 4;
    float4 bv = make_float4(0.f, 0.f, 0.f, 0.f);
    if (bias) bv = *(const float4*)(bias + c0);
#pragma unroll
    for (int i = 0; i < 4; ++i) {
        int r = rowBase + ty * 4 + i;
        float4 y;
        y.x = acc[i][0] + bv.x; y.y = acc[i][1] + bv.y;
        y.z = acc[i][2] + bv.z; y.w = acc[i][3] + bv.w;
        if (EPI == 1) {
            y.x = gelu_exact(y.x); y.y = gelu_exact(y.y);
            y.z = gelu_exact(y.z); y.w = gelu_exact(y.w);
        }
        if (EPI >= 2) {
            float4 r1 = *(const float4*)(R1 + (size_t)r * NC + c0);
            y.x += r1.x; y.y += r1.y; y.z += r1.z; y.w += r1.w;
        }
        if (EPI == 3) {
            float4 r2 = *(const float4*)(R2 + (size_t)r * NC + c0);
            y.x += r2.x; y.y += r2.y; y.z += r2.z; y.w += r2.w;
        }
        *(float4*)(Y + (size_t)r * NC + c0) = y;
    }
}

// ------------------------------ LayerNorm ----------------------------------
__global__ __launch_bounds__(256) void ln_kernel(
    const float* __restrict__ X, const float* __restrict__ g,
    const float* __restrict__ bta, float* __restrict__ Y) {
    __shared__ float rs[4], rs2[4];
    __shared__ float mu_s, inv_s;
    int row = blockIdx.x, t = threadIdx.x;
    size_t off = (size_t)row * C_ + t;
    float v = X[off];
    float s = v, s2 = v * v;
#pragma unroll
    for (int o = 32; o > 0; o >>= 1) {
        s += __shfl_down(s, o);
        s2 += __shfl_down(s2, o);
    }
    int w = t >> 6, lane = t & 63;
    if (lane == 0) { rs[w] = s; rs2[w] = s2; }
    __syncthreads();
    if (t == 0) {
        float tot = rs[0] + rs[1] + rs[2] + rs[3];
        float tot2 = rs2[0] + rs2[1] + rs2[2] + rs2[3];
        float mu = tot * (1.f / C_);
        float var = tot2 * (1.f / C_) - mu * mu;
        mu_s = mu;
        inv_s = rsqrtf(var + LN_EPS_);
    }
    __syncthreads();
    Y[off] = (v - mu_s) * inv_s * g[t] + bta[t];
}

// ---------- MFMA Performer pass 1: ctxT[bh][d][m], ksum[bh][m] -------------
// Kbf row-major bf16 [node][C_]; VbfT [bh][d][n] bf16; Pbf [m][d] bf16 (padded).
__global__ __launch_bounds__(256) void p1m_kernel(
    const short* __restrict__ Kbf, const short* __restrict__ VbfT,
    const short* __restrict__ Pbf, short* __restrict__ ctxT,
    float* __restrict__ ksum) {
    int mt = blockIdx.x;   // 0..4
    int bh = blockIdx.y;   // 0..255
    int b = bh >> 2, h = bh & 3;
    __shared__ short Ps[64][72];
    __shared__ short Ks[64][72];
    __shared__ short VTs[64][72];
    __shared__ short Ss[64][72];   // [m][n]
    __shared__ float kred[4][64];
    int tid = threadIdx.x;
    int w = tid >> 6, lane = tid & 63;
    int quad = lane >> 4, l16 = lane & 15;
    int lr = tid >> 2, lb = (tid & 3) << 4;
    {
        const short* p = Pbf + ((size_t)(mt * 64 + lr)) * 64 + lb;
        *(short8*)&Ps[lr][lb] = *(const short8*)p;
        *(short8*)&Ps[lr][lb + 8] = *(const short8*)(p + 8);
    }
    floatx4 cacc[4];
#pragma unroll
    for (int i = 0; i < 4; ++i) cacc[i] = (floatx4){0.f, 0.f, 0.f, 0.f};
    float kacc[4] = {0.f, 0.f, 0.f, 0.f};
    size_t kbase = ((size_t)(b * 512)) * 256 + h * 64;
    size_t vbase = ((size_t)(bh * 64)) * 512;
    for (int nt = 0; nt < 8; ++nt) {
        __syncthreads();
        {
            const short* kp = Kbf + kbase + (size_t)(nt * 64 + lr) * 256 + lb;
            *(short8*)&Ks[lr][lb] = *(const short8*)kp;
            *(short8*)&Ks[lr][lb + 8] = *(const short8*)(kp + 8);
            const short* vp = VbfT + vbase + (size_t)lr * 512 + nt * 64 + lb;
            *(short8*)&VTs[lr][lb] = *(const short8*)vp;
            *(short8*)&VTs[lr][lb + 8] = *(const short8*)(vp + 8);
        }
        __syncthreads();
        // stage A: S = K·P^T, rows n in wave band, cols m
        floatx4 sa[4];
#pragma unroll
        for (int mi = 0; mi < 4; ++mi) sa[mi] = (floatx4){0.f, 0.f, 0.f, 0.f};
#pragma unroll
        for (int kt = 0; kt < 2; ++kt) {
            short8 a = *(const short8*)&Ks[w * 16 + l16][kt * 32 + quad * 8];
#pragma unroll
            for (int mi = 0; mi < 4; ++mi) {
                short8 bq = *(const short8*)&Ps[mi * 16 + l16][kt * 32 + quad * 8];
                sa[mi] = __builtin_amdgcn_mfma_f32_16x16x32_bf16(a, bq, sa[mi], 0, 0, 0);
            }
        }
#pragma unroll
        for (int mi = 0; mi < 4; ++mi) {
            int mg = mt * 64 + mi * 16 + l16;
            short4v sv;
            float kl = 0.f;
#pragma unroll
            for (int r = 0; r < 4; ++r) {
                float v = (mg < M_) ? (fmaxf(sa[mi][r], 0.f) + EPSK_) : 0.f;
                sv[r] = f2bf(v);
                kl += v;
            }
            kacc[mi] += kl;
            *(short4v*)&Ss[mi * 16 + l16][w * 16 + quad * 4] = sv;
        }
        __syncthreads();
        // stage B: ctx += S^T·V, rows m in wave band, cols d
#pragma unroll
        for (int kt = 0; kt < 2; ++kt) {
            short8 a = *(const short8*)&Ss[w * 16 + l16][kt * 32 + quad * 8];
#pragma unroll
            for (int di = 0; di < 4; ++di) {
                short8 bv = *(const short8*)&VTs[di * 16 + l16][kt * 32 + quad * 8];
                cacc[di] = __builtin_amdgcn_mfma_f32_16x16x32_bf16(a, bv, cacc[di], 0, 0, 0);
            }
        }
    }
    // write ctxT[bh][d][mt*64 + m] bf16
    size_t cbase = ((size_t)bh * 64) * MP_ + mt * 64;
#pragma unroll
    for (int di = 0; di < 4; ++di) {
        int d = di * 16 + l16;
        short4v cv;
#pragma unroll
        for (int r = 0; r < 4; ++r) cv[r] = f2bf(cacc[di][r]);
        *(short4v*)(ctxT + cbase + (size_t)d * MP_ + w * 16 + quad * 4) = cv;
    }
    // ksum: reduce across quads then waves
#pragma unroll
    for (int mi = 0; mi < 4; ++mi) {
        kacc[mi] += __shfl_down(kacc[mi], 32);
        kacc[mi] += __shfl_down(kacc[mi], 16);
    }
    if (lane < 16) {
#pragma unroll
        for (int mi = 0; mi < 4; ++mi) kred[w][mi * 16 + lane] = kacc[mi];
    }
    __syncthreads();
    if (tid < 64)
        ksum[(size_t)bh * MP_ + mt * 64 + tid] =
            kred[0][tid] + kred[1][tid] + kred[2][tid] + kred[3][tid];
}

// ---------- MFMA Performer pass 2: att = (qp@ctx) * 1/(qp@ksum) ------------
__global__ __launch_bounds__(256) void p2m_kernel(
    const short* __restrict__ Qbf, const short* __restrict__ Pbf,
    const short* __restrict__ ctxT, const float* __restrict__ ksum,
    float* __restrict__ att) {
    int nt = blockIdx.x;   // 0..7
    int bh = blockIdx.y;   // 0..255
    int b = bh >> 2, h = bh & 3;
    __shared__ short Qs[64][72];
    __shared__ short Ps[64][72];
    __shared__ short CTs[64][72];  // [d][m]
    __shared__ short Ss[64][72];   // [n][m]
    __shared__ float kss[64];
    __shared__ float dredS[64];
    __shared__ float dinvS[64];
    int tid = threadIdx.x;
    int w = tid >> 6, lane = tid & 63;
    int quad = lane >> 4, l16 = lane & 15;
    int lr = tid >> 2, lb = (tid & 3) << 4;
    size_t qbase = ((size_t)(b * 512)) * 256 + h * 64;
    {
        const short* qp = Qbf + qbase + (size_t)(nt * 64 + lr) * 256 + lb;
        *(short8*)&Qs[lr][lb] = *(const short8*)qp;
        *(short8*)&Qs[lr][lb + 8] = *(const short8*)(qp + 8);
    }
    floatx4 aacc[4];
#pragma unroll
    for (int i = 0; i < 4; ++i) aacc[i] = (floatx4){0.f, 0.f, 0.f, 0.f};
    float dd[4] = {0.f, 0.f, 0.f, 0.f};
    size_t cb = ((size_t)bh * 64) * MP_;
    for (int mt = 0; mt < 5; ++mt) {
        __syncthreads();
        {
            const short* p = Pbf + ((size_t)(mt * 64 + lr)) * 64 + lb;
            *(short8*)&Ps[lr][lb] = *(const short8*)p;
            *(short8*)&Ps[lr][lb + 8] = *(const short8*)(p + 8);
            const short* cp = ctxT + cb + (size_t)lr * MP_ + mt * 64 + lb;
            *(short8*)&CTs[lr][lb] = *(const short8*)cp;
            *(short8*)&CTs[lr][lb + 8] = *(const short8*)(cp + 8);
        }
        if (tid < 64) kss[tid] = ksum[(size_t)bh * MP_ + mt * 64 + tid];
        __syncthreads();
        // stage A: S = Q·P^T
        floatx4 sa[4];
#pragma unroll
        for (int mi = 0; mi < 4; ++mi) sa[mi] = (floatx4){0.f, 0.f, 0.f, 0.f};
#pragma unroll
        for (int kt = 0; kt < 2; ++kt) {
            short8 a = *(const short8*)&Qs[w * 16 + l16][kt * 32 + quad * 8];
#pragma unroll
            for (int mi = 0; mi < 4; ++mi) {
                short8 bq = *(const short8*)&Ps[mi * 16 + l16][kt * 32 + quad * 8];
                sa[mi] = __builtin_amdgcn_mfma_f32_16x16x32_bf16(a, bq, sa[mi], 0, 0, 0);
            }
        }
#pragma unroll
        for (int mi = 0; mi < 4; ++mi) {
            int mg = mt * 64 + mi * 16 + l16;
            float ksv = kss[mi * 16 + l16];
#pragma unroll
            for (int r = 0; r < 4; ++r) {
                float v = (mg < M_) ? (fmaxf(sa[mi][r], 0.f) + EPSK_) : 0.f;
                Ss[w * 16 + quad * 4 + r][mi * 16 + l16] = f2bf(v);
                dd[r] += v * ksv;
            }
        }
        __syncthreads();
        // stage B: att += S·ctx, rows n band, cols d
#pragma unroll
        for (int kt = 0; kt < 2; ++kt) {
            short8 a = *(const short8*)&Ss[w * 16 + l16][kt * 32 + quad * 8];
#pragma unroll
            for (int di = 0; di < 4; ++di) {
                short8 bv = *(const short8*)&CTs[di * 16 + l16][kt * 32 + quad * 8];
                aacc[di] = __builtin_amdgcn_mfma_f32_16x16x32_bf16(a, bv, aacc[di], 0, 0, 0);
            }
        }
    }
    // denominator: reduce dd across the 16 l16 lanes of each quad
#pragma unroll
    for (int r = 0; r < 4; ++r) {
        dd[r] += __shfl_xor(dd[r], 1);
        dd[r] += __shfl_xor(dd[r], 2);
        dd[r] += __shfl_xor(dd[r], 4);
        dd[r] += __shfl_xor(dd[r], 8);
    }
    if (l16 == 0) {
#pragma unroll
        for (int r = 0; r < 4; ++r) dredS[w * 16 + quad * 4 + r] = dd[r];
    }
    __syncthreads();
    if (tid < 64) dinvS[tid] = 1.f / dredS[tid];
    __syncthreads();
#pragma unroll
    for (int di = 0; di < 4; ++di) {
        int d = di * 16 + l16;
#pragma unroll
        for (int r = 0; r < 4; ++r) {
            int n = w * 16 + quad * 4 + r;
            att[((size_t)(b * 512 + nt * 64 + n)) * 256 + h * 64 + d] =
                aacc[di][r] * dinvS[n];
        }
    }
}

// ---------------- fp32 Performer fallbacks (old path) ----------------------
__global__ __launch_bounds__(256) void p1_kernel(
    const float* __restrict__ kbuf, const float* __restrict__ vbuf,
    const float* __restrict__ proj, float* __restrict__ ctx,
    float* __restrict__ ksum) {
    int mt = blockIdx.x;
    int bh = blockIdx.y;
    int b = bh >> 2, h = bh & 3;
    __shared__ float Pt[64][65];
    __shared__ float KV[64][65];
    __shared__ float S[64][65];
    int tid = threadIdx.x;
    int tx = tid & 15, ty = tid >> 4;
    for (int idx = tid; idx < 4096; idx += 256) {
        int r = idx >> 6, c = idx & 63;
        int mg = mt * 64 + r;
        Pt[r][c] = (mg < M_) ? proj[mg * DH_ + c] : 0.f;
    }
    float cacc[4][4] = {};
    float ksacc = 0.f;
    size_t base = ((size_t)b * N_) * C_ + h * DH_;
    for (int nt = 0; nt < 8; ++nt) {
        __syncthreads();
        for (int idx = tid; idx < 4096; idx += 256) {
            int r = idx >> 6, c = idx & 63;
            KV[r][c] = kbuf[base + (size_t)(nt * 64 + r) * C_ + c];
        }
        __syncthreads();
        float s[4][4] = {};
        for (int dd = 0; dd < 64; ++dd) {
            float a[4], bq[4];
#pragma unroll
            for (int i = 0; i < 4; ++i) a[i] = KV[ty * 4 + i][dd];
#pragma unroll
            for (int j = 0; j < 4; ++j) bq[j] = Pt[16 * j + tx][dd];
#pragma unroll
            for (int i = 0; i < 4; ++i)
#pragma unroll
                for (int j = 0; j < 4; ++j) s[i][j] = fmaf(a[i], bq[j], s[i][j]);
        }
        __syncthreads();
#pragma unroll
        for (int i = 0; i < 4; ++i)
#pragma unroll
            for (int j = 0; j < 4; ++j) {
                int mg = mt * 64 + 16 * j + tx;
                S[ty * 4 + i][16 * j + tx] =
                    (mg < M_) ? (fmaxf(s[i][j], 0.f) + EPSK_) : 0.f;
            }
        for (int idx = tid; idx < 4096; idx += 256) {
            int r = idx >> 6, c = idx & 63;
            KV[r][c] = vbuf[base + (size_t)(nt * 64 + r) * C_ + c];
        }
        __syncthreads();
        for (int nn = 0; nn < 64; ++nn) {
            float sm[4], vd[4];
#pragma unroll
            for (int i = 0; i < 4; ++i) sm[i] = S[nn][ty * 4 + i];
#pragma unroll
            for (int j = 0; j < 4; ++j) vd[j] = KV[nn][tx * 4 + j];
#pragma unroll
            for (int i = 0; i < 4; ++i)
#pragma unroll
                for (int j = 0; j < 4; ++j) cacc[i][j] = fmaf(sm[i], vd[j], cacc[i][j]);
        }
        if (tid < 64) {
            for (int nn = 0; nn < 64; ++nn) ksacc += S[nn][tid];
        }
    }
    float* cp = ctx + ((size_t)bh * MP_ + mt * 64) * DH_;
#pragma unroll
    for (int i = 0; i < 4; ++i)
#pragma unroll
        for (int j = 0; j < 4; ++j)
            cp[(ty * 4 + i) * DH_ + tx * 4 + j] = cacc[i][j];
    if (tid < 64) ksum[bh * MP_ + mt * 64 + tid] = ksacc;
}

__global__ __launch_bounds__(256) void p2_kernel(
    const float* __restrict__ qbuf, const float* __restrict__ proj,
    const float* __restrict__ ctx, const float* __restrict__ ksum,
    float* __restrict__ attout) {
    int nt = blockIdx.x;
    int bh = blockIdx.y;
    int b = bh >> 2, h = bh & 3;
    __shared__ float Qt[64][65];
    __shared__ float PC[64][65];
    __shared__ float S[64][65];
    __shared__ float ks[64], dinv[64];
    int tid = threadIdx.x;
    int tx = tid & 15, ty = tid >> 4;
    size_t base = ((size_t)b * N_) * C_ + h * DH_;
    for (int idx = tid; idx < 4096; idx += 256) {
        int r = idx >> 6, c = idx & 63;
        Qt[r][c] = qbuf[base + (size_t)(nt * 64 + r) * C_ + c];
    }
    float aacc[4][4] = {};
    float dacc = 0.f;
    for (int mt = 0; mt < 5; ++mt) {
        __syncthreads();
        for (int idx = tid; idx < 4096; idx += 256) {
            int r = idx >> 6, c = idx & 63;
            int mg = mt * 64 + r;
            PC[r][c] = (mg < M_) ? proj[mg * DH_ + c] : 0.f;
        }
        if (tid < 64) ks[tid] = ksum[bh * MP_ + mt * 64 + tid];
        __syncthreads();
        float s[4][4] = {};
        for (int dd = 0; dd < 64; ++dd) {
            float a[4], bq[4];
#pragma unroll
            for (int i = 0; i < 4; ++i) a[i] = Qt[ty * 4 + i][dd];
#pragma unroll
            for (int j = 0; j < 4; ++j) bq[j] = PC[16 * j + tx][dd];
#pragma unroll
            for (int i = 0; i < 4; ++i)
#pragma unroll
                for (int j = 0; j < 4; ++j) s[i][j] = fmaf(a[i], bq[j], s[i][j]);
        }
        __syncthreads();
#pragma unroll
        for (int i = 0; i < 4; ++i)
#pragma unroll
            for (int j = 0; j < 4; ++j) {
                int mg = mt * 64 + 16 * j + tx;
                S[ty * 4 + i][16 * j + tx] =
                    (mg < M_) ? (fmaxf(s[i][j], 0.f) + EPSK_) : 0.f;
            }
        for (int idx = tid; idx < 4096; idx += 256) {
            int r = idx >> 6, c = idx & 63;
            PC[r][c] = ctx[((size_t)bh * MP_ + mt * 64 + r) * DH_ + c];
        }
        __syncthreads();
        for (int mm = 0; mm < 64; ++mm) {
            float sm[4], cd[4];
#pragma unroll
            for (int i = 0; i < 4; ++i) sm[i] = S[ty * 4 + i][mm];
#pragma unroll
            for (int j = 0; j < 4; ++j) cd[j] = PC[mm][tx * 4 + j];
#pragma unroll
            for (int i = 0; i < 4; ++i)
#pragma unroll
                for (int j = 0; j < 4; ++j) aacc[i][j] = fmaf(sm[i], cd[j], aacc[i][j]);
        }
        if (tid < 64) {
            for (int mm = 0; mm < 64; ++mm) dacc = fmaf(S[tid][mm], ks[mm], dacc);
        }
    }
    __syncthreads();
    if (tid < 64) dinv[tid] = 1.f / dacc;
    __syncthreads();
#pragma unroll
    for (int i = 0; i < 4; ++i) {
        int n = ty * 4 + i;
        float di = dinv[n];
        float4 y = make_float4(aacc[i][0] * di, aacc[i][1] * di,
                               aacc[i][2] * di, aacc[i][3] * di);
        *(float4*)(attout + base + (size_t)(nt * 64 + n) * C_ + tx * 4) = y;
    }
}

// ------------------------------ mean pool ----------------------------------
__global__ __launch_bounds__(256) void pool_kernel(const float* __restrict__ atoms,
                                                   float* __restrict__ out) {
    int b = blockIdx.x >> 3;
    int chunk = blockIdx.x & 7;
    int c = threadIdx.x;
    const float* p = atoms + ((size_t)(b * N_ + chunk * 64)) * C_ + c;
    float s = 0.f;
    for (int n = 0; n < 64; ++n) s += p[(size_t)n * C_];
    atomicAdd(out + b * C_ + c, s * (1.f / 512.f));
}

extern "C" void kernel_launch(void* const* d_in, const int* in_sizes, int n_in,
                              void* d_out, int out_size, void* d_ws, size_t ws_size,
                              hipStream_t stream) {
    (void)in_sizes; (void)n_in;
    const float* x = (const float*)d_in[0];
    const float* edge_attr = (const float*)d_in[1];
    const int* edge_index = (const int*)d_in[2];
    const float* node_w = (const float*)d_in[4];
    const float* node_b = (const float*)d_in[5];
    const float* edge_w = (const float*)d_in[6];
    const float* edge_b = (const float*)d_in[7];
    const float* gine_w1 = (const float*)d_in[8];
    const float* gine_b1 = (const float*)d_in[9];
    const float* gine_w2 = (const float*)d_in[10];
    const float* gine_b2 = (const float*)d_in[11];
    const float* q_w = (const float*)d_in[12];
    const float* k_w = (const float*)d_in[13];
    const float* v_w = (const float*)d_in[14];
    const float* o_w = (const float*)d_in[15];
    const float* o_b = (const float*)d_in[16];
    const float* proj = (const float*)d_in[17];
    const float* n1g = (const float*)d_in[18];
    const float* n1b = (const float*)d_in[19];
    const float* n2g = (const float*)d_in[20];
    const float* n2b = (const float*)d_in[21];
    const float* n3g = (const float*)d_in[22];
    const float* n3b = (const float*)d_in[23];
    const float* mw1 = (const float*)d_in[24];
    const float* mb1 = (const float*)d_in[25];
    const float* mw2 = (const float*)d_in[26];
    const float* mb2 = (const float*)d_in[27];

    const size_t SZ = (size_t)TN * C_;
    float* ws = (float*)d_ws;
    float* A  = ws;                 // atoms
    float* AG = A + SZ;             // aggr fp32; then Qbf/Kbf bf16; then FFN out
    float* T  = AG + SZ;            // t1; then ctxT+ksum+att; then t2 (2*SZ)
    float* HL = T + 2 * SZ;         // h_loc
    float* Vb = HL + SZ;            // VbfT bf16; then h_att fp32

    short* Qbf   = (short*)AG;                     // SZ shorts
    short* Kbf   = Qbf + SZ;                       // SZ shorts
    short* VbfT  = (short*)Vb;                     // SZ shorts
    short* ctxTb = (short*)T;                      // 256*64*MP_ shorts
    float* KS2   = (float*)(ctxTb + (size_t)256 * 64 * MP_);
    float* ATT   = T + SZ;                         // fp32 att (row-major)

    int* deg    = (int*)(ws + 6 * SZ);
    int* offs   = deg + TN;
    int* cursor = offs + TN + 1;
    int* esrc   = cursor + TN;
    int* eidl   = esrc + E_;
    short* WT   = (short*)(eidl + E_);
    const size_t W65 = (size_t)5 * 65536;
    short* WTg1 = WT;
    short* WTg2 = WTg1 + W65;
    short* WTq  = WTg2 + W65;
    short* WTk  = WTq + W65;
    short* WTv  = WTk + W65;
    short* WTo  = WTv + W65;
    short* WTm1 = WTo + W65;
    short* WTm2 = WTm1 + (size_t)5 * 131072;
    short* Pbf  = WTm2 + (size_t)5 * 131072;
    size_t need = 6 * SZ * sizeof(float) +
                  (size_t)(3 * TN + 1 + 2 * E_) * sizeof(int) +
                  ((size_t)6 * 5 * 65536 + (size_t)2 * 5 * 131072 +
                   (size_t)L_ * MP_ * 64) * sizeof(short);
    bool full = ws_size >= need;

    dim3 gm256(2, 256), gm512(4, 256);
    dim3 g256(4, 512), g512(8, 512);

    embed_kernel<<<TN, 256, 0, stream>>>(x, node_w, node_b, A);
    if (full) {
        hipMemsetAsync(deg, 0, TN * sizeof(int), stream);
        count_kernel<<<E_ / 256, 256, 0, stream>>>(edge_index, deg);
        scan_kernel<<<1, 1024, 0, stream>>>(deg, offs, cursor);
        fill_kernel<<<E_ / 256, 256, 0, stream>>>(edge_index, cursor, esrc, eidl);
        wt_kernel<<<dim3(4, 4, L_), 256, 0, stream>>>(gine_w1, WTg1, 256, 256);
        wt_kernel<<<dim3(4, 4, L_), 256, 0, stream>>>(gine_w2, WTg2, 256, 256);
        wt_kernel<<<dim3(4, 4, L_), 256, 0, stream>>>(q_w, WTq, 256, 256);
        wt_kernel<<<dim3(4, 4, L_), 256, 0, stream>>>(k_w, WTk, 256, 256);
        wt_kernel<<<dim3(4, 4, L_), 256, 0, stream>>>(v_w, WTv, 256, 256);
        wt_kernel<<<dim3(4, 4, L_), 256, 0, stream>>>(o_w, WTo, 256, 256);
        wt_kernel<<<dim3(8, 4, L_), 256, 0, stream>>>(mw1, WTm1, 256, 512);
        wt_kernel<<<dim3(4, 8, L_), 256, 0, stream>>>(mw2, WTm2, 512, 256);
        pcast_kernel<<<L_, 256, 0, stream>>>(proj, Pbf);
    }
    for (int l = 0; l < L_; ++l) {
        if (full) {
            gather_kernel<<<TN, 256, 0, stream>>>(A, edge_attr, offs, esrc, eidl,
                                                  edge_w, edge_b, AG);
            mfmm_kernel<true, 1, 0><<<gm256, 256, 0, stream>>>(
                A, AG, WTg1 + (size_t)l * 65536, gine_b1 + l * 256,
                nullptr, nullptr, T, 256, 256);
            mfmm_kernel<false, 2, 0><<<gm256, 256, 0, stream>>>(
                T, nullptr, WTg2 + (size_t)l * 65536, gine_b2 + l * 256,
                A, nullptr, HL, 256, 256);
            ln_kernel<<<TN, 256, 0, stream>>>(HL, n1g + l * 256, n1b + l * 256, HL);
            mfmm_kernel<false, 0, 1><<<gm256, 256, 0, stream>>>(
                A, nullptr, WTq + (size_t)l * 65536, nullptr, nullptr, nullptr,
                Qbf, 256, 256);
            mfmm_kernel<false, 0, 1><<<gm256, 256, 0, stream>>>(
                A, nullptr, WTk + (size_t)l * 65536, nullptr, nullptr, nullptr,
                Kbf, 256, 256);
            mfmm_kernel<false, 0, 2><<<gm256, 256, 0, stream>>>(
                A, nullptr, WTv + (size_t)l * 65536, nullptr, nullptr, nullptr,
                VbfT, 256, 256);
            p1m_kernel<<<dim3(5, 256), 256, 0, stream>>>(
                Kbf, VbfT, Pbf + (size_t)l * MP_ * 64, ctxTb, KS2);
            p2m_kernel<<<dim3(8, 256), 256, 0, stream>>>(
                Qbf, Pbf + (size_t)l * MP_ * 64, ctxTb, KS2, ATT);
            mfmm_kernel<false, 2, 0><<<gm256, 256, 0, stream>>>(
                ATT, nullptr, WTo + (size_t)l * 65536, o_b + l * 256,
                A, nullptr, Vb, 256, 256);
            ln_kernel<<<TN, 256, 0, stream>>>(Vb, n2g + l * 256, n2b + l * 256, Vb);
            mfmm_kernel<true, 1, 0><<<gm512, 256, 0, stream>>>(
                HL, Vb, WTm1 + (size_t)l * 131072, mb1 + l * 512,
                nullptr, nullptr, T, 256, 512);
            mfmm_kernel<false, 3, 0><<<gm256, 256, 0, stream>>>(
                T, nullptr, WTm2 + (size_t)l * 131072, mb2 + l * 256,
                HL, Vb, AG, 512, 256);
            ln_kernel<<<TN, 256, 0, stream>>>(AG, n3g + l * 256, n3b + l * 256, A);
        } else {
            float* Qf = AG;
            float* Kf = T;
            float* CTXf = T + SZ;
            float* KSf = CTXf + (size_t)256 * MP_ * DH_;
            hipMemsetAsync(AG, 0, SZ * sizeof(float), stream);
            scatter_kernel<<<E_ * 64 / 256, 256, 0, stream>>>(A, edge_attr, edge_index,
                                                              edge_w, edge_b, AG);
            mm_kernel<true, 1><<<g256, 256, 0, stream>>>(A, AG, gine_w1 + l * 65536,
                                                         gine_b1 + l * 256, nullptr,
                                                         nullptr, T, 256, 256);
            mm_kernel<false, 2><<<g256, 256, 0, stream>>>(T, nullptr, gine_w2 + l * 65536,
                                                          gine_b2 + l * 256, A, nullptr,
                                                          HL, 256, 256);
            ln_kernel<<<TN, 256, 0, stream>>>(HL, n1g + l * 256, n1b + l * 256, HL);
            mm_kernel<false, 0><<<g256, 256, 0, stream>>>(A, nullptr, q_w + l * 65536,
                                                          nullptr, nullptr, nullptr,
                                                          Qf, 256, 256);
            mm_kernel<false, 0><<<g256, 256, 0, stream>>>(A, nullptr, k_w + l * 65536,
                                                          nullptr, nullptr, nullptr,
                                                          Kf, 256, 256);
            mm_kernel<false, 0><<<g256, 256, 0, stream>>>(A, nullptr, v_w + l * 65536,
                                                          nullptr, nullptr, nullptr,
                                                          Vb, 256, 256);
            p1_kernel<<<dim3(5, 256), 256, 0, stream>>>(Kf, Vb, proj + l * (M_ * DH_),
                                                        CTXf, KSf);
            p2_kernel<<<dim3(8, 256), 256, 0, stream>>>(Qf, proj + l * (M_ * DH_),
                                                        CTXf, KSf, Kf);
            mm_kernel<false, 2><<<g256, 256, 0, stream>>>(Kf, nullptr, o_w + l * 65536,
                                                          o_b + l * 256, A, nullptr,
                                                          Qf, 256, 256);
            ln_kernel<<<TN, 256, 0, stream>>>(Qf, n2g + l * 256, n2b + l * 256, Qf);
            mm_kernel<true, 1><<<g512, 256, 0, stream>>>(HL, Qf, mw1 + l * 131072,
                                                         mb1 + l * 512, nullptr, nullptr,
                                                         T, 256, 512);
            mm_kernel<false, 3><<<g256, 256, 0, stream>>>(T, nullptr, mw2 + l * 131072,
                                                          mb2 + l * 256, HL, Qf,
                                                          Vb, 512, 256);
            ln_kernel<<<TN, 256, 0, stream>>>(Vb, n3g + l * 256, n3b + l * 256, A);
        }
    }
    hipMemsetAsync(d_out, 0, (size_t)out_size * sizeof(float), stream);
    pool_kernel<<<512, 256, 0, stream>>>(A, (float*)d_out);
}

// Round 5
// 2233.355 us; speedup vs baseline: 6.7846x; 1.1585x over previous
//
#include <hip/hip_runtime.h>
#include <math.h>

#define TN 32768
#define C_ 256
#define E_ 524288
#define B_ 64
#define N_ 512
#define H_ 4
#define DH_ 64
#define M_ 266
#define MP_ 320
#define L_ 5
#define LN_EPS_ 1e-5f
#define EPSK_ 1e-3f

typedef short short8 __attribute__((ext_vector_type(8)));
typedef short short4v __attribute__((ext_vector_type(4)));
typedef float floatx4 __attribute__((ext_vector_type(4)));

__device__ __forceinline__ float gelu_exact(float v) {
    return 0.5f * v * (1.0f + erff(v * 0.70710678118654752f));
}

__device__ __forceinline__ short f2bf(float f) {
    union { float f; unsigned u; } v; v.f = f;
    unsigned r = v.u + 0x7FFF + ((v.u >> 16) & 1);
    return (short)(r >> 16);
}

__device__ __forceinline__ float bf2f(short s) {
    union { unsigned u; float f; } v;
    v.u = ((unsigned)(unsigned short)s) << 16;
    return v.f;
}

// ---------------- embed: atoms = log(x+1) @ node_w + node_b ----------------
__global__ __launch_bounds__(256) void embed_kernel(
    const float* __restrict__ x, const float* __restrict__ nw,
    const float* __restrict__ nb, float* __restrict__ atoms,
    short* __restrict__ abf) {
    int node = blockIdx.x;
    int c = threadIdx.x;
    __shared__ float lx[11];
    if (c < 11) lx[c] = logf(x[node * 11 + c] + 1.0f);
    __syncthreads();
    float acc = nb[c];
#pragma unroll
    for (int j = 0; j < 11; ++j) acc = fmaf(lx[j], nw[j * C_ + c], acc);
    atoms[(size_t)node * C_ + c] = acc;
    abf[(size_t)node * C_ + c] = f2bf(acc);
}

// ----------------------- CSR build: count / scan / fill --------------------
__global__ __launch_bounds__(256) void count_kernel(const int* __restrict__ eidx,
                                                    int* __restrict__ deg) {
    int e = blockIdx.x * 256 + threadIdx.x;
    atomicAdd(&deg[eidx[E_ + e]], 1);
}

__global__ __launch_bounds__(1024) void scan_kernel(const int* __restrict__ deg,
                                                    int* __restrict__ offs,
                                                    int* __restrict__ cursor) {
    __shared__ int tsum[1024];
    int t = threadIdx.x;
    int base = t * 32;
    int local[32];
    int s = 0;
#pragma unroll
    for (int i = 0; i < 32; ++i) { local[i] = deg[base + i]; s += local[i]; }
    tsum[t] = s;
    __syncthreads();
    for (int off = 1; off < 1024; off <<= 1) {
        int v = tsum[t];
        int add = (t >= off) ? tsum[t - off] : 0;
        __syncthreads();
        tsum[t] = v + add;
        __syncthreads();
    }
    int run = tsum[t] - s;
#pragma unroll
    for (int i = 0; i < 32; ++i) {
        offs[base + i] = run;
        cursor[base + i] = run;
        run += local[i];
    }
    if (t == 1023) offs[TN] = run;
}

__global__ __launch_bounds__(256) void fill_kernel(const int* __restrict__ eidx,
                                                   int* __restrict__ cursor,
                                                   int* __restrict__ esrc,
                                                   int* __restrict__ eidl) {
    int e = blockIdx.x * 256 + threadIdx.x;
    int d = eidx[E_ + e];
    int pos = atomicAdd(&cursor[d], 1);
    esrc[pos] = eidx[e];
    eidl[pos] = e;
}

// --- GINE message + gather, bf16 atoms; emits bf16 MLP input (atoms+aggr) --
__global__ __launch_bounds__(256) void gather_kernel(
    const short* __restrict__ abf, const float* __restrict__ atoms,
    const float* __restrict__ eattr, const int* __restrict__ offs,
    const int* __restrict__ esrc, const int* __restrict__ eidl,
    const float* __restrict__ ew, const float* __restrict__ eb,
    short* __restrict__ x1bf) {
    int node = blockIdx.x;
    int c = threadIdx.x;
    __shared__ int s_src[64];
    __shared__ float4 s_ea[64];
    int start = offs[node];
    int cnt = offs[node + 1] - start;
    float w0 = ew[c], w1 = ew[C_ + c], w2 = ew[2 * C_ + c], w3 = ew[3 * C_ + c];
    float bb = eb[c];
    float acc = 0.f;
    for (int baseI = 0; baseI < cnt; baseI += 64) {
        int nb = min(64, cnt - baseI);
        if (c < nb) {
            s_src[c] = esrc[start + baseI + c];
            int e = eidl[start + baseI + c];
            s_ea[c] = *(const float4*)(eattr + (size_t)e * 4);
        }
        __syncthreads();
        int i = 0;
        for (; i + 1 < nb; i += 2) {
            float a0 = bf2f(abf[(size_t)s_src[i] * C_ + c]);
            float a1 = bf2f(abf[(size_t)s_src[i + 1] * C_ + c]);
            float4 e0 = s_ea[i], e1 = s_ea[i + 1];
            float m0 = fmaf(e0.x, w0, fmaf(e0.y, w1, fmaf(e0.z, w2,
                        fmaf(e0.w, w3, a0 + bb))));
            float m1 = fmaf(e1.x, w0, fmaf(e1.y, w1, fmaf(e1.z, w2,
                        fmaf(e1.w, w3, a1 + bb))));
            acc += fmaxf(m0, 0.f) + fmaxf(m1, 0.f);
        }
        if (i < nb) {
            float a0 = bf2f(abf[(size_t)s_src[i] * C_ + c]);
            float4 e0 = s_ea[i];
            float m0 = fmaf(e0.x, w0, fmaf(e0.y, w1, fmaf(e0.z, w2,
                        fmaf(e0.w, w3, a0 + bb))));
            acc += fmaxf(m0, 0.f);
        }
        __syncthreads();
    }
    x1bf[(size_t)node * C_ + c] = f2bf(atoms[(size_t)node * C_ + c] + acc);
}

// ------------- fallback: atomic scatter (if ws too small) ------------------
__global__ __launch_bounds__(256) void scatter_kernel(
    const float* __restrict__ atoms, const float* __restrict__ eattr,
    const int* __restrict__ eidx, const float* __restrict__ ew,
    const float* __restrict__ eb, float* __restrict__ aggr) {
    int gid = blockIdx.x * 256 + threadIdx.x;
    int e = gid >> 6;
    int q = (gid & 63) << 2;
    int src = eidx[e];
    int dst = eidx[E_ + e];
    float4 ea = *(const float4*)(eattr + (size_t)e * 4);
    float4 w0 = *(const float4*)(ew + 0 * C_ + q);
    float4 w1 = *(const float4*)(ew + 1 * C_ + q);
    float4 w2 = *(const float4*)(ew + 2 * C_ + q);
    float4 w3 = *(const float4*)(ew + 3 * C_ + q);
    float4 bb = *(const float4*)(eb + q);
    float4 av = *(const float4*)(atoms + (size_t)src * C_ + q);
    float m0 = av.x + bb.x + ea.x * w0.x + ea.y * w1.x + ea.z * w2.x + ea.w * w3.x;
    float m1 = av.y + bb.y + ea.x * w0.y + ea.y * w1.y + ea.z * w2.y + ea.w * w3.y;
    float m2 = av.z + bb.z + ea.x * w0.z + ea.y * w1.z + ea.z * w2.z + ea.w * w3.z;
    float m3 = av.w + bb.w + ea.x * w0.w + ea.y * w1.w + ea.z * w2.w + ea.w * w3.w;
    float* base = aggr + (size_t)dst * C_ + q;
    atomicAdd(base + 0, fmaxf(m0, 0.f));
    atomicAdd(base + 1, fmaxf(m1, 0.f));
    atomicAdd(base + 2, fmaxf(m2, 0.f));
    atomicAdd(base + 3, fmaxf(m3, 0.f));
}

// --- weight transpose+cast: dst[rowBase+n][k] bf16 from W[l][k][n] fp32 ----
__global__ __launch_bounds__(256) void wt_kernel(const float* __restrict__ W,
                                                 short* __restrict__ Wt,
                                                 int K, int NC,
                                                 size_t lstride, int rowBase) {
    __shared__ short tile[64][65];
    int l = blockIdx.z;
    int k0 = blockIdx.y * 64, n0 = blockIdx.x * 64;
    const float* Wl = W + (size_t)l * K * NC;
    short* Wtl = Wt + (size_t)l * lstride + (size_t)rowBase * K;
    int t = threadIdx.x;
    int rr = t >> 4;
    int cc = (t & 15) * 4;
#pragma unroll
    for (int rep = 0; rep < 4; ++rep) {
        int r = rr + rep * 16;
        float4 v = *(const float4*)(Wl + (size_t)(k0 + r) * NC + n0 + cc);
        tile[cc + 0][r] = f2bf(v.x);
        tile[cc + 1][r] = f2bf(v.y);
        tile[cc + 2][r] = f2bf(v.z);
        tile[cc + 3][r] = f2bf(v.w);
    }
    __syncthreads();
#pragma unroll
    for (int rep = 0; rep < 4; ++rep) {
        int r = rr + rep * 16;
        short4v s;
        s.x = tile[r][cc + 0];
        s.y = tile[r][cc + 1];
        s.z = tile[r][cc + 2];
        s.w = tile[r][cc + 3];
        *(short4v*)(Wtl + (size_t)(n0 + r) * K + k0 + cc) = s;
    }
}

// ---------- proj cast: Pbf[l][m][d] bf16, padded to MP_ with zeros ---------
__global__ __launch_bounds__(256) void pcast_kernel(const float* __restrict__ proj,
                                                    short* __restrict__ Pbf) {
    int l = blockIdx.x;
    for (int idx = threadIdx.x; idx < MP_ * 64; idx += 256) {
        int m = idx >> 6, d = idx & 63;
        float v = (m < M_) ? proj[(size_t)l * M_ * 64 + m * 64 + d] : 0.f;
        Pbf[(size_t)l * MP_ * 64 + idx] = f2bf(v);
    }
}

// ---------------- MFMA bf16 matmul: Y = Xbf @ Wt (+epilogue) ---------------
// X bf16 row-major [rows][K]; Wt bf16 [NC][K]. 128x128 tile, 4 waves.
// EPI: 0=none, 1=gelu, 2=+R1f(fp32), 3=+R1b(bf16)
// OUT: 0=fp32 rm, 1=bf16 rm, 3=QKV split (NC=768: Q|K rm 256; V transposed, Yv)
template <int EPI, int OUT>
__global__ __launch_bounds__(256) void mfmm_kernel(
    const short* __restrict__ Xb, const short* __restrict__ Wt,
    const float* __restrict__ bias, const float* __restrict__ R1f,
    const short* __restrict__ R1b, void* __restrict__ Yout,
    short* __restrict__ Yv, int K, int NC) {
    __shared__ short As[128][56];
    __shared__ short Bs[128][56];
    int tid = threadIdx.x;
    int rowBase = blockIdx.y * 128, colBase = blockIdx.x * 128;
    int w = tid >> 6, lane = tid & 63;
    int wm = w & 1, wn = w >> 1;
    int quad = lane >> 4, l16 = lane & 15;
    int sr = tid >> 1;
    int sk = (tid & 1) * 16;
    const short* Xp = Xb + (size_t)(rowBase + sr) * K + sk;
    const short* Wp = Wt + (size_t)(colBase + sr) * K + sk;
    floatx4 acc[4][4];
#pragma unroll
    for (int i = 0; i < 4; ++i)
#pragma unroll
        for (int j = 0; j < 4; ++j)
            acc[i][j] = (floatx4){0.f, 0.f, 0.f, 0.f};
    for (int k0 = 0; k0 < K; k0 += 32) {
        short8 xa0 = *(const short8*)(Xp + k0);
        short8 xa1 = *(const short8*)(Xp + k0 + 8);
        short8 wb0 = *(const short8*)(Wp + k0);
        short8 wb1 = *(const short8*)(Wp + k0 + 8);
        __syncthreads();
        *(short8*)&As[sr][sk] = xa0;
        *(short8*)&As[sr][sk + 8] = xa1;
        *(short8*)&Bs[sr][sk] = wb0;
        *(short8*)&Bs[sr][sk + 8] = wb1;
        __syncthreads();
        short8 a[4], b[4];
#pragma unroll
        for (int mi = 0; mi < 4; ++mi)
            a[mi] = *(const short8*)&As[wm * 64 + mi * 16 + l16][quad * 8];
#pragma unroll
        for (int ni = 0; ni < 4; ++ni)
            b[ni] = *(const short8*)&Bs[wn * 64 + ni * 16 + l16][quad * 8];
#pragma unroll
        for (int mi = 0; mi < 4; ++mi)
#pragma unroll
            for (int ni = 0; ni < 4; ++ni)
                acc[mi][ni] = __builtin_amdgcn_mfma_f32_16x16x32_bf16(
                    a[mi], b[ni], acc[mi][ni], 0, 0, 0);
    }
    if (OUT == 3) {
        int region = colBase >> 8;   // 0=Q, 1=K, 2=V (uniform per block)
        if (region < 2) {
            short* dst = (short*)Yout + (size_t)region * (size_t)TN * 256;
#pragma unroll
            for (int ni = 0; ni < 4; ++ni) {
                int cl = (colBase + wn * 64 + ni * 16 + l16) & 255;
#pragma unroll
                for (int mi = 0; mi < 4; ++mi) {
#pragma unroll
                    for (int r = 0; r < 4; ++r) {
                        int rowg = rowBase + wm * 64 + mi * 16 + quad * 4 + r;
                        dst[(size_t)rowg * 256 + cl] = f2bf(acc[mi][ni][r]);
                    }
                }
            }
        } else {
#pragma unroll
            for (int ni = 0; ni < 4; ++ni) {
                int cl = (colBase + wn * 64 + ni * 16 + l16) & 255;
                int hh = cl >> 6, dd = cl & 63;
#pragma unroll
                for (int mi = 0; mi < 4; ++mi) {
                    int rowg0 = rowBase + wm * 64 + mi * 16 + quad * 4;
                    int bb = rowg0 >> 9, ng = rowg0 & 511;
                    short4v pv;
#pragma unroll
                    for (int r = 0; r < 4; ++r) pv[r] = f2bf(acc[mi][ni][r]);
                    *(short4v*)(Yv + (((size_t)bb * 4 + hh) * 64 + dd) * 512 + ng) = pv;
                }
            }
        }
        return;
    }
#pragma unroll
    for (int ni = 0; ni < 4; ++ni) {
        int colg = colBase + wn * 64 + ni * 16 + l16;
        float bv = bias ? bias[colg] : 0.f;
#pragma unroll
        for (int mi = 0; mi < 4; ++mi) {
#pragma unroll
            for (int r = 0; r < 4; ++r) {
                int rowg = rowBase + wm * 64 + mi * 16 + quad * 4 + r;
                float y = acc[mi][ni][r] + bv;
                if (EPI == 1) y = gelu_exact(y);
                if (EPI == 2) y += R1f[(size_t)rowg * NC + colg];
                if (EPI == 3) y += bf2f(R1b[(size_t)rowg * NC + colg]);
                if (OUT == 0)
                    ((float*)Yout)[(size_t)rowg * NC + colg] = y;
                else
                    ((short*)Yout)[(size_t)rowg * NC + colg] = f2bf(y);
            }
        }
    }
}

// ------------- fallback fp32 tiled matmul (old path) -----------------------
template <bool IN_ADD, int EPI>
__global__ __launch_bounds__(256) void mm_kernel(
    const float* __restrict__ X, const float* __restrict__ X2,
    const float* __restrict__ W, const float* __restrict__ bias,
    const float* __restrict__ R1, const float* __restrict__ R2,
    float* __restrict__ Y, int K, int NC) {
    __shared__ float Xs[16][65];
    __shared__ float Ws[16][68];
    int tid = threadIdx.x;
    int tx = tid & 15, ty = tid >> 4;
    int rowBase = blockIdx.y * 64;
    int colBase = blockIdx.x * 64;
    int lr = tid >> 2;
    int lk = (tid & 3) << 2;
    int wk = tid >> 4;
    int wc = (tid & 15) << 2;
    const float* Xp = X + (size_t)(rowBase + lr) * K + lk;
    const float* X2p = IN_ADD ? (X2 + (size_t)(rowBase + lr) * K + lk) : X;
    const float* Wp = W + (size_t)wk * NC + colBase + wc;
    float acc[4][4] = {};
    for (int k0 = 0; k0 < K; k0 += 16) {
        float4 xv = *(const float4*)(Xp + k0);
        if (IN_ADD) {
            float4 x2 = *(const float4*)(X2p + k0);
            xv.x += x2.x; xv.y += x2.y; xv.z += x2.z; xv.w += x2.w;
        }
        float4 wv = *(const float4*)(Wp + (size_t)k0 * NC);
        __syncthreads();
        Xs[lk + 0][lr] = xv.x;
        Xs[lk + 1][lr] = xv.y;
        Xs[lk + 2][lr] = xv.z;
        Xs[lk + 3][lr] = xv.w;
        *(float4*)&Ws[wk][wc] = wv;
        __syncthreads();
#pragma unroll
        for (int kk = 0; kk < 16; ++kk) {
            float a[4], b[4];
#pragma unroll
            for (int i = 0; i < 4; ++i) a[i] = Xs[kk][ty * 4 + i];
#pragma unroll
            for (int j = 0; j < 4; ++j) b[j] = Ws[kk][tx * 4 + j];
#pragma unroll
            for (int i = 0; i < 4; ++i)
#pragma unroll
                for (int j = 0; j < 4; ++j) acc[i][j] = fmaf(a[i], b[j], acc[i][j]);
        }
    }
    int c0 = colBase + tx * 4;
    float4 bv = make_float4(0.f, 0.f, 0.f, 0.f);
    if (bias) bv = *(const float4*)(bias + c0);
#pragma unroll
    for (int i = 0; i < 4; ++i) {
        int r = rowBase + ty * 4 + i;
        float4 y;
        y.x = acc[i][0] + bv.x; y.y = acc[i][1] + bv.y;
        y.z = acc[i][2] + bv.z; y.w = acc[i][3] + bv.w;
        if (EPI == 1) {
            y.x = gelu_exact(y.x); y.y = gelu_exact(y.y);
            y.z = gelu_exact(y.z); y.w = gelu_exact(y.w);
        }
        if (EPI >= 2) {
            float4 r1 = *(const float4*)(R1 + (size_t)r * NC + c0);
            y.x += r1.x; y.y += r1.y; y.z += r1.z; y.w += r1.w;
        }
        if (EPI == 3) {
            float4 r2 = *(const float4*)(R2 + (size_t)r * NC + c0);
            y.x += r2.x; y.y += r2.y; y.z += r2.z; y.w += r2.w;
        }
        *(float4*)(Y + (size_t)r * NC + c0) = y;
    }
}

// ------------------------------ LayerNorms ---------------------------------
__global__ __launch_bounds__(256) void ln_kernel(
    const float* __restrict__ X, const float* __restrict__ g,
    const float* __restrict__ bta, float* __restrict__ Y) {
    __shared__ float rs[4], rs2[4];
    __shared__ float mu_s, inv_s;
    int row = blockIdx.x, t = threadIdx.x;
    size_t off = (size_t)row * C_ + t;
    float v = X[off];
    float s = v, s2 = v * v;
#pragma unroll
    for (int o = 32; o > 0; o >>= 1) {
        s += __shfl_down(s, o);
        s2 += __shfl_down(s2, o);
    }
    int w = t >> 6, lane = t & 63;
    if (lane == 0) { rs[w] = s; rs2[w] = s2; }
    __syncthreads();
    if (t == 0) {
        float tot = rs[0] + rs[1] + rs[2] + rs[3];
        float tot2 = rs2[0] + rs2[1] + rs2[2] + rs2[3];
        float mu = tot * (1.f / C_);
        float var = tot2 * (1.f / C_) - mu * mu;
        mu_s = mu;
        inv_s = rsqrtf(var + LN_EPS_);
    }
    __syncthreads();
    Y[off] = (v - mu_s) * inv_s * g[t] + bta[t];
}

// ln2: SUMbf = bf16( HL + LN(HAbf) )   (bf16 input, fp32 add-stream)
__global__ __launch_bounds__(256) void ln2_kernel(
    const short* __restrict__ Xb, const float* __restrict__ g,
    const float* __restrict__ bta, const float* __restrict__ addf,
    short* __restrict__ outBf) {
    __shared__ float rs[4], rs2[4];
    __shared__ float mu_s, inv_s;
    int row = blockIdx.x, t = threadIdx.x;
    size_t off = (size_t)row * C_ + t;
    float v = bf2f(Xb[off]);
    float s = v, s2 = v * v;
#pragma unroll
    for (int o = 32; o > 0; o >>= 1) {
        s += __shfl_down(s, o);
        s2 += __shfl_down(s2, o);
    }
    int w = t >> 6, lane = t & 63;
    if (lane == 0) { rs[w] = s; rs2[w] = s2; }
    __syncthreads();
    if (t == 0) {
        float tot = rs[0] + rs[1] + rs[2] + rs[3];
        float tot2 = rs2[0] + rs2[1] + rs2[2] + rs2[3];
        float mu = tot * (1.f / C_);
        float var = tot2 * (1.f / C_) - mu * mu;
        mu_s = mu;
        inv_s = rsqrtf(var + LN_EPS_);
    }
    __syncthreads();
    float y = (v - mu_s) * inv_s * g[t] + bta[t];
    outBf[off] = f2bf(y + addf[off]);
}

// ln3: A = LN(X), Abf = bf16(A)
__global__ __launch_bounds__(256) void ln3_kernel(
    const float* __restrict__ X, const float* __restrict__ g,
    const float* __restrict__ bta, float* __restrict__ Y,
    short* __restrict__ Ybf) {
    __shared__ float rs[4], rs2[4];
    __shared__ float mu_s, inv_s;
    int row = blockIdx.x, t = threadIdx.x;
    size_t off = (size_t)row * C_ + t;
    float v = X[off];
    float s = v, s2 = v * v;
#pragma unroll
    for (int o = 32; o > 0; o >>= 1) {
        s += __shfl_down(s, o);
        s2 += __shfl_down(s2, o);
    }
    int w = t >> 6, lane = t & 63;
    if (lane == 0) { rs[w] = s; rs2[w] = s2; }
    __syncthreads();
    if (t == 0) {
        float tot = rs[0] + rs[1] + rs[2] + rs[3];
        float tot2 = rs2[0] + rs2[1] + rs2[2] + rs2[3];
        float mu = tot * (1.f / C_);
        float var = tot2 * (1.f / C_) - mu * mu;
        mu_s = mu;
        inv_s = rsqrtf(var + LN_EPS_);
    }
    __syncthreads();
    float y = (v - mu_s) * inv_s * g[t] + bta[t];
    Y[off] = y;
    Ybf[off] = f2bf(y);
}

// ---------- MFMA Performer pass 1: ctxT[bh][d][m], ksum[bh][m] -------------
__global__ __launch_bounds__(256) void p1m_kernel(
    const short* __restrict__ Kbf, const short* __restrict__ VbfT,
    const short* __restrict__ Pbf, short* __restrict__ ctxT,
    float* __restrict__ ksum) {
    int mt = blockIdx.x;   // 0..4
    int bh = blockIdx.y;   // 0..255
    int b = bh >> 2, h = bh & 3;
    __shared__ short Ps[64][72];
    __shared__ short Ks[64][72];
    __shared__ short VTs[64][72];
    __shared__ short Ss[64][72];   // [m][n]
    __shared__ float kred[4][64];
    int tid = threadIdx.x;
    int w = tid >> 6, lane = tid & 63;
    int quad = lane >> 4, l16 = lane & 15;
    int lr = tid >> 2, lb = (tid & 3) << 4;
    {
        const short* p = Pbf + ((size_t)(mt * 64 + lr)) * 64 + lb;
        *(short8*)&Ps[lr][lb] = *(const short8*)p;
        *(short8*)&Ps[lr][lb + 8] = *(const short8*)(p + 8);
    }
    floatx4 cacc[4];
#pragma unroll
    for (int i = 0; i < 4; ++i) cacc[i] = (floatx4){0.f, 0.f, 0.f, 0.f};
    float kacc[4] = {0.f, 0.f, 0.f, 0.f};
    size_t kbase = ((size_t)(b * 512)) * 256 + h * 64;
    size_t vbase = ((size_t)(bh * 64)) * 512;
    for (int nt = 0; nt < 8; ++nt) {
        __syncthreads();
        {
            const short* kp = Kbf + kbase + (size_t)(nt * 64 + lr) * 256 + lb;
            *(short8*)&Ks[lr][lb] = *(const short8*)kp;
            *(short8*)&Ks[lr][lb + 8] = *(const short8*)(kp + 8);
            const short* vp = VbfT + vbase + (size_t)lr * 512 + nt * 64 + lb;
            *(short8*)&VTs[lr][lb] = *(const short8*)vp;
            *(short8*)&VTs[lr][lb + 8] = *(const short8*)(vp + 8);
        }
        __syncthreads();
        floatx4 sa[4];
#pragma unroll
        for (int mi = 0; mi < 4; ++mi) sa[mi] = (floatx4){0.f, 0.f, 0.f, 0.f};
#pragma unroll
        for (int kt = 0; kt < 2; ++kt) {
            short8 a = *(const short8*)&Ks[w * 16 + l16][kt * 32 + quad * 8];
#pragma unroll
            for (int mi = 0; mi < 4; ++mi) {
                short8 bq = *(const short8*)&Ps[mi * 16 + l16][kt * 32 + quad * 8];
                sa[mi] = __builtin_amdgcn_mfma_f32_16x16x32_bf16(a, bq, sa[mi], 0, 0, 0);
            }
        }
#pragma unroll
        for (int mi = 0; mi < 4; ++mi) {
            int mg = mt * 64 + mi * 16 + l16;
            short4v sv;
            float kl = 0.f;
#pragma unroll
            for (int r = 0; r < 4; ++r) {
                float v = (mg < M_) ? (fmaxf(sa[mi][r], 0.f) + EPSK_) : 0.f;
                sv[r] = f2bf(v);
                kl += v;
            }
            kacc[mi] += kl;
            *(short4v*)&Ss[mi * 16 + l16][w * 16 + quad * 4] = sv;
        }
        __syncthreads();
#pragma unroll
        for (int kt = 0; kt < 2; ++kt) {
            short8 a = *(const short8*)&Ss[w * 16 + l16][kt * 32 + quad * 8];
#pragma unroll
            for (int di = 0; di < 4; ++di) {
                short8 bv = *(const short8*)&VTs[di * 16 + l16][kt * 32 + quad * 8];
                cacc[di] = __builtin_amdgcn_mfma_f32_16x16x32_bf16(a, bv, cacc[di], 0, 0, 0);
            }
        }
    }
    size_t cbase = ((size_t)bh * 64) * MP_ + mt * 64;
#pragma unroll
    for (int di = 0; di < 4; ++di) {
        int d = di * 16 + l16;
        short4v cv;
#pragma unroll
        for (int r = 0; r < 4; ++r) cv[r] = f2bf(cacc[di][r]);
        *(short4v*)(ctxT + cbase + (size_t)d * MP_ + w * 16 + quad * 4) = cv;
    }
#pragma unroll
    for (int mi = 0; mi < 4; ++mi) {
        kacc[mi] += __shfl_down(kacc[mi], 32);
        kacc[mi] += __shfl_down(kacc[mi], 16);
    }
    if (lane < 16) {
#pragma unroll
        for (int mi = 0; mi < 4; ++mi) kred[w][mi * 16 + lane] = kacc[mi];
    }
    __syncthreads();
    if (tid < 64)
        ksum[(size_t)bh * MP_ + mt * 64 + tid] =
            kred[0][tid] + kred[1][tid] + kred[2][tid] + kred[3][tid];
}

// ---------- MFMA Performer pass 2: attbf = bf16((qp@ctx)/(qp@ksum)) --------
__global__ __launch_bounds__(256) void p2m_kernel(
    const short* __restrict__ Qbf, const short* __restrict__ Pbf,
    const short* __restrict__ ctxT, const float* __restrict__ ksum,
    short* __restrict__ attbf) {
    int nt = blockIdx.x;   // 0..7
    int bh = blockIdx.y;   // 0..255
    int b = bh >> 2, h = bh & 3;
    __shared__ short Qs[64][72];
    __shared__ short Ps[64][72];
    __shared__ short CTs[64][72];  // [d][m]
    __shared__ short Ss[64][72];   // [n][m]
    __shared__ float kss[64];
    __shared__ float dredS[64];
    __shared__ float dinvS[64];
    int tid = threadIdx.x;
    int w = tid >> 6, lane = tid & 63;
    int quad = lane >> 4, l16 = lane & 15;
    int lr = tid >> 2, lb = (tid & 3) << 4;
    size_t qbase = ((size_t)(b * 512)) * 256 + h * 64;
    {
        const short* qp = Qbf + qbase + (size_t)(nt * 64 + lr) * 256 + lb;
        *(short8*)&Qs[lr][lb] = *(const short8*)qp;
        *(short8*)&Qs[lr][lb + 8] = *(const short8*)(qp + 8);
    }
    floatx4 aacc[4];
#pragma unroll
    for (int i = 0; i < 4; ++i) aacc[i] = (floatx4){0.f, 0.f, 0.f, 0.f};
    float dd[4] = {0.f, 0.f, 0.f, 0.f};
    size_t cb = ((size_t)bh * 64) * MP_;
    for (int mt = 0; mt < 5; ++mt) {
        __syncthreads();
        {
            const short* p = Pbf + ((size_t)(mt * 64 + lr)) * 64 + lb;
            *(short8*)&Ps[lr][lb] = *(const short8*)p;
            *(short8*)&Ps[lr][lb + 8] = *(const short8*)(p + 8);
            const short* cp = ctxT + cb + (size_t)lr * MP_ + mt * 64 + lb;
            *(short8*)&CTs[lr][lb] = *(const short8*)cp;
            *(short8*)&CTs[lr][lb + 8] = *(const short8*)(cp + 8);
        }
        if (tid < 64) kss[tid] = ksum[(size_t)bh * MP_ + mt * 64 + tid];
        __syncthreads();
        floatx4 sa[4];
#pragma unroll
        for (int mi = 0; mi < 4; ++mi) sa[mi] = (floatx4){0.f, 0.f, 0.f, 0.f};
#pragma unroll
        for (int kt = 0; kt < 2; ++kt) {
            short8 a = *(const short8*)&Qs[w * 16 + l16][kt * 32 + quad * 8];
#pragma unroll
            for (int mi = 0; mi < 4; ++mi) {
                short8 bq = *(const short8*)&Ps[mi * 16 + l16][kt * 32 + quad * 8];
                sa[mi] = __builtin_amdgcn_mfma_f32_16x16x32_bf16(a, bq, sa[mi], 0, 0, 0);
            }
        }
#pragma unroll
        for (int mi = 0; mi < 4; ++mi) {
            int mg = mt * 64 + mi * 16 + l16;
            float ksv = kss[mi * 16 + l16];
#pragma unroll
            for (int r = 0; r < 4; ++r) {
                float v = (mg < M_) ? (fmaxf(sa[mi][r], 0.f) + EPSK_) : 0.f;
                Ss[w * 16 + quad * 4 + r][mi * 16 + l16] = f2bf(v);
                dd[r] += v * ksv;
            }
        }
        __syncthreads();
#pragma unroll
        for (int kt = 0; kt < 2; ++kt) {
            short8 a = *(const short8*)&Ss[w * 16 + l16][kt * 32 + quad * 8];
#pragma unroll
            for (int di = 0; di < 4; ++di) {
                short8 bv = *(const short8*)&CTs[di * 16 + l16][kt * 32 + quad * 8];
                aacc[di] = __builtin_amdgcn_mfma_f32_16x16x32_bf16(a, bv, aacc[di], 0, 0, 0);
            }
        }
    }
#pragma unroll
    for (int r = 0; r < 4; ++r) {
        dd[r] += __shfl_xor(dd[r], 1);
        dd[r] += __shfl_xor(dd[r], 2);
        dd[r] += __shfl_xor(dd[r], 4);
        dd[r] += __shfl_xor(dd[r], 8);
    }
    if (l16 == 0) {
#pragma unroll
        for (int r = 0; r < 4; ++r) dredS[w * 16 + quad * 4 + r] = dd[r];
    }
    __syncthreads();
    if (tid < 64) dinvS[tid] = 1.f / dredS[tid];
    __syncthreads();
#pragma unroll
    for (int di = 0; di < 4; ++di) {
        int d = di * 16 + l16;
#pragma unroll
        for (int r = 0; r < 4; ++r) {
            int n = w * 16 + quad * 4 + r;
            attbf[((size_t)(b * 512 + nt * 64 + n)) * 256 + h * 64 + d] =
                f2bf(aacc[di][r] * dinvS[n]);
        }
    }
}

// ---------------- fp32 Performer fallbacks (old path) ----------------------
__global__ __launch_bounds__(256) void p1_kernel(
    const float* __restrict__ kbuf, const float* __restrict__ vbuf,
    const float* __restrict__ proj, float* __restrict__ ctx,
    float* __restrict__ ksum) {
    int mt = blockIdx.x;
    int bh = blockIdx.y;
    int b = bh >> 2, h = bh & 3;
    __shared__ float Pt[64][65];
    __shared__ float KV[64][65];
    __shared__ float S[64][65];
    int tid = threadIdx.x;
    int tx = tid & 15, ty = tid >> 4;
    for (int idx = tid; idx < 4096; idx += 256) {
        int r = idx >> 6, c = idx & 63;
        int mg = mt * 64 + r;
        Pt[r][c] = (mg < M_) ? proj[mg * DH_ + c] : 0.f;
    }
    float cacc[4][4] = {};
    float ksacc = 0.f;
    size_t base = ((size_t)b * N_) * C_ + h * DH_;
    for (int nt = 0; nt < 8; ++nt) {
        __syncthreads();
        for (int idx = tid; idx < 4096; idx += 256) {
            int r = idx >> 6, c = idx & 63;
            KV[r][c] = kbuf[base + (size_t)(nt * 64 + r) * C_ + c];
        }
        __syncthreads();
        float s[4][4] = {};
        for (int dd = 0; dd < 64; ++dd) {
            float a[4], bq[4];
#pragma unroll
            for (int i = 0; i < 4; ++i) a[i] = KV[ty * 4 + i][dd];
#pragma unroll
            for (int j = 0; j < 4; ++j) bq[j] = Pt[16 * j + tx][dd];
#pragma unroll
            for (int i = 0; i < 4; ++i)
#pragma unroll
                for (int j = 0; j < 4; ++j) s[i][j] = fmaf(a[i], bq[j], s[i][j]);
        }
        __syncthreads();
#pragma unroll
        for (int i = 0; i < 4; ++i)
#pragma unroll
            for (int j = 0; j < 4; ++j) {
                int mg = mt * 64 + 16 * j + tx;
                S[ty * 4 + i][16 * j + tx] =
                    (mg < M_) ? (fmaxf(s[i][j], 0.f) + EPSK_) : 0.f;
            }
        for (int idx = tid; idx < 4096; idx += 256) {
            int r = idx >> 6, c = idx & 63;
            KV[r][c] = vbuf[base + (size_t)(nt * 64 + r) * C_ + c];
        }
        __syncthreads();
        for (int nn = 0; nn < 64; ++nn) {
            float sm[4], vd[4];
#pragma unroll
            for (int i = 0; i < 4; ++i) sm[i] = S[nn][ty * 4 + i];
#pragma unroll
            for (int j = 0; j < 4; ++j) vd[j] = KV[nn][tx * 4 + j];
#pragma unroll
            for (int i = 0; i < 4; ++i)
#pragma unroll
                for (int j = 0; j < 4; ++j) cacc[i][j] = fmaf(sm[i], vd[j], cacc[i][j]);
        }
        if (tid < 64) {
            for (int nn = 0; nn < 64; ++nn) ksacc += S[nn][tid];
        }
    }
    float* cp = ctx + ((size_t)bh * MP_ + mt * 64) * DH_;
#pragma unroll
    for (int i = 0; i < 4; ++i)
#pragma unroll
        for (int j = 0; j < 4; ++j)
            cp[(ty * 4 + i) * DH_ + tx * 4 + j] = cacc[i][j];
    if (tid < 64) ksum[bh * MP_ + mt * 64 + tid] = ksacc;
}

__global__ __launch_bounds__(256) void p2_kernel(
    const float* __restrict__ qbuf, const float* __restrict__ proj,
    const float* __restrict__ ctx, const float* __restrict__ ksum,
    float* __restrict__ attout) {
    int nt = blockIdx.x;
    int bh = blockIdx.y;
    int b = bh >> 2, h = bh & 3;
    __shared__ float Qt[64][65];
    __shared__ float PC[64][65];
    __shared__ float S[64][65];
    __shared__ float ks[64], dinv[64];
    int tid = threadIdx.x;
    int tx = tid & 15, ty = tid >> 4;
    size_t base = ((size_t)b * N_) * C_ + h * DH_;
    for (int idx = tid; idx < 4096; idx += 256) {
        int r = idx >> 6, c = idx & 63;
        Qt[r][c] = qbuf[base + (size_t)(nt * 64 + r) * C_ + c];
    }
    float aacc[4][4] = {};
    float dacc = 0.f;
    for (int mt = 0; mt < 5; ++mt) {
        __syncthreads();
        for (int idx = tid; idx < 4096; idx += 256) {
            int r = idx >> 6, c = idx & 63;
            int mg = mt * 64 + r;
            PC[r][c] = (mg < M_) ? proj[mg * DH_ + c] : 0.f;
        }
        if (tid < 64) ks[tid] = ksum[bh * MP_ + mt * 64 + tid];
        __syncthreads();
        float s[4][4] = {};
        for (int dd = 0; dd < 64; ++dd) {
            float a[4], bq[4];
#pragma unroll
            for (int i = 0; i < 4; ++i) a[i] = Qt[ty * 4 + i][dd];
#pragma unroll
            for (int j = 0; j < 4; ++j) bq[j] = PC[16 * j + tx][dd];
#pragma unroll
            for (int i = 0; i < 4; ++i)
#pragma unroll
                for (int j = 0; j < 4; ++j) s[i][j] = fmaf(a[i], bq[j], s[i][j]);
        }
        __syncthreads();
#pragma unroll
        for (int i = 0; i < 4; ++i)
#pragma unroll
            for (int j = 0; j < 4; ++j) {
                int mg = mt * 64 + 16 * j + tx;
                S[ty * 4 + i][16 * j + tx] =
                    (mg < M_) ? (fmaxf(s[i][j], 0.f) + EPSK_) : 0.f;
            }
        for (int idx = tid; idx < 4096; idx += 256) {
            int r = idx >> 6, c = idx & 63;
            PC[r][c] = ctx[((size_t)bh * MP_ + mt * 64 + r) * DH_ + c];
        }
        __syncthreads();
        for (int mm = 0; mm < 64; ++mm) {
            float sm[4], cd[4];
#pragma unroll
            for (int i = 0; i < 4; ++i) sm[i] = S[ty * 4 + i][mm];
#pragma unroll
            for (int j = 0; j < 4; ++j) cd[j] = PC[mm][tx * 4 + j];
#pragma unroll
            for (int i = 0; i < 4; ++i)
#pragma unroll
                for (int j = 0; j < 4; ++j) aacc[i][j] = fmaf(sm[i], cd[j], aacc[i][j]);
        }
        if (tid < 64) {
            for (int mm = 0; mm < 64; ++mm) dacc = fmaf(S[tid][mm], ks[mm], dacc);
        }
    }
    __syncthreads();
    if (tid < 64) dinv[tid] = 1.f / dacc;
    __syncthreads();
#pragma unroll
    for (int i = 0; i < 4; ++i) {
        int n = ty * 4 + i;
        float di = dinv[n];
        float4 y = make_float4(aacc[i][0] * di, aacc[i][1] * di,
                               aacc[i][2] * di, aacc[i][3] * di);
        *(float4*)(attout + base + (size_t)(nt * 64 + n) * C_ + tx * 4) = y;
    }
}

// ------------------------------ mean pool ----------------------------------
__global__ __launch_bounds__(256) void pool_kernel(const float* __restrict__ atoms,
                                                   float* __restrict__ out) {
    int b = blockIdx.x >> 3;
    int chunk = blockIdx.x & 7;
    int c = threadIdx.x;
    const float* p = atoms + ((size_t)(b * N_ + chunk * 64)) * C_ + c;
    float s = 0.f;
    for (int n = 0; n < 64; ++n) s += p[(size_t)n * C_];
    atomicAdd(out + b * C_ + c, s * (1.f / 512.f));
}

extern "C" void kernel_launch(void* const* d_in, const int* in_sizes, int n_in,
                              void* d_out, int out_size, void* d_ws, size_t ws_size,
                              hipStream_t stream) {
    (void)in_sizes; (void)n_in;
    const float* x = (const float*)d_in[0];
    const float* edge_attr = (const float*)d_in[1];
    const int* edge_index = (const int*)d_in[2];
    const float* node_w = (const float*)d_in[4];
    const float* node_b = (const float*)d_in[5];
    const float* edge_w = (const float*)d_in[6];
    const float* edge_b = (const float*)d_in[7];
    const float* gine_w1 = (const float*)d_in[8];
    const float* gine_b1 = (const float*)d_in[9];
    const float* gine_w2 = (const float*)d_in[10];
    const float* gine_b2 = (const float*)d_in[11];
    const float* q_w = (const float*)d_in[12];
    const float* k_w = (const float*)d_in[13];
    const float* v_w = (const float*)d_in[14];
    const float* o_w = (const float*)d_in[15];
    const float* o_b = (const float*)d_in[16];
    const float* proj = (const float*)d_in[17];
    const float* n1g = (const float*)d_in[18];
    const float* n1b = (const float*)d_in[19];
    const float* n2g = (const float*)d_in[20];
    const float* n2b = (const float*)d_in[21];
    const float* n3g = (const float*)d_in[22];
    const float* n3b = (const float*)d_in[23];
    const float* mw1 = (const float*)d_in[24];
    const float* mb1 = (const float*)d_in[25];
    const float* mw2 = (const float*)d_in[26];
    const float* mb2 = (const float*)d_in[27];

    const size_t SZ = (size_t)TN * C_;   // 8,388,608
    float* ws = (float*)d_ws;
    // arena (floats): [0,1)A [1,1.5)Abf [1.5,2.5)HL/R3 [2.5,3)SUMbf
    //                 [3,4)X1bf|t1bf / t2bf  [4,5)Qbf|Kbf (later HAbf|ATTbf)
    //                 [5,6)VbfT | ctxT+ksum
    float* A     = ws;
    short* Abf   = (short*)(ws + SZ);
    float* HL    = ws + SZ + SZ / 2;
    float* R3    = HL;
    short* SUMbf = (short*)(ws + 2 * SZ + SZ / 2);
    short* X1bf  = (short*)(ws + 3 * SZ);
    short* t1bf  = X1bf + SZ;
    short* t2bf  = X1bf;
    short* Qbf   = (short*)(ws + 4 * SZ);
    short* Kbf   = Qbf + SZ;
    short* ATTbf = Kbf;
    short* HAbf  = Qbf;
    short* VbfT  = (short*)(ws + 5 * SZ);
    short* ctxTb = VbfT + SZ;
    float* KS2   = (float*)(ctxTb + (size_t)256 * 64 * MP_);

    int* deg    = (int*)(ws + 6 * SZ);
    int* offs   = deg + TN;
    int* cursor = offs + TN + 1;
    int* esrc   = cursor + TN;
    int* eidl   = esrc + E_;
    short* WTg1  = (short*)(eidl + E_);
    short* WTg2  = WTg1 + (size_t)5 * 65536;
    short* WTqkv = WTg2 + (size_t)5 * 65536;
    short* WTo   = WTqkv + (size_t)5 * 196608;
    short* WTm1  = WTo + (size_t)5 * 65536;
    short* WTm2  = WTm1 + (size_t)5 * 131072;
    short* Pbf   = WTm2 + (size_t)5 * 131072;
    size_t need = 6 * SZ * sizeof(float) +
                  (size_t)(3 * TN + 1 + 2 * E_) * sizeof(int) +
                  ((size_t)5 * (3 * 65536 + 196608 + 2 * 131072 + MP_ * 64)) *
                      sizeof(short);
    bool full = ws_size >= need;

    dim3 gm256(2, 256), gm512(4, 256), gm768(6, 256);
    dim3 g256(4, 512), g512(8, 512);

    embed_kernel<<<TN, 256, 0, stream>>>(x, node_w, node_b, A, Abf);
    if (full) {
        hipMemsetAsync(deg, 0, TN * sizeof(int), stream);
        count_kernel<<<E_ / 256, 256, 0, stream>>>(edge_index, deg);
        scan_kernel<<<1, 1024, 0, stream>>>(deg, offs, cursor);
        fill_kernel<<<E_ / 256, 256, 0, stream>>>(edge_index, cursor, esrc, eidl);
        wt_kernel<<<dim3(4, 4, L_), 256, 0, stream>>>(gine_w1, WTg1, 256, 256, 65536, 0);
        wt_kernel<<<dim3(4, 4, L_), 256, 0, stream>>>(gine_w2, WTg2, 256, 256, 65536, 0);
        wt_kernel<<<dim3(4, 4, L_), 256, 0, stream>>>(q_w, WTqkv, 256, 256, 196608, 0);
        wt_kernel<<<dim3(4, 4, L_), 256, 0, stream>>>(k_w, WTqkv, 256, 256, 196608, 256);
        wt_kernel<<<dim3(4, 4, L_), 256, 0, stream>>>(v_w, WTqkv, 256, 256, 196608, 512);
        wt_kernel<<<dim3(4, 4, L_), 256, 0, stream>>>(o_w, WTo, 256, 256, 65536, 0);
        wt_kernel<<<dim3(8, 4, L_), 256, 0, stream>>>(mw1, WTm1, 256, 512, 131072, 0);
        wt_kernel<<<dim3(4, 8, L_), 256, 0, stream>>>(mw2, WTm2, 512, 256, 131072, 0);
        pcast_kernel<<<L_, 256, 0, stream>>>(proj, Pbf);
    }
    for (int l = 0; l < L_; ++l) {
        if (full) {
            gather_kernel<<<TN, 256, 0, stream>>>(Abf, A, edge_attr, offs, esrc,
                                                  eidl, edge_w, edge_b, X1bf);
            mfmm_kernel<1, 1><<<gm256, 256, 0, stream>>>(
                X1bf, WTg1 + (size_t)l * 65536, gine_b1 + l * 256,
                nullptr, nullptr, t1bf, nullptr, 256, 256);
            mfmm_kernel<2, 0><<<gm256, 256, 0, stream>>>(
                t1bf, WTg2 + (size_t)l * 65536, gine_b2 + l * 256,
                A, nullptr, HL, nullptr, 256, 256);
            ln_kernel<<<TN, 256, 0, stream>>>(HL, n1g + l * 256, n1b + l * 256, HL);
            mfmm_kernel<0, 3><<<gm768, 256, 0, stream>>>(
                Abf, WTqkv + (size_t)l * 196608, nullptr,
                nullptr, nullptr, Qbf, VbfT, 256, 768);
            p1m_kernel<<<dim3(5, 256), 256, 0, stream>>>(
                Kbf, VbfT, Pbf + (size_t)l * MP_ * 64, ctxTb, KS2);
            p2m_kernel<<<dim3(8, 256), 256, 0, stream>>>(
                Qbf, Pbf + (size_t)l * MP_ * 64, ctxTb, KS2, ATTbf);
            mfmm_kernel<2, 1><<<gm256, 256, 0, stream>>>(
                ATTbf, WTo + (size_t)l * 65536, o_b + l * 256,
                A, nullptr, HAbf, nullptr, 256, 256);
            ln2_kernel<<<TN, 256, 0, stream>>>(HAbf, n2g + l * 256, n2b + l * 256,
                                               HL, SUMbf);
            mfmm_kernel<1, 1><<<gm512, 256, 0, stream>>>(
                SUMbf, WTm1 + (size_t)l * 131072, mb1 + l * 512,
                nullptr, nullptr, t2bf, nullptr, 256, 512);
            mfmm_kernel<3, 0><<<gm256, 256, 0, stream>>>(
                t2bf, WTm2 + (size_t)l * 131072, mb2 + l * 256,
                nullptr, SUMbf, R3, nullptr, 512, 256);
            ln3_kernel<<<TN, 256, 0, stream>>>(R3, n3g + l * 256, n3b + l * 256,
                                               A, Abf);
        } else {
            float* AGf = A + SZ;
            float* Tf = AGf + SZ;
            float* HLf = Tf + 2 * SZ;
            float* Vbf2 = HLf + SZ;
            float* Qf = AGf;
            float* Kf = Tf;
            float* CTXf = Tf + SZ;
            float* KSf = CTXf + (size_t)256 * MP_ * DH_;
            hipMemsetAsync(AGf, 0, SZ * sizeof(float), stream);
            scatter_kernel<<<E_ * 64 / 256, 256, 0, stream>>>(A, edge_attr, edge_index,
                                                              edge_w, edge_b, AGf);
            mm_kernel<true, 1><<<g256, 256, 0, stream>>>(A, AGf, gine_w1 + l * 65536,
                                                         gine_b1 + l * 256, nullptr,
                                                         nullptr, Tf, 256, 256);
            mm_kernel<false, 2><<<g256, 256, 0, stream>>>(Tf, nullptr, gine_w2 + l * 65536,
                                                          gine_b2 + l * 256, A, nullptr,
                                                          HLf, 256, 256);
            ln_kernel<<<TN, 256, 0, stream>>>(HLf, n1g + l * 256, n1b + l * 256, HLf);
            mm_kernel<false, 0><<<g256, 256, 0, stream>>>(A, nullptr, q_w + l * 65536,
                                                          nullptr, nullptr, nullptr,
                                                          Qf, 256, 256);
            mm_kernel<false, 0><<<g256, 256, 0, stream>>>(A, nullptr, k_w + l * 65536,
                                                          nullptr, nullptr, nullptr,
                                                          Kf, 256, 256);
            mm_kernel<false, 0><<<g256, 256, 0, stream>>>(A, nullptr, v_w + l * 65536,
                                                          nullptr, nullptr, nullptr,
                                                          Vbf2, 256, 256);
            p1_kernel<<<dim3(5, 256), 256, 0, stream>>>(Kf, Vbf2, proj + l * (M_ * DH_),
                                                        CTXf, KSf);
            p2_kernel<<<dim3(8, 256), 256, 0, stream>>>(Qf, proj + l * (M_ * DH_),
                                                        CTXf, KSf, Kf);
            mm_kernel<false, 2><<<g256, 256, 0, stream>>>(Kf, nullptr, o_w + l * 65536,
                                                          o_b + l * 256, A, nullptr,
                                                          Qf, 256, 256);
            ln_kernel<<<TN, 256, 0, stream>>>(Qf, n2g + l * 256, n2b + l * 256, Qf);
            mm_kernel<true, 1><<<g512, 256, 0, stream>>>(HLf, Qf, mw1 + l * 131072,
                                                         mb1 + l * 512, nullptr, nullptr,
                                                         Tf, 256, 512);
            mm_kernel<false, 3><<<g256, 256, 0, stream>>>(Tf, nullptr, mw2 + l * 131072,
                                                          mb2 + l * 256, HLf, Qf,
                                                          Vbf2, 512, 256);
            ln_kernel<<<TN, 256, 0, stream>>>(Vbf2, n3g + l * 256, n3b + l * 256, A);
        }
    }
    hipMemsetAsync(d_out, 0, (size_t)out_size * sizeof(float), stream);
    pool_kernel<<<512, 256, 0, stream>>>(A, (float*)d_out);
}

// Round 6
// 2079.762 us; speedup vs baseline: 7.2856x; 1.0739x over previous
//
#include <hip/hip_runtime.h>
#include <math.h>
#include <stdint.h>

#define TN 32768
#define C_ 256
#define E_ 524288
#define B_ 64
#define N_ 512
#define H_ 4
#define DH_ 64
#define M_ 266
#define MP_ 320
#define L_ 5
#define LN_EPS_ 1e-5f
#define EPSK_ 1e-3f

typedef short short8 __attribute__((ext_vector_type(8)));
typedef short short4v __attribute__((ext_vector_type(4)));
typedef float floatx4 __attribute__((ext_vector_type(4)));

__device__ __forceinline__ float gelu_exact(float v) {
    return 0.5f * v * (1.0f + erff(v * 0.70710678118654752f));
}

__device__ __forceinline__ short f2bf(float f) {
    union { float f; unsigned u; } v; v.f = f;
    unsigned r = v.u + 0x7FFF + ((v.u >> 16) & 1);
    return (short)(r >> 16);
}

__device__ __forceinline__ float bf2f(short s) {
    union { unsigned u; float f; } v;
    v.u = ((unsigned)(unsigned short)s) << 16;
    return v.f;
}

__device__ __forceinline__ float bflo(unsigned u) {
    union { unsigned u; float f; } v;
    v.u = u << 16;
    return v.f;
}
__device__ __forceinline__ float bfhi(unsigned u) {
    union { unsigned u; float f; } v;
    v.u = u & 0xffff0000u;
    return v.f;
}

// ---------------- embed: atoms = log(x+1) @ node_w + node_b ----------------
__global__ __launch_bounds__(256) void embed_kernel(
    const float* __restrict__ x, const float* __restrict__ nw,
    const float* __restrict__ nb, float* __restrict__ atoms,
    short* __restrict__ abf) {
    int node = blockIdx.x;
    int c = threadIdx.x;
    __shared__ float lx[11];
    if (c < 11) lx[c] = logf(x[node * 11 + c] + 1.0f);
    __syncthreads();
    float acc = nb[c];
#pragma unroll
    for (int j = 0; j < 11; ++j) acc = fmaf(lx[j], nw[j * C_ + c], acc);
    atoms[(size_t)node * C_ + c] = acc;
    abf[(size_t)node * C_ + c] = f2bf(acc);
}

// ----------------------- CSR build: count / scan / fill --------------------
__global__ __launch_bounds__(256) void count_kernel(const int* __restrict__ eidx,
                                                    int* __restrict__ deg) {
    int e = blockIdx.x * 256 + threadIdx.x;
    atomicAdd(&deg[eidx[E_ + e]], 1);
}

__global__ __launch_bounds__(1024) void scan_kernel(const int* __restrict__ deg,
                                                    int* __restrict__ offs,
                                                    int* __restrict__ cursor) {
    __shared__ int tsum[1024];
    int t = threadIdx.x;
    int base = t * 32;
    int local[32];
    int s = 0;
#pragma unroll
    for (int i = 0; i < 32; ++i) { local[i] = deg[base + i]; s += local[i]; }
    tsum[t] = s;
    __syncthreads();
    for (int off = 1; off < 1024; off <<= 1) {
        int v = tsum[t];
        int add = (t >= off) ? tsum[t - off] : 0;
        __syncthreads();
        tsum[t] = v + add;
        __syncthreads();
    }
    int run = tsum[t] - s;
#pragma unroll
    for (int i = 0; i < 32; ++i) {
        offs[base + i] = run;
        cursor[base + i] = run;
        run += local[i];
    }
    if (t == 1023) offs[TN] = run;
}

// fill: dst-sorted src list + pre-gathered edge_attr (float4)
__global__ __launch_bounds__(256) void fill_kernel(const int* __restrict__ eidx,
                                                   const float* __restrict__ eattr,
                                                   int* __restrict__ cursor,
                                                   int* __restrict__ esrc,
                                                   float* __restrict__ easrt) {
    int e = blockIdx.x * 256 + threadIdx.x;
    int d = eidx[E_ + e];
    int pos = atomicAdd(&cursor[d], 1);
    esrc[pos] = eidx[e];
    *(float4*)(easrt + (size_t)pos * 4) = *(const float4*)(eattr + (size_t)e * 4);
}

// --- GINE gather v2: one WAVE per node, no barriers, 4 ch/lane -------------
__global__ __launch_bounds__(256) void gather_kernel(
    const short* __restrict__ abf, const float* __restrict__ atoms,
    const int* __restrict__ offs, const int* __restrict__ esrc,
    const float* __restrict__ easrt, const float* __restrict__ ew,
    const float* __restrict__ eb, short* __restrict__ x1bf) {
    int wv = threadIdx.x >> 6;
    int lane = threadIdx.x & 63;
    int node = blockIdx.x * 4 + wv;
    int c0 = lane * 4;
    float4 w0 = *(const float4*)(ew + c0);
    float4 w1 = *(const float4*)(ew + C_ + c0);
    float4 w2 = *(const float4*)(ew + 2 * C_ + c0);
    float4 w3 = *(const float4*)(ew + 3 * C_ + c0);
    float4 bb = *(const float4*)(eb + c0);
    int j = offs[node];
    int end = offs[node + 1];
    float4 acc = make_float4(0.f, 0.f, 0.f, 0.f);
    float4 acc2 = make_float4(0.f, 0.f, 0.f, 0.f);
    for (; j + 1 < end; j += 2) {
        int s0 = esrc[j];
        int s1 = esrc[j + 1];
        float4 e0 = *(const float4*)(easrt + (size_t)j * 4);
        float4 e1 = *(const float4*)(easrt + (size_t)(j + 1) * 4);
        uint2 p0 = *(const uint2*)(abf + (size_t)s0 * C_ + c0);
        uint2 p1 = *(const uint2*)(abf + (size_t)s1 * C_ + c0);
        float a0x = bflo(p0.x), a0y = bfhi(p0.x), a0z = bflo(p0.y), a0w = bfhi(p0.y);
        float a1x = bflo(p1.x), a1y = bfhi(p1.x), a1z = bflo(p1.y), a1w = bfhi(p1.y);
        float m;
        m = fmaf(e0.x, w0.x, fmaf(e0.y, w1.x, fmaf(e0.z, w2.x, fmaf(e0.w, w3.x, a0x + bb.x))));
        acc.x += fmaxf(m, 0.f);
        m = fmaf(e0.x, w0.y, fmaf(e0.y, w1.y, fmaf(e0.z, w2.y, fmaf(e0.w, w3.y, a0y + bb.y))));
        acc.y += fmaxf(m, 0.f);
        m = fmaf(e0.x, w0.z, fmaf(e0.y, w1.z, fmaf(e0.z, w2.z, fmaf(e0.w, w3.z, a0z + bb.z))));
        acc.z += fmaxf(m, 0.f);
        m = fmaf(e0.x, w0.w, fmaf(e0.y, w1.w, fmaf(e0.z, w2.w, fmaf(e0.w, w3.w, a0w + bb.w))));
        acc.w += fmaxf(m, 0.f);
        m = fmaf(e1.x, w0.x, fmaf(e1.y, w1.x, fmaf(e1.z, w2.x, fmaf(e1.w, w3.x, a1x + bb.x))));
        acc2.x += fmaxf(m, 0.f);
        m = fmaf(e1.x, w0.y, fmaf(e1.y, w1.y, fmaf(e1.z, w2.y, fmaf(e1.w, w3.y, a1y + bb.y))));
        acc2.y += fmaxf(m, 0.f);
        m = fmaf(e1.x, w0.z, fmaf(e1.y, w1.z, fmaf(e1.z, w2.z, fmaf(e1.w, w3.z, a1z + bb.z))));
        acc2.z += fmaxf(m, 0.f);
        m = fmaf(e1.x, w0.w, fmaf(e1.y, w1.w, fmaf(e1.z, w2.w, fmaf(e1.w, w3.w, a1w + bb.w))));
        acc2.w += fmaxf(m, 0.f);
    }
    if (j < end) {
        int s0 = esrc[j];
        float4 e0 = *(const float4*)(easrt + (size_t)j * 4);
        uint2 p0 = *(const uint2*)(abf + (size_t)s0 * C_ + c0);
        float a0x = bflo(p0.x), a0y = bfhi(p0.x), a0z = bflo(p0.y), a0w = bfhi(p0.y);
        float m;
        m = fmaf(e0.x, w0.x, fmaf(e0.y, w1.x, fmaf(e0.z, w2.x, fmaf(e0.w, w3.x, a0x + bb.x))));
        acc.x += fmaxf(m, 0.f);
        m = fmaf(e0.x, w0.y, fmaf(e0.y, w1.y, fmaf(e0.z, w2.y, fmaf(e0.w, w3.y, a0y + bb.y))));
        acc.y += fmaxf(m, 0.f);
        m = fmaf(e0.x, w0.z, fmaf(e0.y, w1.z, fmaf(e0.z, w2.z, fmaf(e0.w, w3.z, a0z + bb.z))));
        acc.z += fmaxf(m, 0.f);
        m = fmaf(e0.x, w0.w, fmaf(e0.y, w1.w, fmaf(e0.z, w2.w, fmaf(e0.w, w3.w, a0w + bb.w))));
        acc.w += fmaxf(m, 0.f);
    }
    float4 at = *(const float4*)(atoms + (size_t)node * C_ + c0);
    short4v o;
    o.x = f2bf(at.x + acc.x + acc2.x);
    o.y = f2bf(at.y + acc.y + acc2.y);
    o.z = f2bf(at.z + acc.z + acc2.z);
    o.w = f2bf(at.w + acc.w + acc2.w);
    *(short4v*)(x1bf + (size_t)node * C_ + c0) = o;
}

// ------------- fallback: atomic scatter (if ws too small) ------------------
__global__ __launch_bounds__(256) void scatter_kernel(
    const float* __restrict__ atoms, const float* __restrict__ eattr,
    const int* __restrict__ eidx, const float* __restrict__ ew,
    const float* __restrict__ eb, float* __restrict__ aggr) {
    int gid = blockIdx.x * 256 + threadIdx.x;
    int e = gid >> 6;
    int q = (gid & 63) << 2;
    int src = eidx[e];
    int dst = eidx[E_ + e];
    float4 ea = *(const float4*)(eattr + (size_t)e * 4);
    float4 w0 = *(const float4*)(ew + 0 * C_ + q);
    float4 w1 = *(const float4*)(ew + 1 * C_ + q);
    float4 w2 = *(const float4*)(ew + 2 * C_ + q);
    float4 w3 = *(const float4*)(ew + 3 * C_ + q);
    float4 bb = *(const float4*)(eb + q);
    float4 av = *(const float4*)(atoms + (size_t)src * C_ + q);
    float m0 = av.x + bb.x + ea.x * w0.x + ea.y * w1.x + ea.z * w2.x + ea.w * w3.x;
    float m1 = av.y + bb.y + ea.x * w0.y + ea.y * w1.y + ea.z * w2.y + ea.w * w3.y;
    float m2 = av.z + bb.z + ea.x * w0.z + ea.y * w1.z + ea.z * w2.z + ea.w * w3.z;
    float m3 = av.w + bb.w + ea.x * w0.w + ea.y * w1.w + ea.z * w2.w + ea.w * w3.w;
    float* base = aggr + (size_t)dst * C_ + q;
    atomicAdd(base + 0, fmaxf(m0, 0.f));
    atomicAdd(base + 1, fmaxf(m1, 0.f));
    atomicAdd(base + 2, fmaxf(m2, 0.f));
    atomicAdd(base + 3, fmaxf(m3, 0.f));
}

// --- weight transpose+cast: dst[rowBase+n][k] bf16 from W[l][k][n] fp32 ----
__global__ __launch_bounds__(256) void wt_kernel(const float* __restrict__ W,
                                                 short* __restrict__ Wt,
                                                 int K, int NC,
                                                 size_t lstride, int rowBase) {
    __shared__ short tile[64][65];
    int l = blockIdx.z;
    int k0 = blockIdx.y * 64, n0 = blockIdx.x * 64;
    const float* Wl = W + (size_t)l * K * NC;
    short* Wtl = Wt + (size_t)l * lstride + (size_t)rowBase * K;
    int t = threadIdx.x;
    int rr = t >> 4;
    int cc = (t & 15) * 4;
#pragma unroll
    for (int rep = 0; rep < 4; ++rep) {
        int r = rr + rep * 16;
        float4 v = *(const float4*)(Wl + (size_t)(k0 + r) * NC + n0 + cc);
        tile[cc + 0][r] = f2bf(v.x);
        tile[cc + 1][r] = f2bf(v.y);
        tile[cc + 2][r] = f2bf(v.z);
        tile[cc + 3][r] = f2bf(v.w);
    }
    __syncthreads();
#pragma unroll
    for (int rep = 0; rep < 4; ++rep) {
        int r = rr + rep * 16;
        short4v s;
        s.x = tile[r][cc + 0];
        s.y = tile[r][cc + 1];
        s.z = tile[r][cc + 2];
        s.w = tile[r][cc + 3];
        *(short4v*)(Wtl + (size_t)(n0 + r) * K + k0 + cc) = s;
    }
}

// ---------- proj cast: Pbf[l][m][d] bf16, padded to MP_ with zeros ---------
__global__ __launch_bounds__(256) void pcast_kernel(const float* __restrict__ proj,
                                                    short* __restrict__ Pbf) {
    int l = blockIdx.x;
    for (int idx = threadIdx.x; idx < MP_ * 64; idx += 256) {
        int m = idx >> 6, d = idx & 63;
        float v = (m < M_) ? proj[(size_t)l * M_ * 64 + m * 64 + d] : 0.f;
        Pbf[(size_t)l * MP_ * 64 + idx] = f2bf(v);
    }
}

// ---------------- MFMA bf16 matmul: Y = Xbf @ Wt (+epilogue) ---------------
// EPI: 0=none, 1=gelu, 2=+R1f(fp32), 3=+R1b(bf16)
// OUT: 0=fp32 rm, 1=bf16 rm, 3=QKV split (NC=768: Q|K rm 256; V transposed, Yv)
template <int EPI, int OUT>
__global__ __launch_bounds__(256) void mfmm_kernel(
    const short* __restrict__ Xb, const short* __restrict__ Wt,
    const float* __restrict__ bias, const float* __restrict__ R1f,
    const short* __restrict__ R1b, void* __restrict__ Yout,
    short* __restrict__ Yv, int K, int NC) {
    __shared__ short As[128][56];
    __shared__ short Bs[128][56];
    int tid = threadIdx.x;
    int rowBase = blockIdx.y * 128, colBase = blockIdx.x * 128;
    int w = tid >> 6, lane = tid & 63;
    int wm = w & 1, wn = w >> 1;
    int quad = lane >> 4, l16 = lane & 15;
    int sr = tid >> 1;
    int sk = (tid & 1) * 16;
    const short* Xp = Xb + (size_t)(rowBase + sr) * K + sk;
    const short* Wp = Wt + (size_t)(colBase + sr) * K + sk;
    floatx4 acc[4][4];
#pragma unroll
    for (int i = 0; i < 4; ++i)
#pragma unroll
        for (int j = 0; j < 4; ++j)
            acc[i][j] = (floatx4){0.f, 0.f, 0.f, 0.f};
    for (int k0 = 0; k0 < K; k0 += 32) {
        short8 xa0 = *(const short8*)(Xp + k0);
        short8 xa1 = *(const short8*)(Xp + k0 + 8);
        short8 wb0 = *(const short8*)(Wp + k0);
        short8 wb1 = *(const short8*)(Wp + k0 + 8);
        __syncthreads();
        *(short8*)&As[sr][sk] = xa0;
        *(short8*)&As[sr][sk + 8] = xa1;
        *(short8*)&Bs[sr][sk] = wb0;
        *(short8*)&Bs[sr][sk + 8] = wb1;
        __syncthreads();
        short8 a[4], b[4];
#pragma unroll
        for (int mi = 0; mi < 4; ++mi)
            a[mi] = *(const short8*)&As[wm * 64 + mi * 16 + l16][quad * 8];
#pragma unroll
        for (int ni = 0; ni < 4; ++ni)
            b[ni] = *(const short8*)&Bs[wn * 64 + ni * 16 + l16][quad * 8];
#pragma unroll
        for (int mi = 0; mi < 4; ++mi)
#pragma unroll
            for (int ni = 0; ni < 4; ++ni)
                acc[mi][ni] = __builtin_amdgcn_mfma_f32_16x16x32_bf16(
                    a[mi], b[ni], acc[mi][ni], 0, 0, 0);
    }
    if (OUT == 3) {
        int region = colBase >> 8;   // 0=Q, 1=K, 2=V
        if (region < 2) {
            short* dst = (short*)Yout + (size_t)region * (size_t)TN * 256;
#pragma unroll
            for (int ni = 0; ni < 4; ++ni) {
                int cl = (colBase + wn * 64 + ni * 16 + l16) & 255;
#pragma unroll
                for (int mi = 0; mi < 4; ++mi) {
#pragma unroll
                    for (int r = 0; r < 4; ++r) {
                        int rowg = rowBase + wm * 64 + mi * 16 + quad * 4 + r;
                        dst[(size_t)rowg * 256 + cl] = f2bf(acc[mi][ni][r]);
                    }
                }
            }
        } else {
#pragma unroll
            for (int ni = 0; ni < 4; ++ni) {
                int cl = (colBase + wn * 64 + ni * 16 + l16) & 255;
                int hh = cl >> 6, dd = cl & 63;
#pragma unroll
                for (int mi = 0; mi < 4; ++mi) {
                    int rowg0 = rowBase + wm * 64 + mi * 16 + quad * 4;
                    int bb = rowg0 >> 9, ng = rowg0 & 511;
                    short4v pv;
#pragma unroll
                    for (int r = 0; r < 4; ++r) pv[r] = f2bf(acc[mi][ni][r]);
                    *(short4v*)(Yv + (((size_t)bb * 4 + hh) * 64 + dd) * 512 + ng) = pv;
                }
            }
        }
        return;
    }
#pragma unroll
    for (int ni = 0; ni < 4; ++ni) {
        int colg = colBase + wn * 64 + ni * 16 + l16;
        float bv = bias ? bias[colg] : 0.f;
#pragma unroll
        for (int mi = 0; mi < 4; ++mi) {
#pragma unroll
            for (int r = 0; r < 4; ++r) {
                int rowg = rowBase + wm * 64 + mi * 16 + quad * 4 + r;
                float y = acc[mi][ni][r] + bv;
                if (EPI == 1) y = gelu_exact(y);
                if (EPI == 2) y += R1f[(size_t)rowg * NC + colg];
                if (EPI == 3) y += bf2f(R1b[(size_t)rowg * NC + colg]);
                if (OUT == 0)
                    ((float*)Yout)[(size_t)rowg * NC + colg] = y;
                else
                    ((short*)Yout)[(size_t)rowg * NC + colg] = f2bf(y);
            }
        }
    }
}

// ------------- fallback fp32 tiled matmul (old path) -----------------------
template <bool IN_ADD, int EPI>
__global__ __launch_bounds__(256) void mm_kernel(
    const float* __restrict__ X, const float* __restrict__ X2,
    const float* __restrict__ W, const float* __restrict__ bias,
    const float* __restrict__ R1, const float* __restrict__ R2,
    float* __restrict__ Y, int K, int NC) {
    __shared__ float Xs[16][65];
    __shared__ float Ws[16][68];
    int tid = threadIdx.x;
    int tx = tid & 15, ty = tid >> 4;
    int rowBase = blockIdx.y * 64;
    int colBase = blockIdx.x * 64;
    int lr = tid >> 2;
    int lk = (tid & 3) << 2;
    int wk = tid >> 4;
    int wc = (tid & 15) << 2;
    const float* Xp = X + (size_t)(rowBase + lr) * K + lk;
    const float* X2p = IN_ADD ? (X2 + (size_t)(rowBase + lr) * K + lk) : X;
    const float* Wp = W + (size_t)wk * NC + colBase + wc;
    float acc[4][4] = {};
    for (int k0 = 0; k0 < K; k0 += 16) {
        float4 xv = *(const float4*)(Xp + k0);
        if (IN_ADD) {
            float4 x2 = *(const float4*)(X2p + k0);
            xv.x += x2.x; xv.y += x2.y; xv.z += x2.z; xv.w += x2.w;
        }
        float4 wv = *(const float4*)(Wp + (size_t)k0 * NC);
        __syncthreads();
        Xs[lk + 0][lr] = xv.x;
        Xs[lk + 1][lr] = xv.y;
        Xs[lk + 2][lr] = xv.z;
        Xs[lk + 3][lr] = xv.w;
        *(float4*)&Ws[wk][wc] = wv;
        __syncthreads();
#pragma unroll
        for (int kk = 0; kk < 16; ++kk) {
            float a[4], b[4];
#pragma unroll
            for (int i = 0; i < 4; ++i) a[i] = Xs[kk][ty * 4 + i];
#pragma unroll
            for (int j = 0; j < 4; ++j) b[j] = Ws[kk][tx * 4 + j];
#pragma unroll
            for (int i = 0; i < 4; ++i)
#pragma unroll
                for (int j = 0; j < 4; ++j) acc[i][j] = fmaf(a[i], b[j], acc[i][j]);
        }
    }
    int c0 = colBase + tx * 4;
    float4 bv = make_float4(0.f, 0.f, 0.f, 0.f);
    if (bias) bv = *(const float4*)(bias + c0);
#pragma unroll
    for (int i = 0; i < 4; ++i) {
        int r = rowBase + ty * 4 + i;
        float4 y;
        y.x = acc[i][0] + bv.x; y.y = acc[i][1] + bv.y;
        y.z = acc[i][2] + bv.z; y.w = acc[i][3] + bv.w;
        if (EPI == 1) {
            y.x = gelu_exact(y.x); y.y = gelu_exact(y.y);
            y.z = gelu_exact(y.z); y.w = gelu_exact(y.w);
        }
        if (EPI >= 2) {
            float4 r1 = *(const float4*)(R1 + (size_t)r * NC + c0);
            y.x += r1.x; y.y += r1.y; y.z += r1.z; y.w += r1.w;
        }
        if (EPI == 3) {
            float4 r2 = *(const float4*)(R2 + (size_t)r * NC + c0);
            y.x += r2.x; y.y += r2.y; y.z += r2.z; y.w += r2.w;
        }
        *(float4*)(Y + (size_t)r * NC + c0) = y;
    }
}

// ------------------------------ LayerNorms ---------------------------------
__global__ __launch_bounds__(256) void ln_kernel(
    const float* __restrict__ X, const float* __restrict__ g,
    const float* __restrict__ bta, float* __restrict__ Y) {
    __shared__ float rs[4], rs2[4];
    __shared__ float mu_s, inv_s;
    int row = blockIdx.x, t = threadIdx.x;
    size_t off = (size_t)row * C_ + t;
    float v = X[off];
    float s = v, s2 = v * v;
#pragma unroll
    for (int o = 32; o > 0; o >>= 1) {
        s += __shfl_down(s, o);
        s2 += __shfl_down(s2, o);
    }
    int w = t >> 6, lane = t & 63;
    if (lane == 0) { rs[w] = s; rs2[w] = s2; }
    __syncthreads();
    if (t == 0) {
        float tot = rs[0] + rs[1] + rs[2] + rs[3];
        float tot2 = rs2[0] + rs2[1] + rs2[2] + rs2[3];
        float mu = tot * (1.f / C_);
        float var = tot2 * (1.f / C_) - mu * mu;
        mu_s = mu;
        inv_s = rsqrtf(var + LN_EPS_);
    }
    __syncthreads();
    Y[off] = (v - mu_s) * inv_s * g[t] + bta[t];
}

// ln2: SUMbf = bf16( HL + LN(HAbf) )
__global__ __launch_bounds__(256) void ln2_kernel(
    const short* __restrict__ Xb, const float* __restrict__ g,
    const float* __restrict__ bta, const float* __restrict__ addf,
    short* __restrict__ outBf) {
    __shared__ float rs[4], rs2[4];
    __shared__ float mu_s, inv_s;
    int row = blockIdx.x, t = threadIdx.x;
    size_t off = (size_t)row * C_ + t;
    float v = bf2f(Xb[off]);
    float s = v, s2 = v * v;
#pragma unroll
    for (int o = 32; o > 0; o >>= 1) {
        s += __shfl_down(s, o);
        s2 += __shfl_down(s2, o);
    }
    int w = t >> 6, lane = t & 63;
    if (lane == 0) { rs[w] = s; rs2[w] = s2; }
    __syncthreads();
    if (t == 0) {
        float tot = rs[0] + rs[1] + rs[2] + rs[3];
        float tot2 = rs2[0] + rs2[1] + rs2[2] + rs2[3];
        float mu = tot * (1.f / C_);
        float var = tot2 * (1.f / C_) - mu * mu;
        mu_s = mu;
        inv_s = rsqrtf(var + LN_EPS_);
    }
    __syncthreads();
    float y = (v - mu_s) * inv_s * g[t] + bta[t];
    outBf[off] = f2bf(y + addf[off]);
}

// ln3: A = LN(X), Abf = bf16(A)
__global__ __launch_bounds__(256) void ln3_kernel(
    const float* __restrict__ X, const float* __restrict__ g,
    const float* __restrict__ bta, float* __restrict__ Y,
    short* __restrict__ Ybf) {
    __shared__ float rs[4], rs2[4];
    __shared__ float mu_s, inv_s;
    int row = blockIdx.x, t = threadIdx.x;
    size_t off = (size_t)row * C_ + t;
    float v = X[off];
    float s = v, s2 = v * v;
#pragma unroll
    for (int o = 32; o > 0; o >>= 1) {
        s += __shfl_down(s, o);
        s2 += __shfl_down(s2, o);
    }
    int w = t >> 6, lane = t & 63;
    if (lane == 0) { rs[w] = s; rs2[w] = s2; }
    __syncthreads();
    if (t == 0) {
        float tot = rs[0] + rs[1] + rs[2] + rs[3];
        float tot2 = rs2[0] + rs2[1] + rs2[2] + rs2[3];
        float mu = tot * (1.f / C_);
        float var = tot2 * (1.f / C_) - mu * mu;
        mu_s = mu;
        inv_s = rsqrtf(var + LN_EPS_);
    }
    __syncthreads();
    float y = (v - mu_s) * inv_s * g[t] + bta[t];
    Y[off] = y;
    Ybf[off] = f2bf(y);
}

// ---------- MFMA Performer pass 1: ctxT[bh][d][m], ksum[bh][m] -------------
__global__ __launch_bounds__(256) void p1m_kernel(
    const short* __restrict__ Kbf, const short* __restrict__ VbfT,
    const short* __restrict__ Pbf, short* __restrict__ ctxT,
    float* __restrict__ ksum) {
    int mt = blockIdx.x;
    int bh = blockIdx.y;
    int b = bh >> 2, h = bh & 3;
    __shared__ short Ps[64][72];
    __shared__ short Ks[64][72];
    __shared__ short VTs[64][72];
    __shared__ short Ss[64][72];
    __shared__ float kred[4][64];
    int tid = threadIdx.x;
    int w = tid >> 6, lane = tid & 63;
    int quad = lane >> 4, l16 = lane & 15;
    int lr = tid >> 2, lb = (tid & 3) << 4;
    {
        const short* p = Pbf + ((size_t)(mt * 64 + lr)) * 64 + lb;
        *(short8*)&Ps[lr][lb] = *(const short8*)p;
        *(short8*)&Ps[lr][lb + 8] = *(const short8*)(p + 8);
    }
    floatx4 cacc[4];
#pragma unroll
    for (int i = 0; i < 4; ++i) cacc[i] = (floatx4){0.f, 0.f, 0.f, 0.f};
    float kacc[4] = {0.f, 0.f, 0.f, 0.f};
    size_t kbase = ((size_t)(b * 512)) * 256 + h * 64;
    size_t vbase = ((size_t)(bh * 64)) * 512;
    for (int nt = 0; nt < 8; ++nt) {
        __syncthreads();
        {
            const short* kp = Kbf + kbase + (size_t)(nt * 64 + lr) * 256 + lb;
            *(short8*)&Ks[lr][lb] = *(const short8*)kp;
            *(short8*)&Ks[lr][lb + 8] = *(const short8*)(kp + 8);
            const short* vp = VbfT + vbase + (size_t)lr * 512 + nt * 64 + lb;
            *(short8*)&VTs[lr][lb] = *(const short8*)vp;
            *(short8*)&VTs[lr][lb + 8] = *(const short8*)(vp + 8);
        }
        __syncthreads();
        floatx4 sa[4];
#pragma unroll
        for (int mi = 0; mi < 4; ++mi) sa[mi] = (floatx4){0.f, 0.f, 0.f, 0.f};
#pragma unroll
        for (int kt = 0; kt < 2; ++kt) {
            short8 a = *(const short8*)&Ks[w * 16 + l16][kt * 32 + quad * 8];
#pragma unroll
            for (int mi = 0; mi < 4; ++mi) {
                short8 bq = *(const short8*)&Ps[mi * 16 + l16][kt * 32 + quad * 8];
                sa[mi] = __builtin_amdgcn_mfma_f32_16x16x32_bf16(a, bq, sa[mi], 0, 0, 0);
            }
        }
#pragma unroll
        for (int mi = 0; mi < 4; ++mi) {
            int mg = mt * 64 + mi * 16 + l16;
            short4v sv;
            float kl = 0.f;
#pragma unroll
            for (int r = 0; r < 4; ++r) {
                float v = (mg < M_) ? (fmaxf(sa[mi][r], 0.f) + EPSK_) : 0.f;
                sv[r] = f2bf(v);
                kl += v;
            }
            kacc[mi] += kl;
            *(short4v*)&Ss[mi * 16 + l16][w * 16 + quad * 4] = sv;
        }
        __syncthreads();
#pragma unroll
        for (int kt = 0; kt < 2; ++kt) {
            short8 a = *(const short8*)&Ss[w * 16 + l16][kt * 32 + quad * 8];
#pragma unroll
            for (int di = 0; di < 4; ++di) {
                short8 bv = *(const short8*)&VTs[di * 16 + l16][kt * 32 + quad * 8];
                cacc[di] = __builtin_amdgcn_mfma_f32_16x16x32_bf16(a, bv, cacc[di], 0, 0, 0);
            }
        }
    }
    size_t cbase = ((size_t)bh * 64) * MP_ + mt * 64;
#pragma unroll
    for (int di = 0; di < 4; ++di) {
        int d = di * 16 + l16;
        short4v cv;
#pragma unroll
        for (int r = 0; r < 4; ++r) cv[r] = f2bf(cacc[di][r]);
        *(short4v*)(ctxT + cbase + (size_t)d * MP_ + w * 16 + quad * 4) = cv;
    }
#pragma unroll
    for (int mi = 0; mi < 4; ++mi) {
        kacc[mi] += __shfl_down(kacc[mi], 32);
        kacc[mi] += __shfl_down(kacc[mi], 16);
    }
    if (lane < 16) {
#pragma unroll
        for (int mi = 0; mi < 4; ++mi) kred[w][mi * 16 + lane] = kacc[mi];
    }
    __syncthreads();
    if (tid < 64)
        ksum[(size_t)bh * MP_ + mt * 64 + tid] =
            kred[0][tid] + kred[1][tid] + kred[2][tid] + kred[3][tid];
}

// ---------- MFMA Performer pass 2: attbf = bf16((qp@ctx)/(qp@ksum)) --------
__global__ __launch_bounds__(256) void p2m_kernel(
    const short* __restrict__ Qbf, const short* __restrict__ Pbf,
    const short* __restrict__ ctxT, const float* __restrict__ ksum,
    short* __restrict__ attbf) {
    int nt = blockIdx.x;
    int bh = blockIdx.y;
    int b = bh >> 2, h = bh & 3;
    __shared__ short Qs[64][72];
    __shared__ short Ps[64][72];
    __shared__ short CTs[64][72];
    __shared__ short Ss[64][72];
    __shared__ float kss[64];
    __shared__ float dredS[64];
    __shared__ float dinvS[64];
    int tid = threadIdx.x;
    int w = tid >> 6, lane = tid & 63;
    int quad = lane >> 4, l16 = lane & 15;
    int lr = tid >> 2, lb = (tid & 3) << 4;
    size_t qbase = ((size_t)(b * 512)) * 256 + h * 64;
    {
        const short* qp = Qbf + qbase + (size_t)(nt * 64 + lr) * 256 + lb;
        *(short8*)&Qs[lr][lb] = *(const short8*)qp;
        *(short8*)&Qs[lr][lb + 8] = *(const short8*)(qp + 8);
    }
    floatx4 aacc[4];
#pragma unroll
    for (int i = 0; i < 4; ++i) aacc[i] = (floatx4){0.f, 0.f, 0.f, 0.f};
    float dd[4] = {0.f, 0.f, 0.f, 0.f};
    size_t cb = ((size_t)bh * 64) * MP_;
    for (int mt = 0; mt < 5; ++mt) {
        __syncthreads();
        {
            const short* p = Pbf + ((size_t)(mt * 64 + lr)) * 64 + lb;
            *(short8*)&Ps[lr][lb] = *(const short8*)p;
            *(short8*)&Ps[lr][lb + 8] = *(const short8*)(p + 8);
            const short* cp = ctxT + cb + (size_t)lr * MP_ + mt * 64 + lb;
            *(short8*)&CTs[lr][lb] = *(const short8*)cp;
            *(short8*)&CTs[lr][lb + 8] = *(const short8*)(cp + 8);
        }
        if (tid < 64) kss[tid] = ksum[(size_t)bh * MP_ + mt * 64 + tid];
        __syncthreads();
        floatx4 sa[4];
#pragma unroll
        for (int mi = 0; mi < 4; ++mi) sa[mi] = (floatx4){0.f, 0.f, 0.f, 0.f};
#pragma unroll
        for (int kt = 0; kt < 2; ++kt) {
            short8 a = *(const short8*)&Qs[w * 16 + l16][kt * 32 + quad * 8];
#pragma unroll
            for (int mi = 0; mi < 4; ++mi) {
                short8 bq = *(const short8*)&Ps[mi * 16 + l16][kt * 32 + quad * 8];
                sa[mi] = __builtin_amdgcn_mfma_f32_16x16x32_bf16(a, bq, sa[mi], 0, 0, 0);
            }
        }
#pragma unroll
        for (int mi = 0; mi < 4; ++mi) {
            int mg = mt * 64 + mi * 16 + l16;
            float ksv = kss[mi * 16 + l16];
#pragma unroll
            for (int r = 0; r < 4; ++r) {
                float v = (mg < M_) ? (fmaxf(sa[mi][r], 0.f) + EPSK_) : 0.f;
                Ss[w * 16 + quad * 4 + r][mi * 16 + l16] = f2bf(v);
                dd[r] += v * ksv;
            }
        }
        __syncthreads();
#pragma unroll
        for (int kt = 0; kt < 2; ++kt) {
            short8 a = *(const short8*)&Ss[w * 16 + l16][kt * 32 + quad * 8];
#pragma unroll
            for (int di = 0; di < 4; ++di) {
                short8 bv = *(const short8*)&CTs[di * 16 + l16][kt * 32 + quad * 8];
                aacc[di] = __builtin_amdgcn_mfma_f32_16x16x32_bf16(a, bv, aacc[di], 0, 0, 0);
            }
        }
    }
#pragma unroll
    for (int r = 0; r < 4; ++r) {
        dd[r] += __shfl_xor(dd[r], 1);
        dd[r] += __shfl_xor(dd[r], 2);
        dd[r] += __shfl_xor(dd[r], 4);
        dd[r] += __shfl_xor(dd[r], 8);
    }
    if (l16 == 0) {
#pragma unroll
        for (int r = 0; r < 4; ++r) dredS[w * 16 + quad * 4 + r] = dd[r];
    }
    __syncthreads();
    if (tid < 64) dinvS[tid] = 1.f / dredS[tid];
    __syncthreads();
#pragma unroll
    for (int di = 0; di < 4; ++di) {
        int d = di * 16 + l16;
#pragma unroll
        for (int r = 0; r < 4; ++r) {
            int n = w * 16 + quad * 4 + r;
            attbf[((size_t)(b * 512 + nt * 64 + n)) * 256 + h * 64 + d] =
                f2bf(aacc[di][r] * dinvS[n]);
        }
    }
}

// ---------------- fp32 Performer fallbacks (old path) ----------------------
__global__ __launch_bounds__(256) void p1_kernel(
    const float* __restrict__ kbuf, const float* __restrict__ vbuf,
    const float* __restrict__ proj, float* __restrict__ ctx,
    float* __restrict__ ksum) {
    int mt = blockIdx.x;
    int bh = blockIdx.y;
    int b = bh >> 2, h = bh & 3;
    __shared__ float Pt[64][65];
    __shared__ float KV[64][65];
    __shared__ float S[64][65];
    int tid = threadIdx.x;
    int tx = tid & 15, ty = tid >> 4;
    for (int idx = tid; idx < 4096; idx += 256) {
        int r = idx >> 6, c = idx & 63;
        int mg = mt * 64 + r;
        Pt[r][c] = (mg < M_) ? proj[mg * DH_ + c] : 0.f;
    }
    float cacc[4][4] = {};
    float ksacc = 0.f;
    size_t base = ((size_t)b * N_) * C_ + h * DH_;
    for (int nt = 0; nt < 8; ++nt) {
        __syncthreads();
        for (int idx = tid; idx < 4096; idx += 256) {
            int r = idx >> 6, c = idx & 63;
            KV[r][c] = kbuf[base + (size_t)(nt * 64 + r) * C_ + c];
        }
        __syncthreads();
        float s[4][4] = {};
        for (int dd = 0; dd < 64; ++dd) {
            float a[4], bq[4];
#pragma unroll
            for (int i = 0; i < 4; ++i) a[i] = KV[ty * 4 + i][dd];
#pragma unroll
            for (int j = 0; j < 4; ++j) bq[j] = Pt[16 * j + tx][dd];
#pragma unroll
            for (int i = 0; i < 4; ++i)
#pragma unroll
                for (int j = 0; j < 4; ++j) s[i][j] = fmaf(a[i], bq[j], s[i][j]);
        }
        __syncthreads();
#pragma unroll
        for (int i = 0; i < 4; ++i)
#pragma unroll
            for (int j = 0; j < 4; ++j) {
                int mg = mt * 64 + 16 * j + tx;
                S[ty * 4 + i][16 * j + tx] =
                    (mg < M_) ? (fmaxf(s[i][j], 0.f) + EPSK_) : 0.f;
            }
        for (int idx = tid; idx < 4096; idx += 256) {
            int r = idx >> 6, c = idx & 63;
            KV[r][c] = vbuf[base + (size_t)(nt * 64 + r) * C_ + c];
        }
        __syncthreads();
        for (int nn = 0; nn < 64; ++nn) {
            float sm[4], vd[4];
#pragma unroll
            for (int i = 0; i < 4; ++i) sm[i] = S[nn][ty * 4 + i];
#pragma unroll
            for (int j = 0; j < 4; ++j) vd[j] = KV[nn][tx * 4 + j];
#pragma unroll
            for (int i = 0; i < 4; ++i)
#pragma unroll
                for (int j = 0; j < 4; ++j) cacc[i][j] = fmaf(sm[i], vd[j], cacc[i][j]);
        }
        if (tid < 64) {
            for (int nn = 0; nn < 64; ++nn) ksacc += S[nn][tid];
        }
    }
    float* cp = ctx + ((size_t)bh * MP_ + mt * 64) * DH_;
#pragma unroll
    for (int i = 0; i < 4; ++i)
#pragma unroll
        for (int j = 0; j < 4; ++j)
            cp[(ty * 4 + i) * DH_ + tx * 4 + j] = cacc[i][j];
    if (tid < 64) ksum[bh * MP_ + mt * 64 + tid] = ksacc;
}

__global__ __launch_bounds__(256) void p2_kernel(
    const float* __restrict__ qbuf, const float* __restrict__ proj,
    const float* __restrict__ ctx, const float* __restrict__ ksum,
    float* __restrict__ attout) {
    int nt = blockIdx.x;
    int bh = blockIdx.y;
    int b = bh >> 2, h = bh & 3;
    __shared__ float Qt[64][65];
    __shared__ float PC[64][65];
    __shared__ float S[64][65];
    __shared__ float ks[64], dinv[64];
    int tid = threadIdx.x;
    int tx = tid & 15, ty = tid >> 4;
    size_t base = ((size_t)b * N_) * C_ + h * DH_;
    for (int idx = tid; idx < 4096; idx += 256) {
        int r = idx >> 6, c = idx & 63;
        Qt[r][c] = qbuf[base + (size_t)(nt * 64 + r) * C_ + c];
    }
    float aacc[4][4] = {};
    float dacc = 0.f;
    for (int mt = 0; mt < 5; ++mt) {
        __syncthreads();
        for (int idx = tid; idx < 4096; idx += 256) {
            int r = idx >> 6, c = idx & 63;
            int mg = mt * 64 + r;
            PC[r][c] = (mg < M_) ? proj[mg * DH_ + c] : 0.f;
        }
        if (tid < 64) ks[tid] = ksum[bh * MP_ + mt * 64 + tid];
        __syncthreads();
        float s[4][4] = {};
        for (int dd = 0; dd < 64; ++dd) {
            float a[4], bq[4];
#pragma unroll
            for (int i = 0; i < 4; ++i) a[i] = Qt[ty * 4 + i][dd];
#pragma unroll
            for (int j = 0; j < 4; ++j) bq[j] = PC[16 * j + tx][dd];
#pragma unroll
            for (int i = 0; i < 4; ++i)
#pragma unroll
                for (int j = 0; j < 4; ++j) s[i][j] = fmaf(a[i], bq[j], s[i][j]);
        }
        __syncthreads();
#pragma unroll
        for (int i = 0; i < 4; ++i)
#pragma unroll
            for (int j = 0; j < 4; ++j) {
                int mg = mt * 64 + 16 * j + tx;
                S[ty * 4 + i][16 * j + tx] =
                    (mg < M_) ? (fmaxf(s[i][j], 0.f) + EPSK_) : 0.f;
            }
        for (int idx = tid; idx < 4096; idx += 256) {
            int r = idx >> 6, c = idx & 63;
            PC[r][c] = ctx[((size_t)bh * MP_ + mt * 64 + r) * DH_ + c];
        }
        __syncthreads();
        for (int mm = 0; mm < 64; ++mm) {
            float sm[4], cd[4];
#pragma unroll
            for (int i = 0; i < 4; ++i) sm[i] = S[ty * 4 + i][mm];
#pragma unroll
            for (int j = 0; j < 4; ++j) cd[j] = PC[mm][tx * 4 + j];
#pragma unroll
            for (int i = 0; i < 4; ++i)
#pragma unroll
                for (int j = 0; j < 4; ++j) aacc[i][j] = fmaf(sm[i], cd[j], aacc[i][j]);
        }
        if (tid < 64) {
            for (int mm = 0; mm < 64; ++mm) dacc = fmaf(S[tid][mm], ks[mm], dacc);
        }
    }
    __syncthreads();
    if (tid < 64) dinv[tid] = 1.f / dacc;
    __syncthreads();
#pragma unroll
    for (int i = 0; i < 4; ++i) {
        int n = ty * 4 + i;
        float di = dinv[n];
        float4 y = make_float4(aacc[i][0] * di, aacc[i][1] * di,
                               aacc[i][2] * di, aacc[i][3] * di);
        *(float4*)(attout + base + (size_t)(nt * 64 + n) * C_ + tx * 4) = y;
    }
}

// -------------------- mean pool: direct, no atomics ------------------------
__global__ __launch_bounds__(256) void pool_kernel(const float* __restrict__ atoms,
                                                   float* __restrict__ out) {
    int b = blockIdx.x;
    int c = threadIdx.x;
    const float* p = atoms + (size_t)b * N_ * C_ + c;
    float s = 0.f;
    for (int n = 0; n < N_; ++n) s += p[(size_t)n * C_];
    out[b * C_ + c] = s * (1.f / 512.f);
}

extern "C" void kernel_launch(void* const* d_in, const int* in_sizes, int n_in,
                              void* d_out, int out_size, void* d_ws, size_t ws_size,
                              hipStream_t stream) {
    (void)in_sizes; (void)n_in; (void)out_size;
    const float* x = (const float*)d_in[0];
    const float* edge_attr = (const float*)d_in[1];
    const int* edge_index = (const int*)d_in[2];
    const float* node_w = (const float*)d_in[4];
    const float* node_b = (const float*)d_in[5];
    const float* edge_w = (const float*)d_in[6];
    const float* edge_b = (const float*)d_in[7];
    const float* gine_w1 = (const float*)d_in[8];
    const float* gine_b1 = (const float*)d_in[9];
    const float* gine_w2 = (const float*)d_in[10];
    const float* gine_b2 = (const float*)d_in[11];
    const float* q_w = (const float*)d_in[12];
    const float* k_w = (const float*)d_in[13];
    const float* v_w = (const float*)d_in[14];
    const float* o_w = (const float*)d_in[15];
    const float* o_b = (const float*)d_in[16];
    const float* proj = (const float*)d_in[17];
    const float* n1g = (const float*)d_in[18];
    const float* n1b = (const float*)d_in[19];
    const float* n2g = (const float*)d_in[20];
    const float* n2b = (const float*)d_in[21];
    const float* n3g = (const float*)d_in[22];
    const float* n3b = (const float*)d_in[23];
    const float* mw1 = (const float*)d_in[24];
    const float* mb1 = (const float*)d_in[25];
    const float* mw2 = (const float*)d_in[26];
    const float* mb2 = (const float*)d_in[27];

    const size_t SZ = (size_t)TN * C_;   // 8,388,608
    float* ws = (float*)d_ws;
    float* A     = ws;
    short* Abf   = (short*)(ws + SZ);
    float* HL    = ws + SZ + SZ / 2;
    float* R3    = HL;
    short* SUMbf = (short*)(ws + 2 * SZ + SZ / 2);
    short* X1bf  = (short*)(ws + 3 * SZ);
    short* t1bf  = X1bf + SZ;
    short* t2bf  = X1bf;
    short* Qbf   = (short*)(ws + 4 * SZ);
    short* Kbf   = Qbf + SZ;
    short* ATTbf = Kbf;
    short* HAbf  = Qbf;
    short* VbfT  = (short*)(ws + 5 * SZ);
    short* ctxTb = VbfT + SZ;
    float* KS2   = (float*)(ctxTb + (size_t)256 * 64 * MP_);

    int* deg    = (int*)(ws + 6 * SZ);
    int* offs   = deg + TN;
    int* cursor = offs + TN + 1;
    int* esrc   = cursor + TN;
    float* easrt = (float*)(((uintptr_t)(esrc + E_) + 15) & ~(uintptr_t)15);
    short* WTg1  = (short*)(easrt + (size_t)4 * E_);
    short* WTg2  = WTg1 + (size_t)5 * 65536;
    short* WTqkv = WTg2 + (size_t)5 * 65536;
    short* WTo   = WTqkv + (size_t)5 * 196608;
    short* WTm1  = WTo + (size_t)5 * 65536;
    short* WTm2  = WTm1 + (size_t)5 * 131072;
    short* Pbf   = WTm2 + (size_t)5 * 131072;
    size_t need = 6 * SZ * sizeof(float) +
                  (size_t)(3 * TN + 1 + E_) * sizeof(int) + 16 +
                  (size_t)4 * E_ * sizeof(float) +
                  ((size_t)5 * (3 * 65536 + 196608 + 2 * 131072 + MP_ * 64)) *
                      sizeof(short);
    bool full = ws_size >= need;

    dim3 gm256(2, 256), gm512(4, 256), gm768(6, 256);
    dim3 g256(4, 512), g512(8, 512);

    embed_kernel<<<TN, 256, 0, stream>>>(x, node_w, node_b, A, Abf);
    if (full) {
        hipMemsetAsync(deg, 0, TN * sizeof(int), stream);
        count_kernel<<<E_ / 256, 256, 0, stream>>>(edge_index, deg);
        scan_kernel<<<1, 1024, 0, stream>>>(deg, offs, cursor);
        fill_kernel<<<E_ / 256, 256, 0, stream>>>(edge_index, edge_attr, cursor,
                                                  esrc, easrt);
        wt_kernel<<<dim3(4, 4, L_), 256, 0, stream>>>(gine_w1, WTg1, 256, 256, 65536, 0);
        wt_kernel<<<dim3(4, 4, L_), 256, 0, stream>>>(gine_w2, WTg2, 256, 256, 65536, 0);
        wt_kernel<<<dim3(4, 4, L_), 256, 0, stream>>>(q_w, WTqkv, 256, 256, 196608, 0);
        wt_kernel<<<dim3(4, 4, L_), 256, 0, stream>>>(k_w, WTqkv, 256, 256, 196608, 256);
        wt_kernel<<<dim3(4, 4, L_), 256, 0, stream>>>(v_w, WTqkv, 256, 256, 196608, 512);
        wt_kernel<<<dim3(4, 4, L_), 256, 0, stream>>>(o_w, WTo, 256, 256, 65536, 0);
        wt_kernel<<<dim3(8, 4, L_), 256, 0, stream>>>(mw1, WTm1, 256, 512, 131072, 0);
        wt_kernel<<<dim3(4, 8, L_), 256, 0, stream>>>(mw2, WTm2, 512, 256, 131072, 0);
        pcast_kernel<<<L_, 256, 0, stream>>>(proj, Pbf);
    }
    for (int l = 0; l < L_; ++l) {
        if (full) {
            gather_kernel<<<TN / 4, 256, 0, stream>>>(Abf, A, offs, esrc, easrt,
                                                      edge_w, edge_b, X1bf);
            mfmm_kernel<1, 1><<<gm256, 256, 0, stream>>>(
                X1bf, WTg1 + (size_t)l * 65536, gine_b1 + l * 256,
                nullptr, nullptr, t1bf, nullptr, 256, 256);
            mfmm_kernel<2, 0><<<gm256, 256, 0, stream>>>(
                t1bf, WTg2 + (size_t)l * 65536, gine_b2 + l * 256,
                A, nullptr, HL, nullptr, 256, 256);
            ln_kernel<<<TN, 256, 0, stream>>>(HL, n1g + l * 256, n1b + l * 256, HL);
            mfmm_kernel<0, 3><<<gm768, 256, 0, stream>>>(
                Abf, WTqkv + (size_t)l * 196608, nullptr,
                nullptr, nullptr, Qbf, VbfT, 256, 768);
            p1m_kernel<<<dim3(5, 256), 256, 0, stream>>>(
                Kbf, VbfT, Pbf + (size_t)l * MP_ * 64, ctxTb, KS2);
            p2m_kernel<<<dim3(8, 256), 256, 0, stream>>>(
                Qbf, Pbf + (size_t)l * MP_ * 64, ctxTb, KS2, ATTbf);
            mfmm_kernel<2, 1><<<gm256, 256, 0, stream>>>(
                ATTbf, WTo + (size_t)l * 65536, o_b + l * 256,
                A, nullptr, HAbf, nullptr, 256, 256);
            ln2_kernel<<<TN, 256, 0, stream>>>(HAbf, n2g + l * 256, n2b + l * 256,
                                               HL, SUMbf);
            mfmm_kernel<1, 1><<<gm512, 256, 0, stream>>>(
                SUMbf, WTm1 + (size_t)l * 131072, mb1 + l * 512,
                nullptr, nullptr, t2bf, nullptr, 256, 512);
            mfmm_kernel<3, 0><<<gm256, 256, 0, stream>>>(
                t2bf, WTm2 + (size_t)l * 131072, mb2 + l * 256,
                nullptr, SUMbf, R3, nullptr, 512, 256);
            ln3_kernel<<<TN, 256, 0, stream>>>(R3, n3g + l * 256, n3b + l * 256,
                                               A, Abf);
        } else {
            float* AGf = A + SZ;
            float* Tf = AGf + SZ;
            float* HLf = Tf + 2 * SZ;
            float* Vbf2 = HLf + SZ;
            float* Qf = AGf;
            float* Kf = Tf;
            float* CTXf = Tf + SZ;
            float* KSf = CTXf + (size_t)256 * MP_ * DH_;
            hipMemsetAsync(AGf, 0, SZ * sizeof(float), stream);
            scatter_kernel<<<E_ * 64 / 256, 256, 0, stream>>>(A, edge_attr, edge_index,
                                                              edge_w, edge_b, AGf);
            mm_kernel<true, 1><<<g256, 256, 0, stream>>>(A, AGf, gine_w1 + l * 65536,
                                                         gine_b1 + l * 256, nullptr,
                                                         nullptr, Tf, 256, 256);
            mm_kernel<false, 2><<<g256, 256, 0, stream>>>(Tf, nullptr, gine_w2 + l * 65536,
                                                          gine_b2 + l * 256, A, nullptr,
                                                          HLf, 256, 256);
            ln_kernel<<<TN, 256, 0, stream>>>(HLf, n1g + l * 256, n1b + l * 256, HLf);
            mm_kernel<false, 0><<<g256, 256, 0, stream>>>(A, nullptr, q_w + l * 65536,
                                                          nullptr, nullptr, nullptr,
                                                          Qf, 256, 256);
            mm_kernel<false, 0><<<g256, 256, 0, stream>>>(A, nullptr, k_w + l * 65536,
                                                          nullptr, nullptr, nullptr,
                                                          Kf, 256, 256);
            mm_kernel<false, 0><<<g256, 256, 0, stream>>>(A, nullptr, v_w + l * 65536,
                                                          nullptr, nullptr, nullptr,
                                                          Vbf2, 256, 256);
            p1_kernel<<<dim3(5, 256), 256, 0, stream>>>(Kf, Vbf2, proj + l * (M_ * DH_),
                                                        CTXf, KSf);
            p2_kernel<<<dim3(8, 256), 256, 0, stream>>>(Qf, proj + l * (M_ * DH_),
                                                        CTXf, KSf, Kf);
            mm_kernel<false, 2><<<g256, 256, 0, stream>>>(Kf, nullptr, o_w + l * 65536,
                                                          o_b + l * 256, A, nullptr,
                                                          Qf, 256, 256);
            ln_kernel<<<TN, 256, 0, stream>>>(Qf, n2g + l * 256, n2b + l * 256, Qf);
            mm_kernel<true, 1><<<g512, 256, 0, stream>>>(HLf, Qf, mw1 + l * 131072,
                                                         mb1 + l * 512, nullptr, nullptr,
                                                         Tf, 256, 512);
            mm_kernel<false, 3><<<g256, 256, 0, stream>>>(Tf, nullptr, mw2 + l * 131072,
                                                          mb2 + l * 256, HLf, Qf,
                                                          Vbf2, 512, 256);
            ln_kernel<<<TN, 256, 0, stream>>>(Vbf2, n3g + l * 256, n3b + l * 256, A);
        }
    }
    pool_kernel<<<B_, 256, 0, stream>>>(A, (float*)d_out);
}

// Round 7
// 1778.993 us; speedup vs baseline: 8.5174x; 1.1691x over previous
//
#include <hip/hip_runtime.h>
#include <math.h>
#include <stdint.h>

#define TN 32768
#define C_ 256
#define E_ 524288
#define B_ 64
#define N_ 512
#define H_ 4
#define DH_ 64
#define M_ 266
#define MP_ 320
#define L_ 5
#define LN_EPS_ 1e-5f
#define EPSK_ 1e-3f

typedef short short8 __attribute__((ext_vector_type(8)));
typedef short short4v __attribute__((ext_vector_type(4)));
typedef float floatx4 __attribute__((ext_vector_type(4)));

__device__ __forceinline__ float gelu_exact(float v) {
    return 0.5f * v * (1.0f + erff(v * 0.70710678118654752f));
}

__device__ __forceinline__ short f2bf(float f) {
    union { float f; unsigned u; } v; v.f = f;
    unsigned r = v.u + 0x7FFF + ((v.u >> 16) & 1);
    return (short)(r >> 16);
}

__device__ __forceinline__ float bf2f(short s) {
    union { unsigned u; float f; } v;
    v.u = ((unsigned)(unsigned short)s) << 16;
    return v.f;
}

__device__ __forceinline__ float bflo(unsigned u) {
    union { unsigned u; float f; } v;
    v.u = u << 16;
    return v.f;
}
__device__ __forceinline__ float bfhi(unsigned u) {
    union { unsigned u; float f; } v;
    v.u = u & 0xffff0000u;
    return v.f;
}

// ---------------- embed: atoms = log(x+1) @ node_w + node_b ----------------
__global__ __launch_bounds__(256) void embed_kernel(
    const float* __restrict__ x, const float* __restrict__ nw,
    const float* __restrict__ nb, float* __restrict__ atoms,
    short* __restrict__ abf) {
    int node = blockIdx.x;
    int c = threadIdx.x;
    __shared__ float lx[11];
    if (c < 11) lx[c] = logf(x[node * 11 + c] + 1.0f);
    __syncthreads();
    float acc = nb[c];
#pragma unroll
    for (int j = 0; j < 11; ++j) acc = fmaf(lx[j], nw[j * C_ + c], acc);
    atoms[(size_t)node * C_ + c] = acc;   // fp32 copy kept for fallback path only
    abf[(size_t)node * C_ + c] = f2bf(acc);
}

// ----------------------- CSR build: count / scan / fill --------------------
__global__ __launch_bounds__(256) void count_kernel(const int* __restrict__ eidx,
                                                    int* __restrict__ deg) {
    int e = blockIdx.x * 256 + threadIdx.x;
    atomicAdd(&deg[eidx[E_ + e]], 1);
}

__global__ __launch_bounds__(1024) void scan_kernel(const int* __restrict__ deg,
                                                    int* __restrict__ offs,
                                                    int* __restrict__ cursor) {
    __shared__ int tsum[1024];
    int t = threadIdx.x;
    int base = t * 32;
    int local[32];
    int s = 0;
#pragma unroll
    for (int i = 0; i < 32; ++i) { local[i] = deg[base + i]; s += local[i]; }
    tsum[t] = s;
    __syncthreads();
    for (int off = 1; off < 1024; off <<= 1) {
        int v = tsum[t];
        int add = (t >= off) ? tsum[t - off] : 0;
        __syncthreads();
        tsum[t] = v + add;
        __syncthreads();
    }
    int run = tsum[t] - s;
#pragma unroll
    for (int i = 0; i < 32; ++i) {
        offs[base + i] = run;
        cursor[base + i] = run;
        run += local[i];
    }
    if (t == 1023) offs[TN] = run;
}

__global__ __launch_bounds__(256) void fill_kernel(const int* __restrict__ eidx,
                                                   const float* __restrict__ eattr,
                                                   int* __restrict__ cursor,
                                                   int* __restrict__ esrc,
                                                   float* __restrict__ easrt) {
    int e = blockIdx.x * 256 + threadIdx.x;
    int d = eidx[E_ + e];
    int pos = atomicAdd(&cursor[d], 1);
    esrc[pos] = eidx[e];
    *(float4*)(easrt + (size_t)pos * 4) = *(const float4*)(eattr + (size_t)e * 4);
}

// --- GINE gather: one WAVE per node, no barriers, all-bf16 atoms -----------
__global__ __launch_bounds__(256) void gather_kernel(
    const short* __restrict__ abf, const int* __restrict__ offs,
    const int* __restrict__ esrc, const float* __restrict__ easrt,
    const float* __restrict__ ew, const float* __restrict__ eb,
    short* __restrict__ x1bf) {
    int wv = threadIdx.x >> 6;
    int lane = threadIdx.x & 63;
    int node = blockIdx.x * 4 + wv;
    int c0 = lane * 4;
    float4 w0 = *(const float4*)(ew + c0);
    float4 w1 = *(const float4*)(ew + C_ + c0);
    float4 w2 = *(const float4*)(ew + 2 * C_ + c0);
    float4 w3 = *(const float4*)(ew + 3 * C_ + c0);
    float4 bb = *(const float4*)(eb + c0);
    int j = offs[node];
    int end = offs[node + 1];
    float4 acc = make_float4(0.f, 0.f, 0.f, 0.f);
    float4 acc2 = make_float4(0.f, 0.f, 0.f, 0.f);
    for (; j + 1 < end; j += 2) {
        int s0 = esrc[j];
        int s1 = esrc[j + 1];
        float4 e0 = *(const float4*)(easrt + (size_t)j * 4);
        float4 e1 = *(const float4*)(easrt + (size_t)(j + 1) * 4);
        uint2 p0 = *(const uint2*)(abf + (size_t)s0 * C_ + c0);
        uint2 p1 = *(const uint2*)(abf + (size_t)s1 * C_ + c0);
        float a0x = bflo(p0.x), a0y = bfhi(p0.x), a0z = bflo(p0.y), a0w = bfhi(p0.y);
        float a1x = bflo(p1.x), a1y = bfhi(p1.x), a1z = bflo(p1.y), a1w = bfhi(p1.y);
        float m;
        m = fmaf(e0.x, w0.x, fmaf(e0.y, w1.x, fmaf(e0.z, w2.x, fmaf(e0.w, w3.x, a0x + bb.x))));
        acc.x += fmaxf(m, 0.f);
        m = fmaf(e0.x, w0.y, fmaf(e0.y, w1.y, fmaf(e0.z, w2.y, fmaf(e0.w, w3.y, a0y + bb.y))));
        acc.y += fmaxf(m, 0.f);
        m = fmaf(e0.x, w0.z, fmaf(e0.y, w1.z, fmaf(e0.z, w2.z, fmaf(e0.w, w3.z, a0z + bb.z))));
        acc.z += fmaxf(m, 0.f);
        m = fmaf(e0.x, w0.w, fmaf(e0.y, w1.w, fmaf(e0.z, w2.w, fmaf(e0.w, w3.w, a0w + bb.w))));
        acc.w += fmaxf(m, 0.f);
        m = fmaf(e1.x, w0.x, fmaf(e1.y, w1.x, fmaf(e1.z, w2.x, fmaf(e1.w, w3.x, a1x + bb.x))));
        acc2.x += fmaxf(m, 0.f);
        m = fmaf(e1.x, w0.y, fmaf(e1.y, w1.y, fmaf(e1.z, w2.y, fmaf(e1.w, w3.y, a1y + bb.y))));
        acc2.y += fmaxf(m, 0.f);
        m = fmaf(e1.x, w0.z, fmaf(e1.y, w1.z, fmaf(e1.z, w2.z, fmaf(e1.w, w3.z, a1z + bb.z))));
        acc2.z += fmaxf(m, 0.f);
        m = fmaf(e1.x, w0.w, fmaf(e1.y, w1.w, fmaf(e1.z, w2.w, fmaf(e1.w, w3.w, a1w + bb.w))));
        acc2.w += fmaxf(m, 0.f);
    }
    if (j < end) {
        int s0 = esrc[j];
        float4 e0 = *(const float4*)(easrt + (size_t)j * 4);
        uint2 p0 = *(const uint2*)(abf + (size_t)s0 * C_ + c0);
        float a0x = bflo(p0.x), a0y = bfhi(p0.x), a0z = bflo(p0.y), a0w = bfhi(p0.y);
        float m;
        m = fmaf(e0.x, w0.x, fmaf(e0.y, w1.x, fmaf(e0.z, w2.x, fmaf(e0.w, w3.x, a0x + bb.x))));
        acc.x += fmaxf(m, 0.f);
        m = fmaf(e0.x, w0.y, fmaf(e0.y, w1.y, fmaf(e0.z, w2.y, fmaf(e0.w, w3.y, a0y + bb.y))));
        acc.y += fmaxf(m, 0.f);
        m = fmaf(e0.x, w0.z, fmaf(e0.y, w1.z, fmaf(e0.z, w2.z, fmaf(e0.w, w3.z, a0z + bb.z))));
        acc.z += fmaxf(m, 0.f);
        m = fmaf(e0.x, w0.w, fmaf(e0.y, w1.w, fmaf(e0.z, w2.w, fmaf(e0.w, w3.w, a0w + bb.w))));
        acc.w += fmaxf(m, 0.f);
    }
    uint2 po = *(const uint2*)(abf + (size_t)node * C_ + c0);
    short4v o;
    o.x = f2bf(bflo(po.x) + acc.x + acc2.x);
    o.y = f2bf(bfhi(po.x) + acc.y + acc2.y);
    o.z = f2bf(bflo(po.y) + acc.z + acc2.z);
    o.w = f2bf(bfhi(po.y) + acc.w + acc2.w);
    *(short4v*)(x1bf + (size_t)node * C_ + c0) = o;
}

// ------------- fallback: atomic scatter (if ws too small) ------------------
__global__ __launch_bounds__(256) void scatter_kernel(
    const float* __restrict__ atoms, const float* __restrict__ eattr,
    const int* __restrict__ eidx, const float* __restrict__ ew,
    const float* __restrict__ eb, float* __restrict__ aggr) {
    int gid = blockIdx.x * 256 + threadIdx.x;
    int e = gid >> 6;
    int q = (gid & 63) << 2;
    int src = eidx[e];
    int dst = eidx[E_ + e];
    float4 ea = *(const float4*)(eattr + (size_t)e * 4);
    float4 w0 = *(const float4*)(ew + 0 * C_ + q);
    float4 w1 = *(const float4*)(ew + 1 * C_ + q);
    float4 w2 = *(const float4*)(ew + 2 * C_ + q);
    float4 w3 = *(const float4*)(ew + 3 * C_ + q);
    float4 bb = *(const float4*)(eb + q);
    float4 av = *(const float4*)(atoms + (size_t)src * C_ + q);
    float m0 = av.x + bb.x + ea.x * w0.x + ea.y * w1.x + ea.z * w2.x + ea.w * w3.x;
    float m1 = av.y + bb.y + ea.x * w0.y + ea.y * w1.y + ea.z * w2.y + ea.w * w3.y;
    float m2 = av.z + bb.z + ea.x * w0.z + ea.y * w1.z + ea.z * w2.z + ea.w * w3.z;
    float m3 = av.w + bb.w + ea.x * w0.w + ea.y * w1.w + ea.z * w2.w + ea.w * w3.w;
    float* base = aggr + (size_t)dst * C_ + q;
    atomicAdd(base + 0, fmaxf(m0, 0.f));
    atomicAdd(base + 1, fmaxf(m1, 0.f));
    atomicAdd(base + 2, fmaxf(m2, 0.f));
    atomicAdd(base + 3, fmaxf(m3, 0.f));
}

// --- weight transpose+cast: dst[rowBase+n][k] bf16 from W[l][k][n] fp32 ----
__global__ __launch_bounds__(256) void wt_kernel(const float* __restrict__ W,
                                                 short* __restrict__ Wt,
                                                 int K, int NC,
                                                 size_t lstride, int rowBase) {
    __shared__ short tile[64][65];
    int l = blockIdx.z;
    int k0 = blockIdx.y * 64, n0 = blockIdx.x * 64;
    const float* Wl = W + (size_t)l * K * NC;
    short* Wtl = Wt + (size_t)l * lstride + (size_t)rowBase * K;
    int t = threadIdx.x;
    int rr = t >> 4;
    int cc = (t & 15) * 4;
#pragma unroll
    for (int rep = 0; rep < 4; ++rep) {
        int r = rr + rep * 16;
        float4 v = *(const float4*)(Wl + (size_t)(k0 + r) * NC + n0 + cc);
        tile[cc + 0][r] = f2bf(v.x);
        tile[cc + 1][r] = f2bf(v.y);
        tile[cc + 2][r] = f2bf(v.z);
        tile[cc + 3][r] = f2bf(v.w);
    }
    __syncthreads();
#pragma unroll
    for (int rep = 0; rep < 4; ++rep) {
        int r = rr + rep * 16;
        short4v s;
        s.x = tile[r][cc + 0];
        s.y = tile[r][cc + 1];
        s.z = tile[r][cc + 2];
        s.w = tile[r][cc + 3];
        *(short4v*)(Wtl + (size_t)(n0 + r) * K + k0 + cc) = s;
    }
}

// ---------- proj cast: Pbf[l][m][d] bf16, padded to MP_ with zeros ---------
__global__ __launch_bounds__(256) void pcast_kernel(const float* __restrict__ proj,
                                                    short* __restrict__ Pbf) {
    int l = blockIdx.x;
    for (int idx = threadIdx.x; idx < MP_ * 64; idx += 256) {
        int m = idx >> 6, d = idx & 63;
        float v = (m < M_) ? proj[(size_t)l * M_ * 64 + m * 64 + d] : 0.f;
        Pbf[(size_t)l * MP_ * 64 + idx] = f2bf(v);
    }
}

// ---------------- MFMA bf16 matmul: Y = Xbf @ Wt (+epilogue) ---------------
// EPI: 0=none, 1=gelu, 2=+R1f(fp32), 3=+R1b(bf16)
// OUT: 0=fp32 rm, 1=bf16 rm, 3=QKV split (NC=768: Q|K rm 256; V transposed, Yv)
template <int EPI, int OUT>
__global__ __launch_bounds__(256) void mfmm_kernel(
    const short* __restrict__ Xb, const short* __restrict__ Wt,
    const float* __restrict__ bias, const float* __restrict__ R1f,
    const short* __restrict__ R1b, void* __restrict__ Yout,
    short* __restrict__ Yv, int K, int NC) {
    __shared__ short As[128][56];
    __shared__ short Bs[128][56];
    int tid = threadIdx.x;
    int rowBase = blockIdx.y * 128, colBase = blockIdx.x * 128;
    int w = tid >> 6, lane = tid & 63;
    int wm = w & 1, wn = w >> 1;
    int quad = lane >> 4, l16 = lane & 15;
    int sr = tid >> 1;
    int sk = (tid & 1) * 16;
    const short* Xp = Xb + (size_t)(rowBase + sr) * K + sk;
    const short* Wp = Wt + (size_t)(colBase + sr) * K + sk;
    floatx4 acc[4][4];
#pragma unroll
    for (int i = 0; i < 4; ++i)
#pragma unroll
        for (int j = 0; j < 4; ++j)
            acc[i][j] = (floatx4){0.f, 0.f, 0.f, 0.f};
    for (int k0 = 0; k0 < K; k0 += 32) {
        short8 xa0 = *(const short8*)(Xp + k0);
        short8 xa1 = *(const short8*)(Xp + k0 + 8);
        short8 wb0 = *(const short8*)(Wp + k0);
        short8 wb1 = *(const short8*)(Wp + k0 + 8);
        __syncthreads();
        *(short8*)&As[sr][sk] = xa0;
        *(short8*)&As[sr][sk + 8] = xa1;
        *(short8*)&Bs[sr][sk] = wb0;
        *(short8*)&Bs[sr][sk + 8] = wb1;
        __syncthreads();
        short8 a[4], b[4];
#pragma unroll
        for (int mi = 0; mi < 4; ++mi)
            a[mi] = *(const short8*)&As[wm * 64 + mi * 16 + l16][quad * 8];
#pragma unroll
        for (int ni = 0; ni < 4; ++ni)
            b[ni] = *(const short8*)&Bs[wn * 64 + ni * 16 + l16][quad * 8];
#pragma unroll
        for (int mi = 0; mi < 4; ++mi)
#pragma unroll
            for (int ni = 0; ni < 4; ++ni)
                acc[mi][ni] = __builtin_amdgcn_mfma_f32_16x16x32_bf16(
                    a[mi], b[ni], acc[mi][ni], 0, 0, 0);
    }
    if (OUT == 3) {
        int region = colBase >> 8;   // 0=Q, 1=K, 2=V
        if (region < 2) {
            short* dst = (short*)Yout + (size_t)region * (size_t)TN * 256;
#pragma unroll
            for (int ni = 0; ni < 4; ++ni) {
                int cl = (colBase + wn * 64 + ni * 16 + l16) & 255;
#pragma unroll
                for (int mi = 0; mi < 4; ++mi) {
#pragma unroll
                    for (int r = 0; r < 4; ++r) {
                        int rowg = rowBase + wm * 64 + mi * 16 + quad * 4 + r;
                        dst[(size_t)rowg * 256 + cl] = f2bf(acc[mi][ni][r]);
                    }
                }
            }
        } else {
#pragma unroll
            for (int ni = 0; ni < 4; ++ni) {
                int cl = (colBase + wn * 64 + ni * 16 + l16) & 255;
                int hh = cl >> 6, dd = cl & 63;
#pragma unroll
                for (int mi = 0; mi < 4; ++mi) {
                    int rowg0 = rowBase + wm * 64 + mi * 16 + quad * 4;
                    int bb = rowg0 >> 9, ng = rowg0 & 511;
                    short4v pv;
#pragma unroll
                    for (int r = 0; r < 4; ++r) pv[r] = f2bf(acc[mi][ni][r]);
                    *(short4v*)(Yv + (((size_t)bb * 4 + hh) * 64 + dd) * 512 + ng) = pv;
                }
            }
        }
        return;
    }
#pragma unroll
    for (int ni = 0; ni < 4; ++ni) {
        int colg = colBase + wn * 64 + ni * 16 + l16;
        float bv = bias ? bias[colg] : 0.f;
#pragma unroll
        for (int mi = 0; mi < 4; ++mi) {
#pragma unroll
            for (int r = 0; r < 4; ++r) {
                int rowg = rowBase + wm * 64 + mi * 16 + quad * 4 + r;
                float y = acc[mi][ni][r] + bv;
                if (EPI == 1) y = gelu_exact(y);
                if (EPI == 2) y += R1f[(size_t)rowg * NC + colg];
                if (EPI == 3) y += bf2f(R1b[(size_t)rowg * NC + colg]);
                if (OUT == 0)
                    ((float*)Yout)[(size_t)rowg * NC + colg] = y;
                else
                    ((short*)Yout)[(size_t)rowg * NC + colg] = f2bf(y);
            }
        }
    }
}

// ------------- fallback fp32 tiled matmul (old path) -----------------------
template <bool IN_ADD, int EPI>
__global__ __launch_bounds__(256) void mm_kernel(
    const float* __restrict__ X, const float* __restrict__ X2,
    const float* __restrict__ W, const float* __restrict__ bias,
    const float* __restrict__ R1, const float* __restrict__ R2,
    float* __restrict__ Y, int K, int NC) {
    __shared__ float Xs[16][65];
    __shared__ float Ws[16][68];
    int tid = threadIdx.x;
    int tx = tid & 15, ty = tid >> 4;
    int rowBase = blockIdx.y * 64;
    int colBase = blockIdx.x * 64;
    int lr = tid >> 2;
    int lk = (tid & 3) << 2;
    int wk = tid >> 4;
    int wc = (tid & 15) << 2;
    const float* Xp = X + (size_t)(rowBase + lr) * K + lk;
    const float* X2p = IN_ADD ? (X2 + (size_t)(rowBase + lr) * K + lk) : X;
    const float* Wp = W + (size_t)wk * NC + colBase + wc;
    float acc[4][4] = {};
    for (int k0 = 0; k0 < K; k0 += 16) {
        float4 xv = *(const float4*)(Xp + k0);
        if (IN_ADD) {
            float4 x2 = *(const float4*)(X2p + k0);
            xv.x += x2.x; xv.y += x2.y; xv.z += x2.z; xv.w += x2.w;
        }
        float4 wv = *(const float4*)(Wp + (size_t)k0 * NC);
        __syncthreads();
        Xs[lk + 0][lr] = xv.x;
        Xs[lk + 1][lr] = xv.y;
        Xs[lk + 2][lr] = xv.z;
        Xs[lk + 3][lr] = xv.w;
        *(float4*)&Ws[wk][wc] = wv;
        __syncthreads();
#pragma unroll
        for (int kk = 0; kk < 16; ++kk) {
            float a[4], b[4];
#pragma unroll
            for (int i = 0; i < 4; ++i) a[i] = Xs[kk][ty * 4 + i];
#pragma unroll
            for (int j = 0; j < 4; ++j) b[j] = Ws[kk][tx * 4 + j];
#pragma unroll
            for (int i = 0; i < 4; ++i)
#pragma unroll
                for (int j = 0; j < 4; ++j) acc[i][j] = fmaf(a[i], b[j], acc[i][j]);
        }
    }
    int c0 = colBase + tx * 4;
    float4 bv = make_float4(0.f, 0.f, 0.f, 0.f);
    if (bias) bv = *(const float4*)(bias + c0);
#pragma unroll
    for (int i = 0; i < 4; ++i) {
        int r = rowBase + ty * 4 + i;
        float4 y;
        y.x = acc[i][0] + bv.x; y.y = acc[i][1] + bv.y;
        y.z = acc[i][2] + bv.z; y.w = acc[i][3] + bv.w;
        if (EPI == 1) {
            y.x = gelu_exact(y.x); y.y = gelu_exact(y.y);
            y.z = gelu_exact(y.z); y.w = gelu_exact(y.w);
        }
        if (EPI >= 2) {
            float4 r1 = *(const float4*)(R1 + (size_t)r * NC + c0);
            y.x += r1.x; y.y += r1.y; y.z += r1.z; y.w += r1.w;
        }
        if (EPI == 3) {
            float4 r2 = *(const float4*)(R2 + (size_t)r * NC + c0);
            y.x += r2.x; y.y += r2.y; y.z += r2.z; y.w += r2.w;
        }
        *(float4*)(Y + (size_t)r * NC + c0) = y;
    }
}

// -------- LayerNorm, wave-per-row, bf16 in/out, no barriers ----------------
// out = LN(Xb)*g+b (+ post if non-null).  In-place safe (out may == Xb).
__global__ __launch_bounds__(256) void ln_b_kernel(
    const short* __restrict__ Xb, const float* __restrict__ g,
    const float* __restrict__ bta, const short* __restrict__ post,
    short* __restrict__ out) {
    int row = blockIdx.x * 4 + (threadIdx.x >> 6);
    int lane = threadIdx.x & 63;
    int c0 = lane * 4;
    size_t off = (size_t)row * C_ + c0;
    uint2 p = *(const uint2*)(Xb + off);
    float v0 = bflo(p.x), v1 = bfhi(p.x), v2 = bflo(p.y), v3 = bfhi(p.y);
    float s = v0 + v1 + v2 + v3;
    float s2 = v0 * v0 + v1 * v1 + v2 * v2 + v3 * v3;
#pragma unroll
    for (int m = 1; m < 64; m <<= 1) {
        s += __shfl_xor(s, m);
        s2 += __shfl_xor(s2, m);
    }
    float mu = s * (1.f / C_);
    float var = s2 * (1.f / C_) - mu * mu;
    float inv = rsqrtf(var + LN_EPS_);
    float4 gv = *(const float4*)(g + c0);
    float4 bv = *(const float4*)(bta + c0);
    float y0 = (v0 - mu) * inv * gv.x + bv.x;
    float y1 = (v1 - mu) * inv * gv.y + bv.y;
    float y2 = (v2 - mu) * inv * gv.z + bv.z;
    float y3 = (v3 - mu) * inv * gv.w + bv.w;
    if (post) {
        uint2 q = *(const uint2*)(post + off);
        y0 += bflo(q.x); y1 += bfhi(q.x); y2 += bflo(q.y); y3 += bfhi(q.y);
    }
    short4v o;
    o.x = f2bf(y0); o.y = f2bf(y1); o.z = f2bf(y2); o.w = f2bf(y3);
    *(short4v*)(out + off) = o;
}

// fp32 LN fallback
__global__ __launch_bounds__(256) void ln_kernel(
    const float* __restrict__ X, const float* __restrict__ g,
    const float* __restrict__ bta, float* __restrict__ Y) {
    __shared__ float rs[4], rs2[4];
    __shared__ float mu_s, inv_s;
    int row = blockIdx.x, t = threadIdx.x;
    size_t off = (size_t)row * C_ + t;
    float v = X[off];
    float s = v, s2 = v * v;
#pragma unroll
    for (int o = 32; o > 0; o >>= 1) {
        s += __shfl_down(s, o);
        s2 += __shfl_down(s2, o);
    }
    int w = t >> 6, lane = t & 63;
    if (lane == 0) { rs[w] = s; rs2[w] = s2; }
    __syncthreads();
    if (t == 0) {
        float tot = rs[0] + rs[1] + rs[2] + rs[3];
        float tot2 = rs2[0] + rs2[1] + rs2[2] + rs2[3];
        float mu = tot * (1.f / C_);
        float var = tot2 * (1.f / C_) - mu * mu;
        mu_s = mu;
        inv_s = rsqrtf(var + LN_EPS_);
    }
    __syncthreads();
    Y[off] = (v - mu_s) * inv_s * g[t] + bta[t];
}

// ---------- MFMA Performer pass 1: ctxT[bh][d][m], ksum[bh][m] -------------
__global__ __launch_bounds__(256) void p1m_kernel(
    const short* __restrict__ Kbf, const short* __restrict__ VbfT,
    const short* __restrict__ Pbf, short* __restrict__ ctxT,
    float* __restrict__ ksum) {
    int mt = blockIdx.x;
    int bh = blockIdx.y;
    int b = bh >> 2, h = bh & 3;
    __shared__ short Ps[64][72];
    __shared__ short Ks[64][72];
    __shared__ short VTs[64][72];
    __shared__ short Ss[64][72];
    __shared__ float kred[4][64];
    int tid = threadIdx.x;
    int w = tid >> 6, lane = tid & 63;
    int quad = lane >> 4, l16 = lane & 15;
    int lr = tid >> 2, lb = (tid & 3) << 4;
    {
        const short* p = Pbf + ((size_t)(mt * 64 + lr)) * 64 + lb;
        *(short8*)&Ps[lr][lb] = *(const short8*)p;
        *(short8*)&Ps[lr][lb + 8] = *(const short8*)(p + 8);
    }
    floatx4 cacc[4];
#pragma unroll
    for (int i = 0; i < 4; ++i) cacc[i] = (floatx4){0.f, 0.f, 0.f, 0.f};
    float kacc[4] = {0.f, 0.f, 0.f, 0.f};
    size_t kbase = ((size_t)(b * 512)) * 256 + h * 64;
    size_t vbase = ((size_t)(bh * 64)) * 512;
    for (int nt = 0; nt < 8; ++nt) {
        __syncthreads();
        {
            const short* kp = Kbf + kbase + (size_t)(nt * 64 + lr) * 256 + lb;
            *(short8*)&Ks[lr][lb] = *(const short8*)kp;
            *(short8*)&Ks[lr][lb + 8] = *(const short8*)(kp + 8);
            const short* vp = VbfT + vbase + (size_t)lr * 512 + nt * 64 + lb;
            *(short8*)&VTs[lr][lb] = *(const short8*)vp;
            *(short8*)&VTs[lr][lb + 8] = *(const short8*)(vp + 8);
        }
        __syncthreads();
        floatx4 sa[4];
#pragma unroll
        for (int mi = 0; mi < 4; ++mi) sa[mi] = (floatx4){0.f, 0.f, 0.f, 0.f};
#pragma unroll
        for (int kt = 0; kt < 2; ++kt) {
            short8 a = *(const short8*)&Ks[w * 16 + l16][kt * 32 + quad * 8];
#pragma unroll
            for (int mi = 0; mi < 4; ++mi) {
                short8 bq = *(const short8*)&Ps[mi * 16 + l16][kt * 32 + quad * 8];
                sa[mi] = __builtin_amdgcn_mfma_f32_16x16x32_bf16(a, bq, sa[mi], 0, 0, 0);
            }
        }
#pragma unroll
        for (int mi = 0; mi < 4; ++mi) {
            int mg = mt * 64 + mi * 16 + l16;
            short4v sv;
            float kl = 0.f;
#pragma unroll
            for (int r = 0; r < 4; ++r) {
                float v = (mg < M_) ? (fmaxf(sa[mi][r], 0.f) + EPSK_) : 0.f;
                sv[r] = f2bf(v);
                kl += v;
            }
            kacc[mi] += kl;
            *(short4v*)&Ss[mi * 16 + l16][w * 16 + quad * 4] = sv;
        }
        __syncthreads();
#pragma unroll
        for (int kt = 0; kt < 2; ++kt) {
            short8 a = *(const short8*)&Ss[w * 16 + l16][kt * 32 + quad * 8];
#pragma unroll
            for (int di = 0; di < 4; ++di) {
                short8 bv = *(const short8*)&VTs[di * 16 + l16][kt * 32 + quad * 8];
                cacc[di] = __builtin_amdgcn_mfma_f32_16x16x32_bf16(a, bv, cacc[di], 0, 0, 0);
            }
        }
    }
    size_t cbase = ((size_t)bh * 64) * MP_ + mt * 64;
#pragma unroll
    for (int di = 0; di < 4; ++di) {
        int d = di * 16 + l16;
        short4v cv;
#pragma unroll
        for (int r = 0; r < 4; ++r) cv[r] = f2bf(cacc[di][r]);
        *(short4v*)(ctxT + cbase + (size_t)d * MP_ + w * 16 + quad * 4) = cv;
    }
#pragma unroll
    for (int mi = 0; mi < 4; ++mi) {
        kacc[mi] += __shfl_down(kacc[mi], 32);
        kacc[mi] += __shfl_down(kacc[mi], 16);
    }
    if (lane < 16) {
#pragma unroll
        for (int mi = 0; mi < 4; ++mi) kred[w][mi * 16 + lane] = kacc[mi];
    }
    __syncthreads();
    if (tid < 64)
        ksum[(size_t)bh * MP_ + mt * 64 + tid] =
            kred[0][tid] + kred[1][tid] + kred[2][tid] + kred[3][tid];
}

// ---------- MFMA Performer pass 2: attbf = bf16((qp@ctx)/(qp@ksum)) --------
__global__ __launch_bounds__(256) void p2m_kernel(
    const short* __restrict__ Qbf, const short* __restrict__ Pbf,
    const short* __restrict__ ctxT, const float* __restrict__ ksum,
    short* __restrict__ attbf) {
    int nt = blockIdx.x;
    int bh = blockIdx.y;
    int b = bh >> 2, h = bh & 3;
    __shared__ short Qs[64][72];
    __shared__ short Ps[64][72];
    __shared__ short CTs[64][72];
    __shared__ short Ss[64][72];
    __shared__ float kss[64];
    __shared__ float dredS[64];
    __shared__ float dinvS[64];
    int tid = threadIdx.x;
    int w = tid >> 6, lane = tid & 63;
    int quad = lane >> 4, l16 = lane & 15;
    int lr = tid >> 2, lb = (tid & 3) << 4;
    size_t qbase = ((size_t)(b * 512)) * 256 + h * 64;
    {
        const short* qp = Qbf + qbase + (size_t)(nt * 64 + lr) * 256 + lb;
        *(short8*)&Qs[lr][lb] = *(const short8*)qp;
        *(short8*)&Qs[lr][lb + 8] = *(const short8*)(qp + 8);
    }
    floatx4 aacc[4];
#pragma unroll
    for (int i = 0; i < 4; ++i) aacc[i] = (floatx4){0.f, 0.f, 0.f, 0.f};
    float dd[4] = {0.f, 0.f, 0.f, 0.f};
    size_t cb = ((size_t)bh * 64) * MP_;
    for (int mt = 0; mt < 5; ++mt) {
        __syncthreads();
        {
            const short* p = Pbf + ((size_t)(mt * 64 + lr)) * 64 + lb;
            *(short8*)&Ps[lr][lb] = *(const short8*)p;
            *(short8*)&Ps[lr][lb + 8] = *(const short8*)(p + 8);
            const short* cp = ctxT + cb + (size_t)lr * MP_ + mt * 64 + lb;
            *(short8*)&CTs[lr][lb] = *(const short8*)cp;
            *(short8*)&CTs[lr][lb + 8] = *(const short8*)(cp + 8);
        }
        if (tid < 64) kss[tid] = ksum[(size_t)bh * MP_ + mt * 64 + tid];
        __syncthreads();
        floatx4 sa[4];
#pragma unroll
        for (int mi = 0; mi < 4; ++mi) sa[mi] = (floatx4){0.f, 0.f, 0.f, 0.f};
#pragma unroll
        for (int kt = 0; kt < 2; ++kt) {
            short8 a = *(const short8*)&Qs[w * 16 + l16][kt * 32 + quad * 8];
#pragma unroll
            for (int mi = 0; mi < 4; ++mi) {
                short8 bq = *(const short8*)&Ps[mi * 16 + l16][kt * 32 + quad * 8];
                sa[mi] = __builtin_amdgcn_mfma_f32_16x16x32_bf16(a, bq, sa[mi], 0, 0, 0);
            }
        }
#pragma unroll
        for (int mi = 0; mi < 4; ++mi) {
            int mg = mt * 64 + mi * 16 + l16;
            float ksv = kss[mi * 16 + l16];
#pragma unroll
            for (int r = 0; r < 4; ++r) {
                float v = (mg < M_) ? (fmaxf(sa[mi][r], 0.f) + EPSK_) : 0.f;
                Ss[w * 16 + quad * 4 + r][mi * 16 + l16] = f2bf(v);
                dd[r] += v * ksv;
            }
        }
        __syncthreads();
#pragma unroll
        for (int kt = 0; kt < 2; ++kt) {
            short8 a = *(const short8*)&Ss[w * 16 + l16][kt * 32 + quad * 8];
#pragma unroll
            for (int di = 0; di < 4; ++di) {
                short8 bv = *(const short8*)&CTs[di * 16 + l16][kt * 32 + quad * 8];
                aacc[di] = __builtin_amdgcn_mfma_f32_16x16x32_bf16(a, bv, aacc[di], 0, 0, 0);
            }
        }
    }
#pragma unroll
    for (int r = 0; r < 4; ++r) {
        dd[r] += __shfl_xor(dd[r], 1);
        dd[r] += __shfl_xor(dd[r], 2);
        dd[r] += __shfl_xor(dd[r], 4);
        dd[r] += __shfl_xor(dd[r], 8);
    }
    if (l16 == 0) {
#pragma unroll
        for (int r = 0; r < 4; ++r) dredS[w * 16 + quad * 4 + r] = dd[r];
    }
    __syncthreads();
    if (tid < 64) dinvS[tid] = 1.f / dredS[tid];
    __syncthreads();
#pragma unroll
    for (int di = 0; di < 4; ++di) {
        int d = di * 16 + l16;
#pragma unroll
        for (int r = 0; r < 4; ++r) {
            int n = w * 16 + quad * 4 + r;
            attbf[((size_t)(b * 512 + nt * 64 + n)) * 256 + h * 64 + d] =
                f2bf(aacc[di][r] * dinvS[n]);
        }
    }
}

// ---------------- fp32 Performer fallbacks (old path) ----------------------
__global__ __launch_bounds__(256) void p1_kernel(
    const float* __restrict__ kbuf, const float* __restrict__ vbuf,
    const float* __restrict__ proj, float* __restrict__ ctx,
    float* __restrict__ ksum) {
    int mt = blockIdx.x;
    int bh = blockIdx.y;
    int b = bh >> 2, h = bh & 3;
    __shared__ float Pt[64][65];
    __shared__ float KV[64][65];
    __shared__ float S[64][65];
    int tid = threadIdx.x;
    int tx = tid & 15, ty = tid >> 4;
    for (int idx = tid; idx < 4096; idx += 256) {
        int r = idx >> 6, c = idx & 63;
        int mg = mt * 64 + r;
        Pt[r][c] = (mg < M_) ? proj[mg * DH_ + c] : 0.f;
    }
    float cacc[4][4] = {};
    float ksacc = 0.f;
    size_t base = ((size_t)b * N_) * C_ + h * DH_;
    for (int nt = 0; nt < 8; ++nt) {
        __syncthreads();
        for (int idx = tid; idx < 4096; idx += 256) {
            int r = idx >> 6, c = idx & 63;
            KV[r][c] = kbuf[base + (size_t)(nt * 64 + r) * C_ + c];
        }
        __syncthreads();
        float s[4][4] = {};
        for (int dd = 0; dd < 64; ++dd) {
            float a[4], bq[4];
#pragma unroll
            for (int i = 0; i < 4; ++i) a[i] = KV[ty * 4 + i][dd];
#pragma unroll
            for (int j = 0; j < 4; ++j) bq[j] = Pt[16 * j + tx][dd];
#pragma unroll
            for (int i = 0; i < 4; ++i)
#pragma unroll
                for (int j = 0; j < 4; ++j) s[i][j] = fmaf(a[i], bq[j], s[i][j]);
        }
        __syncthreads();
#pragma unroll
        for (int i = 0; i < 4; ++i)
#pragma unroll
            for (int j = 0; j < 4; ++j) {
                int mg = mt * 64 + 16 * j + tx;
                S[ty * 4 + i][16 * j + tx] =
                    (mg < M_) ? (fmaxf(s[i][j], 0.f) + EPSK_) : 0.f;
            }
        for (int idx = tid; idx < 4096; idx += 256) {
            int r = idx >> 6, c = idx & 63;
            KV[r][c] = vbuf[base + (size_t)(nt * 64 + r) * C_ + c];
        }
        __syncthreads();
        for (int nn = 0; nn < 64; ++nn) {
            float sm[4], vd[4];
#pragma unroll
            for (int i = 0; i < 4; ++i) sm[i] = S[nn][ty * 4 + i];
#pragma unroll
            for (int j = 0; j < 4; ++j) vd[j] = KV[nn][tx * 4 + j];
#pragma unroll
            for (int i = 0; i < 4; ++i)
#pragma unroll
                for (int j = 0; j < 4; ++j) cacc[i][j] = fmaf(sm[i], vd[j], cacc[i][j]);
        }
        if (tid < 64) {
            for (int nn = 0; nn < 64; ++nn) ksacc += S[nn][tid];
        }
    }
    float* cp = ctx + ((size_t)bh * MP_ + mt * 64) * DH_;
#pragma unroll
    for (int i = 0; i < 4; ++i)
#pragma unroll
        for (int j = 0; j < 4; ++j)
            cp[(ty * 4 + i) * DH_ + tx * 4 + j] = cacc[i][j];
    if (tid < 64) ksum[bh * MP_ + mt * 64 + tid] = ksacc;
}

__global__ __launch_bounds__(256) void p2_kernel(
    const float* __restrict__ qbuf, const float* __restrict__ proj,
    const float* __restrict__ ctx, const float* __restrict__ ksum,
    float* __restrict__ attout) {
    int nt = blockIdx.x;
    int bh = blockIdx.y;
    int b = bh >> 2, h = bh & 3;
    __shared__ float Qt[64][65];
    __shared__ float PC[64][65];
    __shared__ float S[64][65];
    __shared__ float ks[64], dinv[64];
    int tid = threadIdx.x;
    int tx = tid & 15, ty = tid >> 4;
    size_t base = ((size_t)b * N_) * C_ + h * DH_;
    for (int idx = tid; idx < 4096; idx += 256) {
        int r = idx >> 6, c = idx & 63;
        Qt[r][c] = qbuf[base + (size_t)(nt * 64 + r) * C_ + c];
    }
    float aacc[4][4] = {};
    float dacc = 0.f;
    for (int mt = 0; mt < 5; ++mt) {
        __syncthreads();
        for (int idx = tid; idx < 4096; idx += 256) {
            int r = idx >> 6, c = idx & 63;
            int mg = mt * 64 + r;
            PC[r][c] = (mg < M_) ? proj[mg * DH_ + c] : 0.f;
        }
        if (tid < 64) ks[tid] = ksum[bh * MP_ + mt * 64 + tid];
        __syncthreads();
        float s[4][4] = {};
        for (int dd = 0; dd < 64; ++dd) {
            float a[4], bq[4];
#pragma unroll
            for (int i = 0; i < 4; ++i) a[i] = Qt[ty * 4 + i][dd];
#pragma unroll
            for (int j = 0; j < 4; ++j) bq[j] = PC[16 * j + tx][dd];
#pragma unroll
            for (int i = 0; i < 4; ++i)
#pragma unroll
                for (int j = 0; j < 4; ++j) s[i][j] = fmaf(a[i], bq[j], s[i][j]);
        }
        __syncthreads();
#pragma unroll
        for (int i = 0; i < 4; ++i)
#pragma unroll
            for (int j = 0; j < 4; ++j) {
                int mg = mt * 64 + 16 * j + tx;
                S[ty * 4 + i][16 * j + tx] =
                    (mg < M_) ? (fmaxf(s[i][j], 0.f) + EPSK_) : 0.f;
            }
        for (int idx = tid; idx < 4096; idx += 256) {
            int r = idx >> 6, c = idx & 63;
            PC[r][c] = ctx[((size_t)bh * MP_ + mt * 64 + r) * DH_ + c];
        }
        __syncthreads();
        for (int mm = 0; mm < 64; ++mm) {
            float sm[4], cd[4];
#pragma unroll
            for (int i = 0; i < 4; ++i) sm[i] = S[ty * 4 + i][mm];
#pragma unroll
            for (int j = 0; j < 4; ++j) cd[j] = PC[mm][tx * 4 + j];
#pragma unroll
            for (int i = 0; i < 4; ++i)
#pragma unroll
                for (int j = 0; j < 4; ++j) aacc[i][j] = fmaf(sm[i], cd[j], aacc[i][j]);
        }
        if (tid < 64) {
            for (int mm = 0; mm < 64; ++mm) dacc = fmaf(S[tid][mm], ks[mm], dacc);
        }
    }
    __syncthreads();
    if (tid < 64) dinv[tid] = 1.f / dacc;
    __syncthreads();
#pragma unroll
    for (int i = 0; i < 4; ++i) {
        int n = ty * 4 + i;
        float di = dinv[n];
        float4 y = make_float4(aacc[i][0] * di, aacc[i][1] * di,
                               aacc[i][2] * di, aacc[i][3] * di);
        *(float4*)(attout + base + (size_t)(nt * 64 + n) * C_ + tx * 4) = y;
    }
}

// -------------------- mean pool (bf16 in, fp32 out) ------------------------
__global__ __launch_bounds__(256) void pool_kernel(const short* __restrict__ abf,
                                                   float* __restrict__ out) {
    int b = blockIdx.x;
    int c = threadIdx.x;
    const short* p = abf + (size_t)b * N_ * C_ + c;
    float s = 0.f;
    for (int n = 0; n < N_; ++n) s += bf2f(p[(size_t)n * C_]);
    out[b * C_ + c] = s * (1.f / 512.f);
}

__global__ __launch_bounds__(256) void poolf_kernel(const float* __restrict__ atoms,
                                                    float* __restrict__ out) {
    int b = blockIdx.x;
    int c = threadIdx.x;
    const float* p = atoms + (size_t)b * N_ * C_ + c;
    float s = 0.f;
    for (int n = 0; n < N_; ++n) s += p[(size_t)n * C_];
    out[b * C_ + c] = s * (1.f / 512.f);
}

extern "C" void kernel_launch(void* const* d_in, const int* in_sizes, int n_in,
                              void* d_out, int out_size, void* d_ws, size_t ws_size,
                              hipStream_t stream) {
    (void)in_sizes; (void)n_in; (void)out_size;
    const float* x = (const float*)d_in[0];
    const float* edge_attr = (const float*)d_in[1];
    const int* edge_index = (const int*)d_in[2];
    const float* node_w = (const float*)d_in[4];
    const float* node_b = (const float*)d_in[5];
    const float* edge_w = (const float*)d_in[6];
    const float* edge_b = (const float*)d_in[7];
    const float* gine_w1 = (const float*)d_in[8];
    const float* gine_b1 = (const float*)d_in[9];
    const float* gine_w2 = (const float*)d_in[10];
    const float* gine_b2 = (const float*)d_in[11];
    const float* q_w = (const float*)d_in[12];
    const float* k_w = (const float*)d_in[13];
    const float* v_w = (const float*)d_in[14];
    const float* o_w = (const float*)d_in[15];
    const float* o_b = (const float*)d_in[16];
    const float* proj = (const float*)d_in[17];
    const float* n1g = (const float*)d_in[18];
    const float* n1b = (const float*)d_in[19];
    const float* n2g = (const float*)d_in[20];
    const float* n2b = (const float*)d_in[21];
    const float* n3g = (const float*)d_in[22];
    const float* n3b = (const float*)d_in[23];
    const float* mw1 = (const float*)d_in[24];
    const float* mb1 = (const float*)d_in[25];
    const float* mw2 = (const float*)d_in[26];
    const float* mb2 = (const float*)d_in[27];

    const size_t SZ = (size_t)TN * C_;   // 8,388,608
    float* ws = (float*)d_ws;
    // bf16 arena (each slot = SZ shorts = SZ/2 floats):
    float* A     = ws;                               // fp32 atoms (fallback only)
    short* Abf   = (short*)(ws + SZ);
    short* X1bf  = (short*)(ws + SZ + SZ / 2);       // also t2bf
    short* t2bf  = X1bf;
    short* t1bf  = (short*)(ws + 2 * SZ);            // also ATTbf
    short* ATTbf = t1bf;
    short* HLbf  = (short*)(ws + 2 * SZ + SZ / 2);
    short* Qbf   = (short*)(ws + 3 * SZ);            // also R3bf
    short* R3bf  = Qbf;
    short* Kbf   = (short*)(ws + 3 * SZ + SZ / 2);   // = Qbf + SZ shorts
    short* VbfT  = (short*)(ws + 4 * SZ);
    short* ctxTb = (short*)(ws + 4 * SZ + SZ / 2);
    float* KS2   = (float*)(ctxTb + (size_t)256 * 64 * MP_);
    short* HAbf  = (short*)(ws + 5 * SZ);            // also SUMbf (in-place LN)
    short* SUMbf = HAbf;

    int* deg    = (int*)(ws + 6 * SZ);
    int* offs   = deg + TN;
    int* cursor = offs + TN + 1;
    int* esrc   = cursor + TN;
    float* easrt = (float*)(((uintptr_t)(esrc + E_) + 15) & ~(uintptr_t)15);
    short* WTg1  = (short*)(easrt + (size_t)4 * E_);
    short* WTg2  = WTg1 + (size_t)5 * 65536;
    short* WTqkv = WTg2 + (size_t)5 * 65536;
    short* WTo   = WTqkv + (size_t)5 * 196608;
    short* WTm1  = WTo + (size_t)5 * 65536;
    short* WTm2  = WTm1 + (size_t)5 * 131072;
    short* Pbf   = WTm2 + (size_t)5 * 131072;
    size_t need = 6 * SZ * sizeof(float) +
                  (size_t)(3 * TN + 1 + E_) * sizeof(int) + 16 +
                  (size_t)4 * E_ * sizeof(float) +
                  ((size_t)5 * (3 * 65536 + 196608 + 2 * 131072 + MP_ * 64)) *
                      sizeof(short);
    bool full = ws_size >= need;

    dim3 gm256(2, 256), gm512(4, 256), gm768(6, 256);
    dim3 g256(4, 512), g512(8, 512);

    embed_kernel<<<TN, 256, 0, stream>>>(x, node_w, node_b, A, Abf);
    if (full) {
        hipMemsetAsync(deg, 0, TN * sizeof(int), stream);
        count_kernel<<<E_ / 256, 256, 0, stream>>>(edge_index, deg);
        scan_kernel<<<1, 1024, 0, stream>>>(deg, offs, cursor);
        fill_kernel<<<E_ / 256, 256, 0, stream>>>(edge_index, edge_attr, cursor,
                                                  esrc, easrt);
        wt_kernel<<<dim3(4, 4, L_), 256, 0, stream>>>(gine_w1, WTg1, 256, 256, 65536, 0);
        wt_kernel<<<dim3(4, 4, L_), 256, 0, stream>>>(gine_w2, WTg2, 256, 256, 65536, 0);
        wt_kernel<<<dim3(4, 4, L_), 256, 0, stream>>>(q_w, WTqkv, 256, 256, 196608, 0);
        wt_kernel<<<dim3(4, 4, L_), 256, 0, stream>>>(k_w, WTqkv, 256, 256, 196608, 256);
        wt_kernel<<<dim3(4, 4, L_), 256, 0, stream>>>(v_w, WTqkv, 256, 256, 196608, 512);
        wt_kernel<<<dim3(4, 4, L_), 256, 0, stream>>>(o_w, WTo, 256, 256, 65536, 0);
        wt_kernel<<<dim3(8, 4, L_), 256, 0, stream>>>(mw1, WTm1, 256, 512, 131072, 0);
        wt_kernel<<<dim3(4, 8, L_), 256, 0, stream>>>(mw2, WTm2, 512, 256, 131072, 0);
        pcast_kernel<<<L_, 256, 0, stream>>>(proj, Pbf);
    }
    for (int l = 0; l < L_; ++l) {
        if (full) {
            gather_kernel<<<TN / 4, 256, 0, stream>>>(Abf, offs, esrc, easrt,
                                                      edge_w, edge_b, X1bf);
            // t1 = gelu(X1 @ g1 + b1)
            mfmm_kernel<1, 1><<<gm256, 256, 0, stream>>>(
                X1bf, WTg1 + (size_t)l * 65536, gine_b1 + l * 256,
                nullptr, nullptr, t1bf, nullptr, 256, 256);
            // HLraw = t1 @ g2 + b2 + Abf  (bf16)
            mfmm_kernel<3, 1><<<gm256, 256, 0, stream>>>(
                t1bf, WTg2 + (size_t)l * 65536, gine_b2 + l * 256,
                nullptr, Abf, HLbf, nullptr, 256, 256);
            // HL = LN1(HLraw)  in-place
            ln_b_kernel<<<TN / 4, 256, 0, stream>>>(HLbf, n1g + l * 256,
                                                    n1b + l * 256, nullptr, HLbf);
            // QKV fused
            mfmm_kernel<0, 3><<<gm768, 256, 0, stream>>>(
                Abf, WTqkv + (size_t)l * 196608, nullptr,
                nullptr, nullptr, Qbf, VbfT, 256, 768);
            p1m_kernel<<<dim3(5, 256), 256, 0, stream>>>(
                Kbf, VbfT, Pbf + (size_t)l * MP_ * 64, ctxTb, KS2);
            p2m_kernel<<<dim3(8, 256), 256, 0, stream>>>(
                Qbf, Pbf + (size_t)l * MP_ * 64, ctxTb, KS2, ATTbf);
            // HAraw = ATT @ o_w + o_b + Abf
            mfmm_kernel<3, 1><<<gm256, 256, 0, stream>>>(
                ATTbf, WTo + (size_t)l * 65536, o_b + l * 256,
                nullptr, Abf, HAbf, nullptr, 256, 256);
            // SUM = LN2(HAraw) + HL  (in-place on HA slot)
            ln_b_kernel<<<TN / 4, 256, 0, stream>>>(HAbf, n2g + l * 256,
                                                    n2b + l * 256, HLbf, SUMbf);
            // t2 = gelu(SUM @ m1 + b1)  [NC=512]
            mfmm_kernel<1, 1><<<gm512, 256, 0, stream>>>(
                SUMbf, WTm1 + (size_t)l * 131072, mb1 + l * 512,
                nullptr, nullptr, t2bf, nullptr, 256, 512);
            // R3 = t2 @ m2 + b2 + SUM  [K=512]
            mfmm_kernel<3, 1><<<gm256, 256, 0, stream>>>(
                t2bf, WTm2 + (size_t)l * 131072, mb2 + l * 256,
                nullptr, SUMbf, R3bf, nullptr, 512, 256);
            // Abf = LN3(R3)
            ln_b_kernel<<<TN / 4, 256, 0, stream>>>(R3bf, n3g + l * 256,
                                                    n3b + l * 256, nullptr, Abf);
        } else {
            float* AGf = A + SZ;
            float* Tf = AGf + SZ;
            float* HLf = Tf + 2 * SZ;
            float* Vbf2 = HLf + SZ;
            float* Qf = AGf;
            float* Kf = Tf;
            float* CTXf = Tf + SZ;
            float* KSf = CTXf + (size_t)256 * MP_ * DH_;
            hipMemsetAsync(AGf, 0, SZ * sizeof(float), stream);
            scatter_kernel<<<E_ * 64 / 256, 256, 0, stream>>>(A, edge_attr, edge_index,
                                                              edge_w, edge_b, AGf);
            mm_kernel<true, 1><<<g256, 256, 0, stream>>>(A, AGf, gine_w1 + l * 65536,
                                                         gine_b1 + l * 256, nullptr,
                                                         nullptr, Tf, 256, 256);
            mm_kernel<false, 2><<<g256, 256, 0, stream>>>(Tf, nullptr, gine_w2 + l * 65536,
                                                          gine_b2 + l * 256, A, nullptr,
                                                          HLf, 256, 256);
            ln_kernel<<<TN, 256, 0, stream>>>(HLf, n1g + l * 256, n1b + l * 256, HLf);
            mm_kernel<false, 0><<<g256, 256, 0, stream>>>(A, nullptr, q_w + l * 65536,
                                                          nullptr, nullptr, nullptr,
                                                          Qf, 256, 256);
            mm_kernel<false, 0><<<g256, 256, 0, stream>>>(A, nullptr, k_w + l * 65536,
                                                          nullptr, nullptr, nullptr,
                                                          Kf, 256, 256);
            mm_kernel<false, 0><<<g256, 256, 0, stream>>>(A, nullptr, v_w + l * 65536,
                                                          nullptr, nullptr, nullptr,
                                                          Vbf2, 256, 256);
            p1_kernel<<<dim3(5, 256), 256, 0, stream>>>(Kf, Vbf2, proj + l * (M_ * DH_),
                                                        CTXf, KSf);
            p2_kernel<<<dim3(8, 256), 256, 0, stream>>>(Qf, proj + l * (M_ * DH_),
                                                        CTXf, KSf, Kf);
            mm_kernel<false, 2><<<g256, 256, 0, stream>>>(Kf, nullptr, o_w + l * 65536,
                                                          o_b + l * 256, A, nullptr,
                                                          Qf, 256, 256);
            ln_kernel<<<TN, 256, 0, stream>>>(Qf, n2g + l * 256, n2b + l * 256, Qf);
            mm_kernel<true, 1><<<g512, 256, 0, stream>>>(HLf, Qf, mw1 + l * 131072,
                                                         mb1 + l * 512, nullptr, nullptr,
                                                         Tf, 256, 512);
            mm_kernel<false, 3><<<g256, 256, 0, stream>>>(Tf, nullptr, mw2 + l * 131072,
                                                          mb2 + l * 256, HLf, Qf,
                                                          Vbf2, 512, 256);
            ln_kernel<<<TN, 256, 0, stream>>>(Vbf2, n3g + l * 256, n3b + l * 256, A);
        }
    }
    if (full)
        pool_kernel<<<B_, 256, 0, stream>>>(Abf, (float*)d_out);
    else
        poolf_kernel<<<B_, 256, 0, stream>>>(A, (float*)d_out);
}

// Round 8
// 1718.182 us; speedup vs baseline: 8.8188x; 1.0354x over previous
//
#include <hip/hip_runtime.h>
#include <math.h>
#include <stdint.h>

#define TN 32768
#define C_ 256
#define E_ 524288
#define B_ 64
#define N_ 512
#define H_ 4
#define DH_ 64
#define M_ 266
#define MP_ 320
#define L_ 5
#define LN_EPS_ 1e-5f
#define EPSK_ 1e-3f

typedef short short8 __attribute__((ext_vector_type(8)));
typedef short short4v __attribute__((ext_vector_type(4)));
typedef float floatx4 __attribute__((ext_vector_type(4)));

__device__ __forceinline__ float gelu_exact(float v) {
    return 0.5f * v * (1.0f + erff(v * 0.70710678118654752f));
}

__device__ __forceinline__ short f2bf(float f) {
    union { float f; unsigned u; } v; v.f = f;
    unsigned r = v.u + 0x7FFF + ((v.u >> 16) & 1);
    return (short)(r >> 16);
}

__device__ __forceinline__ float bf2f(short s) {
    union { unsigned u; float f; } v;
    v.u = ((unsigned)(unsigned short)s) << 16;
    return v.f;
}

__device__ __forceinline__ float bflo(unsigned u) {
    union { unsigned u; float f; } v;
    v.u = u << 16;
    return v.f;
}
__device__ __forceinline__ float bfhi(unsigned u) {
    union { unsigned u; float f; } v;
    v.u = u & 0xffff0000u;
    return v.f;
}

// ---------------- embed: atoms = log(x+1) @ node_w + node_b ----------------
__global__ __launch_bounds__(256) void embed_kernel(
    const float* __restrict__ x, const float* __restrict__ nw,
    const float* __restrict__ nb, float* __restrict__ atoms,
    short* __restrict__ abf) {
    int node = blockIdx.x;
    int c = threadIdx.x;
    __shared__ float lx[11];
    if (c < 11) lx[c] = logf(x[node * 11 + c] + 1.0f);
    __syncthreads();
    float acc = nb[c];
#pragma unroll
    for (int j = 0; j < 11; ++j) acc = fmaf(lx[j], nw[j * C_ + c], acc);
    atoms[(size_t)node * C_ + c] = acc;   // fp32 copy for fallback path only
    abf[(size_t)node * C_ + c] = f2bf(acc);
}

// ----------------------- CSR build: count / scan / fill --------------------
__global__ __launch_bounds__(256) void count_kernel(const int* __restrict__ eidx,
                                                    int* __restrict__ deg) {
    int e = blockIdx.x * 256 + threadIdx.x;
    atomicAdd(&deg[eidx[E_ + e]], 1);
}

__global__ __launch_bounds__(1024) void scan_kernel(const int* __restrict__ deg,
                                                    int* __restrict__ offs,
                                                    int* __restrict__ cursor) {
    __shared__ int tsum[1024];
    int t = threadIdx.x;
    int base = t * 32;
    int local[32];
    int s = 0;
#pragma unroll
    for (int i = 0; i < 32; ++i) { local[i] = deg[base + i]; s += local[i]; }
    tsum[t] = s;
    __syncthreads();
    for (int off = 1; off < 1024; off <<= 1) {
        int v = tsum[t];
        int add = (t >= off) ? tsum[t - off] : 0;
        __syncthreads();
        tsum[t] = v + add;
        __syncthreads();
    }
    int run = tsum[t] - s;
#pragma unroll
    for (int i = 0; i < 32; ++i) {
        offs[base + i] = run;
        cursor[base + i] = run;
        run += local[i];
    }
    if (t == 1023) offs[TN] = run;
}

__global__ __launch_bounds__(256) void fill_kernel(const int* __restrict__ eidx,
                                                   const float* __restrict__ eattr,
                                                   int* __restrict__ cursor,
                                                   int* __restrict__ esrc,
                                                   float* __restrict__ easrt) {
    int e = blockIdx.x * 256 + threadIdx.x;
    int d = eidx[E_ + e];
    int pos = atomicAdd(&cursor[d], 1);
    esrc[pos] = eidx[e];
    *(float4*)(easrt + (size_t)pos * 4) = *(const float4*)(eattr + (size_t)e * 4);
}

// --- GINE gather: one WAVE per node, no barriers, all-bf16 atoms -----------
__global__ __launch_bounds__(256) void gather_kernel(
    const short* __restrict__ abf, const int* __restrict__ offs,
    const int* __restrict__ esrc, const float* __restrict__ easrt,
    const float* __restrict__ ew, const float* __restrict__ eb,
    short* __restrict__ x1bf) {
    int wv = threadIdx.x >> 6;
    int lane = threadIdx.x & 63;
    int node = blockIdx.x * 4 + wv;
    int c0 = lane * 4;
    float4 w0 = *(const float4*)(ew + c0);
    float4 w1 = *(const float4*)(ew + C_ + c0);
    float4 w2 = *(const float4*)(ew + 2 * C_ + c0);
    float4 w3 = *(const float4*)(ew + 3 * C_ + c0);
    float4 bb = *(const float4*)(eb + c0);
    int j = offs[node];
    int end = offs[node + 1];
    float4 acc = make_float4(0.f, 0.f, 0.f, 0.f);
    float4 acc2 = make_float4(0.f, 0.f, 0.f, 0.f);
    for (; j + 1 < end; j += 2) {
        int s0 = esrc[j];
        int s1 = esrc[j + 1];
        float4 e0 = *(const float4*)(easrt + (size_t)j * 4);
        float4 e1 = *(const float4*)(easrt + (size_t)(j + 1) * 4);
        uint2 p0 = *(const uint2*)(abf + (size_t)s0 * C_ + c0);
        uint2 p1 = *(const uint2*)(abf + (size_t)s1 * C_ + c0);
        float a0x = bflo(p0.x), a0y = bfhi(p0.x), a0z = bflo(p0.y), a0w = bfhi(p0.y);
        float a1x = bflo(p1.x), a1y = bfhi(p1.x), a1z = bflo(p1.y), a1w = bfhi(p1.y);
        float m;
        m = fmaf(e0.x, w0.x, fmaf(e0.y, w1.x, fmaf(e0.z, w2.x, fmaf(e0.w, w3.x, a0x + bb.x))));
        acc.x += fmaxf(m, 0.f);
        m = fmaf(e0.x, w0.y, fmaf(e0.y, w1.y, fmaf(e0.z, w2.y, fmaf(e0.w, w3.y, a0y + bb.y))));
        acc.y += fmaxf(m, 0.f);
        m = fmaf(e0.x, w0.z, fmaf(e0.y, w1.z, fmaf(e0.z, w2.z, fmaf(e0.w, w3.z, a0z + bb.z))));
        acc.z += fmaxf(m, 0.f);
        m = fmaf(e0.x, w0.w, fmaf(e0.y, w1.w, fmaf(e0.z, w2.w, fmaf(e0.w, w3.w, a0w + bb.w))));
        acc.w += fmaxf(m, 0.f);
        m = fmaf(e1.x, w0.x, fmaf(e1.y, w1.x, fmaf(e1.z, w2.x, fmaf(e1.w, w3.x, a1x + bb.x))));
        acc2.x += fmaxf(m, 0.f);
        m = fmaf(e1.x, w0.y, fmaf(e1.y, w1.y, fmaf(e1.z, w2.y, fmaf(e1.w, w3.y, a1y + bb.y))));
        acc2.y += fmaxf(m, 0.f);
        m = fmaf(e1.x, w0.z, fmaf(e1.y, w1.z, fmaf(e1.z, w2.z, fmaf(e1.w, w3.z, a1z + bb.z))));
        acc2.z += fmaxf(m, 0.f);
        m = fmaf(e1.x, w0.w, fmaf(e1.y, w1.w, fmaf(e1.z, w2.w, fmaf(e1.w, w3.w, a1w + bb.w))));
        acc2.w += fmaxf(m, 0.f);
    }
    if (j < end) {
        int s0 = esrc[j];
        float4 e0 = *(const float4*)(easrt + (size_t)j * 4);
        uint2 p0 = *(const uint2*)(abf + (size_t)s0 * C_ + c0);
        float a0x = bflo(p0.x), a0y = bfhi(p0.x), a0z = bflo(p0.y), a0w = bfhi(p0.y);
        float m;
        m = fmaf(e0.x, w0.x, fmaf(e0.y, w1.x, fmaf(e0.z, w2.x, fmaf(e0.w, w3.x, a0x + bb.x))));
        acc.x += fmaxf(m, 0.f);
        m = fmaf(e0.x, w0.y, fmaf(e0.y, w1.y, fmaf(e0.z, w2.y, fmaf(e0.w, w3.y, a0y + bb.y))));
        acc.y += fmaxf(m, 0.f);
        m = fmaf(e0.x, w0.z, fmaf(e0.y, w1.z, fmaf(e0.z, w2.z, fmaf(e0.w, w3.z, a0z + bb.z))));
        acc.z += fmaxf(m, 0.f);
        m = fmaf(e0.x, w0.w, fmaf(e0.y, w1.w, fmaf(e0.z, w2.w, fmaf(e0.w, w3.w, a0w + bb.w))));
        acc.w += fmaxf(m, 0.f);
    }
    uint2 po = *(const uint2*)(abf + (size_t)node * C_ + c0);
    short4v o;
    o.x = f2bf(bflo(po.x) + acc.x + acc2.x);
    o.y = f2bf(bfhi(po.x) + acc.y + acc2.y);
    o.z = f2bf(bflo(po.y) + acc.z + acc2.z);
    o.w = f2bf(bfhi(po.y) + acc.w + acc2.w);
    *(short4v*)(x1bf + (size_t)node * C_ + c0) = o;
}

// ------------- fallback: atomic scatter (if ws too small) ------------------
__global__ __launch_bounds__(256) void scatter_kernel(
    const float* __restrict__ atoms, const float* __restrict__ eattr,
    const int* __restrict__ eidx, const float* __restrict__ ew,
    const float* __restrict__ eb, float* __restrict__ aggr) {
    int gid = blockIdx.x * 256 + threadIdx.x;
    int e = gid >> 6;
    int q = (gid & 63) << 2;
    int src = eidx[e];
    int dst = eidx[E_ + e];
    float4 ea = *(const float4*)(eattr + (size_t)e * 4);
    float4 w0 = *(const float4*)(ew + 0 * C_ + q);
    float4 w1 = *(const float4*)(ew + 1 * C_ + q);
    float4 w2 = *(const float4*)(ew + 2 * C_ + q);
    float4 w3 = *(const float4*)(ew + 3 * C_ + q);
    float4 bb = *(const float4*)(eb + q);
    float4 av = *(const float4*)(atoms + (size_t)src * C_ + q);
    float m0 = av.x + bb.x + ea.x * w0.x + ea.y * w1.x + ea.z * w2.x + ea.w * w3.x;
    float m1 = av.y + bb.y + ea.x * w0.y + ea.y * w1.y + ea.z * w2.y + ea.w * w3.y;
    float m2 = av.z + bb.z + ea.x * w0.z + ea.y * w1.z + ea.z * w2.z + ea.w * w3.z;
    float m3 = av.w + bb.w + ea.x * w0.w + ea.y * w1.w + ea.z * w2.w + ea.w * w3.w;
    float* base = aggr + (size_t)dst * C_ + q;
    atomicAdd(base + 0, fmaxf(m0, 0.f));
    atomicAdd(base + 1, fmaxf(m1, 0.f));
    atomicAdd(base + 2, fmaxf(m2, 0.f));
    atomicAdd(base + 3, fmaxf(m3, 0.f));
}

// --- weight transpose+cast: dst[rowBase+n][k] bf16 from W[l][k][n] fp32 ----
__global__ __launch_bounds__(256) void wt_kernel(const float* __restrict__ W,
                                                 short* __restrict__ Wt,
                                                 int K, int NC,
                                                 size_t lstride, int rowBase) {
    __shared__ short tile[64][65];
    int l = blockIdx.z;
    int k0 = blockIdx.y * 64, n0 = blockIdx.x * 64;
    const float* Wl = W + (size_t)l * K * NC;
    short* Wtl = Wt + (size_t)l * lstride + (size_t)rowBase * K;
    int t = threadIdx.x;
    int rr = t >> 4;
    int cc = (t & 15) * 4;
#pragma unroll
    for (int rep = 0; rep < 4; ++rep) {
        int r = rr + rep * 16;
        float4 v = *(const float4*)(Wl + (size_t)(k0 + r) * NC + n0 + cc);
        tile[cc + 0][r] = f2bf(v.x);
        tile[cc + 1][r] = f2bf(v.y);
        tile[cc + 2][r] = f2bf(v.z);
        tile[cc + 3][r] = f2bf(v.w);
    }
    __syncthreads();
#pragma unroll
    for (int rep = 0; rep < 4; ++rep) {
        int r = rr + rep * 16;
        short4v s;
        s.x = tile[r][cc + 0];
        s.y = tile[r][cc + 1];
        s.z = tile[r][cc + 2];
        s.w = tile[r][cc + 3];
        *(short4v*)(Wtl + (size_t)(n0 + r) * K + k0 + cc) = s;
    }
}

// ---------- proj cast: Pbf[l][m][d] bf16, padded to MP_ with zeros ---------
__global__ __launch_bounds__(256) void pcast_kernel(const float* __restrict__ proj,
                                                    short* __restrict__ Pbf) {
    int l = blockIdx.x;
    for (int idx = threadIdx.x; idx < MP_ * 64; idx += 256) {
        int m = idx >> 6, d = idx & 63;
        float v = (m < M_) ? proj[(size_t)l * M_ * 64 + m * 64 + d] : 0.f;
        Pbf[(size_t)l * MP_ * 64 + idx] = f2bf(v);
    }
}

// ---------------- MFMA bf16 matmul: Y = Xbf @ Wt (+epilogue) ---------------
// EPI: 0=none, 1=gelu, 3=+R1b(bf16)
// OUT: 1=bf16 rm, 3=QKV split (NC=768: Q|K rm 256; V transposed, Yv)
template <int EPI, int OUT>
__global__ __launch_bounds__(256) void mfmm_kernel(
    const short* __restrict__ Xb, const short* __restrict__ Wt,
    const float* __restrict__ bias, const short* __restrict__ R1b,
    void* __restrict__ Yout, short* __restrict__ Yv, int K, int NC) {
    __shared__ short As[128][56];
    __shared__ short Bs[128][56];
    int tid = threadIdx.x;
    int rowBase = blockIdx.y * 128, colBase = blockIdx.x * 128;
    int w = tid >> 6, lane = tid & 63;
    int wm = w & 1, wn = w >> 1;
    int quad = lane >> 4, l16 = lane & 15;
    int sr = tid >> 1;
    int sk = (tid & 1) * 16;
    const short* Xp = Xb + (size_t)(rowBase + sr) * K + sk;
    const short* Wp = Wt + (size_t)(colBase + sr) * K + sk;
    floatx4 acc[4][4];
#pragma unroll
    for (int i = 0; i < 4; ++i)
#pragma unroll
        for (int j = 0; j < 4; ++j)
            acc[i][j] = (floatx4){0.f, 0.f, 0.f, 0.f};
    for (int k0 = 0; k0 < K; k0 += 32) {
        short8 xa0 = *(const short8*)(Xp + k0);
        short8 xa1 = *(const short8*)(Xp + k0 + 8);
        short8 wb0 = *(const short8*)(Wp + k0);
        short8 wb1 = *(const short8*)(Wp + k0 + 8);
        __syncthreads();
        *(short8*)&As[sr][sk] = xa0;
        *(short8*)&As[sr][sk + 8] = xa1;
        *(short8*)&Bs[sr][sk] = wb0;
        *(short8*)&Bs[sr][sk + 8] = wb1;
        __syncthreads();
        short8 a[4], b[4];
#pragma unroll
        for (int mi = 0; mi < 4; ++mi)
            a[mi] = *(const short8*)&As[wm * 64 + mi * 16 + l16][quad * 8];
#pragma unroll
        for (int ni = 0; ni < 4; ++ni)
            b[ni] = *(const short8*)&Bs[wn * 64 + ni * 16 + l16][quad * 8];
#pragma unroll
        for (int mi = 0; mi < 4; ++mi)
#pragma unroll
            for (int ni = 0; ni < 4; ++ni)
                acc[mi][ni] = __builtin_amdgcn_mfma_f32_16x16x32_bf16(
                    a[mi], b[ni], acc[mi][ni], 0, 0, 0);
    }
    if (OUT == 3) {
        int region = colBase >> 8;   // 0=Q, 1=K, 2=V
        if (region < 2) {
            short* dst = (short*)Yout + (size_t)region * (size_t)TN * 256;
#pragma unroll
            for (int ni = 0; ni < 4; ++ni) {
                int cl = (colBase + wn * 64 + ni * 16 + l16) & 255;
#pragma unroll
                for (int mi = 0; mi < 4; ++mi) {
#pragma unroll
                    for (int r = 0; r < 4; ++r) {
                        int rowg = rowBase + wm * 64 + mi * 16 + quad * 4 + r;
                        dst[(size_t)rowg * 256 + cl] = f2bf(acc[mi][ni][r]);
                    }
                }
            }
        } else {
#pragma unroll
            for (int ni = 0; ni < 4; ++ni) {
                int cl = (colBase + wn * 64 + ni * 16 + l16) & 255;
                int hh = cl >> 6, dd = cl & 63;
#pragma unroll
                for (int mi = 0; mi < 4; ++mi) {
                    int rowg0 = rowBase + wm * 64 + mi * 16 + quad * 4;
                    int bb = rowg0 >> 9, ng = rowg0 & 511;
                    short4v pv;
#pragma unroll
                    for (int r = 0; r < 4; ++r) pv[r] = f2bf(acc[mi][ni][r]);
                    *(short4v*)(Yv + (((size_t)bb * 4 + hh) * 64 + dd) * 512 + ng) = pv;
                }
            }
        }
        return;
    }
#pragma unroll
    for (int ni = 0; ni < 4; ++ni) {
        int colg = colBase + wn * 64 + ni * 16 + l16;
        float bv = bias ? bias[colg] : 0.f;
#pragma unroll
        for (int mi = 0; mi < 4; ++mi) {
#pragma unroll
            for (int r = 0; r < 4; ++r) {
                int rowg = rowBase + wm * 64 + mi * 16 + quad * 4 + r;
                float y = acc[mi][ni][r] + bv;
                if (EPI == 1) y = gelu_exact(y);
                if (EPI == 3) y += bf2f(R1b[(size_t)rowg * NC + colg]);
                ((short*)Yout)[(size_t)rowg * NC + colg] = f2bf(y);
            }
        }
    }
}

// ------ MFMA matmul + fused row-LayerNorm epilogue (NC=256, 64-row tile) ---
// Y = LN(Xb@Wt + bias + Res)*g + beta  [+ Post if HAS_POST]  -> bf16
template <bool HAS_POST>
__global__ __launch_bounds__(256) void mfmm_ln_kernel(
    const short* __restrict__ Xb, const short* __restrict__ Wt,
    const float* __restrict__ bias, const short* __restrict__ Res,
    const short* __restrict__ Post, const float* __restrict__ g,
    const float* __restrict__ bta, short* __restrict__ Yout, int K) {
    __shared__ short As[64][56];
    __shared__ short Bs[256][56];
    __shared__ float redS[4][64];
    __shared__ float redS2[4][64];
    int tid = threadIdx.x;
    int rowBase = blockIdx.x * 64;
    int w = tid >> 6, lane = tid & 63;
    int quad = lane >> 4, l16 = lane & 15;
    int asr = tid >> 2, ask = (tid & 3) * 8;
    const short* Xp = Xb + (size_t)(rowBase + asr) * K + ask;
    const short* Wp = Wt + (size_t)tid * K;
    floatx4 acc[4][4];
#pragma unroll
    for (int i = 0; i < 4; ++i)
#pragma unroll
        for (int j = 0; j < 4; ++j)
            acc[i][j] = (floatx4){0.f, 0.f, 0.f, 0.f};
    for (int k0 = 0; k0 < K; k0 += 32) {
        short8 xa = *(const short8*)(Xp + k0);
        short8 wb0 = *(const short8*)(Wp + k0);
        short8 wb1 = *(const short8*)(Wp + k0 + 8);
        short8 wb2 = *(const short8*)(Wp + k0 + 16);
        short8 wb3 = *(const short8*)(Wp + k0 + 24);
        __syncthreads();
        *(short8*)&As[asr][ask] = xa;
        *(short8*)&Bs[tid][0] = wb0;
        *(short8*)&Bs[tid][8] = wb1;
        *(short8*)&Bs[tid][16] = wb2;
        *(short8*)&Bs[tid][24] = wb3;
        __syncthreads();
        short8 a[4], b[4];
#pragma unroll
        for (int mi = 0; mi < 4; ++mi)
            a[mi] = *(const short8*)&As[mi * 16 + l16][quad * 8];
#pragma unroll
        for (int ni = 0; ni < 4; ++ni)
            b[ni] = *(const short8*)&Bs[w * 64 + ni * 16 + l16][quad * 8];
#pragma unroll
        for (int mi = 0; mi < 4; ++mi)
#pragma unroll
            for (int ni = 0; ni < 4; ++ni)
                acc[mi][ni] = __builtin_amdgcn_mfma_f32_16x16x32_bf16(
                    a[mi], b[ni], acc[mi][ni], 0, 0, 0);
    }
    // ---- epilogue: bias + residual, row stats, LN ----
    int cols[4];
    float gv[4], bv[4], biasv[4];
#pragma unroll
    for (int ni = 0; ni < 4; ++ni) {
        cols[ni] = w * 64 + ni * 16 + l16;
        gv[ni] = g[cols[ni]];
        bv[ni] = bta[cols[ni]];
        biasv[ni] = bias[cols[ni]];
    }
    float ps[4][4], ps2[4][4];
#pragma unroll
    for (int mi = 0; mi < 4; ++mi)
#pragma unroll
        for (int r = 0; r < 4; ++r) { ps[mi][r] = 0.f; ps2[mi][r] = 0.f; }
#pragma unroll
    for (int mi = 0; mi < 4; ++mi) {
#pragma unroll
        for (int r = 0; r < 4; ++r) {
            size_t rowg = rowBase + mi * 16 + quad * 4 + r;
#pragma unroll
            for (int ni = 0; ni < 4; ++ni) {
                float y = acc[mi][ni][r] + biasv[ni] +
                          bf2f(Res[rowg * 256 + cols[ni]]);
                acc[mi][ni][r] = y;
                ps[mi][r] += y;
                ps2[mi][r] += y * y;
            }
        }
    }
#pragma unroll
    for (int mask = 1; mask < 16; mask <<= 1) {
#pragma unroll
        for (int mi = 0; mi < 4; ++mi)
#pragma unroll
            for (int r = 0; r < 4; ++r) {
                ps[mi][r] += __shfl_xor(ps[mi][r], mask);
                ps2[mi][r] += __shfl_xor(ps2[mi][r], mask);
            }
    }
    __syncthreads();   // staging LDS reads done; red arrays are separate but sync waves
    if (l16 == 0) {
#pragma unroll
        for (int mi = 0; mi < 4; ++mi)
#pragma unroll
            for (int r = 0; r < 4; ++r) {
                redS[w][mi * 16 + quad * 4 + r] = ps[mi][r];
                redS2[w][mi * 16 + quad * 4 + r] = ps2[mi][r];
            }
    }
    __syncthreads();
#pragma unroll
    for (int mi = 0; mi < 4; ++mi) {
#pragma unroll
        for (int r = 0; r < 4; ++r) {
            int rl = mi * 16 + quad * 4 + r;
            float s = redS[0][rl] + redS[1][rl] + redS[2][rl] + redS[3][rl];
            float s2 = redS2[0][rl] + redS2[1][rl] + redS2[2][rl] + redS2[3][rl];
            float mu = s * (1.f / 256.f);
            float var = s2 * (1.f / 256.f) - mu * mu;
            float inv = rsqrtf(var + LN_EPS_);
            size_t rowg = rowBase + rl;
#pragma unroll
            for (int ni = 0; ni < 4; ++ni) {
                float y = (acc[mi][ni][r] - mu) * inv * gv[ni] + bv[ni];
                if (HAS_POST) y += bf2f(Post[rowg * 256 + cols[ni]]);
                Yout[rowg * 256 + cols[ni]] = f2bf(y);
            }
        }
    }
}

// ------------- fallback fp32 tiled matmul (old path) -----------------------
template <bool IN_ADD, int EPI>
__global__ __launch_bounds__(256) void mm_kernel(
    const float* __restrict__ X, const float* __restrict__ X2,
    const float* __restrict__ W, const float* __restrict__ bias,
    const float* __restrict__ R1, const float* __restrict__ R2,
    float* __restrict__ Y, int K, int NC) {
    __shared__ float Xs[16][65];
    __shared__ float Ws[16][68];
    int tid = threadIdx.x;
    int tx = tid & 15, ty = tid >> 4;
    int rowBase = blockIdx.y * 64;
    int colBase = blockIdx.x * 64;
    int lr = tid >> 2;
    int lk = (tid & 3) << 2;
    int wk = tid >> 4;
    int wc = (tid & 15) << 2;
    const float* Xp = X + (size_t)(rowBase + lr) * K + lk;
    const float* X2p = IN_ADD ? (X2 + (size_t)(rowBase + lr) * K + lk) : X;
    const float* Wp = W + (size_t)wk * NC + colBase + wc;
    float acc[4][4] = {};
    for (int k0 = 0; k0 < K; k0 += 16) {
        float4 xv = *(const float4*)(Xp + k0);
        if (IN_ADD) {
            float4 x2 = *(const float4*)(X2p + k0);
            xv.x += x2.x; xv.y += x2.y; xv.z += x2.z; xv.w += x2.w;
        }
        float4 wv = *(const float4*)(Wp + (size_t)k0 * NC);
        __syncthreads();
        Xs[lk + 0][lr] = xv.x;
        Xs[lk + 1][lr] = xv.y;
        Xs[lk + 2][lr] = xv.z;
        Xs[lk + 3][lr] = xv.w;
        *(float4*)&Ws[wk][wc] = wv;
        __syncthreads();
#pragma unroll
        for (int kk = 0; kk < 16; ++kk) {
            float a[4], b[4];
#pragma unroll
            for (int i = 0; i < 4; ++i) a[i] = Xs[kk][ty * 4 + i];
#pragma unroll
            for (int j = 0; j < 4; ++j) b[j] = Ws[kk][tx * 4 + j];
#pragma unroll
            for (int i = 0; i < 4; ++i)
#pragma unroll
                for (int j = 0; j < 4; ++j) acc[i][j] = fmaf(a[i], b[j], acc[i][j]);
        }
    }
    int c0 = colBase + tx * 4;
    float4 bv = make_float4(0.f, 0.f, 0.f, 0.f);
    if (bias) bv = *(const float4*)(bias + c0);
#pragma unroll
    for (int i = 0; i < 4; ++i) {
        int r = rowBase + ty * 4 + i;
        float4 y;
        y.x = acc[i][0] + bv.x; y.y = acc[i][1] + bv.y;
        y.z = acc[i][2] + bv.z; y.w = acc[i][3] + bv.w;
        if (EPI == 1) {
            y.x = gelu_exact(y.x); y.y = gelu_exact(y.y);
            y.z = gelu_exact(y.z); y.w = gelu_exact(y.w);
        }
        if (EPI >= 2) {
            float4 r1 = *(const float4*)(R1 + (size_t)r * NC + c0);
            y.x += r1.x; y.y += r1.y; y.z += r1.z; y.w += r1.w;
        }
        if (EPI == 3) {
            float4 r2 = *(const float4*)(R2 + (size_t)r * NC + c0);
            y.x += r2.x; y.y += r2.y; y.z += r2.z; y.w += r2.w;
        }
        *(float4*)(Y + (size_t)r * NC + c0) = y;
    }
}

// fp32 LN fallback
__global__ __launch_bounds__(256) void ln_kernel(
    const float* __restrict__ X, const float* __restrict__ g,
    const float* __restrict__ bta, float* __restrict__ Y) {
    __shared__ float rs[4], rs2[4];
    __shared__ float mu_s, inv_s;
    int row = blockIdx.x, t = threadIdx.x;
    size_t off = (size_t)row * C_ + t;
    float v = X[off];
    float s = v, s2 = v * v;
#pragma unroll
    for (int o = 32; o > 0; o >>= 1) {
        s += __shfl_down(s, o);
        s2 += __shfl_down(s2, o);
    }
    int w = t >> 6, lane = t & 63;
    if (lane == 0) { rs[w] = s; rs2[w] = s2; }
    __syncthreads();
    if (t == 0) {
        float tot = rs[0] + rs[1] + rs[2] + rs[3];
        float tot2 = rs2[0] + rs2[1] + rs2[2] + rs2[3];
        float mu = tot * (1.f / C_);
        float var = tot2 * (1.f / C_) - mu * mu;
        mu_s = mu;
        inv_s = rsqrtf(var + LN_EPS_);
    }
    __syncthreads();
    Y[off] = (v - mu_s) * inv_s * g[t] + bta[t];
}

// ---------- MFMA Performer pass 1: ctxT[bh][d][m], ksum[bh][m] -------------
__global__ __launch_bounds__(256) void p1m_kernel(
    const short* __restrict__ Kbf, const short* __restrict__ VbfT,
    const short* __restrict__ Pbf, short* __restrict__ ctxT,
    float* __restrict__ ksum) {
    int mt = blockIdx.x;
    int bh = blockIdx.y;
    int b = bh >> 2, h = bh & 3;
    __shared__ short Ps[64][72];
    __shared__ short Ks[64][72];
    __shared__ short VTs[64][72];
    __shared__ short Ss[64][72];
    __shared__ float kred[4][64];
    int tid = threadIdx.x;
    int w = tid >> 6, lane = tid & 63;
    int quad = lane >> 4, l16 = lane & 15;
    int lr = tid >> 2, lb = (tid & 3) << 4;
    {
        const short* p = Pbf + ((size_t)(mt * 64 + lr)) * 64 + lb;
        *(short8*)&Ps[lr][lb] = *(const short8*)p;
        *(short8*)&Ps[lr][lb + 8] = *(const short8*)(p + 8);
    }
    floatx4 cacc[4];
#pragma unroll
    for (int i = 0; i < 4; ++i) cacc[i] = (floatx4){0.f, 0.f, 0.f, 0.f};
    float kacc[4] = {0.f, 0.f, 0.f, 0.f};
    size_t kbase = ((size_t)(b * 512)) * 256 + h * 64;
    size_t vbase = ((size_t)(bh * 64)) * 512;
    for (int nt = 0; nt < 8; ++nt) {
        __syncthreads();
        {
            const short* kp = Kbf + kbase + (size_t)(nt * 64 + lr) * 256 + lb;
            *(short8*)&Ks[lr][lb] = *(const short8*)kp;
            *(short8*)&Ks[lr][lb + 8] = *(const short8*)(kp + 8);
            const short* vp = VbfT + vbase + (size_t)lr * 512 + nt * 64 + lb;
            *(short8*)&VTs[lr][lb] = *(const short8*)vp;
            *(short8*)&VTs[lr][lb + 8] = *(const short8*)(vp + 8);
        }
        __syncthreads();
        floatx4 sa[4];
#pragma unroll
        for (int mi = 0; mi < 4; ++mi) sa[mi] = (floatx4){0.f, 0.f, 0.f, 0.f};
#pragma unroll
        for (int kt = 0; kt < 2; ++kt) {
            short8 a = *(const short8*)&Ks[w * 16 + l16][kt * 32 + quad * 8];
#pragma unroll
            for (int mi = 0; mi < 4; ++mi) {
                short8 bq = *(const short8*)&Ps[mi * 16 + l16][kt * 32 + quad * 8];
                sa[mi] = __builtin_amdgcn_mfma_f32_16x16x32_bf16(a, bq, sa[mi], 0, 0, 0);
            }
        }
#pragma unroll
        for (int mi = 0; mi < 4; ++mi) {
            int mg = mt * 64 + mi * 16 + l16;
            short4v sv;
            float kl = 0.f;
#pragma unroll
            for (int r = 0; r < 4; ++r) {
                float v = (mg < M_) ? (fmaxf(sa[mi][r], 0.f) + EPSK_) : 0.f;
                sv[r] = f2bf(v);
                kl += v;
            }
            kacc[mi] += kl;
            *(short4v*)&Ss[mi * 16 + l16][w * 16 + quad * 4] = sv;
        }
        __syncthreads();
#pragma unroll
        for (int kt = 0; kt < 2; ++kt) {
            short8 a = *(const short8*)&Ss[w * 16 + l16][kt * 32 + quad * 8];
#pragma unroll
            for (int di = 0; di < 4; ++di) {
                short8 bv = *(const short8*)&VTs[di * 16 + l16][kt * 32 + quad * 8];
                cacc[di] = __builtin_amdgcn_mfma_f32_16x16x32_bf16(a, bv, cacc[di], 0, 0, 0);
            }
        }
    }
    size_t cbase = ((size_t)bh * 64) * MP_ + mt * 64;
#pragma unroll
    for (int di = 0; di < 4; ++di) {
        int d = di * 16 + l16;
        short4v cv;
#pragma unroll
        for (int r = 0; r < 4; ++r) cv[r] = f2bf(cacc[di][r]);
        *(short4v*)(ctxT + cbase + (size_t)d * MP_ + w * 16 + quad * 4) = cv;
    }
#pragma unroll
    for (int mi = 0; mi < 4; ++mi) {
        kacc[mi] += __shfl_down(kacc[mi], 32);
        kacc[mi] += __shfl_down(kacc[mi], 16);
    }
    if (lane < 16) {
#pragma unroll
        for (int mi = 0; mi < 4; ++mi) kred[w][mi * 16 + lane] = kacc[mi];
    }
    __syncthreads();
    if (tid < 64)
        ksum[(size_t)bh * MP_ + mt * 64 + tid] =
            kred[0][tid] + kred[1][tid] + kred[2][tid] + kred[3][tid];
}

// ---------- MFMA Performer pass 2: attbf = bf16((qp@ctx)/(qp@ksum)) --------
__global__ __launch_bounds__(256) void p2m_kernel(
    const short* __restrict__ Qbf, const short* __restrict__ Pbf,
    const short* __restrict__ ctxT, const float* __restrict__ ksum,
    short* __restrict__ attbf) {
    int nt = blockIdx.x;
    int bh = blockIdx.y;
    int b = bh >> 2, h = bh & 3;
    __shared__ short Qs[64][72];
    __shared__ short Ps[64][72];
    __shared__ short CTs[64][72];
    __shared__ short Ss[64][72];
    __shared__ float kss[64];
    __shared__ float dredS[64];
    __shared__ float dinvS[64];
    int tid = threadIdx.x;
    int w = tid >> 6, lane = tid & 63;
    int quad = lane >> 4, l16 = lane & 15;
    int lr = tid >> 2, lb = (tid & 3) << 4;
    size_t qbase = ((size_t)(b * 512)) * 256 + h * 64;
    {
        const short* qp = Qbf + qbase + (size_t)(nt * 64 + lr) * 256 + lb;
        *(short8*)&Qs[lr][lb] = *(const short8*)qp;
        *(short8*)&Qs[lr][lb + 8] = *(const short8*)(qp + 8);
    }
    floatx4 aacc[4];
#pragma unroll
    for (int i = 0; i < 4; ++i) aacc[i] = (floatx4){0.f, 0.f, 0.f, 0.f};
    float dd[4] = {0.f, 0.f, 0.f, 0.f};
    size_t cb = ((size_t)bh * 64) * MP_;
    for (int mt = 0; mt < 5; ++mt) {
        __syncthreads();
        {
            const short* p = Pbf + ((size_t)(mt * 64 + lr)) * 64 + lb;
            *(short8*)&Ps[lr][lb] = *(const short8*)p;
            *(short8*)&Ps[lr][lb + 8] = *(const short8*)(p + 8);
            const short* cp = ctxT + cb + (size_t)lr * MP_ + mt * 64 + lb;
            *(short8*)&CTs[lr][lb] = *(const short8*)cp;
            *(short8*)&CTs[lr][lb + 8] = *(const short8*)(cp + 8);
        }
        if (tid < 64) kss[tid] = ksum[(size_t)bh * MP_ + mt * 64 + tid];
        __syncthreads();
        floatx4 sa[4];
#pragma unroll
        for (int mi = 0; mi < 4; ++mi) sa[mi] = (floatx4){0.f, 0.f, 0.f, 0.f};
#pragma unroll
        for (int kt = 0; kt < 2; ++kt) {
            short8 a = *(const short8*)&Qs[w * 16 + l16][kt * 32 + quad * 8];
#pragma unroll
            for (int mi = 0; mi < 4; ++mi) {
                short8 bq = *(const short8*)&Ps[mi * 16 + l16][kt * 32 + quad * 8];
                sa[mi] = __builtin_amdgcn_mfma_f32_16x16x32_bf16(a, bq, sa[mi], 0, 0, 0);
            }
        }
#pragma unroll
        for (int mi = 0; mi < 4; ++mi) {
            int mg = mt * 64 + mi * 16 + l16;
            float ksv = kss[mi * 16 + l16];
#pragma unroll
            for (int r = 0; r < 4; ++r) {
                float v = (mg < M_) ? (fmaxf(sa[mi][r], 0.f) + EPSK_) : 0.f;
                Ss[w * 16 + quad * 4 + r][mi * 16 + l16] = f2bf(v);
                dd[r] += v * ksv;
            }
        }
        __syncthreads();
#pragma unroll
        for (int kt = 0; kt < 2; ++kt) {
            short8 a = *(const short8*)&Ss[w * 16 + l16][kt * 32 + quad * 8];
#pragma unroll
            for (int di = 0; di < 4; ++di) {
                short8 bv = *(const short8*)&CTs[di * 16 + l16][kt * 32 + quad * 8];
                aacc[di] = __builtin_amdgcn_mfma_f32_16x16x32_bf16(a, bv, aacc[di], 0, 0, 0);
            }
        }
    }
#pragma unroll
    for (int r = 0; r < 4; ++r) {
        dd[r] += __shfl_xor(dd[r], 1);
        dd[r] += __shfl_xor(dd[r], 2);
        dd[r] += __shfl_xor(dd[r], 4);
        dd[r] += __shfl_xor(dd[r], 8);
    }
    if (l16 == 0) {
#pragma unroll
        for (int r = 0; r < 4; ++r) dredS[w * 16 + quad * 4 + r] = dd[r];
    }
    __syncthreads();
    if (tid < 64) dinvS[tid] = 1.f / dredS[tid];
    __syncthreads();
#pragma unroll
    for (int di = 0; di < 4; ++di) {
        int d = di * 16 + l16;
#pragma unroll
        for (int r = 0; r < 4; ++r) {
            int n = w * 16 + quad * 4 + r;
            attbf[((size_t)(b * 512 + nt * 64 + n)) * 256 + h * 64 + d] =
                f2bf(aacc[di][r] * dinvS[n]);
        }
    }
}

// ---------------- fp32 Performer fallbacks (old path) ----------------------
__global__ __launch_bounds__(256) void p1_kernel(
    const float* __restrict__ kbuf, const float* __restrict__ vbuf,
    const float* __restrict__ proj, float* __restrict__ ctx,
    float* __restrict__ ksum) {
    int mt = blockIdx.x;
    int bh = blockIdx.y;
    int b = bh >> 2, h = bh & 3;
    __shared__ float Pt[64][65];
    __shared__ float KV[64][65];
    __shared__ float S[64][65];
    int tid = threadIdx.x;
    int tx = tid & 15, ty = tid >> 4;
    for (int idx = tid; idx < 4096; idx += 256) {
        int r = idx >> 6, c = idx & 63;
        int mg = mt * 64 + r;
        Pt[r][c] = (mg < M_) ? proj[mg * DH_ + c] : 0.f;
    }
    float cacc[4][4] = {};
    float ksacc = 0.f;
    size_t base = ((size_t)b * N_) * C_ + h * DH_;
    for (int nt = 0; nt < 8; ++nt) {
        __syncthreads();
        for (int idx = tid; idx < 4096; idx += 256) {
            int r = idx >> 6, c = idx & 63;
            KV[r][c] = kbuf[base + (size_t)(nt * 64 + r) * C_ + c];
        }
        __syncthreads();
        float s[4][4] = {};
        for (int dd = 0; dd < 64; ++dd) {
            float a[4], bq[4];
#pragma unroll
            for (int i = 0; i < 4; ++i) a[i] = KV[ty * 4 + i][dd];
#pragma unroll
            for (int j = 0; j < 4; ++j) bq[j] = Pt[16 * j + tx][dd];
#pragma unroll
            for (int i = 0; i < 4; ++i)
#pragma unroll
                for (int j = 0; j < 4; ++j) s[i][j] = fmaf(a[i], bq[j], s[i][j]);
        }
        __syncthreads();
#pragma unroll
        for (int i = 0; i < 4; ++i)
#pragma unroll
            for (int j = 0; j < 4; ++j) {
                int mg = mt * 64 + 16 * j + tx;
                S[ty * 4 + i][16 * j + tx] =
                    (mg < M_) ? (fmaxf(s[i][j], 0.f) + EPSK_) : 0.f;
            }
        for (int idx = tid; idx < 4096; idx += 256) {
            int r = idx >> 6, c = idx & 63;
            KV[r][c] = vbuf[base + (size_t)(nt * 64 + r) * C_ + c];
        }
        __syncthreads();
        for (int nn = 0; nn < 64; ++nn) {
            float sm[4], vd[4];
#pragma unroll
            for (int i = 0; i < 4; ++i) sm[i] = S[nn][ty * 4 + i];
#pragma unroll
            for (int j = 0; j < 4; ++j) vd[j] = KV[nn][tx * 4 + j];
#pragma unroll
            for (int i = 0; i < 4; ++i)
#pragma unroll
                for (int j = 0; j < 4; ++j) cacc[i][j] = fmaf(sm[i], vd[j], cacc[i][j]);
        }
        if (tid < 64) {
            for (int nn = 0; nn < 64; ++nn) ksacc += S[nn][tid];
        }
    }
    float* cp = ctx + ((size_t)bh * MP_ + mt * 64) * DH_;
#pragma unroll
    for (int i = 0; i < 4; ++i)
#pragma unroll
        for (int j = 0; j < 4; ++j)
            cp[(ty * 4 + i) * DH_ + tx * 4 + j] = cacc[i][j];
    if (tid < 64) ksum[bh * MP_ + mt * 64 + tid] = ksacc;
}

__global__ __launch_bounds__(256) void p2_kernel(
    const float* __restrict__ qbuf, const float* __restrict__ proj,
    const float* __restrict__ ctx, const float* __restrict__ ksum,
    float* __restrict__ attout) {
    int nt = blockIdx.x;
    int bh = blockIdx.y;
    int b = bh >> 2, h = bh & 3;
    __shared__ float Qt[64][65];
    __shared__ float PC[64][65];
    __shared__ float S[64][65];
    __shared__ float ks[64], dinv[64];
    int tid = threadIdx.x;
    int tx = tid & 15, ty = tid >> 4;
    size_t base = ((size_t)b * N_) * C_ + h * DH_;
    for (int idx = tid; idx < 4096; idx += 256) {
        int r = idx >> 6, c = idx & 63;
        Qt[r][c] = qbuf[base + (size_t)(nt * 64 + r) * C_ + c];
    }
    float aacc[4][4] = {};
    float dacc = 0.f;
    for (int mt = 0; mt < 5; ++mt) {
        __syncthreads();
        for (int idx = tid; idx < 4096; idx += 256) {
            int r = idx >> 6, c = idx & 63;
            int mg = mt * 64 + r;
            PC[r][c] = (mg < M_) ? proj[mg * DH_ + c] : 0.f;
        }
        if (tid < 64) ks[tid] = ksum[bh * MP_ + mt * 64 + tid];
        __syncthreads();
        float s[4][4] = {};
        for (int dd = 0; dd < 64; ++dd) {
            float a[4], bq[4];
#pragma unroll
            for (int i = 0; i < 4; ++i) a[i] = Qt[ty * 4 + i][dd];
#pragma unroll
            for (int j = 0; j < 4; ++j) bq[j] = PC[16 * j + tx][dd];
#pragma unroll
            for (int i = 0; i < 4; ++i)
#pragma unroll
                for (int j = 0; j < 4; ++j) s[i][j] = fmaf(a[i], bq[j], s[i][j]);
        }
        __syncthreads();
#pragma unroll
        for (int i = 0; i < 4; ++i)
#pragma unroll
            for (int j = 0; j < 4; ++j) {
                int mg = mt * 64 + 16 * j + tx;
                S[ty * 4 + i][16 * j + tx] =
                    (mg < M_) ? (fmaxf(s[i][j], 0.f) + EPSK_) : 0.f;
            }
        for (int idx = tid; idx < 4096; idx += 256) {
            int r = idx >> 6, c = idx & 63;
            PC[r][c] = ctx[((size_t)bh * MP_ + mt * 64 + r) * DH_ + c];
        }
        __syncthreads();
        for (int mm = 0; mm < 64; ++mm) {
            float sm[4], cd[4];
#pragma unroll
            for (int i = 0; i < 4; ++i) sm[i] = S[ty * 4 + i][mm];
#pragma unroll
            for (int j = 0; j < 4; ++j) cd[j] = PC[mm][tx * 4 + j];
#pragma unroll
            for (int i = 0; i < 4; ++i)
#pragma unroll
                for (int j = 0; j < 4; ++j) aacc[i][j] = fmaf(sm[i], cd[j], aacc[i][j]);
        }
        if (tid < 64) {
            for (int mm = 0; mm < 64; ++mm) dacc = fmaf(S[tid][mm], ks[mm], dacc);
        }
    }
    __syncthreads();
    if (tid < 64) dinv[tid] = 1.f / dacc;
    __syncthreads();
#pragma unroll
    for (int i = 0; i < 4; ++i) {
        int n = ty * 4 + i;
        float di = dinv[n];
        float4 y = make_float4(aacc[i][0] * di, aacc[i][1] * di,
                               aacc[i][2] * di, aacc[i][3] * di);
        *(float4*)(attout + base + (size_t)(nt * 64 + n) * C_ + tx * 4) = y;
    }
}

// -------------------- mean pool (bf16 in, fp32 out) ------------------------
__global__ __launch_bounds__(256) void pool_kernel(const short* __restrict__ abf,
                                                   float* __restrict__ out) {
    int b = blockIdx.x;
    int c = threadIdx.x;
    const short* p = abf + (size_t)b * N_ * C_ + c;
    float s = 0.f;
    for (int n = 0; n < N_; ++n) s += bf2f(p[(size_t)n * C_]);
    out[b * C_ + c] = s * (1.f / 512.f);
}

__global__ __launch_bounds__(256) void poolf_kernel(const float* __restrict__ atoms,
                                                    float* __restrict__ out) {
    int b = blockIdx.x;
    int c = threadIdx.x;
    const float* p = atoms + (size_t)b * N_ * C_ + c;
    float s = 0.f;
    for (int n = 0; n < N_; ++n) s += p[(size_t)n * C_];
    out[b * C_ + c] = s * (1.f / 512.f);
}

extern "C" void kernel_launch(void* const* d_in, const int* in_sizes, int n_in,
                              void* d_out, int out_size, void* d_ws, size_t ws_size,
                              hipStream_t stream) {
    (void)in_sizes; (void)n_in; (void)out_size;
    const float* x = (const float*)d_in[0];
    const float* edge_attr = (const float*)d_in[1];
    const int* edge_index = (const int*)d_in[2];
    const float* node_w = (const float*)d_in[4];
    const float* node_b = (const float*)d_in[5];
    const float* edge_w = (const float*)d_in[6];
    const float* edge_b = (const float*)d_in[7];
    const float* gine_w1 = (const float*)d_in[8];
    const float* gine_b1 = (const float*)d_in[9];
    const float* gine_w2 = (const float*)d_in[10];
    const float* gine_b2 = (const float*)d_in[11];
    const float* q_w = (const float*)d_in[12];
    const float* k_w = (const float*)d_in[13];
    const float* v_w = (const float*)d_in[14];
    const float* o_w = (const float*)d_in[15];
    const float* o_b = (const float*)d_in[16];
    const float* proj = (const float*)d_in[17];
    const float* n1g = (const float*)d_in[18];
    const float* n1b = (const float*)d_in[19];
    const float* n2g = (const float*)d_in[20];
    const float* n2b = (const float*)d_in[21];
    const float* n3g = (const float*)d_in[22];
    const float* n3b = (const float*)d_in[23];
    const float* mw1 = (const float*)d_in[24];
    const float* mb1 = (const float*)d_in[25];
    const float* mw2 = (const float*)d_in[26];
    const float* mb2 = (const float*)d_in[27];

    const size_t SZ = (size_t)TN * C_;   // 8,388,608
    float* ws = (float*)d_ws;
    float* A     = ws;                               // fp32 atoms (fallback only)
    short* Abf   = (short*)(ws + SZ);
    short* X1bf  = (short*)(ws + SZ + SZ / 2);       // also t2bf
    short* t2bf  = X1bf;
    short* t1bf  = (short*)(ws + 2 * SZ);            // also ATTbf
    short* ATTbf = t1bf;
    short* HLbf  = (short*)(ws + 2 * SZ + SZ / 2);
    short* Qbf   = (short*)(ws + 3 * SZ);            // also R3 (dead alias)
    short* Kbf   = (short*)(ws + 3 * SZ + SZ / 2);
    short* VbfT  = (short*)(ws + 4 * SZ);
    short* ctxTb = (short*)(ws + 4 * SZ + SZ / 2);
    float* KS2   = (float*)(ctxTb + (size_t)256 * 64 * MP_);
    short* SUMbf = (short*)(ws + 5 * SZ);

    int* deg    = (int*)(ws + 6 * SZ);
    int* offs   = deg + TN;
    int* cursor = offs + TN + 1;
    int* esrc   = cursor + TN;
    float* easrt = (float*)(((uintptr_t)(esrc + E_) + 15) & ~(uintptr_t)15);
    short* WTg1  = (short*)(easrt + (size_t)4 * E_);
    short* WTg2  = WTg1 + (size_t)5 * 65536;
    short* WTqkv = WTg2 + (size_t)5 * 65536;
    short* WTo   = WTqkv + (size_t)5 * 196608;
    short* WTm1  = WTo + (size_t)5 * 65536;
    short* WTm2  = WTm1 + (size_t)5 * 131072;
    short* Pbf   = WTm2 + (size_t)5 * 131072;
    size_t need = 6 * SZ * sizeof(float) +
                  (size_t)(3 * TN + 1 + E_) * sizeof(int) + 16 +
                  (size_t)4 * E_ * sizeof(float) +
                  ((size_t)5 * (3 * 65536 + 196608 + 2 * 131072 + MP_ * 64)) *
                      sizeof(short);
    bool full = ws_size >= need;

    dim3 gm256(2, 256), gm512(4, 256), gm768(6, 256);
    dim3 g256(4, 512), g512(8, 512);

    embed_kernel<<<TN, 256, 0, stream>>>(x, node_w, node_b, A, Abf);
    if (full) {
        hipMemsetAsync(deg, 0, TN * sizeof(int), stream);
        count_kernel<<<E_ / 256, 256, 0, stream>>>(edge_index, deg);
        scan_kernel<<<1, 1024, 0, stream>>>(deg, offs, cursor);
        fill_kernel<<<E_ / 256, 256, 0, stream>>>(edge_index, edge_attr, cursor,
                                                  esrc, easrt);
        wt_kernel<<<dim3(4, 4, L_), 256, 0, stream>>>(gine_w1, WTg1, 256, 256, 65536, 0);
        wt_kernel<<<dim3(4, 4, L_), 256, 0, stream>>>(gine_w2, WTg2, 256, 256, 65536, 0);
        wt_kernel<<<dim3(4, 4, L_), 256, 0, stream>>>(q_w, WTqkv, 256, 256, 196608, 0);
        wt_kernel<<<dim3(4, 4, L_), 256, 0, stream>>>(k_w, WTqkv, 256, 256, 196608, 256);
        wt_kernel<<<dim3(4, 4, L_), 256, 0, stream>>>(v_w, WTqkv, 256, 256, 196608, 512);
        wt_kernel<<<dim3(4, 4, L_), 256, 0, stream>>>(o_w, WTo, 256, 256, 65536, 0);
        wt_kernel<<<dim3(8, 4, L_), 256, 0, stream>>>(mw1, WTm1, 256, 512, 131072, 0);
        wt_kernel<<<dim3(4, 8, L_), 256, 0, stream>>>(mw2, WTm2, 512, 256, 131072, 0);
        pcast_kernel<<<L_, 256, 0, stream>>>(proj, Pbf);
    }
    for (int l = 0; l < L_; ++l) {
        if (full) {
            gather_kernel<<<TN / 4, 256, 0, stream>>>(Abf, offs, esrc, easrt,
                                                      edge_w, edge_b, X1bf);
            // t1 = gelu(X1 @ g1 + b1)
            mfmm_kernel<1, 1><<<gm256, 256, 0, stream>>>(
                X1bf, WTg1 + (size_t)l * 65536, gine_b1 + l * 256,
                nullptr, t1bf, nullptr, 256, 256);
            // HL = LN1(t1 @ g2 + b2 + Abf)   [fused]
            mfmm_ln_kernel<false><<<TN / 64, 256, 0, stream>>>(
                t1bf, WTg2 + (size_t)l * 65536, gine_b2 + l * 256,
                Abf, nullptr, n1g + l * 256, n1b + l * 256, HLbf, 256);
            // QKV fused
            mfmm_kernel<0, 3><<<gm768, 256, 0, stream>>>(
                Abf, WTqkv + (size_t)l * 196608, nullptr,
                nullptr, Qbf, VbfT, 256, 768);
            p1m_kernel<<<dim3(5, 256), 256, 0, stream>>>(
                Kbf, VbfT, Pbf + (size_t)l * MP_ * 64, ctxTb, KS2);
            p2m_kernel<<<dim3(8, 256), 256, 0, stream>>>(
                Qbf, Pbf + (size_t)l * MP_ * 64, ctxTb, KS2, ATTbf);
            // SUM = LN2(ATT @ o_w + o_b + Abf) + HL   [fused]
            mfmm_ln_kernel<true><<<TN / 64, 256, 0, stream>>>(
                ATTbf, WTo + (size_t)l * 65536, o_b + l * 256,
                Abf, HLbf, n2g + l * 256, n2b + l * 256, SUMbf, 256);
            // t2 = gelu(SUM @ m1 + b1)  [NC=512]
            mfmm_kernel<1, 1><<<gm512, 256, 0, stream>>>(
                SUMbf, WTm1 + (size_t)l * 131072, mb1 + l * 512,
                nullptr, t2bf, nullptr, 256, 512);
            // Abf = LN3(t2 @ m2 + b2 + SUM)  [K=512, fused]
            mfmm_ln_kernel<false><<<TN / 64, 256, 0, stream>>>(
                t2bf, WTm2 + (size_t)l * 131072, mb2 + l * 256,
                SUMbf, nullptr, n3g + l * 256, n3b + l * 256, Abf, 512);
        } else {
            float* AGf = A + SZ;
            float* Tf = AGf + SZ;
            float* HLf = Tf + 2 * SZ;
            float* Vbf2 = HLf + SZ;
            float* Qf = AGf;
            float* Kf = Tf;
            float* CTXf = Tf + SZ;
            float* KSf = CTXf + (size_t)256 * MP_ * DH_;
            hipMemsetAsync(AGf, 0, SZ * sizeof(float), stream);
            scatter_kernel<<<E_ * 64 / 256, 256, 0, stream>>>(A, edge_attr, edge_index,
                                                              edge_w, edge_b, AGf);
            mm_kernel<true, 1><<<g256, 256, 0, stream>>>(A, AGf, gine_w1 + l * 65536,
                                                         gine_b1 + l * 256, nullptr,
                                                         nullptr, Tf, 256, 256);
            mm_kernel<false, 2><<<g256, 256, 0, stream>>>(Tf, nullptr, gine_w2 + l * 65536,
                                                          gine_b2 + l * 256, A, nullptr,
                                                          HLf, 256, 256);
            ln_kernel<<<TN, 256, 0, stream>>>(HLf, n1g + l * 256, n1b + l * 256, HLf);
            mm_kernel<false, 0><<<g256, 256, 0, stream>>>(A, nullptr, q_w + l * 65536,
                                                          nullptr, nullptr, nullptr,
                                                          Qf, 256, 256);
            mm_kernel<false, 0><<<g256, 256, 0, stream>>>(A, nullptr, k_w + l * 65536,
                                                          nullptr, nullptr, nullptr,
                                                          Kf, 256, 256);
            mm_kernel<false, 0><<<g256, 256, 0, stream>>>(A, nullptr, v_w + l * 65536,
                                                          nullptr, nullptr, nullptr,
                                                          Vbf2, 256, 256);
            p1_kernel<<<dim3(5, 256), 256, 0, stream>>>(Kf, Vbf2, proj + l * (M_ * DH_),
                                                        CTXf, KSf);
            p2_kernel<<<dim3(8, 256), 256, 0, stream>>>(Qf, proj + l * (M_ * DH_),
                                                        CTXf, KSf, Kf);
            mm_kernel<false, 2><<<g256, 256, 0, stream>>>(Kf, nullptr, o_w + l * 65536,
                                                          o_b + l * 256, A, nullptr,
                                                          Qf, 256, 256);
            ln_kernel<<<TN, 256, 0, stream>>>(Qf, n2g + l * 256, n2b + l * 256, Qf);
            mm_kernel<true, 1><<<g512, 256, 0, stream>>>(HLf, Qf, mw1 + l * 131072,
                                                         mb1 + l * 512, nullptr, nullptr,
                                                         Tf, 256, 512);
            mm_kernel<false, 3><<<g256, 256, 0, stream>>>(Tf, nullptr, mw2 + l * 131072,
                                                          mb2 + l * 256, HLf, Qf,
                                                          Vbf2, 512, 256);
            ln_kernel<<<TN, 256, 0, stream>>>(Vbf2, n3g + l * 256, n3b + l * 256, A);
        }
    }
    if (full)
        pool_kernel<<<B_, 256, 0, stream>>>(Abf, (float*)d_out);
    else
        poolf_kernel<<<B_, 256, 0, stream>>>(A, (float*)d_out);
}

// Round 9
// 1698.791 us; speedup vs baseline: 8.9195x; 1.0114x over previous
//
#include <hip/hip_runtime.h>
#include <math.h>
#include <stdint.h>

#define TN 32768
#define C_ 256
#define E_ 524288
#define B_ 64
#define N_ 512
#define H_ 4
#define DH_ 64
#define M_ 266
#define MP_ 320
#define L_ 5
#define LN_EPS_ 1e-5f
#define EPSK_ 1e-3f

typedef short short8 __attribute__((ext_vector_type(8)));
typedef short short4v __attribute__((ext_vector_type(4)));
typedef float floatx4 __attribute__((ext_vector_type(4)));

__device__ __forceinline__ float gelu_exact(float v) {
    return 0.5f * v * (1.0f + erff(v * 0.70710678118654752f));
}

__device__ __forceinline__ short f2bf(float f) {
    union { float f; unsigned u; } v; v.f = f;
    unsigned r = v.u + 0x7FFF + ((v.u >> 16) & 1);
    return (short)(r >> 16);
}

__device__ __forceinline__ float bf2f(short s) {
    union { unsigned u; float f; } v;
    v.u = ((unsigned)(unsigned short)s) << 16;
    return v.f;
}

__device__ __forceinline__ float bflo(unsigned u) {
    union { unsigned u; float f; } v;
    v.u = u << 16;
    return v.f;
}
__device__ __forceinline__ float bfhi(unsigned u) {
    union { unsigned u; float f; } v;
    v.u = u & 0xffff0000u;
    return v.f;
}

// async global->LDS, 16B per lane, dest = lds_base + lane*16
__device__ __forceinline__ void gl2lds16(const short* g, short* l) {
    __builtin_amdgcn_global_load_lds(
        (const __attribute__((address_space(1))) unsigned int*)g,
        (__attribute__((address_space(3))) unsigned int*)l, 16, 0, 0);
}

// ---------------- embed: atoms = log(x+1) @ node_w + node_b ----------------
__global__ __launch_bounds__(256) void embed_kernel(
    const float* __restrict__ x, const float* __restrict__ nw,
    const float* __restrict__ nb, float* __restrict__ atoms,
    short* __restrict__ abf) {
    int node = blockIdx.x;
    int c = threadIdx.x;
    __shared__ float lx[11];
    if (c < 11) lx[c] = logf(x[node * 11 + c] + 1.0f);
    __syncthreads();
    float acc = nb[c];
#pragma unroll
    for (int j = 0; j < 11; ++j) acc = fmaf(lx[j], nw[j * C_ + c], acc);
    atoms[(size_t)node * C_ + c] = acc;   // fp32 copy for fallback path only
    abf[(size_t)node * C_ + c] = f2bf(acc);
}

// ----------------------- CSR build: count / scan / fill --------------------
__global__ __launch_bounds__(256) void count_kernel(const int* __restrict__ eidx,
                                                    int* __restrict__ deg) {
    int e = blockIdx.x * 256 + threadIdx.x;
    atomicAdd(&deg[eidx[E_ + e]], 1);
}

__global__ __launch_bounds__(1024) void scan_kernel(const int* __restrict__ deg,
                                                    int* __restrict__ offs,
                                                    int* __restrict__ cursor) {
    __shared__ int tsum[1024];
    int t = threadIdx.x;
    int base = t * 32;
    int local[32];
    int s = 0;
#pragma unroll
    for (int i = 0; i < 32; ++i) { local[i] = deg[base + i]; s += local[i]; }
    tsum[t] = s;
    __syncthreads();
    for (int off = 1; off < 1024; off <<= 1) {
        int v = tsum[t];
        int add = (t >= off) ? tsum[t - off] : 0;
        __syncthreads();
        tsum[t] = v + add;
        __syncthreads();
    }
    int run = tsum[t] - s;
#pragma unroll
    for (int i = 0; i < 32; ++i) {
        offs[base + i] = run;
        cursor[base + i] = run;
        run += local[i];
    }
    if (t == 1023) offs[TN] = run;
}

__global__ __launch_bounds__(256) void fill_kernel(const int* __restrict__ eidx,
                                                   const float* __restrict__ eattr,
                                                   int* __restrict__ cursor,
                                                   int* __restrict__ esrc,
                                                   float* __restrict__ easrt) {
    int e = blockIdx.x * 256 + threadIdx.x;
    int d = eidx[E_ + e];
    int pos = atomicAdd(&cursor[d], 1);
    esrc[pos] = eidx[e];
    *(float4*)(easrt + (size_t)pos * 4) = *(const float4*)(eattr + (size_t)e * 4);
}

// --- GINE gather: one WAVE per node, no barriers, all-bf16 atoms -----------
__global__ __launch_bounds__(256) void gather_kernel(
    const short* __restrict__ abf, const int* __restrict__ offs,
    const int* __restrict__ esrc, const float* __restrict__ easrt,
    const float* __restrict__ ew, const float* __restrict__ eb,
    short* __restrict__ x1bf) {
    int wv = threadIdx.x >> 6;
    int lane = threadIdx.x & 63;
    int node = blockIdx.x * 4 + wv;
    int c0 = lane * 4;
    float4 w0 = *(const float4*)(ew + c0);
    float4 w1 = *(const float4*)(ew + C_ + c0);
    float4 w2 = *(const float4*)(ew + 2 * C_ + c0);
    float4 w3 = *(const float4*)(ew + 3 * C_ + c0);
    float4 bb = *(const float4*)(eb + c0);
    int j = offs[node];
    int end = offs[node + 1];
    float4 acc = make_float4(0.f, 0.f, 0.f, 0.f);
    float4 acc2 = make_float4(0.f, 0.f, 0.f, 0.f);
    for (; j + 1 < end; j += 2) {
        int s0 = esrc[j];
        int s1 = esrc[j + 1];
        float4 e0 = *(const float4*)(easrt + (size_t)j * 4);
        float4 e1 = *(const float4*)(easrt + (size_t)(j + 1) * 4);
        uint2 p0 = *(const uint2*)(abf + (size_t)s0 * C_ + c0);
        uint2 p1 = *(const uint2*)(abf + (size_t)s1 * C_ + c0);
        float a0x = bflo(p0.x), a0y = bfhi(p0.x), a0z = bflo(p0.y), a0w = bfhi(p0.y);
        float a1x = bflo(p1.x), a1y = bfhi(p1.x), a1z = bflo(p1.y), a1w = bfhi(p1.y);
        float m;
        m = fmaf(e0.x, w0.x, fmaf(e0.y, w1.x, fmaf(e0.z, w2.x, fmaf(e0.w, w3.x, a0x + bb.x))));
        acc.x += fmaxf(m, 0.f);
        m = fmaf(e0.x, w0.y, fmaf(e0.y, w1.y, fmaf(e0.z, w2.y, fmaf(e0.w, w3.y, a0y + bb.y))));
        acc.y += fmaxf(m, 0.f);
        m = fmaf(e0.x, w0.z, fmaf(e0.y, w1.z, fmaf(e0.z, w2.z, fmaf(e0.w, w3.z, a0z + bb.z))));
        acc.z += fmaxf(m, 0.f);
        m = fmaf(e0.x, w0.w, fmaf(e0.y, w1.w, fmaf(e0.z, w2.w, fmaf(e0.w, w3.w, a0w + bb.w))));
        acc.w += fmaxf(m, 0.f);
        m = fmaf(e1.x, w0.x, fmaf(e1.y, w1.x, fmaf(e1.z, w2.x, fmaf(e1.w, w3.x, a1x + bb.x))));
        acc2.x += fmaxf(m, 0.f);
        m = fmaf(e1.x, w0.y, fmaf(e1.y, w1.y, fmaf(e1.z, w2.y, fmaf(e1.w, w3.y, a1y + bb.y))));
        acc2.y += fmaxf(m, 0.f);
        m = fmaf(e1.x, w0.z, fmaf(e1.y, w1.z, fmaf(e1.z, w2.z, fmaf(e1.w, w3.z, a1z + bb.z))));
        acc2.z += fmaxf(m, 0.f);
        m = fmaf(e1.x, w0.w, fmaf(e1.y, w1.w, fmaf(e1.z, w2.w, fmaf(e1.w, w3.w, a1w + bb.w))));
        acc2.w += fmaxf(m, 0.f);
    }
    if (j < end) {
        int s0 = esrc[j];
        float4 e0 = *(const float4*)(easrt + (size_t)j * 4);
        uint2 p0 = *(const uint2*)(abf + (size_t)s0 * C_ + c0);
        float a0x = bflo(p0.x), a0y = bfhi(p0.x), a0z = bflo(p0.y), a0w = bfhi(p0.y);
        float m;
        m = fmaf(e0.x, w0.x, fmaf(e0.y, w1.x, fmaf(e0.z, w2.x, fmaf(e0.w, w3.x, a0x + bb.x))));
        acc.x += fmaxf(m, 0.f);
        m = fmaf(e0.x, w0.y, fmaf(e0.y, w1.y, fmaf(e0.z, w2.y, fmaf(e0.w, w3.y, a0y + bb.y))));
        acc.y += fmaxf(m, 0.f);
        m = fmaf(e0.x, w0.z, fmaf(e0.y, w1.z, fmaf(e0.z, w2.z, fmaf(e0.w, w3.z, a0z + bb.z))));
        acc.z += fmaxf(m, 0.f);
        m = fmaf(e0.x, w0.w, fmaf(e0.y, w1.w, fmaf(e0.z, w2.w, fmaf(e0.w, w3.w, a0w + bb.w))));
        acc.w += fmaxf(m, 0.f);
    }
    uint2 po = *(const uint2*)(abf + (size_t)node * C_ + c0);
    short4v o;
    o.x = f2bf(bflo(po.x) + acc.x + acc2.x);
    o.y = f2bf(bfhi(po.x) + acc.y + acc2.y);
    o.z = f2bf(bflo(po.y) + acc.z + acc2.z);
    o.w = f2bf(bfhi(po.y) + acc.w + acc2.w);
    *(short4v*)(x1bf + (size_t)node * C_ + c0) = o;
}

// ------------- fallback: atomic scatter (if ws too small) ------------------
__global__ __launch_bounds__(256) void scatter_kernel(
    const float* __restrict__ atoms, const float* __restrict__ eattr,
    const int* __restrict__ eidx, const float* __restrict__ ew,
    const float* __restrict__ eb, float* __restrict__ aggr) {
    int gid = blockIdx.x * 256 + threadIdx.x;
    int e = gid >> 6;
    int q = (gid & 63) << 2;
    int src = eidx[e];
    int dst = eidx[E_ + e];
    float4 ea = *(const float4*)(eattr + (size_t)e * 4);
    float4 w0 = *(const float4*)(ew + 0 * C_ + q);
    float4 w1 = *(const float4*)(ew + 1 * C_ + q);
    float4 w2 = *(const float4*)(ew + 2 * C_ + q);
    float4 w3 = *(const float4*)(ew + 3 * C_ + q);
    float4 bb = *(const float4*)(eb + q);
    float4 av = *(const float4*)(atoms + (size_t)src * C_ + q);
    float m0 = av.x + bb.x + ea.x * w0.x + ea.y * w1.x + ea.z * w2.x + ea.w * w3.x;
    float m1 = av.y + bb.y + ea.x * w0.y + ea.y * w1.y + ea.z * w2.y + ea.w * w3.y;
    float m2 = av.z + bb.z + ea.x * w0.z + ea.y * w1.z + ea.z * w2.z + ea.w * w3.z;
    float m3 = av.w + bb.w + ea.x * w0.w + ea.y * w1.w + ea.z * w2.w + ea.w * w3.w;
    float* base = aggr + (size_t)dst * C_ + q;
    atomicAdd(base + 0, fmaxf(m0, 0.f));
    atomicAdd(base + 1, fmaxf(m1, 0.f));
    atomicAdd(base + 2, fmaxf(m2, 0.f));
    atomicAdd(base + 3, fmaxf(m3, 0.f));
}

// --- weight transpose+cast: dst[rowBase+n][k] bf16 from W[l][k][n] fp32 ----
__global__ __launch_bounds__(256) void wt_kernel(const float* __restrict__ W,
                                                 short* __restrict__ Wt,
                                                 int K, int NC,
                                                 size_t lstride, int rowBase) {
    __shared__ short tile[64][65];
    int l = blockIdx.z;
    int k0 = blockIdx.y * 64, n0 = blockIdx.x * 64;
    const float* Wl = W + (size_t)l * K * NC;
    short* Wtl = Wt + (size_t)l * lstride + (size_t)rowBase * K;
    int t = threadIdx.x;
    int rr = t >> 4;
    int cc = (t & 15) * 4;
#pragma unroll
    for (int rep = 0; rep < 4; ++rep) {
        int r = rr + rep * 16;
        float4 v = *(const float4*)(Wl + (size_t)(k0 + r) * NC + n0 + cc);
        tile[cc + 0][r] = f2bf(v.x);
        tile[cc + 1][r] = f2bf(v.y);
        tile[cc + 2][r] = f2bf(v.z);
        tile[cc + 3][r] = f2bf(v.w);
    }
    __syncthreads();
#pragma unroll
    for (int rep = 0; rep < 4; ++rep) {
        int r = rr + rep * 16;
        short4v s;
        s.x = tile[r][cc + 0];
        s.y = tile[r][cc + 1];
        s.z = tile[r][cc + 2];
        s.w = tile[r][cc + 3];
        *(short4v*)(Wtl + (size_t)(n0 + r) * K + k0 + cc) = s;
    }
}

// ---------- proj cast: Pbf[l][m][d] bf16, padded to MP_ with zeros ---------
__global__ __launch_bounds__(256) void pcast_kernel(const float* __restrict__ proj,
                                                    short* __restrict__ Pbf) {
    int l = blockIdx.x;
    for (int idx = threadIdx.x; idx < MP_ * 64; idx += 256) {
        int m = idx >> 6, d = idx & 63;
        float v = (m < M_) ? proj[(size_t)l * M_ * 64 + m * 64 + d] : 0.f;
        Pbf[(size_t)l * MP_ * 64 + idx] = f2bf(v);
    }
}

// ---------------- MFMA bf16 matmul: Y = Xbf @ Wt (+epilogue) ---------------
// global_load_lds staging, XOR-swizzled unpadded LDS (lane q = (l&3)^((l>>3)&3);
// read column (quad ^ ((l16>>1)&3))*8 -> 2-way max bank aliasing = free).
// EPI: 0=none, 1=gelu, 3=+R1b(bf16)
// OUT: 1=bf16 rm, 3=QKV split (NC=768: Q|K rm 256; V transposed, Yv)
template <int EPI, int OUT>
__global__ __launch_bounds__(256) void mfmm_kernel(
    const short* __restrict__ Xb, const short* __restrict__ Wt,
    const float* __restrict__ bias, const short* __restrict__ R1b,
    void* __restrict__ Yout, short* __restrict__ Yv, int K, int NC) {
    __shared__ short As[128][32];   // unpadded, 64B rows
    __shared__ short Bs[128][32];
    int tid = threadIdx.x;
    int rowBase = blockIdx.y * 128, colBase = blockIdx.x * 128;
    int lane = tid & 63;
    int wvu = __builtin_amdgcn_readfirstlane(tid >> 6);
    int wm = wvu & 1, wn = wvu >> 1;
    int quad = lane >> 4, l16 = lane & 15;
    int srow = lane >> 2;                       // row within 16-row chunk
    int sq = (lane & 3) ^ ((lane >> 3) & 3);    // swizzled global k-quad
    int csw = ((quad ^ ((l16 >> 1) & 3)) * 8);  // read column (shorts)
    const short* XpA = Xb + (size_t)(rowBase + wvu * 32 + srow) * K + sq * 8;
    const short* XpA2 = XpA + (size_t)16 * K;
    const short* WpB = Wt + (size_t)(colBase + wvu * 32 + srow) * K + sq * 8;
    const short* WpB2 = WpB + (size_t)16 * K;
    short* ldsA = &As[wvu * 32][0];
    short* ldsA2 = &As[wvu * 32 + 16][0];
    short* ldsB = &Bs[wvu * 32][0];
    short* ldsB2 = &Bs[wvu * 32 + 16][0];
    floatx4 acc[4][4];
#pragma unroll
    for (int i = 0; i < 4; ++i)
#pragma unroll
        for (int j = 0; j < 4; ++j)
            acc[i][j] = (floatx4){0.f, 0.f, 0.f, 0.f};
    for (int k0 = 0; k0 < K; k0 += 32) {
        __syncthreads();
        gl2lds16(XpA + k0, ldsA);
        gl2lds16(XpA2 + k0, ldsA2);
        gl2lds16(WpB + k0, ldsB);
        gl2lds16(WpB2 + k0, ldsB2);
        __syncthreads();
        short8 a[4], b[4];
#pragma unroll
        for (int mi = 0; mi < 4; ++mi)
            a[mi] = *(const short8*)&As[wm * 64 + mi * 16 + l16][csw];
#pragma unroll
        for (int ni = 0; ni < 4; ++ni)
            b[ni] = *(const short8*)&Bs[wn * 64 + ni * 16 + l16][csw];
#pragma unroll
        for (int mi = 0; mi < 4; ++mi)
#pragma unroll
            for (int ni = 0; ni < 4; ++ni)
                acc[mi][ni] = __builtin_amdgcn_mfma_f32_16x16x32_bf16(
                    a[mi], b[ni], acc[mi][ni], 0, 0, 0);
    }
    if (OUT == 3) {
        int region = colBase >> 8;   // 0=Q, 1=K, 2=V
        if (region < 2) {
            short* dst = (short*)Yout + (size_t)region * (size_t)TN * 256;
#pragma unroll
            for (int ni = 0; ni < 4; ++ni) {
                int cl = (colBase + wn * 64 + ni * 16 + l16) & 255;
#pragma unroll
                for (int mi = 0; mi < 4; ++mi) {
#pragma unroll
                    for (int r = 0; r < 4; ++r) {
                        int rowg = rowBase + wm * 64 + mi * 16 + quad * 4 + r;
                        dst[(size_t)rowg * 256 + cl] = f2bf(acc[mi][ni][r]);
                    }
                }
            }
        } else {
#pragma unroll
            for (int ni = 0; ni < 4; ++ni) {
                int cl = (colBase + wn * 64 + ni * 16 + l16) & 255;
                int hh = cl >> 6, dd = cl & 63;
#pragma unroll
                for (int mi = 0; mi < 4; ++mi) {
                    int rowg0 = rowBase + wm * 64 + mi * 16 + quad * 4;
                    int bb = rowg0 >> 9, ng = rowg0 & 511;
                    short4v pv;
#pragma unroll
                    for (int r = 0; r < 4; ++r) pv[r] = f2bf(acc[mi][ni][r]);
                    *(short4v*)(Yv + (((size_t)bb * 4 + hh) * 64 + dd) * 512 + ng) = pv;
                }
            }
        }
        return;
    }
#pragma unroll
    for (int ni = 0; ni < 4; ++ni) {
        int colg = colBase + wn * 64 + ni * 16 + l16;
        float bv = bias ? bias[colg] : 0.f;
#pragma unroll
        for (int mi = 0; mi < 4; ++mi) {
#pragma unroll
            for (int r = 0; r < 4; ++r) {
                int rowg = rowBase + wm * 64 + mi * 16 + quad * 4 + r;
                float y = acc[mi][ni][r] + bv;
                if (EPI == 1) y = gelu_exact(y);
                if (EPI == 3) y += bf2f(R1b[(size_t)rowg * NC + colg]);
                ((short*)Yout)[(size_t)rowg * NC + colg] = f2bf(y);
            }
        }
    }
}

// ------ MFMA matmul + fused row-LayerNorm epilogue (NC=256, 64-row tile) ---
// Y = LN(Xb@Wt + bias + Res)*g + beta  [+ Post if HAS_POST]  -> bf16
template <bool HAS_POST>
__global__ __launch_bounds__(256) void mfmm_ln_kernel(
    const short* __restrict__ Xb, const short* __restrict__ Wt,
    const float* __restrict__ bias, const short* __restrict__ Res,
    const short* __restrict__ Post, const float* __restrict__ g,
    const float* __restrict__ bta, short* __restrict__ Yout, int K) {
    __shared__ short As[64][32];    // 4 chunks
    __shared__ short Bs[256][32];   // 16 chunks
    __shared__ float redS[4][64];
    __shared__ float redS2[4][64];
    int tid = threadIdx.x;
    int rowBase = blockIdx.x * 64;
    int lane = tid & 63;
    int wvu = __builtin_amdgcn_readfirstlane(tid >> 6);
    int quad = lane >> 4, l16 = lane & 15;
    int srow = lane >> 2;
    int sq = (lane & 3) ^ ((lane >> 3) & 3);
    int csw = ((quad ^ ((l16 >> 1) & 3)) * 8);
    const short* Xp = Xb + (size_t)(rowBase + wvu * 16 + srow) * K + sq * 8;
    const short* Wp = Wt + (size_t)(wvu * 64 + srow) * K + sq * 8;
    short* ldsA = &As[wvu * 16][0];
    short* ldsB0 = &Bs[wvu * 64][0];
    short* ldsB1 = &Bs[wvu * 64 + 16][0];
    short* ldsB2 = &Bs[wvu * 64 + 32][0];
    short* ldsB3 = &Bs[wvu * 64 + 48][0];
    floatx4 acc[4][4];
#pragma unroll
    for (int i = 0; i < 4; ++i)
#pragma unroll
        for (int j = 0; j < 4; ++j)
            acc[i][j] = (floatx4){0.f, 0.f, 0.f, 0.f};
    for (int k0 = 0; k0 < K; k0 += 32) {
        __syncthreads();
        gl2lds16(Xp + k0, ldsA);
        gl2lds16(Wp + k0, ldsB0);
        gl2lds16(Wp + (size_t)16 * K + k0, ldsB1);
        gl2lds16(Wp + (size_t)32 * K + k0, ldsB2);
        gl2lds16(Wp + (size_t)48 * K + k0, ldsB3);
        __syncthreads();
        short8 a[4], b[4];
#pragma unroll
        for (int mi = 0; mi < 4; ++mi)
            a[mi] = *(const short8*)&As[mi * 16 + l16][csw];
#pragma unroll
        for (int ni = 0; ni < 4; ++ni)
            b[ni] = *(const short8*)&Bs[wvu * 64 + ni * 16 + l16][csw];
#pragma unroll
        for (int mi = 0; mi < 4; ++mi)
#pragma unroll
            for (int ni = 0; ni < 4; ++ni)
                acc[mi][ni] = __builtin_amdgcn_mfma_f32_16x16x32_bf16(
                    a[mi], b[ni], acc[mi][ni], 0, 0, 0);
    }
    // ---- epilogue: bias + residual, row stats, LN ----
    int cols[4];
    float gv[4], bv[4], biasv[4];
#pragma unroll
    for (int ni = 0; ni < 4; ++ni) {
        cols[ni] = wvu * 64 + ni * 16 + l16;
        gv[ni] = g[cols[ni]];
        bv[ni] = bta[cols[ni]];
        biasv[ni] = bias[cols[ni]];
    }
    float ps[4][4], ps2[4][4];
#pragma unroll
    for (int mi = 0; mi < 4; ++mi)
#pragma unroll
        for (int r = 0; r < 4; ++r) { ps[mi][r] = 0.f; ps2[mi][r] = 0.f; }
#pragma unroll
    for (int mi = 0; mi < 4; ++mi) {
#pragma unroll
        for (int r = 0; r < 4; ++r) {
            size_t rowg = rowBase + mi * 16 + quad * 4 + r;
#pragma unroll
            for (int ni = 0; ni < 4; ++ni) {
                float y = acc[mi][ni][r] + biasv[ni] +
                          bf2f(Res[rowg * 256 + cols[ni]]);
                acc[mi][ni][r] = y;
                ps[mi][r] += y;
                ps2[mi][r] += y * y;
            }
        }
    }
#pragma unroll
    for (int mask = 1; mask < 16; mask <<= 1) {
#pragma unroll
        for (int mi = 0; mi < 4; ++mi)
#pragma unroll
            for (int r = 0; r < 4; ++r) {
                ps[mi][r] += __shfl_xor(ps[mi][r], mask);
                ps2[mi][r] += __shfl_xor(ps2[mi][r], mask);
            }
    }
    __syncthreads();
    if (l16 == 0) {
#pragma unroll
        for (int mi = 0; mi < 4; ++mi)
#pragma unroll
            for (int r = 0; r < 4; ++r) {
                redS[wvu][mi * 16 + quad * 4 + r] = ps[mi][r];
                redS2[wvu][mi * 16 + quad * 4 + r] = ps2[mi][r];
            }
    }
    __syncthreads();
#pragma unroll
    for (int mi = 0; mi < 4; ++mi) {
#pragma unroll
        for (int r = 0; r < 4; ++r) {
            int rl = mi * 16 + quad * 4 + r;
            float s = redS[0][rl] + redS[1][rl] + redS[2][rl] + redS[3][rl];
            float s2 = redS2[0][rl] + redS2[1][rl] + redS2[2][rl] + redS2[3][rl];
            float mu = s * (1.f / 256.f);
            float var = s2 * (1.f / 256.f) - mu * mu;
            float inv = rsqrtf(var + LN_EPS_);
            size_t rowg = rowBase + rl;
#pragma unroll
            for (int ni = 0; ni < 4; ++ni) {
                float y = (acc[mi][ni][r] - mu) * inv * gv[ni] + bv[ni];
                if (HAS_POST) y += bf2f(Post[rowg * 256 + cols[ni]]);
                Yout[rowg * 256 + cols[ni]] = f2bf(y);
            }
        }
    }
}

// ------------- fallback fp32 tiled matmul (old path) -----------------------
template <bool IN_ADD, int EPI>
__global__ __launch_bounds__(256) void mm_kernel(
    const float* __restrict__ X, const float* __restrict__ X2,
    const float* __restrict__ W, const float* __restrict__ bias,
    const float* __restrict__ R1, const float* __restrict__ R2,
    float* __restrict__ Y, int K, int NC) {
    __shared__ float Xs[16][65];
    __shared__ float Ws[16][68];
    int tid = threadIdx.x;
    int tx = tid & 15, ty = tid >> 4;
    int rowBase = blockIdx.y * 64;
    int colBase = blockIdx.x * 64;
    int lr = tid >> 2;
    int lk = (tid & 3) << 2;
    int wk = tid >> 4;
    int wc = (tid & 15) << 2;
    const float* Xp = X + (size_t)(rowBase + lr) * K + lk;
    const float* X2p = IN_ADD ? (X2 + (size_t)(rowBase + lr) * K + lk) : X;
    const float* Wp = W + (size_t)wk * NC + colBase + wc;
    float acc[4][4] = {};
    for (int k0 = 0; k0 < K; k0 += 16) {
        float4 xv = *(const float4*)(Xp + k0);
        if (IN_ADD) {
            float4 x2 = *(const float4*)(X2p + k0);
            xv.x += x2.x; xv.y += x2.y; xv.z += x2.z; xv.w += x2.w;
        }
        float4 wv = *(const float4*)(Wp + (size_t)k0 * NC);
        __syncthreads();
        Xs[lk + 0][lr] = xv.x;
        Xs[lk + 1][lr] = xv.y;
        Xs[lk + 2][lr] = xv.z;
        Xs[lk + 3][lr] = xv.w;
        *(float4*)&Ws[wk][wc] = wv;
        __syncthreads();
#pragma unroll
        for (int kk = 0; kk < 16; ++kk) {
            float a[4], b[4];
#pragma unroll
            for (int i = 0; i < 4; ++i) a[i] = Xs[kk][ty * 4 + i];
#pragma unroll
            for (int j = 0; j < 4; ++j) b[j] = Ws[kk][tx * 4 + j];
#pragma unroll
            for (int i = 0; i < 4; ++i)
#pragma unroll
                for (int j = 0; j < 4; ++j) acc[i][j] = fmaf(a[i], b[j], acc[i][j]);
        }
    }
    int c0 = colBase + tx * 4;
    float4 bv = make_float4(0.f, 0.f, 0.f, 0.f);
    if (bias) bv = *(const float4*)(bias + c0);
#pragma unroll
    for (int i = 0; i < 4; ++i) {
        int r = rowBase + ty * 4 + i;
        float4 y;
        y.x = acc[i][0] + bv.x; y.y = acc[i][1] + bv.y;
        y.z = acc[i][2] + bv.z; y.w = acc[i][3] + bv.w;
        if (EPI == 1) {
            y.x = gelu_exact(y.x); y.y = gelu_exact(y.y);
            y.z = gelu_exact(y.z); y.w = gelu_exact(y.w);
        }
        if (EPI >= 2) {
            float4 r1 = *(const float4*)(R1 + (size_t)r * NC + c0);
            y.x += r1.x; y.y += r1.y; y.z += r1.z; y.w += r1.w;
        }
        if (EPI == 3) {
            float4 r2 = *(const float4*)(R2 + (size_t)r * NC + c0);
            y.x += r2.x; y.y += r2.y; y.z += r2.z; y.w += r2.w;
        }
        *(float4*)(Y + (size_t)r * NC + c0) = y;
    }
}

// fp32 LN fallback
__global__ __launch_bounds__(256) void ln_kernel(
    const float* __restrict__ X, const float* __restrict__ g,
    const float* __restrict__ bta, float* __restrict__ Y) {
    __shared__ float rs[4], rs2[4];
    __shared__ float mu_s, inv_s;
    int row = blockIdx.x, t = threadIdx.x;
    size_t off = (size_t)row * C_ + t;
    float v = X[off];
    float s = v, s2 = v * v;
#pragma unroll
    for (int o = 32; o > 0; o >>= 1) {
        s += __shfl_down(s, o);
        s2 += __shfl_down(s2, o);
    }
    int w = t >> 6, lane = t & 63;
    if (lane == 0) { rs[w] = s; rs2[w] = s2; }
    __syncthreads();
    if (t == 0) {
        float tot = rs[0] + rs[1] + rs[2] + rs[3];
        float tot2 = rs2[0] + rs2[1] + rs2[2] + rs2[3];
        float mu = tot * (1.f / C_);
        float var = tot2 * (1.f / C_) - mu * mu;
        mu_s = mu;
        inv_s = rsqrtf(var + LN_EPS_);
    }
    __syncthreads();
    Y[off] = (v - mu_s) * inv_s * g[t] + bta[t];
}

// ---------- MFMA Performer pass 1: ctxT[bh][d][m], ksum[bh][m] -------------
__global__ __launch_bounds__(256) void p1m_kernel(
    const short* __restrict__ Kbf, const short* __restrict__ VbfT,
    const short* __restrict__ Pbf, short* __restrict__ ctxT,
    float* __restrict__ ksum) {
    int mt = blockIdx.x;
    int bh = blockIdx.y;
    int b = bh >> 2, h = bh & 3;
    __shared__ short Ps[64][72];
    __shared__ short Ks[64][72];
    __shared__ short VTs[64][72];
    __shared__ short Ss[64][72];
    __shared__ float kred[4][64];
    int tid = threadIdx.x;
    int w = tid >> 6, lane = tid & 63;
    int quad = lane >> 4, l16 = lane & 15;
    int lr = tid >> 2, lb = (tid & 3) << 4;
    {
        const short* p = Pbf + ((size_t)(mt * 64 + lr)) * 64 + lb;
        *(short8*)&Ps[lr][lb] = *(const short8*)p;
        *(short8*)&Ps[lr][lb + 8] = *(const short8*)(p + 8);
    }
    floatx4 cacc[4];
#pragma unroll
    for (int i = 0; i < 4; ++i) cacc[i] = (floatx4){0.f, 0.f, 0.f, 0.f};
    float kacc[4] = {0.f, 0.f, 0.f, 0.f};
    size_t kbase = ((size_t)(b * 512)) * 256 + h * 64;
    size_t vbase = ((size_t)(bh * 64)) * 512;
    for (int nt = 0; nt < 8; ++nt) {
        __syncthreads();
        {
            const short* kp = Kbf + kbase + (size_t)(nt * 64 + lr) * 256 + lb;
            *(short8*)&Ks[lr][lb] = *(const short8*)kp;
            *(short8*)&Ks[lr][lb + 8] = *(const short8*)(kp + 8);
            const short* vp = VbfT + vbase + (size_t)lr * 512 + nt * 64 + lb;
            *(short8*)&VTs[lr][lb] = *(const short8*)vp;
            *(short8*)&VTs[lr][lb + 8] = *(const short8*)(vp + 8);
        }
        __syncthreads();
        floatx4 sa[4];
#pragma unroll
        for (int mi = 0; mi < 4; ++mi) sa[mi] = (floatx4){0.f, 0.f, 0.f, 0.f};
#pragma unroll
        for (int kt = 0; kt < 2; ++kt) {
            short8 a = *(const short8*)&Ks[w * 16 + l16][kt * 32 + quad * 8];
#pragma unroll
            for (int mi = 0; mi < 4; ++mi) {
                short8 bq = *(const short8*)&Ps[mi * 16 + l16][kt * 32 + quad * 8];
                sa[mi] = __builtin_amdgcn_mfma_f32_16x16x32_bf16(a, bq, sa[mi], 0, 0, 0);
            }
        }
#pragma unroll
        for (int mi = 0; mi < 4; ++mi) {
            int mg = mt * 64 + mi * 16 + l16;
            short4v sv;
            float kl = 0.f;
#pragma unroll
            for (int r = 0; r < 4; ++r) {
                float v = (mg < M_) ? (fmaxf(sa[mi][r], 0.f) + EPSK_) : 0.f;
                sv[r] = f2bf(v);
                kl += v;
            }
            kacc[mi] += kl;
            *(short4v*)&Ss[mi * 16 + l16][w * 16 + quad * 4] = sv;
        }
        __syncthreads();
#pragma unroll
        for (int kt = 0; kt < 2; ++kt) {
            short8 a = *(const short8*)&Ss[w * 16 + l16][kt * 32 + quad * 8];
#pragma unroll
            for (int di = 0; di < 4; ++di) {
                short8 bv = *(const short8*)&VTs[di * 16 + l16][kt * 32 + quad * 8];
                cacc[di] = __builtin_amdgcn_mfma_f32_16x16x32_bf16(a, bv, cacc[di], 0, 0, 0);
            }
        }
    }
    size_t cbase = ((size_t)bh * 64) * MP_ + mt * 64;
#pragma unroll
    for (int di = 0; di < 4; ++di) {
        int d = di * 16 + l16;
        short4v cv;
#pragma unroll
        for (int r = 0; r < 4; ++r) cv[r] = f2bf(cacc[di][r]);
        *(short4v*)(ctxT + cbase + (size_t)d * MP_ + w * 16 + quad * 4) = cv;
    }
#pragma unroll
    for (int mi = 0; mi < 4; ++mi) {
        kacc[mi] += __shfl_down(kacc[mi], 32);
        kacc[mi] += __shfl_down(kacc[mi], 16);
    }
    if (lane < 16) {
#pragma unroll
        for (int mi = 0; mi < 4; ++mi) kred[w][mi * 16 + lane] = kacc[mi];
    }
    __syncthreads();
    if (tid < 64)
        ksum[(size_t)bh * MP_ + mt * 64 + tid] =
            kred[0][tid] + kred[1][tid] + kred[2][tid] + kred[3][tid];
}

// ---------- MFMA Performer pass 2: attbf = bf16((qp@ctx)/(qp@ksum)) --------
__global__ __launch_bounds__(256) void p2m_kernel(
    const short* __restrict__ Qbf, const short* __restrict__ Pbf,
    const short* __restrict__ ctxT, const float* __restrict__ ksum,
    short* __restrict__ attbf) {
    int nt = blockIdx.x;
    int bh = blockIdx.y;
    int b = bh >> 2, h = bh & 3;
    __shared__ short Qs[64][72];
    __shared__ short Ps[64][72];
    __shared__ short CTs[64][72];
    __shared__ short Ss[64][72];
    __shared__ float kss[64];
    __shared__ float dredS[64];
    __shared__ float dinvS[64];
    int tid = threadIdx.x;
    int w = tid >> 6, lane = tid & 63;
    int quad = lane >> 4, l16 = lane & 15;
    int lr = tid >> 2, lb = (tid & 3) << 4;
    size_t qbase = ((size_t)(b * 512)) * 256 + h * 64;
    {
        const short* qp = Qbf + qbase + (size_t)(nt * 64 + lr) * 256 + lb;
        *(short8*)&Qs[lr][lb] = *(const short8*)qp;
        *(short8*)&Qs[lr][lb + 8] = *(const short8*)(qp + 8);
    }
    floatx4 aacc[4];
#pragma unroll
    for (int i = 0; i < 4; ++i) aacc[i] = (floatx4){0.f, 0.f, 0.f, 0.f};
    float dd[4] = {0.f, 0.f, 0.f, 0.f};
    size_t cb = ((size_t)bh * 64) * MP_;
    for (int mt = 0; mt < 5; ++mt) {
        __syncthreads();
        {
            const short* p = Pbf + ((size_t)(mt * 64 + lr)) * 64 + lb;
            *(short8*)&Ps[lr][lb] = *(const short8*)p;
            *(short8*)&Ps[lr][lb + 8] = *(const short8*)(p + 8);
            const short* cp = ctxT + cb + (size_t)lr * MP_ + mt * 64 + lb;
            *(short8*)&CTs[lr][lb] = *(const short8*)cp;
            *(short8*)&CTs[lr][lb + 8] = *(const short8*)(cp + 8);
        }
        if (tid < 64) kss[tid] = ksum[(size_t)bh * MP_ + mt * 64 + tid];
        __syncthreads();
        floatx4 sa[4];
#pragma unroll
        for (int mi = 0; mi < 4; ++mi) sa[mi] = (floatx4){0.f, 0.f, 0.f, 0.f};
#pragma unroll
        for (int kt = 0; kt < 2; ++kt) {
            short8 a = *(const short8*)&Qs[w * 16 + l16][kt * 32 + quad * 8];
#pragma unroll
            for (int mi = 0; mi < 4; ++mi) {
                short8 bq = *(const short8*)&Ps[mi * 16 + l16][kt * 32 + quad * 8];
                sa[mi] = __builtin_amdgcn_mfma_f32_16x16x32_bf16(a, bq, sa[mi], 0, 0, 0);
            }
        }
#pragma unroll
        for (int mi = 0; mi < 4; ++mi) {
            int mg = mt * 64 + mi * 16 + l16;
            float ksv = kss[mi * 16 + l16];
#pragma unroll
            for (int r = 0; r < 4; ++r) {
                float v = (mg < M_) ? (fmaxf(sa[mi][r], 0.f) + EPSK_) : 0.f;
                Ss[w * 16 + quad * 4 + r][mi * 16 + l16] = f2bf(v);
                dd[r] += v * ksv;
            }
        }
        __syncthreads();
#pragma unroll
        for (int kt = 0; kt < 2; ++kt) {
            short8 a = *(const short8*)&Ss[w * 16 + l16][kt * 32 + quad * 8];
#pragma unroll
            for (int di = 0; di < 4; ++di) {
                short8 bv = *(const short8*)&CTs[di * 16 + l16][kt * 32 + quad * 8];
                aacc[di] = __builtin_amdgcn_mfma_f32_16x16x32_bf16(a, bv, aacc[di], 0, 0, 0);
            }
        }
    }
#pragma unroll
    for (int r = 0; r < 4; ++r) {
        dd[r] += __shfl_xor(dd[r], 1);
        dd[r] += __shfl_xor(dd[r], 2);
        dd[r] += __shfl_xor(dd[r], 4);
        dd[r] += __shfl_xor(dd[r], 8);
    }
    if (l16 == 0) {
#pragma unroll
        for (int r = 0; r < 4; ++r) dredS[w * 16 + quad * 4 + r] = dd[r];
    }
    __syncthreads();
    if (tid < 64) dinvS[tid] = 1.f / dredS[tid];
    __syncthreads();
#pragma unroll
    for (int di = 0; di < 4; ++di) {
        int d = di * 16 + l16;
#pragma unroll
        for (int r = 0; r < 4; ++r) {
            int n = w * 16 + quad * 4 + r;
            attbf[((size_t)(b * 512 + nt * 64 + n)) * 256 + h * 64 + d] =
                f2bf(aacc[di][r] * dinvS[n]);
        }
    }
}

// ---------------- fp32 Performer fallbacks (old path) ----------------------
__global__ __launch_bounds__(256) void p1_kernel(
    const float* __restrict__ kbuf, const float* __restrict__ vbuf,
    const float* __restrict__ proj, float* __restrict__ ctx,
    float* __restrict__ ksum) {
    int mt = blockIdx.x;
    int bh = blockIdx.y;
    int b = bh >> 2, h = bh & 3;
    __shared__ float Pt[64][65];
    __shared__ float KV[64][65];
    __shared__ float S[64][65];
    int tid = threadIdx.x;
    int tx = tid & 15, ty = tid >> 4;
    for (int idx = tid; idx < 4096; idx += 256) {
        int r = idx >> 6, c = idx & 63;
        int mg = mt * 64 + r;
        Pt[r][c] = (mg < M_) ? proj[mg * DH_ + c] : 0.f;
    }
    float cacc[4][4] = {};
    float ksacc = 0.f;
    size_t base = ((size_t)b * N_) * C_ + h * DH_;
    for (int nt = 0; nt < 8; ++nt) {
        __syncthreads();
        for (int idx = tid; idx < 4096; idx += 256) {
            int r = idx >> 6, c = idx & 63;
            KV[r][c] = kbuf[base + (size_t)(nt * 64 + r) * C_ + c];
        }
        __syncthreads();
        float s[4][4] = {};
        for (int dd = 0; dd < 64; ++dd) {
            float a[4], bq[4];
#pragma unroll
            for (int i = 0; i < 4; ++i) a[i] = KV[ty * 4 + i][dd];
#pragma unroll
            for (int j = 0; j < 4; ++j) bq[j] = Pt[16 * j + tx][dd];
#pragma unroll
            for (int i = 0; i < 4; ++i)
#pragma unroll
                for (int j = 0; j < 4; ++j) s[i][j] = fmaf(a[i], bq[j], s[i][j]);
        }
        __syncthreads();
#pragma unroll
        for (int i = 0; i < 4; ++i)
#pragma unroll
            for (int j = 0; j < 4; ++j) {
                int mg = mt * 64 + 16 * j + tx;
                S[ty * 4 + i][16 * j + tx] =
                    (mg < M_) ? (fmaxf(s[i][j], 0.f) + EPSK_) : 0.f;
            }
        for (int idx = tid; idx < 4096; idx += 256) {
            int r = idx >> 6, c = idx & 63;
            KV[r][c] = vbuf[base + (size_t)(nt * 64 + r) * C_ + c];
        }
        __syncthreads();
        for (int nn = 0; nn < 64; ++nn) {
            float sm[4], vd[4];
#pragma unroll
            for (int i = 0; i < 4; ++i) sm[i] = S[nn][ty * 4 + i];
#pragma unroll
            for (int j = 0; j < 4; ++j) vd[j] = KV[nn][tx * 4 + j];
#pragma unroll
            for (int i = 0; i < 4; ++i)
#pragma unroll
                for (int j = 0; j < 4; ++j) cacc[i][j] = fmaf(sm[i], vd[j], cacc[i][j]);
        }
        if (tid < 64) {
            for (int nn = 0; nn < 64; ++nn) ksacc += S[nn][tid];
        }
    }
    float* cp = ctx + ((size_t)bh * MP_ + mt * 64) * DH_;
#pragma unroll
    for (int i = 0; i < 4; ++i)
#pragma unroll
        for (int j = 0; j < 4; ++j)
            cp[(ty * 4 + i) * DH_ + tx * 4 + j] = cacc[i][j];
    if (tid < 64) ksum[bh * MP_ + mt * 64 + tid] = ksacc;
}

__global__ __launch_bounds__(256) void p2_kernel(
    const float* __restrict__ qbuf, const float* __restrict__ proj,
    const float* __restrict__ ctx, const float* __restrict__ ksum,
    float* __restrict__ attout) {
    int nt = blockIdx.x;
    int bh = blockIdx.y;
    int b = bh >> 2, h = bh & 3;
    __shared__ float Qt[64][65];
    __shared__ float PC[64][65];
    __shared__ float S[64][65];
    __shared__ float ks[64], dinv[64];
    int tid = threadIdx.x;
    int tx = tid & 15, ty = tid >> 4;
    size_t base = ((size_t)b * N_) * C_ + h * DH_;
    for (int idx = tid; idx < 4096; idx += 256) {
        int r = idx >> 6, c = idx & 63;
        Qt[r][c] = qbuf[base + (size_t)(nt * 64 + r) * C_ + c];
    }
    float aacc[4][4] = {};
    float dacc = 0.f;
    for (int mt = 0; mt < 5; ++mt) {
        __syncthreads();
        for (int idx = tid; idx < 4096; idx += 256) {
            int r = idx >> 6, c = idx & 63;
            int mg = mt * 64 + r;
            PC[r][c] = (mg < M_) ? proj[mg * DH_ + c] : 0.f;
        }
        if (tid < 64) ks[tid] = ksum[bh * MP_ + mt * 64 + tid];
        __syncthreads();
        float s[4][4] = {};
        for (int dd = 0; dd < 64; ++dd) {
            float a[4], bq[4];
#pragma unroll
            for (int i = 0; i < 4; ++i) a[i] = Qt[ty * 4 + i][dd];
#pragma unroll
            for (int j = 0; j < 4; ++j) bq[j] = PC[16 * j + tx][dd];
#pragma unroll
            for (int i = 0; i < 4; ++i)
#pragma unroll
                for (int j = 0; j < 4; ++j) s[i][j] = fmaf(a[i], bq[j], s[i][j]);
        }
        __syncthreads();
#pragma unroll
        for (int i = 0; i < 4; ++i)
#pragma unroll
            for (int j = 0; j < 4; ++j) {
                int mg = mt * 64 + 16 * j + tx;
                S[ty * 4 + i][16 * j + tx] =
                    (mg < M_) ? (fmaxf(s[i][j], 0.f) + EPSK_) : 0.f;
            }
        for (int idx = tid; idx < 4096; idx += 256) {
            int r = idx >> 6, c = idx & 63;
            PC[r][c] = ctx[((size_t)bh * MP_ + mt * 64 + r) * DH_ + c];
        }
        __syncthreads();
        for (int mm = 0; mm < 64; ++mm) {
            float sm[4], cd[4];
#pragma unroll
            for (int i = 0; i < 4; ++i) sm[i] = S[ty * 4 + i][mm];
#pragma unroll
            for (int j = 0; j < 4; ++j) cd[j] = PC[mm][tx * 4 + j];
#pragma unroll
            for (int i = 0; i < 4; ++i)
#pragma unroll
                for (int j = 0; j < 4; ++j) aacc[i][j] = fmaf(sm[i], cd[j], aacc[i][j]);
        }
        if (tid < 64) {
            for (int mm = 0; mm < 64; ++mm) dacc = fmaf(S[tid][mm], ks[mm], dacc);
        }
    }
    __syncthreads();
    if (tid < 64) dinv[tid] = 1.f / dacc;
    __syncthreads();
#pragma unroll
    for (int i = 0; i < 4; ++i) {
        int n = ty * 4 + i;
        float di = dinv[n];
        float4 y = make_float4(aacc[i][0] * di, aacc[i][1] * di,
                               aacc[i][2] * di, aacc[i][3] * di);
        *(float4*)(attout + base + (size_t)(nt * 64 + n) * C_ + tx * 4) = y;
    }
}

// -------------------- mean pool (bf16 in, fp32 out) ------------------------
__global__ __launch_bounds__(256) void pool_kernel(const short* __restrict__ abf,
                                                   float* __restrict__ out) {
    int b = blockIdx.x;
    int c = threadIdx.x;
    const short* p = abf + (size_t)b * N_ * C_ + c;
    float s = 0.f;
    for (int n = 0; n < N_; ++n) s += bf2f(p[(size_t)n * C_]);
    out[b * C_ + c] = s * (1.f / 512.f);
}

__global__ __launch_bounds__(256) void poolf_kernel(const float* __restrict__ atoms,
                                                    float* __restrict__ out) {
    int b = blockIdx.x;
    int c = threadIdx.x;
    const float* p = atoms + (size_t)b * N_ * C_ + c;
    float s = 0.f;
    for (int n = 0; n < N_; ++n) s += p[(size_t)n * C_];
    out[b * C_ + c] = s * (1.f / 512.f);
}

extern "C" void kernel_launch(void* const* d_in, const int* in_sizes, int n_in,
                              void* d_out, int out_size, void* d_ws, size_t ws_size,
                              hipStream_t stream) {
    (void)in_sizes; (void)n_in; (void)out_size;
    const float* x = (const float*)d_in[0];
    const float* edge_attr = (const float*)d_in[1];
    const int* edge_index = (const int*)d_in[2];
    const float* node_w = (const float*)d_in[4];
    const float* node_b = (const float*)d_in[5];
    const float* edge_w = (const float*)d_in[6];
    const float* edge_b = (const float*)d_in[7];
    const float* gine_w1 = (const float*)d_in[8];
    const float* gine_b1 = (const float*)d_in[9];
    const float* gine_w2 = (const float*)d_in[10];
    const float* gine_b2 = (const float*)d_in[11];
    const float* q_w = (const float*)d_in[12];
    const float* k_w = (const float*)d_in[13];
    const float* v_w = (const float*)d_in[14];
    const float* o_w = (const float*)d_in[15];
    const float* o_b = (const float*)d_in[16];
    const float* proj = (const float*)d_in[17];
    const float* n1g = (const float*)d_in[18];
    const float* n1b = (const float*)d_in[19];
    const float* n2g = (const float*)d_in[20];
    const float* n2b = (const float*)d_in[21];
    const float* n3g = (const float*)d_in[22];
    const float* n3b = (const float*)d_in[23];
    const float* mw1 = (const float*)d_in[24];
    const float* mb1 = (const float*)d_in[25];
    const float* mw2 = (const float*)d_in[26];
    const float* mb2 = (const float*)d_in[27];

    const size_t SZ = (size_t)TN * C_;   // 8,388,608
    float* ws = (float*)d_ws;
    float* A     = ws;                               // fp32 atoms (fallback only)
    short* Abf   = (short*)(ws + SZ);
    short* X1bf  = (short*)(ws + SZ + SZ / 2);       // also t2bf
    short* t2bf  = X1bf;
    short* t1bf  = (short*)(ws + 2 * SZ);            // also ATTbf
    short* ATTbf = t1bf;
    short* HLbf  = (short*)(ws + 2 * SZ + SZ / 2);
    short* Qbf   = (short*)(ws + 3 * SZ);
    short* Kbf   = (short*)(ws + 3 * SZ + SZ / 2);
    short* VbfT  = (short*)(ws + 4 * SZ);
    short* ctxTb = (short*)(ws + 4 * SZ + SZ / 2);
    float* KS2   = (float*)(ctxTb + (size_t)256 * 64 * MP_);
    short* SUMbf = (short*)(ws + 5 * SZ);

    int* deg    = (int*)(ws + 6 * SZ);
    int* offs   = deg + TN;
    int* cursor = offs + TN + 1;
    int* esrc   = cursor + TN;
    float* easrt = (float*)(((uintptr_t)(esrc + E_) + 15) & ~(uintptr_t)15);
    short* WTg1  = (short*)(easrt + (size_t)4 * E_);
    short* WTg2  = WTg1 + (size_t)5 * 65536;
    short* WTqkv = WTg2 + (size_t)5 * 65536;
    short* WTo   = WTqkv + (size_t)5 * 196608;
    short* WTm1  = WTo + (size_t)5 * 65536;
    short* WTm2  = WTm1 + (size_t)5 * 131072;
    short* Pbf   = WTm2 + (size_t)5 * 131072;
    size_t need = 6 * SZ * sizeof(float) +
                  (size_t)(3 * TN + 1 + E_) * sizeof(int) + 16 +
                  (size_t)4 * E_ * sizeof(float) +
                  ((size_t)5 * (3 * 65536 + 196608 + 2 * 131072 + MP_ * 64)) *
                      sizeof(short);
    bool full = ws_size >= need;

    dim3 gm256(2, 256), gm512(4, 256), gm768(6, 256);
    dim3 g256(4, 512), g512(8, 512);

    embed_kernel<<<TN, 256, 0, stream>>>(x, node_w, node_b, A, Abf);
    if (full) {
        hipMemsetAsync(deg, 0, TN * sizeof(int), stream);
        count_kernel<<<E_ / 256, 256, 0, stream>>>(edge_index, deg);
        scan_kernel<<<1, 1024, 0, stream>>>(deg, offs, cursor);
        fill_kernel<<<E_ / 256, 256, 0, stream>>>(edge_index, edge_attr, cursor,
                                                  esrc, easrt);
        wt_kernel<<<dim3(4, 4, L_), 256, 0, stream>>>(gine_w1, WTg1, 256, 256, 65536, 0);
        wt_kernel<<<dim3(4, 4, L_), 256, 0, stream>>>(gine_w2, WTg2, 256, 256, 65536, 0);
        wt_kernel<<<dim3(4, 4, L_), 256, 0, stream>>>(q_w, WTqkv, 256, 256, 196608, 0);
        wt_kernel<<<dim3(4, 4, L_), 256, 0, stream>>>(k_w, WTqkv, 256, 256, 196608, 256);
        wt_kernel<<<dim3(4, 4, L_), 256, 0, stream>>>(v_w, WTqkv, 256, 256, 196608, 512);
        wt_kernel<<<dim3(4, 4, L_), 256, 0, stream>>>(o_w, WTo, 256, 256, 65536, 0);
        wt_kernel<<<dim3(8, 4, L_), 256, 0, stream>>>(mw1, WTm1, 256, 512, 131072, 0);
        wt_kernel<<<dim3(4, 8, L_), 256, 0, stream>>>(mw2, WTm2, 512, 256, 131072, 0);
        pcast_kernel<<<L_, 256, 0, stream>>>(proj, Pbf);
    }
    for (int l = 0; l < L_; ++l) {
        if (full) {
            gather_kernel<<<TN / 4, 256, 0, stream>>>(Abf, offs, esrc, easrt,
                                                      edge_w, edge_b, X1bf);
            // t1 = gelu(X1 @ g1 + b1)
            mfmm_kernel<1, 1><<<gm256, 256, 0, stream>>>(
                X1bf, WTg1 + (size_t)l * 65536, gine_b1 + l * 256,
                nullptr, t1bf, nullptr, 256, 256);
            // HL = LN1(t1 @ g2 + b2 + Abf)   [fused]
            mfmm_ln_kernel<false><<<TN / 64, 256, 0, stream>>>(
                t1bf, WTg2 + (size_t)l * 65536, gine_b2 + l * 256,
                Abf, nullptr, n1g + l * 256, n1b + l * 256, HLbf, 256);
            // QKV fused
            mfmm_kernel<0, 3><<<gm768, 256, 0, stream>>>(
                Abf, WTqkv + (size_t)l * 196608, nullptr,
                nullptr, Qbf, VbfT, 256, 768);
            p1m_kernel<<<dim3(5, 256), 256, 0, stream>>>(
                Kbf, VbfT, Pbf + (size_t)l * MP_ * 64, ctxTb, KS2);
            p2m_kernel<<<dim3(8, 256), 256, 0, stream>>>(
                Qbf, Pbf + (size_t)l * MP_ * 64, ctxTb, KS2, ATTbf);
            // SUM = LN2(ATT @ o_w + o_b + Abf) + HL   [fused]
            mfmm_ln_kernel<true><<<TN / 64, 256, 0, stream>>>(
                ATTbf, WTo + (size_t)l * 65536, o_b + l * 256,
                Abf, HLbf, n2g + l * 256, n2b + l * 256, SUMbf, 256);
            // t2 = gelu(SUM @ m1 + b1)  [NC=512]
            mfmm_kernel<1, 1><<<gm512, 256, 0, stream>>>(
                SUMbf, WTm1 + (size_t)l * 131072, mb1 + l * 512,
                nullptr, t2bf, nullptr, 256, 512);
            // Abf = LN3(t2 @ m2 + b2 + SUM)  [K=512, fused]
            mfmm_ln_kernel<false><<<TN / 64, 256, 0, stream>>>(
                t2bf, WTm2 + (size_t)l * 131072, mb2 + l * 256,
                SUMbf, nullptr, n3g + l * 256, n3b + l * 256, Abf, 512);
        } else {
            float* AGf = A + SZ;
            float* Tf = AGf + SZ;
            float* HLf = Tf + 2 * SZ;
            float* Vbf2 = HLf + SZ;
            float* Qf = AGf;
            float* Kf = Tf;
            float* CTXf = Tf + SZ;
            float* KSf = CTXf + (size_t)256 * MP_ * DH_;
            hipMemsetAsync(AGf, 0, SZ * sizeof(float), stream);
            scatter_kernel<<<E_ * 64 / 256, 256, 0, stream>>>(A, edge_attr, edge_index,
                                                              edge_w, edge_b, AGf);
            mm_kernel<true, 1><<<g256, 256, 0, stream>>>(A, AGf, gine_w1 + l * 65536,
                                                         gine_b1 + l * 256, nullptr,
                                                         nullptr, Tf, 256, 256);
            mm_kernel<false, 2><<<g256, 256, 0, stream>>>(Tf, nullptr, gine_w2 + l * 65536,
                                                          gine_b2 + l * 256, A, nullptr,
                                                          HLf, 256, 256);
            ln_kernel<<<TN, 256, 0, stream>>>(HLf, n1g + l * 256, n1b + l * 256, HLf);
            mm_kernel<false, 0><<<g256, 256, 0, stream>>>(A, nullptr, q_w + l * 65536,
                                                          nullptr, nullptr, nullptr,
                                                          Qf, 256, 256);
            mm_kernel<false, 0><<<g256, 256, 0, stream>>>(A, nullptr, k_w + l * 65536,
                                                          nullptr, nullptr, nullptr,
                                                          Kf, 256, 256);
            mm_kernel<false, 0><<<g256, 256, 0, stream>>>(A, nullptr, v_w + l * 65536,
                                                          nullptr, nullptr, nullptr,
                                                          Vbf2, 256, 256);
            p1_kernel<<<dim3(5, 256), 256, 0, stream>>>(Kf, Vbf2, proj + l * (M_ * DH_),
                                                        CTXf, KSf);
            p2_kernel<<<dim3(8, 256), 256, 0, stream>>>(Qf, proj + l * (M_ * DH_),
                                                        CTXf, KSf, Kf);
            mm_kernel<false, 2><<<g256, 256, 0, stream>>>(Kf, nullptr, o_w + l * 65536,
                                                          o_b + l * 256, A, nullptr,
                                                          Qf, 256, 256);
            ln_kernel<<<TN, 256, 0, stream>>>(Qf, n2g + l * 256, n2b + l * 256, Qf);
            mm_kernel<true, 1><<<g512, 256, 0, stream>>>(HLf, Qf, mw1 + l * 131072,
                                                         mb1 + l * 512, nullptr, nullptr,
                                                         Tf, 256, 512);
            mm_kernel<false, 3><<<g256, 256, 0, stream>>>(Tf, nullptr, mw2 + l * 131072,
                                                          mb2 + l * 256, HLf, Qf,
                                                          Vbf2, 512, 256);
            ln_kernel<<<TN, 256, 0, stream>>>(Vbf2, n3g + l * 256, n3b + l * 256, A);
        }
    }
    if (full)
        pool_kernel<<<B_, 256, 0, stream>>>(Abf, (float*)d_out);
    else
        poolf_kernel<<<B_, 256, 0, stream>>>(A, (float*)d_out);
}